// Round 1
// baseline (1255.102 us; speedup 1.0000x reference)
//
#include <hip/hip_runtime.h>

#define N_NODES 10000
#define N_EDGES 160000
#define N_GRAPHS 16

// ---- workspace layout (float offsets) ----
#define OFF_ES8  0
#define OFF_SHV  (OFF_ES8 + N_EDGES*8)
#define OFF_S    (OFF_SHV + N_EDGES*3)
#define OFF_H    (OFF_S   + N_NODES*128)
#define OFF_GS   (OFF_H   + N_NODES*128)
#define OFF_HS   (OFF_GS  + N_NODES*64)
#define OFF_HV   (OFF_HS  + N_NODES*64)
#define OFF_NS   (OFF_HV  + N_NODES*192)   /* zero-region start */
#define OFF_NV   (OFF_NS  + N_NODES*128)
#define OFF_NMID (OFF_NV  + N_NODES*384)
#define OFF_POOL (OFF_NMID+ N_NODES*128)
#define OFF_CNT  (OFF_POOL+ N_GRAPHS*128)
#define WS_END   (OFF_CNT + N_GRAPHS)

#define INV_SQRT32   0.17677669529663687f
#define INV_SQRT128  0.08838834764831845f
#define INV_SQRT8    0.3535533905932738f
#define INV_SQRT64   0.125f
#define INV_SQRT2048 0.022097086912079608f
#define INV_SQRT1024 0.03125f
#define INV_SQRT10   0.31622776601683794f
#define INV_SQRT3    0.5773502691896258f
#define SQRT3_C      1.7320508075688772f

__device__ __forceinline__ float siluf(float x){ return x / (1.f + __expf(-x)); }
__device__ __forceinline__ float sigf (float x){ return 1.f / (1.f + __expf(-x)); }

// ---------------- edge geometry: bessel basis + unit vec ----------------
__global__ void k_geom(const float* __restrict__ evec,
                       float* __restrict__ es8, float* __restrict__ shv) {
  int e = blockIdx.x*256 + threadIdx.x;
  if (e >= N_EDGES) return;
  float vx = evec[e*3+0], vy = evec[e*3+1], vz = evec[e*3+2];
  float d  = sqrtf(vx*vx + vy*vy + vz*vz);
  float xs = d - 0.25f;
  bool  in = (xs > 0.f) && (xs < 4.0f);
  float safe = xs > 0.f ? xs : 1.f;
  float amp  = in ? 2.0f/safe : 0.f;   // sqrt(2/c)*sqrt(NUM_BASIS) = 2
  const float PI4 = 0.7853981633974483f;
  #pragma unroll
  for (int k = 0; k < 8; ++k)
    es8[e*8+k] = amp * sinf((float)(k+1) * PI4 * safe);
  float invd = d > 0.f ? 1.f/d : 1.f;
  shv[e*3+0] = SQRT3_C*vx*invd;
  shv[e*3+1] = SQRT3_C*vy*invd;
  shv[e*3+2] = SQRT3_C*vz*invd;
}

// ---------------- generic rows x K -> rows x 128 linear ----------------
__global__ void k_linear128(const float* __restrict__ A, const float* __restrict__ W,
                            float* __restrict__ O, int K, float scale, int total) {
  int t = blockIdx.x*256 + threadIdx.x;
  if (t >= total) return;
  int n = t >> 7, j = t & 127;
  const float* a = A + n*K;
  float a0=0.f,a1=0.f,a2=0.f,a3=0.f;
  for (int k = 0; k < K; k += 4) {
    a0 += a[k+0]*W[(k+0)*128+j];
    a1 += a[k+1]*W[(k+1)*128+j];
    a2 += a[k+2]*W[(k+2)*128+j];
    a3 += a[k+3]*W[(k+3)*128+j];
  }
  O[t] = (a0+a1+a2+a3)*scale;
}

// ---------------- graph node counts ----------------
__global__ void k_cnt(const int* __restrict__ batch, float* __restrict__ cnt) {
  __shared__ int lc[N_GRAPHS];
  int t = threadIdx.x;
  if (t < N_GRAPHS) lc[t] = 0;
  __syncthreads();
  int i = blockIdx.x*256 + t;
  if (i < N_NODES) atomicAdd(&lc[batch[i]], 1);
  __syncthreads();
  if (t < N_GRAPHS && lc[t] > 0) atomicAdd(&cnt[t], (float)lc[t]);
}

// ---------------- conv1 edge pass: MLP(8->64->64->256), gather h, scatter ----------------
__global__ __launch_bounds__(512) void k_edge1(
    const float* __restrict__ es8, const float* __restrict__ shv,
    const int* __restrict__ esrc, const int* __restrict__ edst,
    const float* __restrict__ h,
    const float* __restrict__ W0, const float* __restrict__ W1, const float* __restrict__ W2,
    float* __restrict__ n_s, float* __restrict__ n_v) {
  __shared__ float lW0[512];
  __shared__ float lW1[4096];
  __shared__ float lW2[16384];
  __shared__ float lA[8][64];
  __shared__ float lB[8][64];
  for (int i = threadIdx.x; i < 512;   i += 512) lW0[i] = W0[i];
  for (int i = threadIdx.x; i < 4096;  i += 512) lW1[i] = W1[i];
  for (int i = threadIdx.x; i < 16384; i += 512) lW2[i] = W2[i];
  __syncthreads();
  const int wave = threadIdx.x >> 6, lane = threadIdx.x & 63;
  const int nw = gridDim.x * 8;
  const int e0 = blockIdx.x*8 + wave;
  const int iters = (N_EDGES + nw - 1) / nw;
  for (int it = 0; it < iters; ++it) {
    int e = e0 + it*nw;
    bool valid = e < N_EDGES;
    float a = 0.f, sv0=0.f, sv1=0.f, sv2=0.f;
    int src = 0, dst = 0;
    if (valid) {
      const float* ep = es8 + e*8;
      sv0 = shv[e*3+0]; sv1 = shv[e*3+1]; sv2 = shv[e*3+2];
      src = esrc[e]; dst = edst[e];
      a = ep[0]*lW0[lane]      + ep[1]*lW0[64+lane]  + ep[2]*lW0[128+lane] + ep[3]*lW0[192+lane]
        + ep[4]*lW0[256+lane]  + ep[5]*lW0[320+lane] + ep[6]*lW0[384+lane] + ep[7]*lW0[448+lane];
      a = siluf(a * INV_SQRT8);
    }
    lA[wave][lane] = a;
    __syncthreads();
    {
      float b0=0.f,b1=0.f,b2=0.f,b3=0.f;
      #pragma unroll
      for (int k = 0; k < 64; k += 4) {
        b0 += lA[wave][k+0]*lW1[(k+0)*64+lane];
        b1 += lA[wave][k+1]*lW1[(k+1)*64+lane];
        b2 += lA[wave][k+2]*lW1[(k+2)*64+lane];
        b3 += lA[wave][k+3]*lW1[(k+3)*64+lane];
      }
      lB[wave][lane] = siluf((b0+b1+b2+b3) * INV_SQRT64);
    }
    __syncthreads();
    if (valid) {
      float c0=0.f,c1=0.f,c2=0.f,c3=0.f;
      #pragma unroll
      for (int k = 0; k < 64; ++k) {
        float bk = lB[wave][k];
        const float* r = lW2 + k*256;
        c0 += bk*r[lane];
        c1 += bk*r[64+lane];
        c2 += bk*r[128+lane];
        c3 += bk*r[192+lane];
      }
      float hs0 = h[src*128 + lane];
      float hs1 = h[src*128 + 64 + lane];
      float es_a = c0*INV_SQRT64*hs0*INV_SQRT10;
      float es_b = c1*INV_SQRT64*hs1*INV_SQRT10;
      atomicAdd(&n_s[dst*128 + lane],      es_a);
      atomicAdd(&n_s[dst*128 + 64 + lane], es_b);
      float t0 = c2*INV_SQRT64*hs0*INV_SQRT10;
      float t1 = c3*INV_SQRT64*hs1*INV_SQRT10;
      float* nvp = n_v + dst*384;
      atomicAdd(nvp + lane*3+0, t0*sv0);
      atomicAdd(nvp + lane*3+1, t0*sv1);
      atomicAdd(nvp + lane*3+2, t0*sv2);
      atomicAdd(nvp + (64+lane)*3+0, t1*sv0);
      atomicAdd(nvp + (64+lane)*3+1, t1*sv1);
      atomicAdd(nvp + (64+lane)*3+2, t1*sv2);
    }
  }
}

// ---------------- conv1 node pass + gating + conv2 node linears ----------------
__global__ __launch_bounds__(128) void k_node1(
    const float* __restrict__ n_s, const float* __restrict__ n_v,
    const float* __restrict__ s,   const float* __restrict__ na,
    const float* __restrict__ Wls, const float* __restrict__ Wlv,
    const float* __restrict__ Csc, const float* __restrict__ W2s, const float* __restrict__ W2v,
    float* __restrict__ gs_out, float* __restrict__ hs_out, float* __restrict__ hv_out) {
  __shared__ float l_ns[512], l_s[512], l_na[64], l_nv[1536];
  __shared__ float l_outs[512], l_ov[768], l_gs[256], l_gv[768];
  const int j = threadIdx.x;
  const int n0 = blockIdx.x*4;
  for (int i = j; i < 512;  i += 128) { l_ns[i] = n_s[n0*128+i]; l_s[i] = s[n0*128+i]; }
  for (int i = j; i < 1536; i += 128) l_nv[i] = n_v[n0*384+i];
  if (j < 64) l_na[j] = na[n0*16+j];
  __syncthreads();

  // Phase A: out_s col j for 4 nodes = n_s @ c1_lin2_s + sc1
  float accs[4] = {0.f,0.f,0.f,0.f};
  for (int k = 0; k < 128; ++k) {
    float w = Wls[k*128+j];
    accs[0] += l_ns[k]*w; accs[1] += l_ns[128+k]*w;
    accs[2] += l_ns[256+k]*w; accs[3] += l_ns[384+k]*w;
  }
  float accc[4] = {0.f,0.f,0.f,0.f};
  for (int vt = 0; vt < 16; vt += 4) {
    float a0[4],a1[4],a2[4],a3[4];
    #pragma unroll
    for (int n = 0; n < 4; ++n) {
      a0[n]=l_na[n*16+vt]; a1[n]=l_na[n*16+vt+1];
      a2[n]=l_na[n*16+vt+2]; a3[n]=l_na[n*16+vt+3];
    }
    for (int u = 0; u < 128; ++u) {
      const float* cp = Csc + (u*16+vt)*128 + j;
      float c0=cp[0], c1=cp[128], c2=cp[256], c3=cp[384];
      float s0=l_s[u], s1=l_s[128+u], s2=l_s[256+u], s3=l_s[384+u];
      accc[0] += s0*(a0[0]*c0 + a1[0]*c1 + a2[0]*c2 + a3[0]*c3);
      accc[1] += s1*(a0[1]*c0 + a1[1]*c1 + a2[1]*c2 + a3[1]*c3);
      accc[2] += s2*(a0[2]*c0 + a1[2]*c1 + a2[2]*c2 + a3[2]*c3);
      accc[3] += s3*(a0[3]*c0 + a1[3]*c1 + a2[3]*c2 + a3[3]*c3);
    }
  }
  #pragma unroll
  for (int n = 0; n < 4; ++n)
    l_outs[n*128+j] = accs[n]*INV_SQRT128 + accc[n]*INV_SQRT2048;

  // Phase B: out_v (threads split: jj=col, hh selects node pair)
  const int jj = j & 63, hh = j >> 6;
  float ov[2][3] = {{0.f,0.f,0.f},{0.f,0.f,0.f}};
  for (int u = 0; u < 128; ++u) {
    float w = Wlv[u*64+jj];
    #pragma unroll
    for (int t = 0; t < 2; ++t) {
      int n = 2*hh+t;
      ov[t][0] += l_nv[n*384+u*3+0]*w;
      ov[t][1] += l_nv[n*384+u*3+1]*w;
      ov[t][2] += l_nv[n*384+u*3+2]*w;
    }
  }
  #pragma unroll
  for (int t = 0; t < 2; ++t) {
    int n = 2*hh+t;
    l_ov[n*192+jj*3+0] = ov[t][0]*INV_SQRT128;
    l_ov[n*192+jj*3+1] = ov[t][1]*INV_SQRT128;
    l_ov[n*192+jj*3+2] = ov[t][2]*INV_SQRT128;
  }
  __syncthreads();

  // Phase C: gating
  #pragma unroll
  for (int t = 0; t < 2; ++t) {
    int n = 2*hh+t;
    float gv_s = siluf(l_outs[n*128+jj]);
    float gate = sigf (l_outs[n*128+64+jj]);
    l_gs[n*64+jj] = gv_s;
    gs_out[(n0+n)*64+jj] = gv_s;
    l_gv[n*192+jj*3+0] = gate*l_ov[n*192+jj*3+0];
    l_gv[n*192+jj*3+1] = gate*l_ov[n*192+jj*3+1];
    l_gv[n*192+jj*3+2] = gate*l_ov[n*192+jj*3+2];
  }
  __syncthreads();

  // Phase D: h_s = g_s @ c2_lin1_s
  float ha[2] = {0.f,0.f};
  for (int k = 0; k < 64; ++k) {
    float w = W2s[k*64+jj];
    ha[0] += l_gs[(2*hh+0)*64+k]*w;
    ha[1] += l_gs[(2*hh+1)*64+k]*w;
  }
  hs_out[(n0+2*hh+0)*64+jj] = ha[0]*INV_SQRT64;
  hs_out[(n0+2*hh+1)*64+jj] = ha[1]*INV_SQRT64;

  // Phase E: h_v = einsum(g_v, c2_lin1_v)
  float hv[2][3] = {{0.f,0.f,0.f},{0.f,0.f,0.f}};
  for (int u = 0; u < 64; ++u) {
    float w = W2v[u*64+jj];
    #pragma unroll
    for (int t = 0; t < 2; ++t) {
      int n = 2*hh+t;
      hv[t][0] += l_gv[n*192+u*3+0]*w;
      hv[t][1] += l_gv[n*192+u*3+1]*w;
      hv[t][2] += l_gv[n*192+u*3+2]*w;
    }
  }
  #pragma unroll
  for (int t = 0; t < 2; ++t) {
    int n = 2*hh+t;
    hv_out[(n0+n)*192+jj*3+0] = hv[t][0]*INV_SQRT64;
    hv_out[(n0+n)*192+jj*3+1] = hv[t][1]*INV_SQRT64;
    hv_out[(n0+n)*192+jj*3+2] = hv[t][2]*INV_SQRT64;
  }
}

// ---------------- conv2 edge pass: MLP(8->64->64->128), gather h_s/h_v, scatter ----------------
__global__ __launch_bounds__(512) void k_edge2(
    const float* __restrict__ es8, const float* __restrict__ shv,
    const int* __restrict__ esrc, const int* __restrict__ edst,
    const float* __restrict__ h_s, const float* __restrict__ h_v,
    const float* __restrict__ W0, const float* __restrict__ W1, const float* __restrict__ W2,
    float* __restrict__ n_mid) {
  __shared__ float lW0[512];
  __shared__ float lW1[4096];
  __shared__ float lW2[8192];
  __shared__ float lA[8][64];
  __shared__ float lB[8][64];
  for (int i = threadIdx.x; i < 512;  i += 512) lW0[i] = W0[i];
  for (int i = threadIdx.x; i < 4096; i += 512) lW1[i] = W1[i];
  for (int i = threadIdx.x; i < 8192; i += 512) lW2[i] = W2[i];
  __syncthreads();
  const int wave = threadIdx.x >> 6, lane = threadIdx.x & 63;
  const int nw = gridDim.x * 8;
  const int e0 = blockIdx.x*8 + wave;
  const int iters = (N_EDGES + nw - 1) / nw;
  for (int it = 0; it < iters; ++it) {
    int e = e0 + it*nw;
    bool valid = e < N_EDGES;
    float a = 0.f, sv0=0.f, sv1=0.f, sv2=0.f;
    int src = 0, dst = 0;
    if (valid) {
      const float* ep = es8 + e*8;
      sv0 = shv[e*3+0]; sv1 = shv[e*3+1]; sv2 = shv[e*3+2];
      src = esrc[e]; dst = edst[e];
      a = ep[0]*lW0[lane]      + ep[1]*lW0[64+lane]  + ep[2]*lW0[128+lane] + ep[3]*lW0[192+lane]
        + ep[4]*lW0[256+lane]  + ep[5]*lW0[320+lane] + ep[6]*lW0[384+lane] + ep[7]*lW0[448+lane];
      a = siluf(a * INV_SQRT8);
    }
    lA[wave][lane] = a;
    __syncthreads();
    {
      float b0=0.f,b1=0.f,b2=0.f,b3=0.f;
      #pragma unroll
      for (int k = 0; k < 64; k += 4) {
        b0 += lA[wave][k+0]*lW1[(k+0)*64+lane];
        b1 += lA[wave][k+1]*lW1[(k+1)*64+lane];
        b2 += lA[wave][k+2]*lW1[(k+2)*64+lane];
        b3 += lA[wave][k+3]*lW1[(k+3)*64+lane];
      }
      lB[wave][lane] = siluf((b0+b1+b2+b3) * INV_SQRT64);
    }
    __syncthreads();
    if (valid) {
      float c0=0.f, c1=0.f;
      #pragma unroll
      for (int k = 0; k < 64; ++k) {
        float bk = lB[wave][k];
        const float* r = lW2 + k*128;
        c0 += bk*r[lane];
        c1 += bk*r[64+lane];
      }
      float w0v = c0*INV_SQRT64, w1v = c1*INV_SQRT64;
      float hsv = h_s[src*64 + lane];
      const float* hvp = h_v + src*192 + lane*3;
      float dotv = hvp[0]*sv0 + hvp[1]*sv1 + hvp[2]*sv2;
      atomicAdd(&n_mid[dst*128 + lane],      w0v*hsv*INV_SQRT10);
      atomicAdd(&n_mid[dst*128 + 64 + lane], w1v*dotv*INV_SQRT3*INV_SQRT10);
    }
  }
}

// ---------------- conv2 node pass + pooled accumulation ----------------
__global__ __launch_bounds__(128) void k_node2(
    const float* __restrict__ n_mid, const float* __restrict__ gs,
    const float* __restrict__ na, const int* __restrict__ batch,
    const float* __restrict__ W, const float* __restrict__ Csc,
    float* __restrict__ pool) {
  __shared__ float l_nm[512], l_gs[256], l_na[64];
  const int j = threadIdx.x;
  const int n0 = blockIdx.x*4;
  for (int i = j; i < 512; i += 128) l_nm[i] = n_mid[n0*128+i];
  for (int i = j; i < 256; i += 128) l_gs[i] = gs[n0*64+i];
  if (j < 64) l_na[j] = na[n0*16+j];
  __syncthreads();
  float acc[4] = {0.f,0.f,0.f,0.f};
  for (int k = 0; k < 128; ++k) {
    float w = W[k*128+j];
    acc[0] += l_nm[k]*w; acc[1] += l_nm[128+k]*w;
    acc[2] += l_nm[256+k]*w; acc[3] += l_nm[384+k]*w;
  }
  float acc2[4] = {0.f,0.f,0.f,0.f};
  for (int vt = 0; vt < 16; vt += 4) {
    float a0[4],a1[4],a2[4],a3[4];
    #pragma unroll
    for (int n = 0; n < 4; ++n) {
      a0[n]=l_na[n*16+vt]; a1[n]=l_na[n*16+vt+1];
      a2[n]=l_na[n*16+vt+2]; a3[n]=l_na[n*16+vt+3];
    }
    for (int u = 0; u < 64; ++u) {
      const float* cp = Csc + (u*16+vt)*128 + j;
      float c0=cp[0], c1=cp[128], c2=cp[256], c3=cp[384];
      float s0=l_gs[u], s1=l_gs[64+u], s2=l_gs[128+u], s3=l_gs[192+u];
      acc2[0] += s0*(a0[0]*c0 + a1[0]*c1 + a2[0]*c2 + a3[0]*c3);
      acc2[1] += s1*(a0[1]*c0 + a1[1]*c1 + a2[1]*c2 + a3[1]*c3);
      acc2[2] += s2*(a0[2]*c0 + a1[2]*c1 + a2[2]*c2 + a3[2]*c3);
      acc2[3] += s3*(a0[3]*c0 + a1[3]*c1 + a2[3]*c2 + a3[3]*c3);
    }
  }
  float outv[4];
  #pragma unroll
  for (int n = 0; n < 4; ++n)
    outv[n] = acc[n]*INV_SQRT128 + acc2[n]*INV_SQRT1024;
  int b0 = batch[n0], b1 = batch[n0+1], b2 = batch[n0+2], b3 = batch[n0+3];
  float sum = outv[0]; int cur = b0;
  if (b1 == cur) sum += outv[1]; else { atomicAdd(&pool[cur*128+j], sum); cur = b1; sum = outv[1]; }
  if (b2 == cur) sum += outv[2]; else { atomicAdd(&pool[cur*128+j], sum); cur = b2; sum = outv[2]; }
  if (b3 == cur) sum += outv[3]; else { atomicAdd(&pool[cur*128+j], sum); cur = b3; sum = outv[3]; }
  atomicAdd(&pool[cur*128+j], sum);
}

// ---------------- readout head ----------------
__global__ __launch_bounds__(128) void k_head(
    const float* __restrict__ pool, const float* __restrict__ cnt,
    const float* __restrict__ Wr1, const float* __restrict__ Wr2,
    float* __restrict__ out) {
  __shared__ float lp[128];
  __shared__ float lt[128];
  const int j = threadIdx.x;
  for (int g = 0; g < N_GRAPHS; ++g) {
    float inv = 1.f / fmaxf(cnt[g], 1.f);
    lp[j] = pool[g*128+j]*inv;
    __syncthreads();
    float acc = 0.f;
    for (int k = 0; k < 128; ++k) acc += lp[k]*Wr1[k*128+j];
    lt[j] = siluf(acc*INV_SQRT128) * Wr2[j];
    __syncthreads();
    if (j == 0) {
      float ssum = 0.f;
      for (int k = 0; k < 128; ++k) ssum += lt[k];
      out[g] = ssum*INV_SQRT128;
    }
    __syncthreads();
  }
}

extern "C" void kernel_launch(void* const* d_in, const int* in_sizes, int n_in,
                              void* d_out, int out_size, void* d_ws, size_t ws_size,
                              hipStream_t stream) {
  const float* x         = (const float*)d_in[0];
  const float* node_attr = (const float*)d_in[1];
  const int*   esrc      = (const int*)d_in[2];
  const int*   edst      = (const int*)d_in[3];
  const float* evec      = (const float*)d_in[4];
  const int*   batch     = (const int*)d_in[5];
  const float* W_embed   = (const float*)d_in[6];
  const float* c1_lin1   = (const float*)d_in[7];
  const float* c1_fc_w0  = (const float*)d_in[8];
  const float* c1_fc_w1  = (const float*)d_in[9];
  const float* c1_fc_w2  = (const float*)d_in[10];
  const float* c1_lin2_s = (const float*)d_in[11];
  const float* c1_lin2_v = (const float*)d_in[12];
  const float* c1_sc     = (const float*)d_in[13];
  const float* c2_lin1_s = (const float*)d_in[14];
  const float* c2_lin1_v = (const float*)d_in[15];
  const float* c2_fc_w0  = (const float*)d_in[16];
  const float* c2_fc_w1  = (const float*)d_in[17];
  const float* c2_fc_w2  = (const float*)d_in[18];
  const float* c2_lin2   = (const float*)d_in[19];
  const float* c2_sc     = (const float*)d_in[20];
  const float* Wr1       = (const float*)d_in[21];
  const float* Wr2       = (const float*)d_in[22];

  float* ws    = (float*)d_ws;
  float* es8   = ws + OFF_ES8;
  float* shv   = ws + OFF_SHV;
  float* s_    = ws + OFF_S;
  float* h_    = ws + OFF_H;
  float* gs_   = ws + OFF_GS;
  float* hs_   = ws + OFF_HS;
  float* hv_   = ws + OFF_HV;
  float* ns_   = ws + OFF_NS;
  float* nv_   = ws + OFF_NV;
  float* nmid_ = ws + OFF_NMID;
  float* pool_ = ws + OFF_POOL;
  float* cnt_  = ws + OFF_CNT;

  // zero the accumulation region every call (graph replays must be deterministic)
  hipMemsetAsync(ns_, 0, (size_t)(WS_END - OFF_NS)*sizeof(float), stream);

  k_geom<<<N_EDGES/256, 256, 0, stream>>>(evec, es8, shv);
  k_linear128<<<(N_NODES*128)/256, 256, 0, stream>>>(x,  W_embed, s_, 32,  INV_SQRT32,  N_NODES*128);
  k_linear128<<<(N_NODES*128)/256, 256, 0, stream>>>(s_, c1_lin1, h_, 128, INV_SQRT128, N_NODES*128);
  k_cnt<<<(N_NODES+255)/256, 256, 0, stream>>>(batch, cnt_);
  k_edge1<<<256, 512, 0, stream>>>(es8, shv, esrc, edst, h_,
                                   c1_fc_w0, c1_fc_w1, c1_fc_w2, ns_, nv_);
  k_node1<<<N_NODES/4, 128, 0, stream>>>(ns_, nv_, s_, node_attr,
                                         c1_lin2_s, c1_lin2_v, c1_sc,
                                         c2_lin1_s, c2_lin1_v, gs_, hs_, hv_);
  k_edge2<<<512, 512, 0, stream>>>(es8, shv, esrc, edst, hs_, hv_,
                                   c2_fc_w0, c2_fc_w1, c2_fc_w2, nmid_);
  k_node2<<<N_NODES/4, 128, 0, stream>>>(nmid_, gs_, node_attr, batch,
                                         c2_lin2, c2_sc, pool_);
  k_head<<<1, 128, 0, stream>>>(pool_, cnt_, Wr1, Wr2, (float*)d_out);
}

// Round 2
// 1031.004 us; speedup vs baseline: 1.2174x; 1.2174x over previous
//
#include <hip/hip_runtime.h>

#define N_NODES 10000
#define N_EDGES 160000
#define N_GRAPHS 16

// ---- workspace layout (float offsets) ----
#define OFF_ES8  0
#define OFF_SHV  (OFF_ES8 + N_EDGES*8)
#define OFF_S    (OFF_SHV + N_EDGES*3)
#define OFF_H    (OFF_S   + N_NODES*128)
#define OFF_GS   (OFF_H   + N_NODES*128)
#define OFF_HS   (OFF_GS  + N_NODES*64)
#define OFF_HV   (OFF_HS  + N_NODES*64)
#define OFF_NS   (OFF_HV  + N_NODES*192)   /* fallback zero-region start */
#define OFF_NV   (OFF_NS  + N_NODES*128)
#define OFF_NMID (OFF_NV  + N_NODES*384)
#define OFF_POOL (OFF_NMID+ N_NODES*128)   /* new-path zero-region start */
#define OFF_CNT  (OFF_POOL+ N_GRAPHS*128)
#define OFF_HIST (OFF_CNT + N_GRAPHS)
#define OFF_CURS (OFF_HIST+ N_NODES)
#define OFF_OFFS (OFF_CURS+ N_NODES)       /* new-path zero-region end (excl) */
#define OFF_SLOT (OFF_OFFS+ N_NODES + 16)
#define OFF_WBUF (OFF_SLOT+ N_EDGES)
#define WBUF_FLOATS ((size_t)N_EDGES*256)
#define WS_NEED_BYTES ((size_t)(OFF_WBUF + WBUF_FLOATS) * 4)

#define INV_SQRT32   0.17677669529663687f
#define INV_SQRT128  0.08838834764831845f
#define INV_SQRT8    0.3535533905932738f
#define INV_SQRT64   0.125f
#define INV_SQRT2048 0.022097086912079608f
#define INV_SQRT1024 0.03125f
#define INV_SQRT10   0.31622776601683794f
#define INV_SQRT3    0.5773502691896258f
#define SQRT3_C      1.7320508075688772f

__device__ __forceinline__ float siluf(float x){ return x / (1.f + __expf(-x)); }
__device__ __forceinline__ float sigf (float x){ return 1.f / (1.f + __expf(-x)); }

// ---------------- edge geometry: bessel basis + unit vec ----------------
__global__ void k_geom(const float* __restrict__ evec,
                       float* __restrict__ es8, float* __restrict__ shv) {
  int e = blockIdx.x*256 + threadIdx.x;
  if (e >= N_EDGES) return;
  float vx = evec[e*3+0], vy = evec[e*3+1], vz = evec[e*3+2];
  float d  = sqrtf(vx*vx + vy*vy + vz*vz);
  float xs = d - 0.25f;
  bool  in = (xs > 0.f) && (xs < 4.0f);
  float safe = xs > 0.f ? xs : 1.f;
  float amp  = in ? 2.0f/safe : 0.f;   // sqrt(2/c)*sqrt(NUM_BASIS) = 2
  const float PI4 = 0.7853981633974483f;
  #pragma unroll
  for (int k = 0; k < 8; ++k)
    es8[e*8+k] = amp * sinf((float)(k+1) * PI4 * safe);
  float invd = d > 0.f ? 1.f/d : 1.f;
  shv[e*3+0] = SQRT3_C*vx*invd;
  shv[e*3+1] = SQRT3_C*vy*invd;
  shv[e*3+2] = SQRT3_C*vz*invd;
}

// ---------------- generic rows x K -> rows x 128 linear ----------------
__global__ void k_linear128(const float* __restrict__ A, const float* __restrict__ W,
                            float* __restrict__ O, int K, float scale, int total) {
  int t = blockIdx.x*256 + threadIdx.x;
  if (t >= total) return;
  int n = t >> 7, j = t & 127;
  const float* a = A + n*K;
  float a0=0.f,a1=0.f,a2=0.f,a3=0.f;
  for (int k = 0; k < K; k += 4) {
    a0 += a[k+0]*W[(k+0)*128+j];
    a1 += a[k+1]*W[(k+1)*128+j];
    a2 += a[k+2]*W[(k+2)*128+j];
    a3 += a[k+3]*W[(k+3)*128+j];
  }
  O[t] = (a0+a1+a2+a3)*scale;
}

// ---------------- graph node counts ----------------
__global__ void k_cnt(const int* __restrict__ batch, float* __restrict__ cnt) {
  __shared__ int lc[N_GRAPHS];
  int t = threadIdx.x;
  if (t < N_GRAPHS) lc[t] = 0;
  __syncthreads();
  int i = blockIdx.x*256 + t;
  if (i < N_NODES) atomicAdd(&lc[batch[i]], 1);
  __syncthreads();
  if (t < N_GRAPHS && lc[t] > 0) atomicAdd(&cnt[t], (float)lc[t]);
}

// ---------------- CSR build ----------------
__global__ void k_hist(const int* __restrict__ edst, int* __restrict__ hist) {
  int e = blockIdx.x*256 + threadIdx.x;
  if (e < N_EDGES) atomicAdd(&hist[edst[e]], 1);
}

__global__ void k_scan(const int* __restrict__ hist, int* __restrict__ offs) {
  int lane = threadIdx.x;   // 64 threads
  int run = 0;
  if (lane == 0) offs[0] = 0;
  for (int base = 0; base < N_NODES; base += 64) {
    int idx = base + lane;
    int v = (idx < N_NODES) ? hist[idx] : 0;
    #pragma unroll
    for (int d = 1; d < 64; d <<= 1) {
      int t = __shfl_up(v, d);
      if (lane >= d) v += t;
    }
    if (idx < N_NODES) offs[idx+1] = run + v;
    run += __shfl(v, 63);
  }
}

__global__ void k_slot(const int* __restrict__ edst, const int* __restrict__ offs,
                       int* __restrict__ curs, int* __restrict__ slot) {
  int e = blockIdx.x*256 + threadIdx.x;
  if (e < N_EDGES) {
    int d = edst[e];
    int p = offs[d] + atomicAdd(&curs[d], 1);
    slot[p] = e;
  }
}

// ---------------- conv1 edge MLP (8->64->64->256), store w ----------------
__global__ __launch_bounds__(512) void k_edge1_w(
    const float* __restrict__ es8,
    const float* __restrict__ W0, const float* __restrict__ W1, const float* __restrict__ W2,
    float* __restrict__ wbuf) {
  __shared__ float lW0[512];
  __shared__ float lW1[4096];
  __shared__ float lW2[16384];
  __shared__ float lA[8][64];
  __shared__ float lB[8][64];
  for (int i = threadIdx.x; i < 512;   i += 512) lW0[i] = W0[i];
  for (int i = threadIdx.x; i < 4096;  i += 512) lW1[i] = W1[i];
  for (int i = threadIdx.x; i < 16384; i += 512) lW2[i] = W2[i];
  __syncthreads();
  const int wave = threadIdx.x >> 6, lane = threadIdx.x & 63;
  const int nw = gridDim.x * 8;
  const int e0 = blockIdx.x*8 + wave;
  const int iters = (N_EDGES + nw - 1) / nw;
  for (int it = 0; it < iters; ++it) {
    int e = e0 + it*nw;
    bool valid = e < N_EDGES;
    float a = 0.f;
    if (valid) {
      const float4 p0 = *(const float4*)(es8 + e*8);
      const float4 p1 = *(const float4*)(es8 + e*8 + 4);
      a = p0.x*lW0[lane]     + p0.y*lW0[64+lane]  + p0.z*lW0[128+lane] + p0.w*lW0[192+lane]
        + p1.x*lW0[256+lane] + p1.y*lW0[320+lane] + p1.z*lW0[384+lane] + p1.w*lW0[448+lane];
      a = siluf(a * INV_SQRT8);
    }
    lA[wave][lane] = a;
    __syncthreads();
    {
      float b = 0.f;
      #pragma unroll
      for (int k = 0; k < 64; k += 4) {
        float4 ak = *(const float4*)&lA[wave][k];
        b += ak.x*lW1[(k+0)*64+lane] + ak.y*lW1[(k+1)*64+lane]
           + ak.z*lW1[(k+2)*64+lane] + ak.w*lW1[(k+3)*64+lane];
      }
      lB[wave][lane] = siluf(b * INV_SQRT64);
    }
    __syncthreads();
    if (valid) {
      float c0=0.f,c1=0.f,c2=0.f,c3=0.f;
      #pragma unroll
      for (int k = 0; k < 64; k += 4) {
        float4 bk = *(const float4*)&lB[wave][k];
        const float* r = lW2 + k*256;
        c0 += bk.x*r[lane]     + bk.y*r[256+lane] + bk.z*r[512+lane] + bk.w*r[768+lane];
        c1 += bk.x*r[64+lane]  + bk.y*r[320+lane] + bk.z*r[576+lane] + bk.w*r[832+lane];
        c2 += bk.x*r[128+lane] + bk.y*r[384+lane] + bk.z*r[640+lane] + bk.w*r[896+lane];
        c3 += bk.x*r[192+lane] + bk.y*r[448+lane] + bk.z*r[704+lane] + bk.w*r[960+lane];
      }
      float* wp = wbuf + (size_t)e*256;
      wp[lane]      = c0*INV_SQRT64;
      wp[64+lane]   = c1*INV_SQRT64;
      wp[128+lane]  = c2*INV_SQRT64;
      wp[192+lane]  = c3*INV_SQRT64;
    }
  }
}

// ---------------- conv1 gather: CSR pull, no atomics ----------------
__global__ __launch_bounds__(256) void k_gather1(
    const float* __restrict__ wbuf, const float* __restrict__ shv,
    const int* __restrict__ esrc, const int* __restrict__ offs, const int* __restrict__ slot,
    const float* __restrict__ h,
    float* __restrict__ n_s, float* __restrict__ n_v) {
  const int wave = threadIdx.x >> 6, lane = threadIdx.x & 63;
  const int n = blockIdx.x*4 + wave;
  if (n >= N_NODES) return;
  const int s0 = offs[n], s1 = offs[n+1];
  float ns0=0.f, ns1=0.f;
  float nv00=0.f,nv01=0.f,nv02=0.f, nv10=0.f,nv11=0.f,nv12=0.f;
  for (int s = s0; s < s1; ++s) {
    int e = slot[s];
    int src = esrc[e];
    const float* wp = wbuf + (size_t)e*256;
    float c0 = wp[lane], c1 = wp[64+lane], c2 = wp[128+lane], c3 = wp[192+lane];
    float h0 = h[src*128+lane], h1 = h[src*128+64+lane];
    float sv0 = shv[e*3+0], sv1 = shv[e*3+1], sv2 = shv[e*3+2];
    ns0 += c0*h0; ns1 += c1*h1;
    float t0 = c2*h0, t1 = c3*h1;
    nv00 += t0*sv0; nv01 += t0*sv1; nv02 += t0*sv2;
    nv10 += t1*sv0; nv11 += t1*sv1; nv12 += t1*sv2;
  }
  n_s[n*128+lane]    = ns0*INV_SQRT10;
  n_s[n*128+64+lane] = ns1*INV_SQRT10;
  float* nvp = n_v + n*384;
  nvp[lane*3+0] = nv00*INV_SQRT10; nvp[lane*3+1] = nv01*INV_SQRT10; nvp[lane*3+2] = nv02*INV_SQRT10;
  nvp[(64+lane)*3+0] = nv10*INV_SQRT10; nvp[(64+lane)*3+1] = nv11*INV_SQRT10; nvp[(64+lane)*3+2] = nv12*INV_SQRT10;
}

// ---------------- conv2 edge MLP (8->64->64->128), store w ----------------
__global__ __launch_bounds__(512) void k_edge2_w(
    const float* __restrict__ es8,
    const float* __restrict__ W0, const float* __restrict__ W1, const float* __restrict__ W2,
    float* __restrict__ wbuf) {
  __shared__ float lW0[512];
  __shared__ float lW1[4096];
  __shared__ float lW2[8192];
  __shared__ float lA[8][64];
  __shared__ float lB[8][64];
  for (int i = threadIdx.x; i < 512;  i += 512) lW0[i] = W0[i];
  for (int i = threadIdx.x; i < 4096; i += 512) lW1[i] = W1[i];
  for (int i = threadIdx.x; i < 8192; i += 512) lW2[i] = W2[i];
  __syncthreads();
  const int wave = threadIdx.x >> 6, lane = threadIdx.x & 63;
  const int nw = gridDim.x * 8;
  const int e0 = blockIdx.x*8 + wave;
  const int iters = (N_EDGES + nw - 1) / nw;
  for (int it = 0; it < iters; ++it) {
    int e = e0 + it*nw;
    bool valid = e < N_EDGES;
    float a = 0.f;
    if (valid) {
      const float4 p0 = *(const float4*)(es8 + e*8);
      const float4 p1 = *(const float4*)(es8 + e*8 + 4);
      a = p0.x*lW0[lane]     + p0.y*lW0[64+lane]  + p0.z*lW0[128+lane] + p0.w*lW0[192+lane]
        + p1.x*lW0[256+lane] + p1.y*lW0[320+lane] + p1.z*lW0[384+lane] + p1.w*lW0[448+lane];
      a = siluf(a * INV_SQRT8);
    }
    lA[wave][lane] = a;
    __syncthreads();
    {
      float b = 0.f;
      #pragma unroll
      for (int k = 0; k < 64; k += 4) {
        float4 ak = *(const float4*)&lA[wave][k];
        b += ak.x*lW1[(k+0)*64+lane] + ak.y*lW1[(k+1)*64+lane]
           + ak.z*lW1[(k+2)*64+lane] + ak.w*lW1[(k+3)*64+lane];
      }
      lB[wave][lane] = siluf(b * INV_SQRT64);
    }
    __syncthreads();
    if (valid) {
      float c0=0.f, c1=0.f;
      #pragma unroll
      for (int k = 0; k < 64; k += 4) {
        float4 bk = *(const float4*)&lB[wave][k];
        const float* r = lW2 + k*128;
        c0 += bk.x*r[lane]    + bk.y*r[128+lane] + bk.z*r[256+lane] + bk.w*r[384+lane];
        c1 += bk.x*r[64+lane] + bk.y*r[192+lane] + bk.z*r[320+lane] + bk.w*r[448+lane];
      }
      float* wp = wbuf + (size_t)e*128;
      wp[lane]    = c0*INV_SQRT64;
      wp[64+lane] = c1*INV_SQRT64;
    }
  }
}

// ---------------- conv2 gather: CSR pull, no atomics ----------------
__global__ __launch_bounds__(256) void k_gather2(
    const float* __restrict__ wbuf, const float* __restrict__ shv,
    const int* __restrict__ esrc, const int* __restrict__ offs, const int* __restrict__ slot,
    const float* __restrict__ h_s, const float* __restrict__ h_v,
    float* __restrict__ n_mid) {
  const int wave = threadIdx.x >> 6, lane = threadIdx.x & 63;
  const int n = blockIdx.x*4 + wave;
  if (n >= N_NODES) return;
  const int s0 = offs[n], s1 = offs[n+1];
  float acc0 = 0.f, acc1 = 0.f;
  for (int s = s0; s < s1; ++s) {
    int e = slot[s];
    int src = esrc[e];
    const float* wp = wbuf + (size_t)e*128;
    float w0 = wp[lane], w1 = wp[64+lane];
    float hs = h_s[src*64+lane];
    const float* hvp = h_v + src*192 + lane*3;
    float sv0 = shv[e*3+0], sv1 = shv[e*3+1], sv2 = shv[e*3+2];
    float dot = hvp[0]*sv0 + hvp[1]*sv1 + hvp[2]*sv2;
    acc0 += w0*hs;
    acc1 += w1*dot;
  }
  n_mid[n*128+lane]    = acc0*INV_SQRT10;
  n_mid[n*128+64+lane] = acc1*INV_SQRT3*INV_SQRT10;
}

// ======== FALLBACK (atomic) edge kernels — used only if ws too small ========
__global__ __launch_bounds__(512) void k_edge1_at(
    const float* __restrict__ es8, const float* __restrict__ shv,
    const int* __restrict__ esrc, const int* __restrict__ edst,
    const float* __restrict__ h,
    const float* __restrict__ W0, const float* __restrict__ W1, const float* __restrict__ W2,
    float* __restrict__ n_s, float* __restrict__ n_v) {
  __shared__ float lW0[512];
  __shared__ float lW1[4096];
  __shared__ float lW2[16384];
  __shared__ float lA[8][64];
  __shared__ float lB[8][64];
  for (int i = threadIdx.x; i < 512;   i += 512) lW0[i] = W0[i];
  for (int i = threadIdx.x; i < 4096;  i += 512) lW1[i] = W1[i];
  for (int i = threadIdx.x; i < 16384; i += 512) lW2[i] = W2[i];
  __syncthreads();
  const int wave = threadIdx.x >> 6, lane = threadIdx.x & 63;
  const int nw = gridDim.x * 8;
  const int e0 = blockIdx.x*8 + wave;
  const int iters = (N_EDGES + nw - 1) / nw;
  for (int it = 0; it < iters; ++it) {
    int e = e0 + it*nw;
    bool valid = e < N_EDGES;
    float a = 0.f, sv0=0.f, sv1=0.f, sv2=0.f;
    int src = 0, dst = 0;
    if (valid) {
      const float* ep = es8 + e*8;
      sv0 = shv[e*3+0]; sv1 = shv[e*3+1]; sv2 = shv[e*3+2];
      src = esrc[e]; dst = edst[e];
      a = ep[0]*lW0[lane]      + ep[1]*lW0[64+lane]  + ep[2]*lW0[128+lane] + ep[3]*lW0[192+lane]
        + ep[4]*lW0[256+lane]  + ep[5]*lW0[320+lane] + ep[6]*lW0[384+lane] + ep[7]*lW0[448+lane];
      a = siluf(a * INV_SQRT8);
    }
    lA[wave][lane] = a;
    __syncthreads();
    {
      float b0=0.f;
      #pragma unroll
      for (int k = 0; k < 64; ++k) b0 += lA[wave][k]*lW1[k*64+lane];
      lB[wave][lane] = siluf(b0 * INV_SQRT64);
    }
    __syncthreads();
    if (valid) {
      float c0=0.f,c1=0.f,c2=0.f,c3=0.f;
      #pragma unroll
      for (int k = 0; k < 64; ++k) {
        float bk = lB[wave][k];
        const float* r = lW2 + k*256;
        c0 += bk*r[lane]; c1 += bk*r[64+lane]; c2 += bk*r[128+lane]; c3 += bk*r[192+lane];
      }
      float hs0 = h[src*128 + lane];
      float hs1 = h[src*128 + 64 + lane];
      atomicAdd(&n_s[dst*128 + lane],      c0*INV_SQRT64*hs0*INV_SQRT10);
      atomicAdd(&n_s[dst*128 + 64 + lane], c1*INV_SQRT64*hs1*INV_SQRT10);
      float t0 = c2*INV_SQRT64*hs0*INV_SQRT10;
      float t1 = c3*INV_SQRT64*hs1*INV_SQRT10;
      float* nvp = n_v + dst*384;
      atomicAdd(nvp + lane*3+0, t0*sv0);
      atomicAdd(nvp + lane*3+1, t0*sv1);
      atomicAdd(nvp + lane*3+2, t0*sv2);
      atomicAdd(nvp + (64+lane)*3+0, t1*sv0);
      atomicAdd(nvp + (64+lane)*3+1, t1*sv1);
      atomicAdd(nvp + (64+lane)*3+2, t1*sv2);
    }
  }
}

__global__ __launch_bounds__(512) void k_edge2_at(
    const float* __restrict__ es8, const float* __restrict__ shv,
    const int* __restrict__ esrc, const int* __restrict__ edst,
    const float* __restrict__ h_s, const float* __restrict__ h_v,
    const float* __restrict__ W0, const float* __restrict__ W1, const float* __restrict__ W2,
    float* __restrict__ n_mid) {
  __shared__ float lW0[512];
  __shared__ float lW1[4096];
  __shared__ float lW2[8192];
  __shared__ float lA[8][64];
  __shared__ float lB[8][64];
  for (int i = threadIdx.x; i < 512;  i += 512) lW0[i] = W0[i];
  for (int i = threadIdx.x; i < 4096; i += 512) lW1[i] = W1[i];
  for (int i = threadIdx.x; i < 8192; i += 512) lW2[i] = W2[i];
  __syncthreads();
  const int wave = threadIdx.x >> 6, lane = threadIdx.x & 63;
  const int nw = gridDim.x * 8;
  const int e0 = blockIdx.x*8 + wave;
  const int iters = (N_EDGES + nw - 1) / nw;
  for (int it = 0; it < iters; ++it) {
    int e = e0 + it*nw;
    bool valid = e < N_EDGES;
    float a = 0.f, sv0=0.f, sv1=0.f, sv2=0.f;
    int src = 0, dst = 0;
    if (valid) {
      const float* ep = es8 + e*8;
      sv0 = shv[e*3+0]; sv1 = shv[e*3+1]; sv2 = shv[e*3+2];
      src = esrc[e]; dst = edst[e];
      a = ep[0]*lW0[lane]      + ep[1]*lW0[64+lane]  + ep[2]*lW0[128+lane] + ep[3]*lW0[192+lane]
        + ep[4]*lW0[256+lane]  + ep[5]*lW0[320+lane] + ep[6]*lW0[384+lane] + ep[7]*lW0[448+lane];
      a = siluf(a * INV_SQRT8);
    }
    lA[wave][lane] = a;
    __syncthreads();
    {
      float b0=0.f;
      #pragma unroll
      for (int k = 0; k < 64; ++k) b0 += lA[wave][k]*lW1[k*64+lane];
      lB[wave][lane] = siluf(b0 * INV_SQRT64);
    }
    __syncthreads();
    if (valid) {
      float c0=0.f, c1=0.f;
      #pragma unroll
      for (int k = 0; k < 64; ++k) {
        float bk = lB[wave][k];
        const float* r = lW2 + k*128;
        c0 += bk*r[lane]; c1 += bk*r[64+lane];
      }
      float hsv = h_s[src*64 + lane];
      const float* hvp = h_v + src*192 + lane*3;
      float dotv = hvp[0]*sv0 + hvp[1]*sv1 + hvp[2]*sv2;
      atomicAdd(&n_mid[dst*128 + lane],      c0*INV_SQRT64*hsv*INV_SQRT10);
      atomicAdd(&n_mid[dst*128 + 64 + lane], c1*INV_SQRT64*dotv*INV_SQRT3*INV_SQRT10);
    }
  }
}

// ---------------- conv1 node pass + gating + conv2 node linears ----------------
__global__ __launch_bounds__(128) void k_node1(
    const float* __restrict__ n_s, const float* __restrict__ n_v,
    const float* __restrict__ s,   const float* __restrict__ na,
    const float* __restrict__ Wls, const float* __restrict__ Wlv,
    const float* __restrict__ Csc, const float* __restrict__ W2s, const float* __restrict__ W2v,
    float* __restrict__ gs_out, float* __restrict__ hs_out, float* __restrict__ hv_out) {
  __shared__ float l_ns[512], l_s[512], l_na[64], l_nv[1536];
  __shared__ float l_outs[512], l_ov[768], l_gs[256], l_gv[768];
  const int j = threadIdx.x;
  const int n0 = blockIdx.x*4;
  for (int i = j; i < 512;  i += 128) { l_ns[i] = n_s[n0*128+i]; l_s[i] = s[n0*128+i]; }
  for (int i = j; i < 1536; i += 128) l_nv[i] = n_v[n0*384+i];
  if (j < 64) l_na[j] = na[n0*16+j];
  __syncthreads();

  float accs[4] = {0.f,0.f,0.f,0.f};
  for (int k = 0; k < 128; ++k) {
    float w = Wls[k*128+j];
    accs[0] += l_ns[k]*w; accs[1] += l_ns[128+k]*w;
    accs[2] += l_ns[256+k]*w; accs[3] += l_ns[384+k]*w;
  }
  float accc[4] = {0.f,0.f,0.f,0.f};
  for (int vt = 0; vt < 16; vt += 4) {
    float a0[4],a1[4],a2[4],a3[4];
    #pragma unroll
    for (int n = 0; n < 4; ++n) {
      a0[n]=l_na[n*16+vt]; a1[n]=l_na[n*16+vt+1];
      a2[n]=l_na[n*16+vt+2]; a3[n]=l_na[n*16+vt+3];
    }
    for (int u = 0; u < 128; ++u) {
      const float* cp = Csc + (u*16+vt)*128 + j;
      float c0=cp[0], c1=cp[128], c2=cp[256], c3=cp[384];
      float s0=l_s[u], s1=l_s[128+u], s2=l_s[256+u], s3=l_s[384+u];
      accc[0] += s0*(a0[0]*c0 + a1[0]*c1 + a2[0]*c2 + a3[0]*c3);
      accc[1] += s1*(a0[1]*c0 + a1[1]*c1 + a2[1]*c2 + a3[1]*c3);
      accc[2] += s2*(a0[2]*c0 + a1[2]*c1 + a2[2]*c2 + a3[2]*c3);
      accc[3] += s3*(a0[3]*c0 + a1[3]*c1 + a2[3]*c2 + a3[3]*c3);
    }
  }
  #pragma unroll
  for (int n = 0; n < 4; ++n)
    l_outs[n*128+j] = accs[n]*INV_SQRT128 + accc[n]*INV_SQRT2048;

  const int jj = j & 63, hh = j >> 6;
  float ov[2][3] = {{0.f,0.f,0.f},{0.f,0.f,0.f}};
  for (int u = 0; u < 128; ++u) {
    float w = Wlv[u*64+jj];
    #pragma unroll
    for (int t = 0; t < 2; ++t) {
      int n = 2*hh+t;
      ov[t][0] += l_nv[n*384+u*3+0]*w;
      ov[t][1] += l_nv[n*384+u*3+1]*w;
      ov[t][2] += l_nv[n*384+u*3+2]*w;
    }
  }
  #pragma unroll
  for (int t = 0; t < 2; ++t) {
    int n = 2*hh+t;
    l_ov[n*192+jj*3+0] = ov[t][0]*INV_SQRT128;
    l_ov[n*192+jj*3+1] = ov[t][1]*INV_SQRT128;
    l_ov[n*192+jj*3+2] = ov[t][2]*INV_SQRT128;
  }
  __syncthreads();

  #pragma unroll
  for (int t = 0; t < 2; ++t) {
    int n = 2*hh+t;
    float gv_s = siluf(l_outs[n*128+jj]);
    float gate = sigf (l_outs[n*128+64+jj]);
    l_gs[n*64+jj] = gv_s;
    gs_out[(n0+n)*64+jj] = gv_s;
    l_gv[n*192+jj*3+0] = gate*l_ov[n*192+jj*3+0];
    l_gv[n*192+jj*3+1] = gate*l_ov[n*192+jj*3+1];
    l_gv[n*192+jj*3+2] = gate*l_ov[n*192+jj*3+2];
  }
  __syncthreads();

  float ha[2] = {0.f,0.f};
  for (int k = 0; k < 64; ++k) {
    float w = W2s[k*64+jj];
    ha[0] += l_gs[(2*hh+0)*64+k]*w;
    ha[1] += l_gs[(2*hh+1)*64+k]*w;
  }
  hs_out[(n0+2*hh+0)*64+jj] = ha[0]*INV_SQRT64;
  hs_out[(n0+2*hh+1)*64+jj] = ha[1]*INV_SQRT64;

  float hv[2][3] = {{0.f,0.f,0.f},{0.f,0.f,0.f}};
  for (int u = 0; u < 64; ++u) {
    float w = W2v[u*64+jj];
    #pragma unroll
    for (int t = 0; t < 2; ++t) {
      int n = 2*hh+t;
      hv[t][0] += l_gv[n*192+u*3+0]*w;
      hv[t][1] += l_gv[n*192+u*3+1]*w;
      hv[t][2] += l_gv[n*192+u*3+2]*w;
    }
  }
  #pragma unroll
  for (int t = 0; t < 2; ++t) {
    int n = 2*hh+t;
    hv_out[(n0+n)*192+jj*3+0] = hv[t][0]*INV_SQRT64;
    hv_out[(n0+n)*192+jj*3+1] = hv[t][1]*INV_SQRT64;
    hv_out[(n0+n)*192+jj*3+2] = hv[t][2]*INV_SQRT64;
  }
}

// ---------------- conv2 node pass + pooled accumulation ----------------
__global__ __launch_bounds__(128) void k_node2(
    const float* __restrict__ n_mid, const float* __restrict__ gs,
    const float* __restrict__ na, const int* __restrict__ batch,
    const float* __restrict__ W, const float* __restrict__ Csc,
    float* __restrict__ pool) {
  __shared__ float l_nm[512], l_gs[256], l_na[64];
  const int j = threadIdx.x;
  const int n0 = blockIdx.x*4;
  for (int i = j; i < 512; i += 128) l_nm[i] = n_mid[n0*128+i];
  for (int i = j; i < 256; i += 128) l_gs[i] = gs[n0*64+i];
  if (j < 64) l_na[j] = na[n0*16+j];
  __syncthreads();
  float acc[4] = {0.f,0.f,0.f,0.f};
  for (int k = 0; k < 128; ++k) {
    float w = W[k*128+j];
    acc[0] += l_nm[k]*w; acc[1] += l_nm[128+k]*w;
    acc[2] += l_nm[256+k]*w; acc[3] += l_nm[384+k]*w;
  }
  float acc2[4] = {0.f,0.f,0.f,0.f};
  for (int vt = 0; vt < 16; vt += 4) {
    float a0[4],a1[4],a2[4],a3[4];
    #pragma unroll
    for (int n = 0; n < 4; ++n) {
      a0[n]=l_na[n*16+vt]; a1[n]=l_na[n*16+vt+1];
      a2[n]=l_na[n*16+vt+2]; a3[n]=l_na[n*16+vt+3];
    }
    for (int u = 0; u < 64; ++u) {
      const float* cp = Csc + (u*16+vt)*128 + j;
      float c0=cp[0], c1=cp[128], c2=cp[256], c3=cp[384];
      float s0=l_gs[u], s1=l_gs[64+u], s2=l_gs[128+u], s3=l_gs[192+u];
      acc2[0] += s0*(a0[0]*c0 + a1[0]*c1 + a2[0]*c2 + a3[0]*c3);
      acc2[1] += s1*(a0[1]*c0 + a1[1]*c1 + a2[1]*c2 + a3[1]*c3);
      acc2[2] += s2*(a0[2]*c0 + a1[2]*c1 + a2[2]*c2 + a3[2]*c3);
      acc2[3] += s3*(a0[3]*c0 + a1[3]*c1 + a2[3]*c2 + a3[3]*c3);
    }
  }
  float outv[4];
  #pragma unroll
  for (int n = 0; n < 4; ++n)
    outv[n] = acc[n]*INV_SQRT128 + acc2[n]*INV_SQRT1024;
  int b0 = batch[n0], b1 = batch[n0+1], b2 = batch[n0+2], b3 = batch[n0+3];
  float sum = outv[0]; int cur = b0;
  if (b1 == cur) sum += outv[1]; else { atomicAdd(&pool[cur*128+j], sum); cur = b1; sum = outv[1]; }
  if (b2 == cur) sum += outv[2]; else { atomicAdd(&pool[cur*128+j], sum); cur = b2; sum = outv[2]; }
  if (b3 == cur) sum += outv[3]; else { atomicAdd(&pool[cur*128+j], sum); cur = b3; sum = outv[3]; }
  atomicAdd(&pool[cur*128+j], sum);
}

// ---------------- readout head ----------------
__global__ __launch_bounds__(128) void k_head(
    const float* __restrict__ pool, const float* __restrict__ cnt,
    const float* __restrict__ Wr1, const float* __restrict__ Wr2,
    float* __restrict__ out) {
  __shared__ float lp[128];
  __shared__ float lt[128];
  const int j = threadIdx.x;
  for (int g = 0; g < N_GRAPHS; ++g) {
    float inv = 1.f / fmaxf(cnt[g], 1.f);
    lp[j] = pool[g*128+j]*inv;
    __syncthreads();
    float acc = 0.f;
    for (int k = 0; k < 128; ++k) acc += lp[k]*Wr1[k*128+j];
    lt[j] = siluf(acc*INV_SQRT128) * Wr2[j];
    __syncthreads();
    if (j == 0) {
      float ssum = 0.f;
      for (int k = 0; k < 128; ++k) ssum += lt[k];
      out[g] = ssum*INV_SQRT128;
    }
    __syncthreads();
  }
}

extern "C" void kernel_launch(void* const* d_in, const int* in_sizes, int n_in,
                              void* d_out, int out_size, void* d_ws, size_t ws_size,
                              hipStream_t stream) {
  const float* x         = (const float*)d_in[0];
  const float* node_attr = (const float*)d_in[1];
  const int*   esrc      = (const int*)d_in[2];
  const int*   edst      = (const int*)d_in[3];
  const float* evec      = (const float*)d_in[4];
  const int*   batch     = (const int*)d_in[5];
  const float* W_embed   = (const float*)d_in[6];
  const float* c1_lin1   = (const float*)d_in[7];
  const float* c1_fc_w0  = (const float*)d_in[8];
  const float* c1_fc_w1  = (const float*)d_in[9];
  const float* c1_fc_w2  = (const float*)d_in[10];
  const float* c1_lin2_s = (const float*)d_in[11];
  const float* c1_lin2_v = (const float*)d_in[12];
  const float* c1_sc     = (const float*)d_in[13];
  const float* c2_lin1_s = (const float*)d_in[14];
  const float* c2_lin1_v = (const float*)d_in[15];
  const float* c2_fc_w0  = (const float*)d_in[16];
  const float* c2_fc_w1  = (const float*)d_in[17];
  const float* c2_fc_w2  = (const float*)d_in[18];
  const float* c2_lin2   = (const float*)d_in[19];
  const float* c2_sc     = (const float*)d_in[20];
  const float* Wr1       = (const float*)d_in[21];
  const float* Wr2       = (const float*)d_in[22];

  float* ws    = (float*)d_ws;
  float* es8   = ws + OFF_ES8;
  float* shv   = ws + OFF_SHV;
  float* s_    = ws + OFF_S;
  float* h_    = ws + OFF_H;
  float* gs_   = ws + OFF_GS;
  float* hs_   = ws + OFF_HS;
  float* hv_   = ws + OFF_HV;
  float* ns_   = ws + OFF_NS;
  float* nv_   = ws + OFF_NV;
  float* nmid_ = ws + OFF_NMID;
  float* pool_ = ws + OFF_POOL;
  float* cnt_  = ws + OFF_CNT;
  int*   hist_ = (int*)(ws + OFF_HIST);
  int*   curs_ = (int*)(ws + OFF_CURS);
  int*   offs_ = (int*)(ws + OFF_OFFS);
  int*   slot_ = (int*)(ws + OFF_SLOT);
  float* wbuf_ = ws + OFF_WBUF;

  const bool big = ws_size >= WS_NEED_BYTES;

  k_geom<<<N_EDGES/256, 256, 0, stream>>>(evec, es8, shv);
  k_linear128<<<(N_NODES*128)/256, 256, 0, stream>>>(x,  W_embed, s_, 32,  INV_SQRT32,  N_NODES*128);
  k_linear128<<<(N_NODES*128)/256, 256, 0, stream>>>(s_, c1_lin1, h_, 128, INV_SQRT128, N_NODES*128);

  if (big) {
    // zero POOL, CNT, HIST, CURS (contiguous)
    hipMemsetAsync(pool_, 0, (size_t)(OFF_OFFS - OFF_POOL)*sizeof(float), stream);
    k_cnt<<<(N_NODES+255)/256, 256, 0, stream>>>(batch, cnt_);
    // CSR build
    k_hist<<<(N_EDGES+255)/256, 256, 0, stream>>>(edst, hist_);
    k_scan<<<1, 64, 0, stream>>>(hist_, offs_);
    k_slot<<<(N_EDGES+255)/256, 256, 0, stream>>>(edst, offs_, curs_, slot_);
    // conv1
    k_edge1_w<<<256, 512, 0, stream>>>(es8, c1_fc_w0, c1_fc_w1, c1_fc_w2, wbuf_);
    k_gather1<<<(N_NODES+3)/4, 256, 0, stream>>>(wbuf_, shv, esrc, offs_, slot_, h_, ns_, nv_);
    k_node1<<<N_NODES/4, 128, 0, stream>>>(ns_, nv_, s_, node_attr,
                                           c1_lin2_s, c1_lin2_v, c1_sc,
                                           c2_lin1_s, c2_lin1_v, gs_, hs_, hv_);
    // conv2 (wbuf aliased/reused)
    k_edge2_w<<<512, 512, 0, stream>>>(es8, c2_fc_w0, c2_fc_w1, c2_fc_w2, wbuf_);
    k_gather2<<<(N_NODES+3)/4, 256, 0, stream>>>(wbuf_, shv, esrc, offs_, slot_, hs_, hv_, nmid_);
  } else {
    // fallback: atomic scatter path (zero NS..CNT)
    hipMemsetAsync(ns_, 0, (size_t)(OFF_HIST - OFF_NS)*sizeof(float), stream);
    k_cnt<<<(N_NODES+255)/256, 256, 0, stream>>>(batch, cnt_);
    k_edge1_at<<<256, 512, 0, stream>>>(es8, shv, esrc, edst, h_,
                                        c1_fc_w0, c1_fc_w1, c1_fc_w2, ns_, nv_);
    k_node1<<<N_NODES/4, 128, 0, stream>>>(ns_, nv_, s_, node_attr,
                                           c1_lin2_s, c1_lin2_v, c1_sc,
                                           c2_lin1_s, c2_lin1_v, gs_, hs_, hv_);
    k_edge2_at<<<512, 512, 0, stream>>>(es8, shv, esrc, edst, hs_, hv_,
                                        c2_fc_w0, c2_fc_w1, c2_fc_w2, nmid_);
  }

  k_node2<<<N_NODES/4, 128, 0, stream>>>(nmid_, gs_, node_attr, batch,
                                         c2_lin2, c2_sc, pool_);
  k_head<<<1, 128, 0, stream>>>(pool_, cnt_, Wr1, Wr2, (float*)d_out);
}

// Round 3
// 709.695 us; speedup vs baseline: 1.7685x; 1.4527x over previous
//
#include <hip/hip_runtime.h>

#define N_NODES 10000
#define N_EDGES 160000
#define N_GRAPHS 16

typedef __attribute__((ext_vector_type(8))) short s16x8;
typedef __attribute__((ext_vector_type(4))) float f32x4;
typedef unsigned int uint32;
typedef unsigned short ushort16;

// ---- workspace layout (float offsets) ----
#define OFF_ES8  0
#define OFF_SHV  (OFF_ES8 + N_EDGES*8)
#define OFF_S    (OFF_SHV + N_EDGES*3)
#define OFF_H    (OFF_S   + N_NODES*128)
#define OFF_GS   (OFF_H   + N_NODES*128)
#define OFF_HS   (OFF_GS  + N_NODES*64)
#define OFF_HV   (OFF_HS  + N_NODES*64)
#define OFF_NS   (OFF_HV  + N_NODES*192)   /* fallback zero-region start */
#define OFF_NV   (OFF_NS  + N_NODES*128)
#define OFF_NMID (OFF_NV  + N_NODES*384)
#define OFF_POOL (OFF_NMID+ N_NODES*128)   /* new-path zero-region start */
#define OFF_CNT  (OFF_POOL+ N_GRAPHS*128)
#define OFF_HIST (OFF_CNT + N_GRAPHS)
#define OFF_CURS (OFF_HIST+ N_NODES)
#define OFF_OFFS (OFF_CURS+ N_NODES)       /* new-path zero-region end (excl) */
#define OFF_FRAG (OFF_OFFS+ N_NODES + 16)  /* weight fragments: 73728 shorts = 36864 floats */
#define OFF_SLOT (OFF_FRAG+ 36864)
#define OFF_WBUF (OFF_SLOT+ N_EDGES)
#define WBUF_FLOATS ((size_t)N_EDGES*256)
#define WS_NEED_BYTES ((size_t)(OFF_WBUF + WBUF_FLOATS) * 4)

// frag sub-offsets in shorts (each B: 2 planes * NF * KS * 512 shorts)
#define F_B1   0        /* conv1 L1: NF4 KS1 -> 4096  */
#define F_B2   4096     /* conv1 L2: NF4 KS2 -> 8192  */
#define F_B3   12288    /* conv1 L3: NF16 KS2 -> 32768 */
#define F_B1b  45056
#define F_B2b  49152
#define F_B3b  57344    /* conv2 L3: NF8 KS2 -> 16384 */

#define INV_SQRT32   0.17677669529663687f
#define INV_SQRT128  0.08838834764831845f
#define INV_SQRT8    0.3535533905932738f
#define INV_SQRT64   0.125f
#define INV_SQRT2048 0.022097086912079608f
#define INV_SQRT1024 0.03125f
#define INV_SQRT10   0.31622776601683794f
#define INV_SQRT3    0.5773502691896258f
#define SQRT3_C      1.7320508075688772f

__device__ __forceinline__ float siluf(float x){ return x / (1.f + __expf(-x)); }
__device__ __forceinline__ float sigf (float x){ return 1.f / (1.f + __expf(-x)); }
__device__ __forceinline__ unsigned short bf16h(float x){
  uint32 u = __float_as_uint(x);
  u += 0x7FFFu + ((u >> 16) & 1u);
  return (unsigned short)(u >> 16);
}
__device__ __forceinline__ float bf2f(unsigned short h){
  return __uint_as_float(((uint32)h) << 16);
}

// ---------------- edge geometry: bessel basis + unit vec ----------------
__global__ void k_geom(const float* __restrict__ evec,
                       float* __restrict__ es8, float* __restrict__ shv) {
  int e = blockIdx.x*256 + threadIdx.x;
  if (e >= N_EDGES) return;
  float vx = evec[e*3+0], vy = evec[e*3+1], vz = evec[e*3+2];
  float d  = sqrtf(vx*vx + vy*vy + vz*vz);
  float xs = d - 0.25f;
  bool  in = (xs > 0.f) && (xs < 4.0f);
  float safe = xs > 0.f ? xs : 1.f;
  float amp  = in ? 2.0f/safe : 0.f;   // sqrt(2/c)*sqrt(NUM_BASIS) = 2
  const float PI4 = 0.7853981633974483f;
  #pragma unroll
  for (int k = 0; k < 8; ++k)
    es8[e*8+k] = amp * sinf((float)(k+1) * PI4 * safe);
  float invd = d > 0.f ? 1.f/d : 1.f;
  shv[e*3+0] = SQRT3_C*vx*invd;
  shv[e*3+1] = SQRT3_C*vy*invd;
  shv[e*3+2] = SQRT3_C*vz*invd;
}

// ---------------- generic rows x K -> rows x 128 linear ----------------
__global__ void k_linear128(const float* __restrict__ A, const float* __restrict__ W,
                            float* __restrict__ O, int K, float scale, int total) {
  int t = blockIdx.x*256 + threadIdx.x;
  if (t >= total) return;
  int n = t >> 7, j = t & 127;
  const float* a = A + n*K;
  float a0=0.f,a1=0.f,a2=0.f,a3=0.f;
  for (int k = 0; k < K; k += 4) {
    a0 += a[k+0]*W[(k+0)*128+j];
    a1 += a[k+1]*W[(k+1)*128+j];
    a2 += a[k+2]*W[(k+2)*128+j];
    a3 += a[k+3]*W[(k+3)*128+j];
  }
  O[t] = (a0+a1+a2+a3)*scale;
}

// ---------------- graph node counts ----------------
__global__ void k_cnt(const int* __restrict__ batch, float* __restrict__ cnt) {
  __shared__ int lc[N_GRAPHS];
  int t = threadIdx.x;
  if (t < N_GRAPHS) lc[t] = 0;
  __syncthreads();
  int i = blockIdx.x*256 + t;
  if (i < N_NODES) atomicAdd(&lc[batch[i]], 1);
  __syncthreads();
  if (t < N_GRAPHS && lc[t] > 0) atomicAdd(&cnt[t], (float)lc[t]);
}

// ---------------- CSR build ----------------
__global__ void k_hist(const int* __restrict__ edst, int* __restrict__ hist) {
  int e = blockIdx.x*256 + threadIdx.x;
  if (e < N_EDGES) atomicAdd(&hist[edst[e]], 1);
}

__global__ void k_scan(const int* __restrict__ hist, int* __restrict__ offs) {
  int lane = threadIdx.x;   // 64 threads
  int run = 0;
  if (lane == 0) offs[0] = 0;
  for (int base = 0; base < N_NODES; base += 64) {
    int idx = base + lane;
    int v = (idx < N_NODES) ? hist[idx] : 0;
    #pragma unroll
    for (int d = 1; d < 64; d <<= 1) {
      int t = __shfl_up(v, d);
      if (lane >= d) v += t;
    }
    if (idx < N_NODES) offs[idx+1] = run + v;
    run += __shfl(v, 63);
  }
}

__global__ void k_slot(const int* __restrict__ edst, const int* __restrict__ offs,
                       int* __restrict__ curs, int* __restrict__ slot) {
  int e = blockIdx.x*256 + threadIdx.x;
  if (e < N_EDGES) {
    int d = edst[e];
    int p = offs[d] + atomicAdd(&curs[d], 1);
    slot[p] = e;
  }
}

// ---------------- weight fragment prep (split bf16, B-fragment order) ----------------
// flat idx: (((p*NF + nf)*KS + ks)*64 + lane)*8 + j ; k = ks*32+(lane>>4)*8+j ; col = nf*16+(lane&15)
__global__ void k_prepw(const float* __restrict__ W, int Keff, int N, int NF, int KS,
                        float scale, short* __restrict__ dst) {
  int total = 1024*NF*KS;
  for (int t = blockIdx.x*256 + threadIdx.x; t < total; t += gridDim.x*256) {
    int j = t & 7;
    int l = (t >> 3) & 63;
    int rest = t >> 9;
    int ks = rest % KS; rest /= KS;
    int nf = rest % NF;
    int p  = rest / NF;
    int k   = ks*32 + (l >> 4)*8 + j;
    int col = nf*16 + (l & 15);
    float v = (k < Keff) ? W[k*N + col]*scale : 0.f;
    unsigned short hi = bf16h(v);
    unsigned short out = hi;
    if (p) out = bf16h(v - bf2f(hi));
    dst[t] = (short)out;
  }
}

// ---------------- fused 3-layer edge MLP via MFMA (split bf16) ----------------
// Per wave: 64 edges. L1: K=8 (padded to 32) -> 64, silu; L2: 64 -> 64, silu; L3: 64 -> NF3*16.
template<int NF3>
__global__ __launch_bounds__(256) void k_mlp(
    const float* __restrict__ es8,
    const short* __restrict__ fb1, const short* __restrict__ fb2,
    const short* __restrict__ fb3, float* __restrict__ wbuf) {
  __shared__ __align__(16) short route[4][4608];   // 4 waves x (64 rows x 72 shorts)
  const int w = threadIdx.x >> 6, l = threadIdx.x & 63;
  const int lrow = l & 15, lhi = l >> 4;
  const int e0 = (blockIdx.x*4 + w)*64;
  short* rt = route[w];

  // ---- L1 A-fragments from es8 (valid k<8 only -> lanes with lhi==0) ----
  s16x8 ah1[4], al1[4];
  #pragma unroll
  for (int mt = 0; mt < 4; ++mt) {
    s16x8 h = {0,0,0,0,0,0,0,0}, lo = {0,0,0,0,0,0,0,0};
    if (lhi == 0) {
      const float* ep = es8 + (size_t)(e0 + mt*16 + lrow)*8;
      f32x4 p0 = *(const f32x4*)ep;
      f32x4 p1 = *(const f32x4*)(ep + 4);
      float vals[8] = {p0[0],p0[1],p0[2],p0[3],p1[0],p1[1],p1[2],p1[3]};
      #pragma unroll
      for (int j = 0; j < 8; ++j) {
        unsigned short hh = bf16h(vals[j]);
        h[j] = (short)hh;
        lo[j] = (short)bf16h(vals[j] - bf2f(hh));
      }
    }
    ah1[mt] = h; al1[mt] = lo;
  }

  // ---- L1 MFMAs ----
  f32x4 acc1[4][4];
  #pragma unroll
  for (int mt = 0; mt < 4; ++mt)
    #pragma unroll
    for (int nf = 0; nf < 4; ++nf) acc1[mt][nf] = (f32x4){0.f,0.f,0.f,0.f};
  #pragma unroll
  for (int nf = 0; nf < 4; ++nf) {
    s16x8 bh = *(const s16x8*)(fb1 + ((0*4 + nf)*1 + 0)*512 + l*8);
    s16x8 bl = *(const s16x8*)(fb1 + ((1*4 + nf)*1 + 0)*512 + l*8);
    #pragma unroll
    for (int mt = 0; mt < 4; ++mt) {
      acc1[mt][nf] = __builtin_amdgcn_mfma_f32_16x16x32_bf16(ah1[mt], bh, acc1[mt][nf], 0,0,0);
      acc1[mt][nf] = __builtin_amdgcn_mfma_f32_16x16x32_bf16(ah1[mt], bl, acc1[mt][nf], 0,0,0);
      acc1[mt][nf] = __builtin_amdgcn_mfma_f32_16x16x32_bf16(al1[mt], bh, acc1[mt][nf], 0,0,0);
    }
  }
  // silu
  #pragma unroll
  for (int mt = 0; mt < 4; ++mt)
    #pragma unroll
    for (int nf = 0; nf < 4; ++nf)
      #pragma unroll
      for (int r = 0; r < 4; ++r) acc1[mt][nf][r] = siluf(acc1[mt][nf][r]);

  // ---- route L1 -> L2 A-frags (hi plane, read, then lo plane, read) ----
  s16x8 ah2[4][2], al2[4][2];
  #pragma unroll
  for (int mt = 0; mt < 4; ++mt)
    #pragma unroll
    for (int nf = 0; nf < 4; ++nf)
      #pragma unroll
      for (int r = 0; r < 4; ++r)
        rt[(mt*16 + lhi*4 + r)*72 + nf*16 + lrow] = (short)bf16h(acc1[mt][nf][r]);
  #pragma unroll
  for (int mt = 0; mt < 4; ++mt)
    #pragma unroll
    for (int ks = 0; ks < 2; ++ks)
      ah2[mt][ks] = *(const s16x8*)&rt[(mt*16 + lrow)*72 + ks*32 + lhi*8];
  #pragma unroll
  for (int mt = 0; mt < 4; ++mt)
    #pragma unroll
    for (int nf = 0; nf < 4; ++nf)
      #pragma unroll
      for (int r = 0; r < 4; ++r) {
        float v = acc1[mt][nf][r];
        unsigned short hh = bf16h(v);
        rt[(mt*16 + lhi*4 + r)*72 + nf*16 + lrow] = (short)bf16h(v - bf2f(hh));
      }
  #pragma unroll
  for (int mt = 0; mt < 4; ++mt)
    #pragma unroll
    for (int ks = 0; ks < 2; ++ks)
      al2[mt][ks] = *(const s16x8*)&rt[(mt*16 + lrow)*72 + ks*32 + lhi*8];

  // ---- L2 MFMAs ----
  f32x4 acc2[4][4];
  #pragma unroll
  for (int mt = 0; mt < 4; ++mt)
    #pragma unroll
    for (int nf = 0; nf < 4; ++nf) acc2[mt][nf] = (f32x4){0.f,0.f,0.f,0.f};
  #pragma unroll
  for (int nf = 0; nf < 4; ++nf)
    #pragma unroll
    for (int ks = 0; ks < 2; ++ks) {
      s16x8 bh = *(const s16x8*)(fb2 + ((0*4 + nf)*2 + ks)*512 + l*8);
      s16x8 bl = *(const s16x8*)(fb2 + ((1*4 + nf)*2 + ks)*512 + l*8);
      #pragma unroll
      for (int mt = 0; mt < 4; ++mt) {
        acc2[mt][nf] = __builtin_amdgcn_mfma_f32_16x16x32_bf16(ah2[mt][ks], bh, acc2[mt][nf], 0,0,0);
        acc2[mt][nf] = __builtin_amdgcn_mfma_f32_16x16x32_bf16(ah2[mt][ks], bl, acc2[mt][nf], 0,0,0);
        acc2[mt][nf] = __builtin_amdgcn_mfma_f32_16x16x32_bf16(al2[mt][ks], bh, acc2[mt][nf], 0,0,0);
      }
    }
  #pragma unroll
  for (int mt = 0; mt < 4; ++mt)
    #pragma unroll
    for (int nf = 0; nf < 4; ++nf)
      #pragma unroll
      for (int r = 0; r < 4; ++r) acc2[mt][nf][r] = siluf(acc2[mt][nf][r]);

  // ---- route L2 -> L3 A-frags ----
  s16x8 ah3[4][2], al3[4][2];
  #pragma unroll
  for (int mt = 0; mt < 4; ++mt)
    #pragma unroll
    for (int nf = 0; nf < 4; ++nf)
      #pragma unroll
      for (int r = 0; r < 4; ++r)
        rt[(mt*16 + lhi*4 + r)*72 + nf*16 + lrow] = (short)bf16h(acc2[mt][nf][r]);
  #pragma unroll
  for (int mt = 0; mt < 4; ++mt)
    #pragma unroll
    for (int ks = 0; ks < 2; ++ks)
      ah3[mt][ks] = *(const s16x8*)&rt[(mt*16 + lrow)*72 + ks*32 + lhi*8];
  #pragma unroll
  for (int mt = 0; mt < 4; ++mt)
    #pragma unroll
    for (int nf = 0; nf < 4; ++nf)
      #pragma unroll
      for (int r = 0; r < 4; ++r) {
        float v = acc2[mt][nf][r];
        unsigned short hh = bf16h(v);
        rt[(mt*16 + lhi*4 + r)*72 + nf*16 + lrow] = (short)bf16h(v - bf2f(hh));
      }
  #pragma unroll
  for (int mt = 0; mt < 4; ++mt)
    #pragma unroll
    for (int ks = 0; ks < 2; ++ks)
      al3[mt][ks] = *(const s16x8*)&rt[(mt*16 + lrow)*72 + ks*32 + lhi*8];

  // ---- L3 MFMAs + store ----
  for (int nf3 = 0; nf3 < NF3; ++nf3) {
    f32x4 acc3[4];
    #pragma unroll
    for (int mt = 0; mt < 4; ++mt) acc3[mt] = (f32x4){0.f,0.f,0.f,0.f};
    #pragma unroll
    for (int ks = 0; ks < 2; ++ks) {
      s16x8 bh = *(const s16x8*)(fb3 + ((size_t)(0*NF3 + nf3)*2 + ks)*512 + l*8);
      s16x8 bl = *(const s16x8*)(fb3 + ((size_t)(1*NF3 + nf3)*2 + ks)*512 + l*8);
      #pragma unroll
      for (int mt = 0; mt < 4; ++mt) {
        acc3[mt] = __builtin_amdgcn_mfma_f32_16x16x32_bf16(ah3[mt][ks], bh, acc3[mt], 0,0,0);
        acc3[mt] = __builtin_amdgcn_mfma_f32_16x16x32_bf16(ah3[mt][ks], bl, acc3[mt], 0,0,0);
        acc3[mt] = __builtin_amdgcn_mfma_f32_16x16x32_bf16(al3[mt][ks], bh, acc3[mt], 0,0,0);
      }
    }
    #pragma unroll
    for (int mt = 0; mt < 4; ++mt)
      #pragma unroll
      for (int r = 0; r < 4; ++r)
        wbuf[(size_t)(e0 + mt*16 + lhi*4 + r)*(NF3*16) + nf3*16 + lrow] = acc3[mt][r];
  }
}

// ---------------- conv1 gather: CSR pull, no atomics ----------------
__global__ __launch_bounds__(256) void k_gather1(
    const float* __restrict__ wbuf, const float* __restrict__ shv,
    const int* __restrict__ esrc, const int* __restrict__ offs, const int* __restrict__ slot,
    const float* __restrict__ h,
    float* __restrict__ n_s, float* __restrict__ n_v) {
  const int wave = threadIdx.x >> 6, lane = threadIdx.x & 63;
  const int n = blockIdx.x*4 + wave;
  if (n >= N_NODES) return;
  const int s0 = offs[n], s1 = offs[n+1];
  float ns0=0.f, ns1=0.f;
  float nv00=0.f,nv01=0.f,nv02=0.f, nv10=0.f,nv11=0.f,nv12=0.f;
  for (int s = s0; s < s1; ++s) {
    int e = slot[s];
    int src = esrc[e];
    const float* wp = wbuf + (size_t)e*256;
    float c0 = wp[lane], c1 = wp[64+lane], c2 = wp[128+lane], c3 = wp[192+lane];
    float h0 = h[src*128+lane], h1 = h[src*128+64+lane];
    float sv0 = shv[e*3+0], sv1 = shv[e*3+1], sv2 = shv[e*3+2];
    ns0 += c0*h0; ns1 += c1*h1;
    float t0 = c2*h0, t1 = c3*h1;
    nv00 += t0*sv0; nv01 += t0*sv1; nv02 += t0*sv2;
    nv10 += t1*sv0; nv11 += t1*sv1; nv12 += t1*sv2;
  }
  n_s[n*128+lane]    = ns0*INV_SQRT10;
  n_s[n*128+64+lane] = ns1*INV_SQRT10;
  float* nvp = n_v + n*384;
  nvp[lane*3+0] = nv00*INV_SQRT10; nvp[lane*3+1] = nv01*INV_SQRT10; nvp[lane*3+2] = nv02*INV_SQRT10;
  nvp[(64+lane)*3+0] = nv10*INV_SQRT10; nvp[(64+lane)*3+1] = nv11*INV_SQRT10; nvp[(64+lane)*3+2] = nv12*INV_SQRT10;
}

// ---------------- conv2 gather: CSR pull, no atomics ----------------
__global__ __launch_bounds__(256) void k_gather2(
    const float* __restrict__ wbuf, const float* __restrict__ shv,
    const int* __restrict__ esrc, const int* __restrict__ offs, const int* __restrict__ slot,
    const float* __restrict__ h_s, const float* __restrict__ h_v,
    float* __restrict__ n_mid) {
  const int wave = threadIdx.x >> 6, lane = threadIdx.x & 63;
  const int n = blockIdx.x*4 + wave;
  if (n >= N_NODES) return;
  const int s0 = offs[n], s1 = offs[n+1];
  float acc0 = 0.f, acc1 = 0.f;
  for (int s = s0; s < s1; ++s) {
    int e = slot[s];
    int src = esrc[e];
    const float* wp = wbuf + (size_t)e*128;
    float w0 = wp[lane], w1 = wp[64+lane];
    float hs = h_s[src*64+lane];
    const float* hvp = h_v + src*192 + lane*3;
    float sv0 = shv[e*3+0], sv1 = shv[e*3+1], sv2 = shv[e*3+2];
    float dot = hvp[0]*sv0 + hvp[1]*sv1 + hvp[2]*sv2;
    acc0 += w0*hs;
    acc1 += w1*dot;
  }
  n_mid[n*128+lane]    = acc0*INV_SQRT10;
  n_mid[n*128+64+lane] = acc1*INV_SQRT3*INV_SQRT10;
}

// ======== FALLBACK (atomic) edge kernels — used only if ws too small ========
__global__ __launch_bounds__(512) void k_edge1_at(
    const float* __restrict__ es8, const float* __restrict__ shv,
    const int* __restrict__ esrc, const int* __restrict__ edst,
    const float* __restrict__ h,
    const float* __restrict__ W0, const float* __restrict__ W1, const float* __restrict__ W2,
    float* __restrict__ n_s, float* __restrict__ n_v) {
  __shared__ float lW0[512];
  __shared__ float lW1[4096];
  __shared__ float lW2[16384];
  __shared__ float lA[8][64];
  __shared__ float lB[8][64];
  for (int i = threadIdx.x; i < 512;   i += 512) lW0[i] = W0[i];
  for (int i = threadIdx.x; i < 4096;  i += 512) lW1[i] = W1[i];
  for (int i = threadIdx.x; i < 16384; i += 512) lW2[i] = W2[i];
  __syncthreads();
  const int wave = threadIdx.x >> 6, lane = threadIdx.x & 63;
  const int nw = gridDim.x * 8;
  const int e0 = blockIdx.x*8 + wave;
  const int iters = (N_EDGES + nw - 1) / nw;
  for (int it = 0; it < iters; ++it) {
    int e = e0 + it*nw;
    bool valid = e < N_EDGES;
    float a = 0.f, sv0=0.f, sv1=0.f, sv2=0.f;
    int src = 0, dst = 0;
    if (valid) {
      const float* ep = es8 + e*8;
      sv0 = shv[e*3+0]; sv1 = shv[e*3+1]; sv2 = shv[e*3+2];
      src = esrc[e]; dst = edst[e];
      a = ep[0]*lW0[lane]      + ep[1]*lW0[64+lane]  + ep[2]*lW0[128+lane] + ep[3]*lW0[192+lane]
        + ep[4]*lW0[256+lane]  + ep[5]*lW0[320+lane] + ep[6]*lW0[384+lane] + ep[7]*lW0[448+lane];
      a = siluf(a * INV_SQRT8);
    }
    lA[wave][lane] = a;
    __syncthreads();
    {
      float b0=0.f;
      #pragma unroll
      for (int k = 0; k < 64; ++k) b0 += lA[wave][k]*lW1[k*64+lane];
      lB[wave][lane] = siluf(b0 * INV_SQRT64);
    }
    __syncthreads();
    if (valid) {
      float c0=0.f,c1=0.f,c2=0.f,c3=0.f;
      #pragma unroll
      for (int k = 0; k < 64; ++k) {
        float bk = lB[wave][k];
        const float* r = lW2 + k*256;
        c0 += bk*r[lane]; c1 += bk*r[64+lane]; c2 += bk*r[128+lane]; c3 += bk*r[192+lane];
      }
      float hs0 = h[src*128 + lane];
      float hs1 = h[src*128 + 64 + lane];
      atomicAdd(&n_s[dst*128 + lane],      c0*INV_SQRT64*hs0*INV_SQRT10);
      atomicAdd(&n_s[dst*128 + 64 + lane], c1*INV_SQRT64*hs1*INV_SQRT10);
      float t0 = c2*INV_SQRT64*hs0*INV_SQRT10;
      float t1 = c3*INV_SQRT64*hs1*INV_SQRT10;
      float* nvp = n_v + dst*384;
      atomicAdd(nvp + lane*3+0, t0*sv0);
      atomicAdd(nvp + lane*3+1, t0*sv1);
      atomicAdd(nvp + lane*3+2, t0*sv2);
      atomicAdd(nvp + (64+lane)*3+0, t1*sv0);
      atomicAdd(nvp + (64+lane)*3+1, t1*sv1);
      atomicAdd(nvp + (64+lane)*3+2, t1*sv2);
    }
  }
}

__global__ __launch_bounds__(512) void k_edge2_at(
    const float* __restrict__ es8, const float* __restrict__ shv,
    const int* __restrict__ esrc, const int* __restrict__ edst,
    const float* __restrict__ h_s, const float* __restrict__ h_v,
    const float* __restrict__ W0, const float* __restrict__ W1, const float* __restrict__ W2,
    float* __restrict__ n_mid) {
  __shared__ float lW0[512];
  __shared__ float lW1[4096];
  __shared__ float lW2[8192];
  __shared__ float lA[8][64];
  __shared__ float lB[8][64];
  for (int i = threadIdx.x; i < 512;  i += 512) lW0[i] = W0[i];
  for (int i = threadIdx.x; i < 4096; i += 512) lW1[i] = W1[i];
  for (int i = threadIdx.x; i < 8192; i += 512) lW2[i] = W2[i];
  __syncthreads();
  const int wave = threadIdx.x >> 6, lane = threadIdx.x & 63;
  const int nw = gridDim.x * 8;
  const int e0 = blockIdx.x*8 + wave;
  const int iters = (N_EDGES + nw - 1) / nw;
  for (int it = 0; it < iters; ++it) {
    int e = e0 + it*nw;
    bool valid = e < N_EDGES;
    float a = 0.f, sv0=0.f, sv1=0.f, sv2=0.f;
    int src = 0, dst = 0;
    if (valid) {
      const float* ep = es8 + e*8;
      sv0 = shv[e*3+0]; sv1 = shv[e*3+1]; sv2 = shv[e*3+2];
      src = esrc[e]; dst = edst[e];
      a = ep[0]*lW0[lane]      + ep[1]*lW0[64+lane]  + ep[2]*lW0[128+lane] + ep[3]*lW0[192+lane]
        + ep[4]*lW0[256+lane]  + ep[5]*lW0[320+lane] + ep[6]*lW0[384+lane] + ep[7]*lW0[448+lane];
      a = siluf(a * INV_SQRT8);
    }
    lA[wave][lane] = a;
    __syncthreads();
    {
      float b0=0.f;
      #pragma unroll
      for (int k = 0; k < 64; ++k) b0 += lA[wave][k]*lW1[k*64+lane];
      lB[wave][lane] = siluf(b0 * INV_SQRT64);
    }
    __syncthreads();
    if (valid) {
      float c0=0.f, c1=0.f;
      #pragma unroll
      for (int k = 0; k < 64; ++k) {
        float bk = lB[wave][k];
        const float* r = lW2 + k*128;
        c0 += bk*r[lane]; c1 += bk*r[64+lane];
      }
      float hsv = h_s[src*64 + lane];
      const float* hvp = h_v + src*192 + lane*3;
      float dotv = hvp[0]*sv0 + hvp[1]*sv1 + hvp[2]*sv2;
      atomicAdd(&n_mid[dst*128 + lane],      c0*INV_SQRT64*hsv*INV_SQRT10);
      atomicAdd(&n_mid[dst*128 + 64 + lane], c1*INV_SQRT64*dotv*INV_SQRT3*INV_SQRT10);
    }
  }
}

// ---------------- conv1 node pass + gating + conv2 node linears ----------------
__global__ __launch_bounds__(128) void k_node1(
    const float* __restrict__ n_s, const float* __restrict__ n_v,
    const float* __restrict__ s,   const float* __restrict__ na,
    const float* __restrict__ Wls, const float* __restrict__ Wlv,
    const float* __restrict__ Csc, const float* __restrict__ W2s, const float* __restrict__ W2v,
    float* __restrict__ gs_out, float* __restrict__ hs_out, float* __restrict__ hv_out) {
  __shared__ float l_ns[512], l_s[512], l_na[64], l_nv[1536];
  __shared__ float l_outs[512], l_ov[768], l_gs[256], l_gv[768];
  const int j = threadIdx.x;
  const int n0 = blockIdx.x*4;
  for (int i = j; i < 512;  i += 128) { l_ns[i] = n_s[n0*128+i]; l_s[i] = s[n0*128+i]; }
  for (int i = j; i < 1536; i += 128) l_nv[i] = n_v[n0*384+i];
  if (j < 64) l_na[j] = na[n0*16+j];
  __syncthreads();

  float accs[4] = {0.f,0.f,0.f,0.f};
  for (int k = 0; k < 128; ++k) {
    float w = Wls[k*128+j];
    accs[0] += l_ns[k]*w; accs[1] += l_ns[128+k]*w;
    accs[2] += l_ns[256+k]*w; accs[3] += l_ns[384+k]*w;
  }
  float accc[4] = {0.f,0.f,0.f,0.f};
  for (int vt = 0; vt < 16; vt += 4) {
    float a0[4],a1[4],a2[4],a3[4];
    #pragma unroll
    for (int n = 0; n < 4; ++n) {
      a0[n]=l_na[n*16+vt]; a1[n]=l_na[n*16+vt+1];
      a2[n]=l_na[n*16+vt+2]; a3[n]=l_na[n*16+vt+3];
    }
    for (int u = 0; u < 128; ++u) {
      const float* cp = Csc + (u*16+vt)*128 + j;
      float c0=cp[0], c1=cp[128], c2=cp[256], c3=cp[384];
      float s0=l_s[u], s1=l_s[128+u], s2=l_s[256+u], s3=l_s[384+u];
      accc[0] += s0*(a0[0]*c0 + a1[0]*c1 + a2[0]*c2 + a3[0]*c3);
      accc[1] += s1*(a0[1]*c0 + a1[1]*c1 + a2[1]*c2 + a3[1]*c3);
      accc[2] += s2*(a0[2]*c0 + a1[2]*c1 + a2[2]*c2 + a3[2]*c3);
      accc[3] += s3*(a0[3]*c0 + a1[3]*c1 + a2[3]*c2 + a3[3]*c3);
    }
  }
  #pragma unroll
  for (int n = 0; n < 4; ++n)
    l_outs[n*128+j] = accs[n]*INV_SQRT128 + accc[n]*INV_SQRT2048;

  const int jj = j & 63, hh = j >> 6;
  float ov[2][3] = {{0.f,0.f,0.f},{0.f,0.f,0.f}};
  for (int u = 0; u < 128; ++u) {
    float w = Wlv[u*64+jj];
    #pragma unroll
    for (int t = 0; t < 2; ++t) {
      int n = 2*hh+t;
      ov[t][0] += l_nv[n*384+u*3+0]*w;
      ov[t][1] += l_nv[n*384+u*3+1]*w;
      ov[t][2] += l_nv[n*384+u*3+2]*w;
    }
  }
  #pragma unroll
  for (int t = 0; t < 2; ++t) {
    int n = 2*hh+t;
    l_ov[n*192+jj*3+0] = ov[t][0]*INV_SQRT128;
    l_ov[n*192+jj*3+1] = ov[t][1]*INV_SQRT128;
    l_ov[n*192+jj*3+2] = ov[t][2]*INV_SQRT128;
  }
  __syncthreads();

  #pragma unroll
  for (int t = 0; t < 2; ++t) {
    int n = 2*hh+t;
    float gv_s = siluf(l_outs[n*128+jj]);
    float gate = sigf (l_outs[n*128+64+jj]);
    l_gs[n*64+jj] = gv_s;
    gs_out[(n0+n)*64+jj] = gv_s;
    l_gv[n*192+jj*3+0] = gate*l_ov[n*192+jj*3+0];
    l_gv[n*192+jj*3+1] = gate*l_ov[n*192+jj*3+1];
    l_gv[n*192+jj*3+2] = gate*l_ov[n*192+jj*3+2];
  }
  __syncthreads();

  float ha[2] = {0.f,0.f};
  for (int k = 0; k < 64; ++k) {
    float w = W2s[k*64+jj];
    ha[0] += l_gs[(2*hh+0)*64+k]*w;
    ha[1] += l_gs[(2*hh+1)*64+k]*w;
  }
  hs_out[(n0+2*hh+0)*64+jj] = ha[0]*INV_SQRT64;
  hs_out[(n0+2*hh+1)*64+jj] = ha[1]*INV_SQRT64;

  float hv[2][3] = {{0.f,0.f,0.f},{0.f,0.f,0.f}};
  for (int u = 0; u < 64; ++u) {
    float w = W2v[u*64+jj];
    #pragma unroll
    for (int t = 0; t < 2; ++t) {
      int n = 2*hh+t;
      hv[t][0] += l_gv[n*192+u*3+0]*w;
      hv[t][1] += l_gv[n*192+u*3+1]*w;
      hv[t][2] += l_gv[n*192+u*3+2]*w;
    }
  }
  #pragma unroll
  for (int t = 0; t < 2; ++t) {
    int n = 2*hh+t;
    hv_out[(n0+n)*192+jj*3+0] = hv[t][0]*INV_SQRT64;
    hv_out[(n0+n)*192+jj*3+1] = hv[t][1]*INV_SQRT64;
    hv_out[(n0+n)*192+jj*3+2] = hv[t][2]*INV_SQRT64;
  }
}

// ---------------- conv2 node pass + pooled accumulation ----------------
__global__ __launch_bounds__(128) void k_node2(
    const float* __restrict__ n_mid, const float* __restrict__ gs,
    const float* __restrict__ na, const int* __restrict__ batch,
    const float* __restrict__ W, const float* __restrict__ Csc,
    float* __restrict__ pool) {
  __shared__ float l_nm[512], l_gs[256], l_na[64];
  const int j = threadIdx.x;
  const int n0 = blockIdx.x*4;
  for (int i = j; i < 512; i += 128) l_nm[i] = n_mid[n0*128+i];
  for (int i = j; i < 256; i += 128) l_gs[i] = gs[n0*64+i];
  if (j < 64) l_na[j] = na[n0*16+j];
  __syncthreads();
  float acc[4] = {0.f,0.f,0.f,0.f};
  for (int k = 0; k < 128; ++k) {
    float w = W[k*128+j];
    acc[0] += l_nm[k]*w; acc[1] += l_nm[128+k]*w;
    acc[2] += l_nm[256+k]*w; acc[3] += l_nm[384+k]*w;
  }
  float acc2[4] = {0.f,0.f,0.f,0.f};
  for (int vt = 0; vt < 16; vt += 4) {
    float a0[4],a1[4],a2[4],a3[4];
    #pragma unroll
    for (int n = 0; n < 4; ++n) {
      a0[n]=l_na[n*16+vt]; a1[n]=l_na[n*16+vt+1];
      a2[n]=l_na[n*16+vt+2]; a3[n]=l_na[n*16+vt+3];
    }
    for (int u = 0; u < 64; ++u) {
      const float* cp = Csc + (u*16+vt)*128 + j;
      float c0=cp[0], c1=cp[128], c2=cp[256], c3=cp[384];
      float s0=l_gs[u], s1=l_gs[64+u], s2=l_gs[128+u], s3=l_gs[192+u];
      acc2[0] += s0*(a0[0]*c0 + a1[0]*c1 + a2[0]*c2 + a3[0]*c3);
      acc2[1] += s1*(a0[1]*c0 + a1[1]*c1 + a2[1]*c2 + a3[1]*c3);
      acc2[2] += s2*(a0[2]*c0 + a1[2]*c1 + a2[2]*c2 + a3[2]*c3);
      acc2[3] += s3*(a0[3]*c0 + a1[3]*c1 + a2[3]*c2 + a3[3]*c3);
    }
  }
  float outv[4];
  #pragma unroll
  for (int n = 0; n < 4; ++n)
    outv[n] = acc[n]*INV_SQRT128 + acc2[n]*INV_SQRT1024;
  int b0 = batch[n0], b1 = batch[n0+1], b2 = batch[n0+2], b3 = batch[n0+3];
  float sum = outv[0]; int cur = b0;
  if (b1 == cur) sum += outv[1]; else { atomicAdd(&pool[cur*128+j], sum); cur = b1; sum = outv[1]; }
  if (b2 == cur) sum += outv[2]; else { atomicAdd(&pool[cur*128+j], sum); cur = b2; sum = outv[2]; }
  if (b3 == cur) sum += outv[3]; else { atomicAdd(&pool[cur*128+j], sum); cur = b3; sum = outv[3]; }
  atomicAdd(&pool[cur*128+j], sum);
}

// ---------------- readout head ----------------
__global__ __launch_bounds__(128) void k_head(
    const float* __restrict__ pool, const float* __restrict__ cnt,
    const float* __restrict__ Wr1, const float* __restrict__ Wr2,
    float* __restrict__ out) {
  __shared__ float lp[128];
  __shared__ float lt[128];
  const int j = threadIdx.x;
  for (int g = 0; g < N_GRAPHS; ++g) {
    float inv = 1.f / fmaxf(cnt[g], 1.f);
    lp[j] = pool[g*128+j]*inv;
    __syncthreads();
    float acc = 0.f;
    for (int k = 0; k < 128; ++k) acc += lp[k]*Wr1[k*128+j];
    lt[j] = siluf(acc*INV_SQRT128) * Wr2[j];
    __syncthreads();
    if (j == 0) {
      float ssum = 0.f;
      for (int k = 0; k < 128; ++k) ssum += lt[k];
      out[g] = ssum*INV_SQRT128;
    }
    __syncthreads();
  }
}

extern "C" void kernel_launch(void* const* d_in, const int* in_sizes, int n_in,
                              void* d_out, int out_size, void* d_ws, size_t ws_size,
                              hipStream_t stream) {
  const float* x         = (const float*)d_in[0];
  const float* node_attr = (const float*)d_in[1];
  const int*   esrc      = (const int*)d_in[2];
  const int*   edst      = (const int*)d_in[3];
  const float* evec      = (const float*)d_in[4];
  const int*   batch     = (const int*)d_in[5];
  const float* W_embed   = (const float*)d_in[6];
  const float* c1_lin1   = (const float*)d_in[7];
  const float* c1_fc_w0  = (const float*)d_in[8];
  const float* c1_fc_w1  = (const float*)d_in[9];
  const float* c1_fc_w2  = (const float*)d_in[10];
  const float* c1_lin2_s = (const float*)d_in[11];
  const float* c1_lin2_v = (const float*)d_in[12];
  const float* c1_sc     = (const float*)d_in[13];
  const float* c2_lin1_s = (const float*)d_in[14];
  const float* c2_lin1_v = (const float*)d_in[15];
  const float* c2_fc_w0  = (const float*)d_in[16];
  const float* c2_fc_w1  = (const float*)d_in[17];
  const float* c2_fc_w2  = (const float*)d_in[18];
  const float* c2_lin2   = (const float*)d_in[19];
  const float* c2_sc     = (const float*)d_in[20];
  const float* Wr1       = (const float*)d_in[21];
  const float* Wr2       = (const float*)d_in[22];

  float* ws    = (float*)d_ws;
  float* es8   = ws + OFF_ES8;
  float* shv   = ws + OFF_SHV;
  float* s_    = ws + OFF_S;
  float* h_    = ws + OFF_H;
  float* gs_   = ws + OFF_GS;
  float* hs_   = ws + OFF_HS;
  float* hv_   = ws + OFF_HV;
  float* ns_   = ws + OFF_NS;
  float* nv_   = ws + OFF_NV;
  float* nmid_ = ws + OFF_NMID;
  float* pool_ = ws + OFF_POOL;
  float* cnt_  = ws + OFF_CNT;
  int*   hist_ = (int*)(ws + OFF_HIST);
  int*   curs_ = (int*)(ws + OFF_CURS);
  int*   offs_ = (int*)(ws + OFF_OFFS);
  short* frag_ = (short*)(ws + OFF_FRAG);
  int*   slot_ = (int*)(ws + OFF_SLOT);
  float* wbuf_ = ws + OFF_WBUF;

  const bool big = ws_size >= WS_NEED_BYTES;

  k_geom<<<N_EDGES/256, 256, 0, stream>>>(evec, es8, shv);
  k_linear128<<<(N_NODES*128)/256, 256, 0, stream>>>(x,  W_embed, s_, 32,  INV_SQRT32,  N_NODES*128);
  k_linear128<<<(N_NODES*128)/256, 256, 0, stream>>>(s_, c1_lin1, h_, 128, INV_SQRT128, N_NODES*128);

  if (big) {
    // zero POOL, CNT, HIST, CURS (contiguous)
    hipMemsetAsync(pool_, 0, (size_t)(OFF_OFFS - OFF_POOL)*sizeof(float), stream);
    k_cnt<<<(N_NODES+255)/256, 256, 0, stream>>>(batch, cnt_);
    // CSR build
    k_hist<<<(N_EDGES+255)/256, 256, 0, stream>>>(edst, hist_);
    k_scan<<<1, 64, 0, stream>>>(hist_, offs_);
    k_slot<<<(N_EDGES+255)/256, 256, 0, stream>>>(edst, offs_, curs_, slot_);
    // weight fragment prep (split bf16)
    k_prepw<<<16, 256, 0, stream>>>(c1_fc_w0, 8, 64, 4, 1, INV_SQRT8,  frag_ + F_B1);
    k_prepw<<<32, 256, 0, stream>>>(c1_fc_w1, 64, 64, 4, 2, INV_SQRT64, frag_ + F_B2);
    k_prepw<<<128,256, 0, stream>>>(c1_fc_w2, 64, 256, 16, 2, INV_SQRT64, frag_ + F_B3);
    k_prepw<<<16, 256, 0, stream>>>(c2_fc_w0, 8, 64, 4, 1, INV_SQRT8,  frag_ + F_B1b);
    k_prepw<<<32, 256, 0, stream>>>(c2_fc_w1, 64, 64, 4, 2, INV_SQRT64, frag_ + F_B2b);
    k_prepw<<<64, 256, 0, stream>>>(c2_fc_w2, 64, 128, 8, 2, INV_SQRT64, frag_ + F_B3b);
    // conv1
    k_mlp<16><<<625, 256, 0, stream>>>(es8, frag_ + F_B1, frag_ + F_B2, frag_ + F_B3, wbuf_);
    k_gather1<<<(N_NODES+3)/4, 256, 0, stream>>>(wbuf_, shv, esrc, offs_, slot_, h_, ns_, nv_);
    k_node1<<<N_NODES/4, 128, 0, stream>>>(ns_, nv_, s_, node_attr,
                                           c1_lin2_s, c1_lin2_v, c1_sc,
                                           c2_lin1_s, c2_lin1_v, gs_, hs_, hv_);
    // conv2 (wbuf aliased/reused)
    k_mlp<8><<<625, 256, 0, stream>>>(es8, frag_ + F_B1b, frag_ + F_B2b, frag_ + F_B3b, wbuf_);
    k_gather2<<<(N_NODES+3)/4, 256, 0, stream>>>(wbuf_, shv, esrc, offs_, slot_, hs_, hv_, nmid_);
  } else {
    // fallback: atomic scatter path (zero NS..CNT)
    hipMemsetAsync(ns_, 0, (size_t)(OFF_HIST - OFF_NS)*sizeof(float), stream);
    k_cnt<<<(N_NODES+255)/256, 256, 0, stream>>>(batch, cnt_);
    k_edge1_at<<<256, 512, 0, stream>>>(es8, shv, esrc, edst, h_,
                                        c1_fc_w0, c1_fc_w1, c1_fc_w2, ns_, nv_);
    k_node1<<<N_NODES/4, 128, 0, stream>>>(ns_, nv_, s_, node_attr,
                                           c1_lin2_s, c1_lin2_v, c1_sc,
                                           c2_lin1_s, c2_lin1_v, gs_, hs_, hv_);
    k_edge2_at<<<512, 512, 0, stream>>>(es8, shv, esrc, edst, hs_, hv_,
                                        c2_fc_w0, c2_fc_w1, c2_fc_w2, nmid_);
  }

  k_node2<<<N_NODES/4, 128, 0, stream>>>(nmid_, gs_, node_attr, batch,
                                         c2_lin2, c2_sc, pool_);
  k_head<<<1, 128, 0, stream>>>(pool_, cnt_, Wr1, Wr2, (float*)d_out);
}

// Round 4
// 629.297 us; speedup vs baseline: 1.9945x; 1.1278x over previous
//
#include <hip/hip_runtime.h>

#define N_NODES 10000
#define N_EDGES 160000
#define N_GRAPHS 16

typedef __attribute__((ext_vector_type(8))) short s16x8;
typedef __attribute__((ext_vector_type(4))) float f32x4;
typedef unsigned int uint32;

// ---- workspace layout (float offsets) ----
#define OFF_ES8  0
#define OFF_SHV  (OFF_ES8 + N_EDGES*8)
#define OFF_S    (OFF_SHV + N_EDGES*3)
#define OFF_H    (OFF_S   + N_NODES*128)
#define OFF_GS   (OFF_H   + N_NODES*128)
#define OFF_HS   (OFF_GS  + N_NODES*64)
#define OFF_HV   (OFF_HS  + N_NODES*64)
#define OFF_NS   (OFF_HV  + N_NODES*192)   /* fallback zero-region start */
#define OFF_NV   (OFF_NS  + N_NODES*128)
#define OFF_NMID (OFF_NV  + N_NODES*384)
#define OFF_POOL (OFF_NMID+ N_NODES*128)   /* new-path zero-region start */
#define OFF_CNT  (OFF_POOL+ N_GRAPHS*128)
#define OFF_HIST (OFF_CNT + N_GRAPHS)
#define OFF_CURS (OFF_HIST+ N_NODES)
#define OFF_OFFS (OFF_CURS+ N_NODES)       /* new-path zero-region end (excl) */
#define OFF_FRAG (OFF_OFFS+ N_NODES + 16)  /* MLP weight fragments: 73728 shorts = 36864 floats */
#define OFF_SLOT (OFF_FRAG+ 36864)
#define OFF_WBUF (OFF_SLOT+ N_EDGES)
#define WBUF_FLOATS ((size_t)N_EDGES*256)
#define WS_NEED_BYTES ((size_t)(OFF_WBUF + WBUF_FLOATS) * 4)

// frag sub-offsets in shorts (each B: 2 planes * NF * KS * 512 shorts)
#define F_B1   0        /* conv1 L1: NF4 KS1 -> 4096  */
#define F_B2   4096     /* conv1 L2: NF4 KS2 -> 8192  */
#define F_B3   12288    /* conv1 L3: NF16 KS2 -> 32768 */
#define F_B1b  45056
#define F_B2b  49152
#define F_B3b  57344    /* conv2 L3: NF8 KS2 -> 16384 */

// sc-kernel frag sub-offsets in shorts, within the upper-wbuf frag region
#define NF_WLS 0        /* c1_lin2_s: NF8 KS4 -> 32768 */
#define NF_C1  32768    /* c1_sc:   NF128 KS4 -> 524288 */
#define NF_W2  557056   /* c2_lin2:  NF8 KS4 -> 32768 */
#define NF_C2  589824   /* c2_sc:   NF128 KS2 -> 262144 */

#define INV_SQRT32   0.17677669529663687f
#define INV_SQRT128  0.08838834764831845f
#define INV_SQRT8    0.3535533905932738f
#define INV_SQRT64   0.125f
#define INV_SQRT2048 0.022097086912079608f
#define INV_SQRT1024 0.03125f
#define INV_SQRT10   0.31622776601683794f
#define INV_SQRT3    0.5773502691896258f
#define SQRT3_C      1.7320508075688772f

__device__ __forceinline__ float siluf(float x){ return x / (1.f + __expf(-x)); }
__device__ __forceinline__ float sigf (float x){ return 1.f / (1.f + __expf(-x)); }
__device__ __forceinline__ unsigned short bf16h(float x){
  uint32 u = __float_as_uint(x);
  u += 0x7FFFu + ((u >> 16) & 1u);
  return (unsigned short)(u >> 16);
}
__device__ __forceinline__ float bf2f(unsigned short h){
  return __uint_as_float(((uint32)h) << 16);
}
__device__ __forceinline__ void split8(const float* __restrict__ p, s16x8& hi, s16x8& lo) {
  f32x4 v0 = *(const f32x4*)p;
  f32x4 v1 = *(const f32x4*)(p + 4);
  float vals[8] = {v0[0],v0[1],v0[2],v0[3],v1[0],v1[1],v1[2],v1[3]};
  #pragma unroll
  for (int j = 0; j < 8; ++j) {
    unsigned short hh = bf16h(vals[j]);
    hi[j] = (short)hh;
    lo[j] = (short)bf16h(vals[j] - bf2f(hh));
  }
}

// ---------------- edge geometry: bessel basis + unit vec ----------------
__global__ void k_geom(const float* __restrict__ evec,
                       float* __restrict__ es8, float* __restrict__ shv) {
  int e = blockIdx.x*256 + threadIdx.x;
  if (e >= N_EDGES) return;
  float vx = evec[e*3+0], vy = evec[e*3+1], vz = evec[e*3+2];
  float d  = sqrtf(vx*vx + vy*vy + vz*vz);
  float xs = d - 0.25f;
  bool  in = (xs > 0.f) && (xs < 4.0f);
  float safe = xs > 0.f ? xs : 1.f;
  float amp  = in ? 2.0f/safe : 0.f;
  const float PI4 = 0.7853981633974483f;
  #pragma unroll
  for (int k = 0; k < 8; ++k)
    es8[e*8+k] = amp * sinf((float)(k+1) * PI4 * safe);
  float invd = d > 0.f ? 1.f/d : 1.f;
  shv[e*3+0] = SQRT3_C*vx*invd;
  shv[e*3+1] = SQRT3_C*vy*invd;
  shv[e*3+2] = SQRT3_C*vz*invd;
}

// ---------------- generic rows x K -> rows x 128 linear ----------------
__global__ void k_linear128(const float* __restrict__ A, const float* __restrict__ W,
                            float* __restrict__ O, int K, float scale, int total) {
  int t = blockIdx.x*256 + threadIdx.x;
  if (t >= total) return;
  int n = t >> 7, j = t & 127;
  const float* a = A + n*K;
  float a0=0.f,a1=0.f,a2=0.f,a3=0.f;
  for (int k = 0; k < K; k += 4) {
    a0 += a[k+0]*W[(k+0)*128+j];
    a1 += a[k+1]*W[(k+1)*128+j];
    a2 += a[k+2]*W[(k+2)*128+j];
    a3 += a[k+3]*W[(k+3)*128+j];
  }
  O[t] = (a0+a1+a2+a3)*scale;
}

// ---------------- graph node counts ----------------
__global__ void k_cnt(const int* __restrict__ batch, float* __restrict__ cnt) {
  __shared__ int lc[N_GRAPHS];
  int t = threadIdx.x;
  if (t < N_GRAPHS) lc[t] = 0;
  __syncthreads();
  int i = blockIdx.x*256 + t;
  if (i < N_NODES) atomicAdd(&lc[batch[i]], 1);
  __syncthreads();
  if (t < N_GRAPHS && lc[t] > 0) atomicAdd(&cnt[t], (float)lc[t]);
}

// ---------------- CSR build ----------------
__global__ void k_hist(const int* __restrict__ edst, int* __restrict__ hist) {
  int e = blockIdx.x*256 + threadIdx.x;
  if (e < N_EDGES) atomicAdd(&hist[edst[e]], 1);
}

__global__ void k_scan(const int* __restrict__ hist, int* __restrict__ offs) {
  int lane = threadIdx.x;   // 64 threads
  int run = 0;
  if (lane == 0) offs[0] = 0;
  for (int base = 0; base < N_NODES; base += 64) {
    int idx = base + lane;
    int v = (idx < N_NODES) ? hist[idx] : 0;
    #pragma unroll
    for (int d = 1; d < 64; d <<= 1) {
      int t = __shfl_up(v, d);
      if (lane >= d) v += t;
    }
    if (idx < N_NODES) offs[idx+1] = run + v;
    run += __shfl(v, 63);
  }
}

__global__ void k_slot(const int* __restrict__ edst, const int* __restrict__ offs,
                       int* __restrict__ curs, int* __restrict__ slot) {
  int e = blockIdx.x*256 + threadIdx.x;
  if (e < N_EDGES) {
    int d = edst[e];
    int p = offs[d] + atomicAdd(&curs[d], 1);
    slot[p] = e;
  }
}

// ---------------- weight fragment prep (split bf16, B-fragment order) ----------------
// flat idx: (((p*NF + nf)*KS + ks)*64 + lane)*8 + j ; k = ks*32+(lane>>4)*8+j ; col = nf*16+(lane&15)
__global__ void k_prepw(const float* __restrict__ W, int Keff, int N, int NF, int KS,
                        float scale, short* __restrict__ dst) {
  int total = 1024*NF*KS;
  for (int t = blockIdx.x*256 + threadIdx.x; t < total; t += gridDim.x*256) {
    int j = t & 7;
    int l = (t >> 3) & 63;
    int rest = t >> 9;
    int ks = rest % KS; rest /= KS;
    int nf = rest % NF;
    int p  = rest / NF;
    int k   = ks*32 + (l >> 4)*8 + j;
    int col = nf*16 + (l & 15);
    float v = (k < Keff) ? W[k*N + col]*scale : 0.f;
    unsigned short hi = bf16h(v);
    unsigned short out = hi;
    if (p) out = bf16h(v - bf2f(hi));
    dst[t] = (short)out;
  }
}

// ---------------- fused 3-layer edge MLP via MFMA (split bf16) ----------------
template<int NF3>
__global__ __launch_bounds__(256) void k_mlp(
    const float* __restrict__ es8,
    const short* __restrict__ fb1, const short* __restrict__ fb2,
    const short* __restrict__ fb3, float* __restrict__ wbuf) {
  __shared__ __align__(16) short route[4][4608];   // 4 waves x (64 rows x 72 shorts)
  const int w = threadIdx.x >> 6, l = threadIdx.x & 63;
  const int lrow = l & 15, lhi = l >> 4;
  const int e0 = (blockIdx.x*4 + w)*64;
  short* rt = route[w];

  s16x8 ah1[4], al1[4];
  #pragma unroll
  for (int mt = 0; mt < 4; ++mt) {
    s16x8 h = {0,0,0,0,0,0,0,0}, lo = {0,0,0,0,0,0,0,0};
    if (lhi == 0) {
      const float* ep = es8 + (size_t)(e0 + mt*16 + lrow)*8;
      split8(ep, h, lo);
    }
    ah1[mt] = h; al1[mt] = lo;
  }

  f32x4 acc1[4][4];
  #pragma unroll
  for (int mt = 0; mt < 4; ++mt)
    #pragma unroll
    for (int nf = 0; nf < 4; ++nf) acc1[mt][nf] = (f32x4){0.f,0.f,0.f,0.f};
  #pragma unroll
  for (int nf = 0; nf < 4; ++nf) {
    s16x8 bh = *(const s16x8*)(fb1 + ((0*4 + nf)*1 + 0)*512 + l*8);
    s16x8 bl = *(const s16x8*)(fb1 + ((1*4 + nf)*1 + 0)*512 + l*8);
    #pragma unroll
    for (int mt = 0; mt < 4; ++mt) {
      acc1[mt][nf] = __builtin_amdgcn_mfma_f32_16x16x32_bf16(ah1[mt], bh, acc1[mt][nf], 0,0,0);
      acc1[mt][nf] = __builtin_amdgcn_mfma_f32_16x16x32_bf16(ah1[mt], bl, acc1[mt][nf], 0,0,0);
      acc1[mt][nf] = __builtin_amdgcn_mfma_f32_16x16x32_bf16(al1[mt], bh, acc1[mt][nf], 0,0,0);
    }
  }
  #pragma unroll
  for (int mt = 0; mt < 4; ++mt)
    #pragma unroll
    for (int nf = 0; nf < 4; ++nf)
      #pragma unroll
      for (int r = 0; r < 4; ++r) acc1[mt][nf][r] = siluf(acc1[mt][nf][r]);

  s16x8 ah2[4][2], al2[4][2];
  #pragma unroll
  for (int mt = 0; mt < 4; ++mt)
    #pragma unroll
    for (int nf = 0; nf < 4; ++nf)
      #pragma unroll
      for (int r = 0; r < 4; ++r)
        rt[(mt*16 + lhi*4 + r)*72 + nf*16 + lrow] = (short)bf16h(acc1[mt][nf][r]);
  #pragma unroll
  for (int mt = 0; mt < 4; ++mt)
    #pragma unroll
    for (int ks = 0; ks < 2; ++ks)
      ah2[mt][ks] = *(const s16x8*)&rt[(mt*16 + lrow)*72 + ks*32 + lhi*8];
  #pragma unroll
  for (int mt = 0; mt < 4; ++mt)
    #pragma unroll
    for (int nf = 0; nf < 4; ++nf)
      #pragma unroll
      for (int r = 0; r < 4; ++r) {
        float v = acc1[mt][nf][r];
        unsigned short hh = bf16h(v);
        rt[(mt*16 + lhi*4 + r)*72 + nf*16 + lrow] = (short)bf16h(v - bf2f(hh));
      }
  #pragma unroll
  for (int mt = 0; mt < 4; ++mt)
    #pragma unroll
    for (int ks = 0; ks < 2; ++ks)
      al2[mt][ks] = *(const s16x8*)&rt[(mt*16 + lrow)*72 + ks*32 + lhi*8];

  f32x4 acc2[4][4];
  #pragma unroll
  for (int mt = 0; mt < 4; ++mt)
    #pragma unroll
    for (int nf = 0; nf < 4; ++nf) acc2[mt][nf] = (f32x4){0.f,0.f,0.f,0.f};
  #pragma unroll
  for (int nf = 0; nf < 4; ++nf)
    #pragma unroll
    for (int ks = 0; ks < 2; ++ks) {
      s16x8 bh = *(const s16x8*)(fb2 + ((0*4 + nf)*2 + ks)*512 + l*8);
      s16x8 bl = *(const s16x8*)(fb2 + ((1*4 + nf)*2 + ks)*512 + l*8);
      #pragma unroll
      for (int mt = 0; mt < 4; ++mt) {
        acc2[mt][nf] = __builtin_amdgcn_mfma_f32_16x16x32_bf16(ah2[mt][ks], bh, acc2[mt][nf], 0,0,0);
        acc2[mt][nf] = __builtin_amdgcn_mfma_f32_16x16x32_bf16(ah2[mt][ks], bl, acc2[mt][nf], 0,0,0);
        acc2[mt][nf] = __builtin_amdgcn_mfma_f32_16x16x32_bf16(al2[mt][ks], bh, acc2[mt][nf], 0,0,0);
      }
    }
  #pragma unroll
  for (int mt = 0; mt < 4; ++mt)
    #pragma unroll
    for (int nf = 0; nf < 4; ++nf)
      #pragma unroll
      for (int r = 0; r < 4; ++r) acc2[mt][nf][r] = siluf(acc2[mt][nf][r]);

  s16x8 ah3[4][2], al3[4][2];
  #pragma unroll
  for (int mt = 0; mt < 4; ++mt)
    #pragma unroll
    for (int nf = 0; nf < 4; ++nf)
      #pragma unroll
      for (int r = 0; r < 4; ++r)
        rt[(mt*16 + lhi*4 + r)*72 + nf*16 + lrow] = (short)bf16h(acc2[mt][nf][r]);
  #pragma unroll
  for (int mt = 0; mt < 4; ++mt)
    #pragma unroll
    for (int ks = 0; ks < 2; ++ks)
      ah3[mt][ks] = *(const s16x8*)&rt[(mt*16 + lrow)*72 + ks*32 + lhi*8];
  #pragma unroll
  for (int mt = 0; mt < 4; ++mt)
    #pragma unroll
    for (int nf = 0; nf < 4; ++nf)
      #pragma unroll
      for (int r = 0; r < 4; ++r) {
        float v = acc2[mt][nf][r];
        unsigned short hh = bf16h(v);
        rt[(mt*16 + lhi*4 + r)*72 + nf*16 + lrow] = (short)bf16h(v - bf2f(hh));
      }
  #pragma unroll
  for (int mt = 0; mt < 4; ++mt)
    #pragma unroll
    for (int ks = 0; ks < 2; ++ks)
      al3[mt][ks] = *(const s16x8*)&rt[(mt*16 + lrow)*72 + ks*32 + lhi*8];

  for (int nf3 = 0; nf3 < NF3; ++nf3) {
    f32x4 acc3[4];
    #pragma unroll
    for (int mt = 0; mt < 4; ++mt) acc3[mt] = (f32x4){0.f,0.f,0.f,0.f};
    #pragma unroll
    for (int ks = 0; ks < 2; ++ks) {
      s16x8 bh = *(const s16x8*)(fb3 + ((size_t)(0*NF3 + nf3)*2 + ks)*512 + l*8);
      s16x8 bl = *(const s16x8*)(fb3 + ((size_t)(1*NF3 + nf3)*2 + ks)*512 + l*8);
      #pragma unroll
      for (int mt = 0; mt < 4; ++mt) {
        acc3[mt] = __builtin_amdgcn_mfma_f32_16x16x32_bf16(ah3[mt][ks], bh, acc3[mt], 0,0,0);
        acc3[mt] = __builtin_amdgcn_mfma_f32_16x16x32_bf16(ah3[mt][ks], bl, acc3[mt], 0,0,0);
        acc3[mt] = __builtin_amdgcn_mfma_f32_16x16x32_bf16(al3[mt][ks], bh, acc3[mt], 0,0,0);
      }
    }
    #pragma unroll
    for (int mt = 0; mt < 4; ++mt)
      #pragma unroll
      for (int r = 0; r < 4; ++r)
        wbuf[(size_t)(e0 + mt*16 + lhi*4 + r)*(NF3*16) + nf3*16 + lrow] = acc3[mt][r];
  }
}

// ---------------- fused node GEMM: outs = Ad@Wd*sc + einsum(Ao,na,C)*sc ----------------
// KSO = outer K-steps (4 for conv1 K=128, 2 for conv2 K=64). Dense K fixed at 128.
template<int KSO>
__global__ __launch_bounds__(256) void k_sc(
    const float* __restrict__ Ad,   // dense A (row stride 128)
    const float* __restrict__ Ao,   // outer A (row stride KSO*32)
    const float* __restrict__ na,   // node_attr (row stride 16)
    const short* __restrict__ fBd,  // dense W frags: 2p x 8nf x 4ks x 512
    const short* __restrict__ fBc,  // C frags:       2p x 128nf x KSO x 512
    float* __restrict__ outs) {
  __shared__ __align__(16) short lB[KSO*8192];   // one v-chunk of C frags
  const int tid = threadIdx.x;
  const int w = tid >> 6, l = tid & 63;
  const int lrow = l & 15, lhi = l >> 4;
  const int n0 = (blockIdx.x*4 + w)*16;

  // A fragments (dense + outer), split bf16
  s16x8 adh[4], adl[4], aoh[KSO], aol[KSO];
  #pragma unroll
  for (int ks = 0; ks < 4; ++ks)
    split8(Ad + (size_t)(n0 + lrow)*128 + ks*32 + lhi*8, adh[ks], adl[ks]);
  #pragma unroll
  for (int ks = 0; ks < KSO; ++ks)
    split8(Ao + (size_t)(n0 + lrow)*(KSO*32) + ks*32 + lhi*8, aoh[ks], aol[ks]);

  // dense GEMM into acc
  f32x4 acc[8];
  #pragma unroll
  for (int nf = 0; nf < 8; ++nf) acc[nf] = (f32x4){0.f,0.f,0.f,0.f};
  #pragma unroll
  for (int nf = 0; nf < 8; ++nf)
    #pragma unroll
    for (int ks = 0; ks < 4; ++ks) {
      s16x8 bh = *(const s16x8*)(fBd + ((0*8 + nf)*4 + ks)*512 + l*8);
      s16x8 bl = *(const s16x8*)(fBd + ((1*8 + nf)*4 + ks)*512 + l*8);
      acc[nf] = __builtin_amdgcn_mfma_f32_16x16x32_bf16(adh[ks], bh, acc[nf], 0,0,0);
      acc[nf] = __builtin_amdgcn_mfma_f32_16x16x32_bf16(adh[ks], bl, acc[nf], 0,0,0);
      acc[nf] = __builtin_amdgcn_mfma_f32_16x16x32_bf16(adl[ks], bh, acc[nf], 0,0,0);
    }

  // 16 v-chunks of the C contraction
  for (int v = 0; v < 16; ++v) {
    __syncthreads();   // everyone done reading previous chunk
    for (int i = tid; i < KSO*1024; i += 256) {   // 16B groups
      int gl = i & 63;
      int rest = i >> 6;
      int ks = rest % KSO;
      int rest2 = rest / KSO;      // p*8+nf
      int nf = rest2 & 7;
      int p  = rest2 >> 3;
      size_t src = ((((size_t)p*128 + (v*8 + nf))*KSO + ks)*64 + gl)*8;
      *(s16x8*)&lB[(size_t)i*8] = *(const s16x8*)&fBc[src];
    }
    __syncthreads();
    f32x4 dacc[8];
    #pragma unroll
    for (int nf = 0; nf < 8; ++nf) dacc[nf] = (f32x4){0.f,0.f,0.f,0.f};
    #pragma unroll
    for (int nf = 0; nf < 8; ++nf)
      #pragma unroll
      for (int ks = 0; ks < KSO; ++ks) {
        s16x8 bh = *(const s16x8*)&lB[((0*8 + nf)*KSO + ks)*512 + l*8];
        s16x8 bl = *(const s16x8*)&lB[((1*8 + nf)*KSO + ks)*512 + l*8];
        dacc[nf] = __builtin_amdgcn_mfma_f32_16x16x32_bf16(aoh[ks], bh, dacc[nf], 0,0,0);
        dacc[nf] = __builtin_amdgcn_mfma_f32_16x16x32_bf16(aoh[ks], bl, dacc[nf], 0,0,0);
        dacc[nf] = __builtin_amdgcn_mfma_f32_16x16x32_bf16(aol[ks], bh, dacc[nf], 0,0,0);
      }
    #pragma unroll
    for (int r = 0; r < 4; ++r) {
      int nrow = n0 + lhi*4 + r;
      if (nrow > N_NODES-1) nrow = N_NODES-1;
      float nav = na[(size_t)nrow*16 + v];
      #pragma unroll
      for (int nf = 0; nf < 8; ++nf) acc[nf][r] += nav * dacc[nf][r];
    }
  }

  // store
  #pragma unroll
  for (int nf = 0; nf < 8; ++nf)
    #pragma unroll
    for (int r = 0; r < 4; ++r) {
      int row = n0 + lhi*4 + r;
      if (row < N_NODES) outs[(size_t)row*128 + nf*16 + lrow] = acc[nf][r];
    }
}

// ---------------- conv1 gather: CSR pull, no atomics ----------------
__global__ __launch_bounds__(256) void k_gather1(
    const float* __restrict__ wbuf, const float* __restrict__ shv,
    const int* __restrict__ esrc, const int* __restrict__ offs, const int* __restrict__ slot,
    const float* __restrict__ h,
    float* __restrict__ n_s, float* __restrict__ n_v) {
  const int wave = threadIdx.x >> 6, lane = threadIdx.x & 63;
  const int n = blockIdx.x*4 + wave;
  if (n >= N_NODES) return;
  const int s0 = offs[n], s1 = offs[n+1];
  float ns0=0.f, ns1=0.f;
  float nv00=0.f,nv01=0.f,nv02=0.f, nv10=0.f,nv11=0.f,nv12=0.f;
  for (int s = s0; s < s1; ++s) {
    int e = slot[s];
    int src = esrc[e];
    const float* wp = wbuf + (size_t)e*256;
    float c0 = wp[lane], c1 = wp[64+lane], c2 = wp[128+lane], c3 = wp[192+lane];
    float h0 = h[src*128+lane], h1 = h[src*128+64+lane];
    float sv0 = shv[e*3+0], sv1 = shv[e*3+1], sv2 = shv[e*3+2];
    ns0 += c0*h0; ns1 += c1*h1;
    float t0 = c2*h0, t1 = c3*h1;
    nv00 += t0*sv0; nv01 += t0*sv1; nv02 += t0*sv2;
    nv10 += t1*sv0; nv11 += t1*sv1; nv12 += t1*sv2;
  }
  n_s[n*128+lane]    = ns0*INV_SQRT10;
  n_s[n*128+64+lane] = ns1*INV_SQRT10;
  float* nvp = n_v + n*384;
  nvp[lane*3+0] = nv00*INV_SQRT10; nvp[lane*3+1] = nv01*INV_SQRT10; nvp[lane*3+2] = nv02*INV_SQRT10;
  nvp[(64+lane)*3+0] = nv10*INV_SQRT10; nvp[(64+lane)*3+1] = nv11*INV_SQRT10; nvp[(64+lane)*3+2] = nv12*INV_SQRT10;
}

// ---------------- conv2 gather: CSR pull, no atomics ----------------
__global__ __launch_bounds__(256) void k_gather2(
    const float* __restrict__ wbuf, const float* __restrict__ shv,
    const int* __restrict__ esrc, const int* __restrict__ offs, const int* __restrict__ slot,
    const float* __restrict__ h_s, const float* __restrict__ h_v,
    float* __restrict__ n_mid) {
  const int wave = threadIdx.x >> 6, lane = threadIdx.x & 63;
  const int n = blockIdx.x*4 + wave;
  if (n >= N_NODES) return;
  const int s0 = offs[n], s1 = offs[n+1];
  float acc0 = 0.f, acc1 = 0.f;
  for (int s = s0; s < s1; ++s) {
    int e = slot[s];
    int src = esrc[e];
    const float* wp = wbuf + (size_t)e*128;
    float w0 = wp[lane], w1 = wp[64+lane];
    float hs = h_s[src*64+lane];
    const float* hvp = h_v + src*192 + lane*3;
    float sv0 = shv[e*3+0], sv1 = shv[e*3+1], sv2 = shv[e*3+2];
    float dot = hvp[0]*sv0 + hvp[1]*sv1 + hvp[2]*sv2;
    acc0 += w0*hs;
    acc1 += w1*dot;
  }
  n_mid[n*128+lane]    = acc0*INV_SQRT10;
  n_mid[n*128+64+lane] = acc1*INV_SQRT3*INV_SQRT10;
}

// ---------------- gate pass: out_v, gating, h_s, h_v (reads precomputed outs) ----------------
__global__ __launch_bounds__(128) void k_gate1(
    const float* __restrict__ outs, const float* __restrict__ n_v,
    const float* __restrict__ Wlv, const float* __restrict__ W2s, const float* __restrict__ W2v,
    float* __restrict__ gs_out, float* __restrict__ hs_out, float* __restrict__ hv_out) {
  __shared__ float l_outs[512], l_nv[1536];
  __shared__ float l_ov[768], l_gs[256], l_gv[768];
  const int j = threadIdx.x;
  const int n0 = blockIdx.x*4;
  for (int i = j; i < 512;  i += 128) l_outs[i] = outs[(size_t)n0*128 + i];
  for (int i = j; i < 1536; i += 128) l_nv[i] = n_v[n0*384+i];
  __syncthreads();

  const int jj = j & 63, hh = j >> 6;
  float ov[2][3] = {{0.f,0.f,0.f},{0.f,0.f,0.f}};
  for (int u = 0; u < 128; ++u) {
    float w = Wlv[u*64+jj];
    #pragma unroll
    for (int t = 0; t < 2; ++t) {
      int n = 2*hh+t;
      ov[t][0] += l_nv[n*384+u*3+0]*w;
      ov[t][1] += l_nv[n*384+u*3+1]*w;
      ov[t][2] += l_nv[n*384+u*3+2]*w;
    }
  }
  #pragma unroll
  for (int t = 0; t < 2; ++t) {
    int n = 2*hh+t;
    l_ov[n*192+jj*3+0] = ov[t][0]*INV_SQRT128;
    l_ov[n*192+jj*3+1] = ov[t][1]*INV_SQRT128;
    l_ov[n*192+jj*3+2] = ov[t][2]*INV_SQRT128;
  }
  __syncthreads();

  #pragma unroll
  for (int t = 0; t < 2; ++t) {
    int n = 2*hh+t;
    float gv_s = siluf(l_outs[n*128+jj]);
    float gate = sigf (l_outs[n*128+64+jj]);
    l_gs[n*64+jj] = gv_s;
    gs_out[(n0+n)*64+jj] = gv_s;
    l_gv[n*192+jj*3+0] = gate*l_ov[n*192+jj*3+0];
    l_gv[n*192+jj*3+1] = gate*l_ov[n*192+jj*3+1];
    l_gv[n*192+jj*3+2] = gate*l_ov[n*192+jj*3+2];
  }
  __syncthreads();

  float ha[2] = {0.f,0.f};
  for (int k = 0; k < 64; ++k) {
    float w = W2s[k*64+jj];
    ha[0] += l_gs[(2*hh+0)*64+k]*w;
    ha[1] += l_gs[(2*hh+1)*64+k]*w;
  }
  hs_out[(n0+2*hh+0)*64+jj] = ha[0]*INV_SQRT64;
  hs_out[(n0+2*hh+1)*64+jj] = ha[1]*INV_SQRT64;

  float hv[2][3] = {{0.f,0.f,0.f},{0.f,0.f,0.f}};
  for (int u = 0; u < 64; ++u) {
    float w = W2v[u*64+jj];
    #pragma unroll
    for (int t = 0; t < 2; ++t) {
      int n = 2*hh+t;
      hv[t][0] += l_gv[n*192+u*3+0]*w;
      hv[t][1] += l_gv[n*192+u*3+1]*w;
      hv[t][2] += l_gv[n*192+u*3+2]*w;
    }
  }
  #pragma unroll
  for (int t = 0; t < 2; ++t) {
    int n = 2*hh+t;
    hv_out[(n0+n)*192+jj*3+0] = hv[t][0]*INV_SQRT64;
    hv_out[(n0+n)*192+jj*3+1] = hv[t][1]*INV_SQRT64;
    hv_out[(n0+n)*192+jj*3+2] = hv[t][2]*INV_SQRT64;
  }
}

// ---------------- pooled accumulation (RLE on sorted batch) ----------------
__global__ __launch_bounds__(128) void k_pool(
    const float* __restrict__ outs, const int* __restrict__ batch,
    float* __restrict__ pool) {
  const int j = threadIdx.x;
  const int n0 = blockIdx.x*4;
  float outv[4];
  #pragma unroll
  for (int n = 0; n < 4; ++n) outv[n] = outs[(size_t)(n0+n)*128 + j];
  int b0 = batch[n0], b1 = batch[n0+1], b2 = batch[n0+2], b3 = batch[n0+3];
  float sum = outv[0]; int cur = b0;
  if (b1 == cur) sum += outv[1]; else { atomicAdd(&pool[cur*128+j], sum); cur = b1; sum = outv[1]; }
  if (b2 == cur) sum += outv[2]; else { atomicAdd(&pool[cur*128+j], sum); cur = b2; sum = outv[2]; }
  if (b3 == cur) sum += outv[3]; else { atomicAdd(&pool[cur*128+j], sum); cur = b3; sum = outv[3]; }
  atomicAdd(&pool[cur*128+j], sum);
}

// ======== FALLBACK (atomic) kernels — used only if ws too small ========
__global__ __launch_bounds__(512) void k_edge1_at(
    const float* __restrict__ es8, const float* __restrict__ shv,
    const int* __restrict__ esrc, const int* __restrict__ edst,
    const float* __restrict__ h,
    const float* __restrict__ W0, const float* __restrict__ W1, const float* __restrict__ W2,
    float* __restrict__ n_s, float* __restrict__ n_v) {
  __shared__ float lW0[512];
  __shared__ float lW1[4096];
  __shared__ float lW2[16384];
  __shared__ float lA[8][64];
  __shared__ float lB[8][64];
  for (int i = threadIdx.x; i < 512;   i += 512) lW0[i] = W0[i];
  for (int i = threadIdx.x; i < 4096;  i += 512) lW1[i] = W1[i];
  for (int i = threadIdx.x; i < 16384; i += 512) lW2[i] = W2[i];
  __syncthreads();
  const int wave = threadIdx.x >> 6, lane = threadIdx.x & 63;
  const int nw = gridDim.x * 8;
  const int e0 = blockIdx.x*8 + wave;
  const int iters = (N_EDGES + nw - 1) / nw;
  for (int it = 0; it < iters; ++it) {
    int e = e0 + it*nw;
    bool valid = e < N_EDGES;
    float a = 0.f, sv0=0.f, sv1=0.f, sv2=0.f;
    int src = 0, dst = 0;
    if (valid) {
      const float* ep = es8 + e*8;
      sv0 = shv[e*3+0]; sv1 = shv[e*3+1]; sv2 = shv[e*3+2];
      src = esrc[e]; dst = edst[e];
      a = ep[0]*lW0[lane]      + ep[1]*lW0[64+lane]  + ep[2]*lW0[128+lane] + ep[3]*lW0[192+lane]
        + ep[4]*lW0[256+lane]  + ep[5]*lW0[320+lane] + ep[6]*lW0[384+lane] + ep[7]*lW0[448+lane];
      a = siluf(a * INV_SQRT8);
    }
    lA[wave][lane] = a;
    __syncthreads();
    {
      float b0=0.f;
      #pragma unroll
      for (int k = 0; k < 64; ++k) b0 += lA[wave][k]*lW1[k*64+lane];
      lB[wave][lane] = siluf(b0 * INV_SQRT64);
    }
    __syncthreads();
    if (valid) {
      float c0=0.f,c1=0.f,c2=0.f,c3=0.f;
      #pragma unroll
      for (int k = 0; k < 64; ++k) {
        float bk = lB[wave][k];
        const float* r = lW2 + k*256;
        c0 += bk*r[lane]; c1 += bk*r[64+lane]; c2 += bk*r[128+lane]; c3 += bk*r[192+lane];
      }
      float hs0 = h[src*128 + lane];
      float hs1 = h[src*128 + 64 + lane];
      atomicAdd(&n_s[dst*128 + lane],      c0*INV_SQRT64*hs0*INV_SQRT10);
      atomicAdd(&n_s[dst*128 + 64 + lane], c1*INV_SQRT64*hs1*INV_SQRT10);
      float t0 = c2*INV_SQRT64*hs0*INV_SQRT10;
      float t1 = c3*INV_SQRT64*hs1*INV_SQRT10;
      float* nvp = n_v + dst*384;
      atomicAdd(nvp + lane*3+0, t0*sv0);
      atomicAdd(nvp + lane*3+1, t0*sv1);
      atomicAdd(nvp + lane*3+2, t0*sv2);
      atomicAdd(nvp + (64+lane)*3+0, t1*sv0);
      atomicAdd(nvp + (64+lane)*3+1, t1*sv1);
      atomicAdd(nvp + (64+lane)*3+2, t1*sv2);
    }
  }
}

__global__ __launch_bounds__(512) void k_edge2_at(
    const float* __restrict__ es8, const float* __restrict__ shv,
    const int* __restrict__ esrc, const int* __restrict__ edst,
    const float* __restrict__ h_s, const float* __restrict__ h_v,
    const float* __restrict__ W0, const float* __restrict__ W1, const float* __restrict__ W2,
    float* __restrict__ n_mid) {
  __shared__ float lW0[512];
  __shared__ float lW1[4096];
  __shared__ float lW2[8192];
  __shared__ float lA[8][64];
  __shared__ float lB[8][64];
  for (int i = threadIdx.x; i < 512;  i += 512) lW0[i] = W0[i];
  for (int i = threadIdx.x; i < 4096; i += 512) lW1[i] = W1[i];
  for (int i = threadIdx.x; i < 8192; i += 512) lW2[i] = W2[i];
  __syncthreads();
  const int wave = threadIdx.x >> 6, lane = threadIdx.x & 63;
  const int nw = gridDim.x * 8;
  const int e0 = blockIdx.x*8 + wave;
  const int iters = (N_EDGES + nw - 1) / nw;
  for (int it = 0; it < iters; ++it) {
    int e = e0 + it*nw;
    bool valid = e < N_EDGES;
    float a = 0.f, sv0=0.f, sv1=0.f, sv2=0.f;
    int src = 0, dst = 0;
    if (valid) {
      const float* ep = es8 + e*8;
      sv0 = shv[e*3+0]; sv1 = shv[e*3+1]; sv2 = shv[e*3+2];
      src = esrc[e]; dst = edst[e];
      a = ep[0]*lW0[lane]      + ep[1]*lW0[64+lane]  + ep[2]*lW0[128+lane] + ep[3]*lW0[192+lane]
        + ep[4]*lW0[256+lane]  + ep[5]*lW0[320+lane] + ep[6]*lW0[384+lane] + ep[7]*lW0[448+lane];
      a = siluf(a * INV_SQRT8);
    }
    lA[wave][lane] = a;
    __syncthreads();
    {
      float b0=0.f;
      #pragma unroll
      for (int k = 0; k < 64; ++k) b0 += lA[wave][k]*lW1[k*64+lane];
      lB[wave][lane] = siluf(b0 * INV_SQRT64);
    }
    __syncthreads();
    if (valid) {
      float c0=0.f, c1=0.f;
      #pragma unroll
      for (int k = 0; k < 64; ++k) {
        float bk = lB[wave][k];
        const float* r = lW2 + k*128;
        c0 += bk*r[lane]; c1 += bk*r[64+lane];
      }
      float hsv = h_s[src*64 + lane];
      const float* hvp = h_v + src*192 + lane*3;
      float dotv = hvp[0]*sv0 + hvp[1]*sv1 + hvp[2]*sv2;
      atomicAdd(&n_mid[dst*128 + lane],      c0*INV_SQRT64*hsv*INV_SQRT10);
      atomicAdd(&n_mid[dst*128 + 64 + lane], c1*INV_SQRT64*dotv*INV_SQRT3*INV_SQRT10);
    }
  }
}

// ---------------- FALLBACK conv1 node pass (full) ----------------
__global__ __launch_bounds__(128) void k_node1(
    const float* __restrict__ n_s, const float* __restrict__ n_v,
    const float* __restrict__ s,   const float* __restrict__ na,
    const float* __restrict__ Wls, const float* __restrict__ Wlv,
    const float* __restrict__ Csc, const float* __restrict__ W2s, const float* __restrict__ W2v,
    float* __restrict__ gs_out, float* __restrict__ hs_out, float* __restrict__ hv_out) {
  __shared__ float l_ns[512], l_s[512], l_na[64], l_nv[1536];
  __shared__ float l_outs[512], l_ov[768], l_gs[256], l_gv[768];
  const int j = threadIdx.x;
  const int n0 = blockIdx.x*4;
  for (int i = j; i < 512;  i += 128) { l_ns[i] = n_s[n0*128+i]; l_s[i] = s[n0*128+i]; }
  for (int i = j; i < 1536; i += 128) l_nv[i] = n_v[n0*384+i];
  if (j < 64) l_na[j] = na[n0*16+j];
  __syncthreads();

  float accs[4] = {0.f,0.f,0.f,0.f};
  for (int k = 0; k < 128; ++k) {
    float w = Wls[k*128+j];
    accs[0] += l_ns[k]*w; accs[1] += l_ns[128+k]*w;
    accs[2] += l_ns[256+k]*w; accs[3] += l_ns[384+k]*w;
  }
  float accc[4] = {0.f,0.f,0.f,0.f};
  for (int vt = 0; vt < 16; vt += 4) {
    float a0[4],a1[4],a2[4],a3[4];
    #pragma unroll
    for (int n = 0; n < 4; ++n) {
      a0[n]=l_na[n*16+vt]; a1[n]=l_na[n*16+vt+1];
      a2[n]=l_na[n*16+vt+2]; a3[n]=l_na[n*16+vt+3];
    }
    for (int u = 0; u < 128; ++u) {
      const float* cp = Csc + (u*16+vt)*128 + j;
      float c0=cp[0], c1=cp[128], c2=cp[256], c3=cp[384];
      float s0=l_s[u], s1=l_s[128+u], s2=l_s[256+u], s3=l_s[384+u];
      accc[0] += s0*(a0[0]*c0 + a1[0]*c1 + a2[0]*c2 + a3[0]*c3);
      accc[1] += s1*(a0[1]*c0 + a1[1]*c1 + a2[1]*c2 + a3[1]*c3);
      accc[2] += s2*(a0[2]*c0 + a1[2]*c1 + a2[2]*c2 + a3[2]*c3);
      accc[3] += s3*(a0[3]*c0 + a1[3]*c1 + a2[3]*c2 + a3[3]*c3);
    }
  }
  #pragma unroll
  for (int n = 0; n < 4; ++n)
    l_outs[n*128+j] = accs[n]*INV_SQRT128 + accc[n]*INV_SQRT2048;

  const int jj = j & 63, hh = j >> 6;
  float ov[2][3] = {{0.f,0.f,0.f},{0.f,0.f,0.f}};
  for (int u = 0; u < 128; ++u) {
    float w = Wlv[u*64+jj];
    #pragma unroll
    for (int t = 0; t < 2; ++t) {
      int n = 2*hh+t;
      ov[t][0] += l_nv[n*384+u*3+0]*w;
      ov[t][1] += l_nv[n*384+u*3+1]*w;
      ov[t][2] += l_nv[n*384+u*3+2]*w;
    }
  }
  #pragma unroll
  for (int t = 0; t < 2; ++t) {
    int n = 2*hh+t;
    l_ov[n*192+jj*3+0] = ov[t][0]*INV_SQRT128;
    l_ov[n*192+jj*3+1] = ov[t][1]*INV_SQRT128;
    l_ov[n*192+jj*3+2] = ov[t][2]*INV_SQRT128;
  }
  __syncthreads();

  #pragma unroll
  for (int t = 0; t < 2; ++t) {
    int n = 2*hh+t;
    float gv_s = siluf(l_outs[n*128+jj]);
    float gate = sigf (l_outs[n*128+64+jj]);
    l_gs[n*64+jj] = gv_s;
    gs_out[(n0+n)*64+jj] = gv_s;
    l_gv[n*192+jj*3+0] = gate*l_ov[n*192+jj*3+0];
    l_gv[n*192+jj*3+1] = gate*l_ov[n*192+jj*3+1];
    l_gv[n*192+jj*3+2] = gate*l_ov[n*192+jj*3+2];
  }
  __syncthreads();

  float ha[2] = {0.f,0.f};
  for (int k = 0; k < 64; ++k) {
    float w = W2s[k*64+jj];
    ha[0] += l_gs[(2*hh+0)*64+k]*w;
    ha[1] += l_gs[(2*hh+1)*64+k]*w;
  }
  hs_out[(n0+2*hh+0)*64+jj] = ha[0]*INV_SQRT64;
  hs_out[(n0+2*hh+1)*64+jj] = ha[1]*INV_SQRT64;

  float hv[2][3] = {{0.f,0.f,0.f},{0.f,0.f,0.f}};
  for (int u = 0; u < 64; ++u) {
    float w = W2v[u*64+jj];
    #pragma unroll
    for (int t = 0; t < 2; ++t) {
      int n = 2*hh+t;
      hv[t][0] += l_gv[n*192+u*3+0]*w;
      hv[t][1] += l_gv[n*192+u*3+1]*w;
      hv[t][2] += l_gv[n*192+u*3+2]*w;
    }
  }
  #pragma unroll
  for (int t = 0; t < 2; ++t) {
    int n = 2*hh+t;
    hv_out[(n0+n)*192+jj*3+0] = hv[t][0]*INV_SQRT64;
    hv_out[(n0+n)*192+jj*3+1] = hv[t][1]*INV_SQRT64;
    hv_out[(n0+n)*192+jj*3+2] = hv[t][2]*INV_SQRT64;
  }
}

// ---------------- FALLBACK conv2 node pass + pooling ----------------
__global__ __launch_bounds__(128) void k_node2(
    const float* __restrict__ n_mid, const float* __restrict__ gs,
    const float* __restrict__ na, const int* __restrict__ batch,
    const float* __restrict__ W, const float* __restrict__ Csc,
    float* __restrict__ pool) {
  __shared__ float l_nm[512], l_gs[256], l_na[64];
  const int j = threadIdx.x;
  const int n0 = blockIdx.x*4;
  for (int i = j; i < 512; i += 128) l_nm[i] = n_mid[n0*128+i];
  for (int i = j; i < 256; i += 128) l_gs[i] = gs[n0*64+i];
  if (j < 64) l_na[j] = na[n0*16+j];
  __syncthreads();
  float acc[4] = {0.f,0.f,0.f,0.f};
  for (int k = 0; k < 128; ++k) {
    float w = W[k*128+j];
    acc[0] += l_nm[k]*w; acc[1] += l_nm[128+k]*w;
    acc[2] += l_nm[256+k]*w; acc[3] += l_nm[384+k]*w;
  }
  float acc2[4] = {0.f,0.f,0.f,0.f};
  for (int vt = 0; vt < 16; vt += 4) {
    float a0[4],a1[4],a2[4],a3[4];
    #pragma unroll
    for (int n = 0; n < 4; ++n) {
      a0[n]=l_na[n*16+vt]; a1[n]=l_na[n*16+vt+1];
      a2[n]=l_na[n*16+vt+2]; a3[n]=l_na[n*16+vt+3];
    }
    for (int u = 0; u < 64; ++u) {
      const float* cp = Csc + (u*16+vt)*128 + j;
      float c0=cp[0], c1=cp[128], c2=cp[256], c3=cp[384];
      float s0=l_gs[u], s1=l_gs[64+u], s2=l_gs[128+u], s3=l_gs[192+u];
      acc2[0] += s0*(a0[0]*c0 + a1[0]*c1 + a2[0]*c2 + a3[0]*c3);
      acc2[1] += s1*(a0[1]*c0 + a1[1]*c1 + a2[1]*c2 + a3[1]*c3);
      acc2[2] += s2*(a0[2]*c0 + a1[2]*c1 + a2[2]*c2 + a3[2]*c3);
      acc2[3] += s3*(a0[3]*c0 + a1[3]*c1 + a2[3]*c2 + a3[3]*c3);
    }
  }
  float outv[4];
  #pragma unroll
  for (int n = 0; n < 4; ++n)
    outv[n] = acc[n]*INV_SQRT128 + acc2[n]*INV_SQRT1024;
  int b0 = batch[n0], b1 = batch[n0+1], b2 = batch[n0+2], b3 = batch[n0+3];
  float sum = outv[0]; int cur = b0;
  if (b1 == cur) sum += outv[1]; else { atomicAdd(&pool[cur*128+j], sum); cur = b1; sum = outv[1]; }
  if (b2 == cur) sum += outv[2]; else { atomicAdd(&pool[cur*128+j], sum); cur = b2; sum = outv[2]; }
  if (b3 == cur) sum += outv[3]; else { atomicAdd(&pool[cur*128+j], sum); cur = b3; sum = outv[3]; }
  atomicAdd(&pool[cur*128+j], sum);
}

// ---------------- readout head ----------------
__global__ __launch_bounds__(128) void k_head(
    const float* __restrict__ pool, const float* __restrict__ cnt,
    const float* __restrict__ Wr1, const float* __restrict__ Wr2,
    float* __restrict__ out) {
  __shared__ float lp[128];
  __shared__ float lt[128];
  const int j = threadIdx.x;
  for (int g = 0; g < N_GRAPHS; ++g) {
    float inv = 1.f / fmaxf(cnt[g], 1.f);
    lp[j] = pool[g*128+j]*inv;
    __syncthreads();
    float acc = 0.f;
    for (int k = 0; k < 128; ++k) acc += lp[k]*Wr1[k*128+j];
    lt[j] = siluf(acc*INV_SQRT128) * Wr2[j];
    __syncthreads();
    if (j == 0) {
      float ssum = 0.f;
      for (int k = 0; k < 128; ++k) ssum += lt[k];
      out[g] = ssum*INV_SQRT128;
    }
    __syncthreads();
  }
}

extern "C" void kernel_launch(void* const* d_in, const int* in_sizes, int n_in,
                              void* d_out, int out_size, void* d_ws, size_t ws_size,
                              hipStream_t stream) {
  const float* x         = (const float*)d_in[0];
  const float* node_attr = (const float*)d_in[1];
  const int*   esrc      = (const int*)d_in[2];
  const int*   edst      = (const int*)d_in[3];
  const float* evec      = (const float*)d_in[4];
  const int*   batch     = (const int*)d_in[5];
  const float* W_embed   = (const float*)d_in[6];
  const float* c1_lin1   = (const float*)d_in[7];
  const float* c1_fc_w0  = (const float*)d_in[8];
  const float* c1_fc_w1  = (const float*)d_in[9];
  const float* c1_fc_w2  = (const float*)d_in[10];
  const float* c1_lin2_s = (const float*)d_in[11];
  const float* c1_lin2_v = (const float*)d_in[12];
  const float* c1_sc     = (const float*)d_in[13];
  const float* c2_lin1_s = (const float*)d_in[14];
  const float* c2_lin1_v = (const float*)d_in[15];
  const float* c2_fc_w0  = (const float*)d_in[16];
  const float* c2_fc_w1  = (const float*)d_in[17];
  const float* c2_fc_w2  = (const float*)d_in[18];
  const float* c2_lin2   = (const float*)d_in[19];
  const float* c2_sc     = (const float*)d_in[20];
  const float* Wr1       = (const float*)d_in[21];
  const float* Wr2       = (const float*)d_in[22];

  float* ws    = (float*)d_ws;
  float* es8   = ws + OFF_ES8;
  float* shv   = ws + OFF_SHV;
  float* s_    = ws + OFF_S;
  float* h_    = ws + OFF_H;
  float* gs_   = ws + OFF_GS;
  float* hs_   = ws + OFF_HS;
  float* hv_   = ws + OFF_HV;
  float* ns_   = ws + OFF_NS;
  float* nv_   = ws + OFF_NV;
  float* nmid_ = ws + OFF_NMID;
  float* pool_ = ws + OFF_POOL;
  float* cnt_  = ws + OFF_CNT;
  int*   hist_ = (int*)(ws + OFF_HIST);
  int*   curs_ = (int*)(ws + OFF_CURS);
  int*   offs_ = (int*)(ws + OFF_OFFS);
  short* frag_ = (short*)(ws + OFF_FRAG);
  int*   slot_ = (int*)(ws + OFF_SLOT);
  float* wbuf_ = ws + OFF_WBUF;

  // regions carved out of the (dead after gather1 / upper) part of wbuf:
  float* out1_  = wbuf_ + (size_t)N_EDGES*128;               // 1.28M floats
  short* nfrag_ = (short*)(out1_ + (size_t)N_NODES*128);     // 851968 shorts
  float* out2_  = ns_;                                       // ns dead after k_sc<4>

  const bool big = ws_size >= WS_NEED_BYTES;

  k_geom<<<N_EDGES/256, 256, 0, stream>>>(evec, es8, shv);
  k_linear128<<<(N_NODES*128)/256, 256, 0, stream>>>(x,  W_embed, s_, 32,  INV_SQRT32,  N_NODES*128);
  k_linear128<<<(N_NODES*128)/256, 256, 0, stream>>>(s_, c1_lin1, h_, 128, INV_SQRT128, N_NODES*128);

  if (big) {
    hipMemsetAsync(pool_, 0, (size_t)(OFF_OFFS - OFF_POOL)*sizeof(float), stream);
    k_cnt<<<(N_NODES+255)/256, 256, 0, stream>>>(batch, cnt_);
    k_hist<<<(N_EDGES+255)/256, 256, 0, stream>>>(edst, hist_);
    k_scan<<<1, 64, 0, stream>>>(hist_, offs_);
    k_slot<<<(N_EDGES+255)/256, 256, 0, stream>>>(edst, offs_, curs_, slot_);
    // MLP weight frags (persistent region)
    k_prepw<<<16, 256, 0, stream>>>(c1_fc_w0, 8, 64, 4, 1, INV_SQRT8,  frag_ + F_B1);
    k_prepw<<<32, 256, 0, stream>>>(c1_fc_w1, 64, 64, 4, 2, INV_SQRT64, frag_ + F_B2);
    k_prepw<<<128,256, 0, stream>>>(c1_fc_w2, 64, 256, 16, 2, INV_SQRT64, frag_ + F_B3);
    k_prepw<<<16, 256, 0, stream>>>(c2_fc_w0, 8, 64, 4, 1, INV_SQRT8,  frag_ + F_B1b);
    k_prepw<<<32, 256, 0, stream>>>(c2_fc_w1, 64, 64, 4, 2, INV_SQRT64, frag_ + F_B2b);
    k_prepw<<<64, 256, 0, stream>>>(c2_fc_w2, 64, 128, 8, 2, INV_SQRT64, frag_ + F_B3b);
    // conv1 edge MLP + gather
    k_mlp<16><<<625, 256, 0, stream>>>(es8, frag_ + F_B1, frag_ + F_B2, frag_ + F_B3, wbuf_);
    k_gather1<<<(N_NODES+3)/4, 256, 0, stream>>>(wbuf_, shv, esrc, offs_, slot_, h_, ns_, nv_);
    // sc/dense weight frags (upper-wbuf region, free after gather1)
    k_prepw<<<32, 256, 0, stream>>>(c1_lin2_s, 128, 128, 8, 4, INV_SQRT128, nfrag_ + NF_WLS);
    k_prepw<<<512,256, 0, stream>>>(c1_sc, 128, 2048, 128, 4, INV_SQRT2048, nfrag_ + NF_C1);
    k_prepw<<<32, 256, 0, stream>>>(c2_lin2, 128, 128, 8, 4, INV_SQRT128, nfrag_ + NF_W2);
    k_prepw<<<256,256, 0, stream>>>(c2_sc, 64, 2048, 128, 2, INV_SQRT1024, nfrag_ + NF_C2);
    // conv1 node: outs1 = n_s@lin2_s + sc1, then gate pass
    k_sc<4><<<157, 256, 0, stream>>>(ns_, s_, node_attr, nfrag_ + NF_WLS, nfrag_ + NF_C1, out1_);
    k_gate1<<<N_NODES/4, 128, 0, stream>>>(out1_, nv_, c1_lin2_v, c2_lin1_s, c2_lin1_v,
                                           gs_, hs_, hv_);
    // conv2 edge MLP + gather (lower wbuf only)
    k_mlp<8><<<625, 256, 0, stream>>>(es8, frag_ + F_B1b, frag_ + F_B2b, frag_ + F_B3b, wbuf_);
    k_gather2<<<(N_NODES+3)/4, 256, 0, stream>>>(wbuf_, shv, esrc, offs_, slot_, hs_, hv_, nmid_);
    // conv2 node: outs2 = n_mid@c2_lin2 + sc2, then pooling
    k_sc<2><<<157, 256, 0, stream>>>(nmid_, gs_, node_attr, nfrag_ + NF_W2, nfrag_ + NF_C2, out2_);
    k_pool<<<N_NODES/4, 128, 0, stream>>>(out2_, batch, pool_);
  } else {
    hipMemsetAsync(ns_, 0, (size_t)(OFF_HIST - OFF_NS)*sizeof(float), stream);
    k_cnt<<<(N_NODES+255)/256, 256, 0, stream>>>(batch, cnt_);
    k_edge1_at<<<256, 512, 0, stream>>>(es8, shv, esrc, edst, h_,
                                        c1_fc_w0, c1_fc_w1, c1_fc_w2, ns_, nv_);
    k_node1<<<N_NODES/4, 128, 0, stream>>>(ns_, nv_, s_, node_attr,
                                           c1_lin2_s, c1_lin2_v, c1_sc,
                                           c2_lin1_s, c2_lin1_v, gs_, hs_, hv_);
    k_edge2_at<<<512, 512, 0, stream>>>(es8, shv, esrc, edst, hs_, hv_,
                                        c2_fc_w0, c2_fc_w1, c2_fc_w2, nmid_);
    k_node2<<<N_NODES/4, 128, 0, stream>>>(nmid_, gs_, node_attr, batch,
                                           c2_lin2, c2_sc, pool_);
  }

  k_head<<<1, 128, 0, stream>>>(pool_, cnt_, Wr1, Wr2, (float*)d_out);
}

// Round 5
// 569.245 us; speedup vs baseline: 2.2049x; 1.1055x over previous
//
#include <hip/hip_runtime.h>

#define N_NODES 10000
#define N_EDGES 160000
#define N_GRAPHS 16

typedef __attribute__((ext_vector_type(8))) short s16x8;
typedef __attribute__((ext_vector_type(4))) float f32x4;
typedef unsigned int uint32;

// ---- workspace layout (float offsets) ----
#define OFF_ES8  0
#define OFF_SHV  (OFF_ES8 + N_EDGES*8)
#define OFF_S    (OFF_SHV + N_EDGES*3)
#define OFF_H    (OFF_S   + N_NODES*128)
#define OFF_GS   (OFF_H   + N_NODES*128)
#define OFF_HS   (OFF_GS  + N_NODES*64)
#define OFF_HV   (OFF_HS  + N_NODES*64)
#define OFF_NS   (OFF_HV  + N_NODES*192)   /* fallback zero-region start */
#define OFF_NV   (OFF_NS  + N_NODES*128)
#define OFF_NMID (OFF_NV  + N_NODES*384)
#define OFF_POOL (OFF_NMID+ N_NODES*128)   /* new-path zero-region start */
#define OFF_CNT  (OFF_POOL+ N_GRAPHS*128)
#define OFF_HIST (OFF_CNT + N_GRAPHS)
#define OFF_CURS (OFF_HIST+ N_NODES)
#define OFF_OFFS (OFF_CURS+ N_NODES)       /* new-path zero-region end (excl) */
#define OFF_FRAG (OFF_OFFS+ N_NODES + 16)  /* MLP weight fragments: 73728 shorts = 36864 floats */
#define OFF_SLOT (OFF_FRAG+ 36864)
#define OFF_WBUF (OFF_SLOT+ N_EDGES)
#define WBUF_FLOATS ((size_t)N_EDGES*256)
#define WS_NEED_BYTES ((size_t)(OFF_WBUF + WBUF_FLOATS) * 4)

// frag sub-offsets in shorts (each B: 2 planes * NF * KS * 512 shorts)
#define F_B1   0        /* conv1 L1: NF4 KS1 -> 4096  */
#define F_B2   4096     /* conv1 L2: NF4 KS2 -> 8192  */
#define F_B3   12288    /* conv1 L3: NF16 KS2 -> 32768 */
#define F_B1b  45056
#define F_B2b  49152
#define F_B3b  57344    /* conv2 L3: NF8 KS2 -> 16384 */

// sc-kernel frag sub-offsets in shorts, within the upper-wbuf frag region
#define NF_WLS 0        /* c1_lin2_s: NF8 KS4 -> 32768 */
#define NF_C1  32768    /* c1_sc:   NF128 KS4 -> 524288 */
#define NF_W2  557056   /* c2_lin2:  NF8 KS4 -> 32768 */
#define NF_C2  589824   /* c2_sc:   NF128 KS2 -> 262144 */

#define NM128 (N_NODES*128)

#define INV_SQRT32   0.17677669529663687f
#define INV_SQRT128  0.08838834764831845f
#define INV_SQRT8    0.3535533905932738f
#define INV_SQRT64   0.125f
#define INV_SQRT2048 0.022097086912079608f
#define INV_SQRT1024 0.03125f
#define INV_SQRT10   0.31622776601683794f
#define INV_SQRT3    0.5773502691896258f
#define SQRT3_C      1.7320508075688772f

__device__ __forceinline__ float siluf(float x){ return x / (1.f + __expf(-x)); }
__device__ __forceinline__ float sigf (float x){ return 1.f / (1.f + __expf(-x)); }
__device__ __forceinline__ unsigned short bf16h(float x){
  uint32 u = __float_as_uint(x);
  u += 0x7FFFu + ((u >> 16) & 1u);
  return (unsigned short)(u >> 16);
}
__device__ __forceinline__ float bf2f(unsigned short h){
  return __uint_as_float(((uint32)h) << 16);
}
__device__ __forceinline__ void split8(const float* __restrict__ p, s16x8& hi, s16x8& lo) {
  f32x4 v0 = *(const f32x4*)p;
  f32x4 v1 = *(const f32x4*)(p + 4);
  float vals[8] = {v0[0],v0[1],v0[2],v0[3],v1[0],v1[1],v1[2],v1[3]};
  #pragma unroll
  for (int j = 0; j < 8; ++j) {
    unsigned short hh = bf16h(vals[j]);
    hi[j] = (short)hh;
    lo[j] = (short)bf16h(vals[j] - bf2f(hh));
  }
}

// ---------------- edge geometry: bessel basis + unit vec ----------------
__global__ void k_geom(const float* __restrict__ evec,
                       float* __restrict__ es8, float* __restrict__ shv) {
  int e = blockIdx.x*256 + threadIdx.x;
  if (e >= N_EDGES) return;
  float vx = evec[e*3+0], vy = evec[e*3+1], vz = evec[e*3+2];
  float d  = sqrtf(vx*vx + vy*vy + vz*vz);
  float xs = d - 0.25f;
  bool  in = (xs > 0.f) && (xs < 4.0f);
  float safe = xs > 0.f ? xs : 1.f;
  float amp  = in ? 2.0f/safe : 0.f;
  const float PI4 = 0.7853981633974483f;
  #pragma unroll
  for (int k = 0; k < 8; ++k)
    es8[e*8+k] = amp * sinf((float)(k+1) * PI4 * safe);
  float invd = d > 0.f ? 1.f/d : 1.f;
  shv[e*3+0] = SQRT3_C*vx*invd;
  shv[e*3+1] = SQRT3_C*vy*invd;
  shv[e*3+2] = SQRT3_C*vz*invd;
}

// ---------------- generic rows x K -> rows x 128 linear ----------------
__global__ void k_linear128(const float* __restrict__ A, const float* __restrict__ W,
                            float* __restrict__ O, int K, float scale, int total) {
  int t = blockIdx.x*256 + threadIdx.x;
  if (t >= total) return;
  int n = t >> 7, j = t & 127;
  const float* a = A + n*K;
  float a0=0.f,a1=0.f,a2=0.f,a3=0.f;
  for (int k = 0; k < K; k += 4) {
    a0 += a[k+0]*W[(k+0)*128+j];
    a1 += a[k+1]*W[(k+1)*128+j];
    a2 += a[k+2]*W[(k+2)*128+j];
    a3 += a[k+3]*W[(k+3)*128+j];
  }
  O[t] = (a0+a1+a2+a3)*scale;
}

// ---------------- graph node counts ----------------
__global__ void k_cnt(const int* __restrict__ batch, float* __restrict__ cnt) {
  __shared__ int lc[N_GRAPHS];
  int t = threadIdx.x;
  if (t < N_GRAPHS) lc[t] = 0;
  __syncthreads();
  int i = blockIdx.x*256 + t;
  if (i < N_NODES) atomicAdd(&lc[batch[i]], 1);
  __syncthreads();
  if (t < N_GRAPHS && lc[t] > 0) atomicAdd(&cnt[t], (float)lc[t]);
}

// ---------------- CSR build ----------------
__global__ void k_hist(const int* __restrict__ edst, int* __restrict__ hist) {
  int e = blockIdx.x*256 + threadIdx.x;
  if (e < N_EDGES) atomicAdd(&hist[edst[e]], 1);
}

__global__ void k_scan(const int* __restrict__ hist, int* __restrict__ offs) {
  int lane = threadIdx.x;   // 64 threads
  int run = 0;
  if (lane == 0) offs[0] = 0;
  for (int base = 0; base < N_NODES; base += 64) {
    int idx = base + lane;
    int v = (idx < N_NODES) ? hist[idx] : 0;
    #pragma unroll
    for (int d = 1; d < 64; d <<= 1) {
      int t = __shfl_up(v, d);
      if (lane >= d) v += t;
    }
    if (idx < N_NODES) offs[idx+1] = run + v;
    run += __shfl(v, 63);
  }
}

__global__ void k_slot(const int* __restrict__ edst, const int* __restrict__ offs,
                       int* __restrict__ curs, int* __restrict__ slot) {
  int e = blockIdx.x*256 + threadIdx.x;
  if (e < N_EDGES) {
    int d = edst[e];
    int p = offs[d] + atomicAdd(&curs[d], 1);
    slot[p] = e;
  }
}

// ---------------- weight fragment prep (split bf16, B-fragment order) ----------------
// flat idx: (((p*NF + nf)*KS + ks)*64 + lane)*8 + j ; k = ks*32+(lane>>4)*8+j ; col = nf*16+(lane&15)
__global__ void k_prepw(const float* __restrict__ W, int Keff, int N, int NF, int KS,
                        float scale, short* __restrict__ dst) {
  int total = 1024*NF*KS;
  for (int t = blockIdx.x*256 + threadIdx.x; t < total; t += gridDim.x*256) {
    int j = t & 7;
    int l = (t >> 3) & 63;
    int rest = t >> 9;
    int ks = rest % KS; rest /= KS;
    int nf = rest % NF;
    int p  = rest / NF;
    int k   = ks*32 + (l >> 4)*8 + j;
    int col = nf*16 + (l & 15);
    float v = (k < Keff) ? W[k*N + col]*scale : 0.f;
    unsigned short hi = bf16h(v);
    unsigned short out = hi;
    if (p) out = bf16h(v - bf2f(hi));
    dst[t] = (short)out;
  }
}

// ---------------- fused 3-layer edge MLP via MFMA (split bf16) ----------------
template<int NF3>
__global__ __launch_bounds__(256) void k_mlp(
    const float* __restrict__ es8,
    const short* __restrict__ fb1, const short* __restrict__ fb2,
    const short* __restrict__ fb3, float* __restrict__ wbuf) {
  __shared__ __align__(16) short route[4][4608];   // 4 waves x (64 rows x 72 shorts)
  const int w = threadIdx.x >> 6, l = threadIdx.x & 63;
  const int lrow = l & 15, lhi = l >> 4;
  const int e0 = (blockIdx.x*4 + w)*64;
  short* rt = route[w];

  s16x8 ah1[4], al1[4];
  #pragma unroll
  for (int mt = 0; mt < 4; ++mt) {
    s16x8 h = {0,0,0,0,0,0,0,0}, lo = {0,0,0,0,0,0,0,0};
    if (lhi == 0) {
      const float* ep = es8 + (size_t)(e0 + mt*16 + lrow)*8;
      split8(ep, h, lo);
    }
    ah1[mt] = h; al1[mt] = lo;
  }

  f32x4 acc1[4][4];
  #pragma unroll
  for (int mt = 0; mt < 4; ++mt)
    #pragma unroll
    for (int nf = 0; nf < 4; ++nf) acc1[mt][nf] = (f32x4){0.f,0.f,0.f,0.f};
  #pragma unroll
  for (int nf = 0; nf < 4; ++nf) {
    s16x8 bh = *(const s16x8*)(fb1 + ((0*4 + nf)*1 + 0)*512 + l*8);
    s16x8 bl = *(const s16x8*)(fb1 + ((1*4 + nf)*1 + 0)*512 + l*8);
    #pragma unroll
    for (int mt = 0; mt < 4; ++mt) {
      acc1[mt][nf] = __builtin_amdgcn_mfma_f32_16x16x32_bf16(ah1[mt], bh, acc1[mt][nf], 0,0,0);
      acc1[mt][nf] = __builtin_amdgcn_mfma_f32_16x16x32_bf16(ah1[mt], bl, acc1[mt][nf], 0,0,0);
      acc1[mt][nf] = __builtin_amdgcn_mfma_f32_16x16x32_bf16(al1[mt], bh, acc1[mt][nf], 0,0,0);
    }
  }
  #pragma unroll
  for (int mt = 0; mt < 4; ++mt)
    #pragma unroll
    for (int nf = 0; nf < 4; ++nf)
      #pragma unroll
      for (int r = 0; r < 4; ++r) acc1[mt][nf][r] = siluf(acc1[mt][nf][r]);

  s16x8 ah2[4][2], al2[4][2];
  #pragma unroll
  for (int mt = 0; mt < 4; ++mt)
    #pragma unroll
    for (int nf = 0; nf < 4; ++nf)
      #pragma unroll
      for (int r = 0; r < 4; ++r)
        rt[(mt*16 + lhi*4 + r)*72 + nf*16 + lrow] = (short)bf16h(acc1[mt][nf][r]);
  #pragma unroll
  for (int mt = 0; mt < 4; ++mt)
    #pragma unroll
    for (int ks = 0; ks < 2; ++ks)
      ah2[mt][ks] = *(const s16x8*)&rt[(mt*16 + lrow)*72 + ks*32 + lhi*8];
  #pragma unroll
  for (int mt = 0; mt < 4; ++mt)
    #pragma unroll
    for (int nf = 0; nf < 4; ++nf)
      #pragma unroll
      for (int r = 0; r < 4; ++r) {
        float v = acc1[mt][nf][r];
        unsigned short hh = bf16h(v);
        rt[(mt*16 + lhi*4 + r)*72 + nf*16 + lrow] = (short)bf16h(v - bf2f(hh));
      }
  #pragma unroll
  for (int mt = 0; mt < 4; ++mt)
    #pragma unroll
    for (int ks = 0; ks < 2; ++ks)
      al2[mt][ks] = *(const s16x8*)&rt[(mt*16 + lrow)*72 + ks*32 + lhi*8];

  f32x4 acc2[4][4];
  #pragma unroll
  for (int mt = 0; mt < 4; ++mt)
    #pragma unroll
    for (int nf = 0; nf < 4; ++nf) acc2[mt][nf] = (f32x4){0.f,0.f,0.f,0.f};
  #pragma unroll
  for (int nf = 0; nf < 4; ++nf)
    #pragma unroll
    for (int ks = 0; ks < 2; ++ks) {
      s16x8 bh = *(const s16x8*)(fb2 + ((0*4 + nf)*2 + ks)*512 + l*8);
      s16x8 bl = *(const s16x8*)(fb2 + ((1*4 + nf)*2 + ks)*512 + l*8);
      #pragma unroll
      for (int mt = 0; mt < 4; ++mt) {
        acc2[mt][nf] = __builtin_amdgcn_mfma_f32_16x16x32_bf16(ah2[mt][ks], bh, acc2[mt][nf], 0,0,0);
        acc2[mt][nf] = __builtin_amdgcn_mfma_f32_16x16x32_bf16(ah2[mt][ks], bl, acc2[mt][nf], 0,0,0);
        acc2[mt][nf] = __builtin_amdgcn_mfma_f32_16x16x32_bf16(al2[mt][ks], bh, acc2[mt][nf], 0,0,0);
      }
    }
  #pragma unroll
  for (int mt = 0; mt < 4; ++mt)
    #pragma unroll
    for (int nf = 0; nf < 4; ++nf)
      #pragma unroll
      for (int r = 0; r < 4; ++r) acc2[mt][nf][r] = siluf(acc2[mt][nf][r]);

  s16x8 ah3[4][2], al3[4][2];
  #pragma unroll
  for (int mt = 0; mt < 4; ++mt)
    #pragma unroll
    for (int nf = 0; nf < 4; ++nf)
      #pragma unroll
      for (int r = 0; r < 4; ++r)
        rt[(mt*16 + lhi*4 + r)*72 + nf*16 + lrow] = (short)bf16h(acc2[mt][nf][r]);
  #pragma unroll
  for (int mt = 0; mt < 4; ++mt)
    #pragma unroll
    for (int ks = 0; ks < 2; ++ks)
      ah3[mt][ks] = *(const s16x8*)&rt[(mt*16 + lrow)*72 + ks*32 + lhi*8];
  #pragma unroll
  for (int mt = 0; mt < 4; ++mt)
    #pragma unroll
    for (int nf = 0; nf < 4; ++nf)
      #pragma unroll
      for (int r = 0; r < 4; ++r) {
        float v = acc2[mt][nf][r];
        unsigned short hh = bf16h(v);
        rt[(mt*16 + lhi*4 + r)*72 + nf*16 + lrow] = (short)bf16h(v - bf2f(hh));
      }
  #pragma unroll
  for (int mt = 0; mt < 4; ++mt)
    #pragma unroll
    for (int ks = 0; ks < 2; ++ks)
      al3[mt][ks] = *(const s16x8*)&rt[(mt*16 + lrow)*72 + ks*32 + lhi*8];

  for (int nf3 = 0; nf3 < NF3; ++nf3) {
    f32x4 acc3[4];
    #pragma unroll
    for (int mt = 0; mt < 4; ++mt) acc3[mt] = (f32x4){0.f,0.f,0.f,0.f};
    #pragma unroll
    for (int ks = 0; ks < 2; ++ks) {
      s16x8 bh = *(const s16x8*)(fb3 + ((size_t)(0*NF3 + nf3)*2 + ks)*512 + l*8);
      s16x8 bl = *(const s16x8*)(fb3 + ((size_t)(1*NF3 + nf3)*2 + ks)*512 + l*8);
      #pragma unroll
      for (int mt = 0; mt < 4; ++mt) {
        acc3[mt] = __builtin_amdgcn_mfma_f32_16x16x32_bf16(ah3[mt][ks], bh, acc3[mt], 0,0,0);
        acc3[mt] = __builtin_amdgcn_mfma_f32_16x16x32_bf16(ah3[mt][ks], bl, acc3[mt], 0,0,0);
        acc3[mt] = __builtin_amdgcn_mfma_f32_16x16x32_bf16(al3[mt][ks], bh, acc3[mt], 0,0,0);
      }
    }
    #pragma unroll
    for (int mt = 0; mt < 4; ++mt)
      #pragma unroll
      for (int r = 0; r < 4; ++r)
        wbuf[(size_t)(e0 + mt*16 + lhi*4 + r)*(NF3*16) + nf3*16 + lrow] = acc3[mt][r];
  }
}

// ---------------- dense partial: part_slot = Ad @ Wd (M=10000,K=128,N=128) ----------------
__global__ __launch_bounds__(512, 4) void k_densep(
    const float* __restrict__ Ad, const short* __restrict__ fBd,
    float* __restrict__ pslot) {
  __shared__ __align__(16) short lB[32768];   // 64 KB: 2p x 8nf x 4ks x 512
  const int tid = threadIdx.x;
  const int w = tid >> 6, l = tid & 63;
  const int lrow = l & 15, lhi = l >> 4;
  const int n0 = blockIdx.x*128 + w*16;
  for (int i = tid; i < 4096; i += 512)
    *(s16x8*)&lB[(size_t)i*8] = *(const s16x8*)&fBd[(size_t)i*8];
  s16x8 adh[4], adl[4];
  {
    int row = n0 + lrow; if (row > N_NODES-1) row = N_NODES-1;
    #pragma unroll
    for (int ks = 0; ks < 4; ++ks)
      split8(Ad + (size_t)row*128 + ks*32 + lhi*8, adh[ks], adl[ks]);
  }
  __syncthreads();
  f32x4 acc[8];
  #pragma unroll
  for (int nf = 0; nf < 8; ++nf) acc[nf] = (f32x4){0.f,0.f,0.f,0.f};
  #pragma unroll
  for (int nf = 0; nf < 8; ++nf)
    #pragma unroll
    for (int ks = 0; ks < 4; ++ks) {
      s16x8 bh = *(const s16x8*)&lB[((0*8 + nf)*4 + ks)*512 + l*8];
      s16x8 bl = *(const s16x8*)&lB[((1*8 + nf)*4 + ks)*512 + l*8];
      acc[nf] = __builtin_amdgcn_mfma_f32_16x16x32_bf16(adh[ks], bh, acc[nf], 0,0,0);
      acc[nf] = __builtin_amdgcn_mfma_f32_16x16x32_bf16(adh[ks], bl, acc[nf], 0,0,0);
      acc[nf] = __builtin_amdgcn_mfma_f32_16x16x32_bf16(adl[ks], bh, acc[nf], 0,0,0);
    }
  #pragma unroll
  for (int nf = 0; nf < 8; ++nf)
    #pragma unroll
    for (int r = 0; r < 4; ++r) {
      int row = n0 + lhi*4 + r;
      if (row < N_NODES) pslot[(size_t)row*128 + nf*16 + lrow] = acc[nf][r];
    }
}

// ---------------- sc partial: part[vp] = sum_{v in pair} na[:,v]*(Ao @ C_v) ----------------
// grid: (79 M-tiles of 128 rows, 8 v-pairs); 8 waves/block; LDS chunk shared by all waves.
template<int KSO>
__global__ __launch_bounds__(512, 4) void k_scp(
    const float* __restrict__ Ao,   // outer A (row stride KSO*32)
    const float* __restrict__ na,   // node_attr (row stride 16)
    const short* __restrict__ fBc,  // C frags: 2p x 128nf x KSO x 512
    float* __restrict__ part) {
  __shared__ __align__(16) short lB[KSO*8192];
  const int tid = threadIdx.x;
  const int w = tid >> 6, l = tid & 63;
  const int lrow = l & 15, lhi = l >> 4;
  const int n0 = blockIdx.x*128 + w*16;
  const int vp = blockIdx.y;

  s16x8 aoh[KSO], aol[KSO];
  {
    int row = n0 + lrow; if (row > N_NODES-1) row = N_NODES-1;
    #pragma unroll
    for (int ks = 0; ks < KSO; ++ks)
      split8(Ao + (size_t)row*(KSO*32) + ks*32 + lhi*8, aoh[ks], aol[ks]);
  }

  f32x4 acc[8];
  #pragma unroll
  for (int nf = 0; nf < 8; ++nf) acc[nf] = (f32x4){0.f,0.f,0.f,0.f};

  #pragma unroll
  for (int c = 0; c < 2; ++c) {
    const int v = vp*2 + c;
    __syncthreads();   // prior chunk fully consumed
    for (int i = tid; i < KSO*1024; i += 512) {
      int gl = i & 63;
      int rest = i >> 6;
      int ks = rest % KSO;
      int rest2 = rest / KSO;      // p*8+nf
      int nf = rest2 & 7;
      int p  = rest2 >> 3;
      size_t src = ((((size_t)p*128 + (v*8 + nf))*KSO + ks)*64 + gl)*8;
      *(s16x8*)&lB[(size_t)i*8] = *(const s16x8*)&fBc[src];
    }
    __syncthreads();
    f32x4 dacc[8];
    #pragma unroll
    for (int nf = 0; nf < 8; ++nf) dacc[nf] = (f32x4){0.f,0.f,0.f,0.f};
    #pragma unroll
    for (int nf = 0; nf < 8; ++nf)
      #pragma unroll
      for (int ks = 0; ks < KSO; ++ks) {
        s16x8 bh = *(const s16x8*)&lB[((0*8 + nf)*KSO + ks)*512 + l*8];
        s16x8 bl = *(const s16x8*)&lB[((1*8 + nf)*KSO + ks)*512 + l*8];
        dacc[nf] = __builtin_amdgcn_mfma_f32_16x16x32_bf16(aoh[ks], bh, dacc[nf], 0,0,0);
        dacc[nf] = __builtin_amdgcn_mfma_f32_16x16x32_bf16(aoh[ks], bl, dacc[nf], 0,0,0);
        dacc[nf] = __builtin_amdgcn_mfma_f32_16x16x32_bf16(aol[ks], bh, dacc[nf], 0,0,0);
      }
    #pragma unroll
    for (int r = 0; r < 4; ++r) {
      int row = n0 + lhi*4 + r; if (row > N_NODES-1) row = N_NODES-1;
      float nav = na[(size_t)row*16 + v];
      #pragma unroll
      for (int nf = 0; nf < 8; ++nf) acc[nf][r] += nav * dacc[nf][r];
    }
  }

  float* pp = part + (size_t)vp*NM128;
  #pragma unroll
  for (int nf = 0; nf < 8; ++nf)
    #pragma unroll
    for (int r = 0; r < 4; ++r) {
      int row = n0 + lhi*4 + r;
      if (row < N_NODES) pp[(size_t)row*128 + nf*16 + lrow] = acc[nf][r];
    }
}

// ---------------- reduce 9 partials ----------------
__global__ void k_reduce(const float* __restrict__ part, float* __restrict__ outs) {
  int i = blockIdx.x*256 + threadIdx.x;
  if (i >= NM128) return;
  float s = 0.f;
  #pragma unroll
  for (int p = 0; p < 9; ++p) s += part[(size_t)p*NM128 + i];
  outs[i] = s;
}

// ---------------- conv1 gather: CSR pull, no atomics ----------------
__global__ __launch_bounds__(256) void k_gather1(
    const float* __restrict__ wbuf, const float* __restrict__ shv,
    const int* __restrict__ esrc, const int* __restrict__ offs, const int* __restrict__ slot,
    const float* __restrict__ h,
    float* __restrict__ n_s, float* __restrict__ n_v) {
  const int wave = threadIdx.x >> 6, lane = threadIdx.x & 63;
  const int n = blockIdx.x*4 + wave;
  if (n >= N_NODES) return;
  const int s0 = offs[n], s1 = offs[n+1];
  float ns0=0.f, ns1=0.f;
  float nv00=0.f,nv01=0.f,nv02=0.f, nv10=0.f,nv11=0.f,nv12=0.f;
  for (int s = s0; s < s1; ++s) {
    int e = slot[s];
    int src = esrc[e];
    const float* wp = wbuf + (size_t)e*256;
    float c0 = wp[lane], c1 = wp[64+lane], c2 = wp[128+lane], c3 = wp[192+lane];
    float h0 = h[src*128+lane], h1 = h[src*128+64+lane];
    float sv0 = shv[e*3+0], sv1 = shv[e*3+1], sv2 = shv[e*3+2];
    ns0 += c0*h0; ns1 += c1*h1;
    float t0 = c2*h0, t1 = c3*h1;
    nv00 += t0*sv0; nv01 += t0*sv1; nv02 += t0*sv2;
    nv10 += t1*sv0; nv11 += t1*sv1; nv12 += t1*sv2;
  }
  n_s[n*128+lane]    = ns0*INV_SQRT10;
  n_s[n*128+64+lane] = ns1*INV_SQRT10;
  float* nvp = n_v + n*384;
  nvp[lane*3+0] = nv00*INV_SQRT10; nvp[lane*3+1] = nv01*INV_SQRT10; nvp[lane*3+2] = nv02*INV_SQRT10;
  nvp[(64+lane)*3+0] = nv10*INV_SQRT10; nvp[(64+lane)*3+1] = nv11*INV_SQRT10; nvp[(64+lane)*3+2] = nv12*INV_SQRT10;
}

// ---------------- conv2 gather: CSR pull, no atomics ----------------
__global__ __launch_bounds__(256) void k_gather2(
    const float* __restrict__ wbuf, const float* __restrict__ shv,
    const int* __restrict__ esrc, const int* __restrict__ offs, const int* __restrict__ slot,
    const float* __restrict__ h_s, const float* __restrict__ h_v,
    float* __restrict__ n_mid) {
  const int wave = threadIdx.x >> 6, lane = threadIdx.x & 63;
  const int n = blockIdx.x*4 + wave;
  if (n >= N_NODES) return;
  const int s0 = offs[n], s1 = offs[n+1];
  float acc0 = 0.f, acc1 = 0.f;
  for (int s = s0; s < s1; ++s) {
    int e = slot[s];
    int src = esrc[e];
    const float* wp = wbuf + (size_t)e*128;
    float w0 = wp[lane], w1 = wp[64+lane];
    float hs = h_s[src*64+lane];
    const float* hvp = h_v + src*192 + lane*3;
    float sv0 = shv[e*3+0], sv1 = shv[e*3+1], sv2 = shv[e*3+2];
    float dot = hvp[0]*sv0 + hvp[1]*sv1 + hvp[2]*sv2;
    acc0 += w0*hs;
    acc1 += w1*dot;
  }
  n_mid[n*128+lane]    = acc0*INV_SQRT10;
  n_mid[n*128+64+lane] = acc1*INV_SQRT3*INV_SQRT10;
}

// ---------------- gate pass: out_v, gating, h_s, h_v (reads precomputed outs) ----------------
__global__ __launch_bounds__(128) void k_gate1(
    const float* __restrict__ outs, const float* __restrict__ n_v,
    const float* __restrict__ Wlv, const float* __restrict__ W2s, const float* __restrict__ W2v,
    float* __restrict__ gs_out, float* __restrict__ hs_out, float* __restrict__ hv_out) {
  __shared__ float l_outs[512], l_nv[1536];
  __shared__ float l_ov[768], l_gs[256], l_gv[768];
  const int j = threadIdx.x;
  const int n0 = blockIdx.x*4;
  for (int i = j; i < 512;  i += 128) l_outs[i] = outs[(size_t)n0*128 + i];
  for (int i = j; i < 1536; i += 128) l_nv[i] = n_v[n0*384+i];
  __syncthreads();

  const int jj = j & 63, hh = j >> 6;
  float ov[2][3] = {{0.f,0.f,0.f},{0.f,0.f,0.f}};
  for (int u = 0; u < 128; ++u) {
    float w = Wlv[u*64+jj];
    #pragma unroll
    for (int t = 0; t < 2; ++t) {
      int n = 2*hh+t;
      ov[t][0] += l_nv[n*384+u*3+0]*w;
      ov[t][1] += l_nv[n*384+u*3+1]*w;
      ov[t][2] += l_nv[n*384+u*3+2]*w;
    }
  }
  #pragma unroll
  for (int t = 0; t < 2; ++t) {
    int n = 2*hh+t;
    l_ov[n*192+jj*3+0] = ov[t][0]*INV_SQRT128;
    l_ov[n*192+jj*3+1] = ov[t][1]*INV_SQRT128;
    l_ov[n*192+jj*3+2] = ov[t][2]*INV_SQRT128;
  }
  __syncthreads();

  #pragma unroll
  for (int t = 0; t < 2; ++t) {
    int n = 2*hh+t;
    float gv_s = siluf(l_outs[n*128+jj]);
    float gate = sigf (l_outs[n*128+64+jj]);
    l_gs[n*64+jj] = gv_s;
    gs_out[(n0+n)*64+jj] = gv_s;
    l_gv[n*192+jj*3+0] = gate*l_ov[n*192+jj*3+0];
    l_gv[n*192+jj*3+1] = gate*l_ov[n*192+jj*3+1];
    l_gv[n*192+jj*3+2] = gate*l_ov[n*192+jj*3+2];
  }
  __syncthreads();

  float ha[2] = {0.f,0.f};
  for (int k = 0; k < 64; ++k) {
    float w = W2s[k*64+jj];
    ha[0] += l_gs[(2*hh+0)*64+k]*w;
    ha[1] += l_gs[(2*hh+1)*64+k]*w;
  }
  hs_out[(n0+2*hh+0)*64+jj] = ha[0]*INV_SQRT64;
  hs_out[(n0+2*hh+1)*64+jj] = ha[1]*INV_SQRT64;

  float hv[2][3] = {{0.f,0.f,0.f},{0.f,0.f,0.f}};
  for (int u = 0; u < 64; ++u) {
    float w = W2v[u*64+jj];
    #pragma unroll
    for (int t = 0; t < 2; ++t) {
      int n = 2*hh+t;
      hv[t][0] += l_gv[n*192+u*3+0]*w;
      hv[t][1] += l_gv[n*192+u*3+1]*w;
      hv[t][2] += l_gv[n*192+u*3+2]*w;
    }
  }
  #pragma unroll
  for (int t = 0; t < 2; ++t) {
    int n = 2*hh+t;
    hv_out[(n0+n)*192+jj*3+0] = hv[t][0]*INV_SQRT64;
    hv_out[(n0+n)*192+jj*3+1] = hv[t][1]*INV_SQRT64;
    hv_out[(n0+n)*192+jj*3+2] = hv[t][2]*INV_SQRT64;
  }
}

// ---------------- pooled accumulation (RLE on sorted batch) ----------------
__global__ __launch_bounds__(128) void k_pool(
    const float* __restrict__ outs, const int* __restrict__ batch,
    float* __restrict__ pool) {
  const int j = threadIdx.x;
  const int n0 = blockIdx.x*4;
  float outv[4];
  #pragma unroll
  for (int n = 0; n < 4; ++n) outv[n] = outs[(size_t)(n0+n)*128 + j];
  int b0 = batch[n0], b1 = batch[n0+1], b2 = batch[n0+2], b3 = batch[n0+3];
  float sum = outv[0]; int cur = b0;
  if (b1 == cur) sum += outv[1]; else { atomicAdd(&pool[cur*128+j], sum); cur = b1; sum = outv[1]; }
  if (b2 == cur) sum += outv[2]; else { atomicAdd(&pool[cur*128+j], sum); cur = b2; sum = outv[2]; }
  if (b3 == cur) sum += outv[3]; else { atomicAdd(&pool[cur*128+j], sum); cur = b3; sum = outv[3]; }
  atomicAdd(&pool[cur*128+j], sum);
}

// ======== FALLBACK (atomic) kernels — used only if ws too small ========
__global__ __launch_bounds__(512) void k_edge1_at(
    const float* __restrict__ es8, const float* __restrict__ shv,
    const int* __restrict__ esrc, const int* __restrict__ edst,
    const float* __restrict__ h,
    const float* __restrict__ W0, const float* __restrict__ W1, const float* __restrict__ W2,
    float* __restrict__ n_s, float* __restrict__ n_v) {
  __shared__ float lW0[512];
  __shared__ float lW1[4096];
  __shared__ float lW2[16384];
  __shared__ float lA[8][64];
  __shared__ float lB[8][64];
  for (int i = threadIdx.x; i < 512;   i += 512) lW0[i] = W0[i];
  for (int i = threadIdx.x; i < 4096;  i += 512) lW1[i] = W1[i];
  for (int i = threadIdx.x; i < 16384; i += 512) lW2[i] = W2[i];
  __syncthreads();
  const int wave = threadIdx.x >> 6, lane = threadIdx.x & 63;
  const int nw = gridDim.x * 8;
  const int e0 = blockIdx.x*8 + wave;
  const int iters = (N_EDGES + nw - 1) / nw;
  for (int it = 0; it < iters; ++it) {
    int e = e0 + it*nw;
    bool valid = e < N_EDGES;
    float a = 0.f, sv0=0.f, sv1=0.f, sv2=0.f;
    int src = 0, dst = 0;
    if (valid) {
      const float* ep = es8 + e*8;
      sv0 = shv[e*3+0]; sv1 = shv[e*3+1]; sv2 = shv[e*3+2];
      src = esrc[e]; dst = edst[e];
      a = ep[0]*lW0[lane]      + ep[1]*lW0[64+lane]  + ep[2]*lW0[128+lane] + ep[3]*lW0[192+lane]
        + ep[4]*lW0[256+lane]  + ep[5]*lW0[320+lane] + ep[6]*lW0[384+lane] + ep[7]*lW0[448+lane];
      a = siluf(a * INV_SQRT8);
    }
    lA[wave][lane] = a;
    __syncthreads();
    {
      float b0=0.f;
      #pragma unroll
      for (int k = 0; k < 64; ++k) b0 += lA[wave][k]*lW1[k*64+lane];
      lB[wave][lane] = siluf(b0 * INV_SQRT64);
    }
    __syncthreads();
    if (valid) {
      float c0=0.f,c1=0.f,c2=0.f,c3=0.f;
      #pragma unroll
      for (int k = 0; k < 64; ++k) {
        float bk = lB[wave][k];
        const float* r = lW2 + k*256;
        c0 += bk*r[lane]; c1 += bk*r[64+lane]; c2 += bk*r[128+lane]; c3 += bk*r[192+lane];
      }
      float hs0 = h[src*128 + lane];
      float hs1 = h[src*128 + 64 + lane];
      atomicAdd(&n_s[dst*128 + lane],      c0*INV_SQRT64*hs0*INV_SQRT10);
      atomicAdd(&n_s[dst*128 + 64 + lane], c1*INV_SQRT64*hs1*INV_SQRT10);
      float t0 = c2*INV_SQRT64*hs0*INV_SQRT10;
      float t1 = c3*INV_SQRT64*hs1*INV_SQRT10;
      float* nvp = n_v + dst*384;
      atomicAdd(nvp + lane*3+0, t0*sv0);
      atomicAdd(nvp + lane*3+1, t0*sv1);
      atomicAdd(nvp + lane*3+2, t0*sv2);
      atomicAdd(nvp + (64+lane)*3+0, t1*sv0);
      atomicAdd(nvp + (64+lane)*3+1, t1*sv1);
      atomicAdd(nvp + (64+lane)*3+2, t1*sv2);
    }
  }
}

__global__ __launch_bounds__(512) void k_edge2_at(
    const float* __restrict__ es8, const float* __restrict__ shv,
    const int* __restrict__ esrc, const int* __restrict__ edst,
    const float* __restrict__ h_s, const float* __restrict__ h_v,
    const float* __restrict__ W0, const float* __restrict__ W1, const float* __restrict__ W2,
    float* __restrict__ n_mid) {
  __shared__ float lW0[512];
  __shared__ float lW1[4096];
  __shared__ float lW2[8192];
  __shared__ float lA[8][64];
  __shared__ float lB[8][64];
  for (int i = threadIdx.x; i < 512;  i += 512) lW0[i] = W0[i];
  for (int i = threadIdx.x; i < 4096; i += 512) lW1[i] = W1[i];
  for (int i = threadIdx.x; i < 8192; i += 512) lW2[i] = W2[i];
  __syncthreads();
  const int wave = threadIdx.x >> 6, lane = threadIdx.x & 63;
  const int nw = gridDim.x * 8;
  const int e0 = blockIdx.x*8 + wave;
  const int iters = (N_EDGES + nw - 1) / nw;
  for (int it = 0; it < iters; ++it) {
    int e = e0 + it*nw;
    bool valid = e < N_EDGES;
    float a = 0.f, sv0=0.f, sv1=0.f, sv2=0.f;
    int src = 0, dst = 0;
    if (valid) {
      const float* ep = es8 + e*8;
      sv0 = shv[e*3+0]; sv1 = shv[e*3+1]; sv2 = shv[e*3+2];
      src = esrc[e]; dst = edst[e];
      a = ep[0]*lW0[lane]      + ep[1]*lW0[64+lane]  + ep[2]*lW0[128+lane] + ep[3]*lW0[192+lane]
        + ep[4]*lW0[256+lane]  + ep[5]*lW0[320+lane] + ep[6]*lW0[384+lane] + ep[7]*lW0[448+lane];
      a = siluf(a * INV_SQRT8);
    }
    lA[wave][lane] = a;
    __syncthreads();
    {
      float b0=0.f;
      #pragma unroll
      for (int k = 0; k < 64; ++k) b0 += lA[wave][k]*lW1[k*64+lane];
      lB[wave][lane] = siluf(b0 * INV_SQRT64);
    }
    __syncthreads();
    if (valid) {
      float c0=0.f, c1=0.f;
      #pragma unroll
      for (int k = 0; k < 64; ++k) {
        float bk = lB[wave][k];
        const float* r = lW2 + k*128;
        c0 += bk*r[lane]; c1 += bk*r[64+lane];
      }
      float hsv = h_s[src*64 + lane];
      const float* hvp = h_v + src*192 + lane*3;
      float dotv = hvp[0]*sv0 + hvp[1]*sv1 + hvp[2]*sv2;
      atomicAdd(&n_mid[dst*128 + lane],      c0*INV_SQRT64*hsv*INV_SQRT10);
      atomicAdd(&n_mid[dst*128 + 64 + lane], c1*INV_SQRT64*dotv*INV_SQRT3*INV_SQRT10);
    }
  }
}

// ---------------- FALLBACK conv1 node pass (full) ----------------
__global__ __launch_bounds__(128) void k_node1(
    const float* __restrict__ n_s, const float* __restrict__ n_v,
    const float* __restrict__ s,   const float* __restrict__ na,
    const float* __restrict__ Wls, const float* __restrict__ Wlv,
    const float* __restrict__ Csc, const float* __restrict__ W2s, const float* __restrict__ W2v,
    float* __restrict__ gs_out, float* __restrict__ hs_out, float* __restrict__ hv_out) {
  __shared__ float l_ns[512], l_s[512], l_na[64], l_nv[1536];
  __shared__ float l_outs[512], l_ov[768], l_gs[256], l_gv[768];
  const int j = threadIdx.x;
  const int n0 = blockIdx.x*4;
  for (int i = j; i < 512;  i += 128) { l_ns[i] = n_s[n0*128+i]; l_s[i] = s[n0*128+i]; }
  for (int i = j; i < 1536; i += 128) l_nv[i] = n_v[n0*384+i];
  if (j < 64) l_na[j] = na[n0*16+j];
  __syncthreads();

  float accs[4] = {0.f,0.f,0.f,0.f};
  for (int k = 0; k < 128; ++k) {
    float w = Wls[k*128+j];
    accs[0] += l_ns[k]*w; accs[1] += l_ns[128+k]*w;
    accs[2] += l_ns[256+k]*w; accs[3] += l_ns[384+k]*w;
  }
  float accc[4] = {0.f,0.f,0.f,0.f};
  for (int vt = 0; vt < 16; vt += 4) {
    float a0[4],a1[4],a2[4],a3[4];
    #pragma unroll
    for (int n = 0; n < 4; ++n) {
      a0[n]=l_na[n*16+vt]; a1[n]=l_na[n*16+vt+1];
      a2[n]=l_na[n*16+vt+2]; a3[n]=l_na[n*16+vt+3];
    }
    for (int u = 0; u < 128; ++u) {
      const float* cp = Csc + (u*16+vt)*128 + j;
      float c0=cp[0], c1=cp[128], c2=cp[256], c3=cp[384];
      float s0=l_s[u], s1=l_s[128+u], s2=l_s[256+u], s3=l_s[384+u];
      accc[0] += s0*(a0[0]*c0 + a1[0]*c1 + a2[0]*c2 + a3[0]*c3);
      accc[1] += s1*(a0[1]*c0 + a1[1]*c1 + a2[1]*c2 + a3[1]*c3);
      accc[2] += s2*(a0[2]*c0 + a1[2]*c1 + a2[2]*c2 + a3[2]*c3);
      accc[3] += s3*(a0[3]*c0 + a1[3]*c1 + a2[3]*c2 + a3[3]*c3);
    }
  }
  #pragma unroll
  for (int n = 0; n < 4; ++n)
    l_outs[n*128+j] = accs[n]*INV_SQRT128 + accc[n]*INV_SQRT2048;

  const int jj = j & 63, hh = j >> 6;
  float ov[2][3] = {{0.f,0.f,0.f},{0.f,0.f,0.f}};
  for (int u = 0; u < 128; ++u) {
    float w = Wlv[u*64+jj];
    #pragma unroll
    for (int t = 0; t < 2; ++t) {
      int n = 2*hh+t;
      ov[t][0] += l_nv[n*384+u*3+0]*w;
      ov[t][1] += l_nv[n*384+u*3+1]*w;
      ov[t][2] += l_nv[n*384+u*3+2]*w;
    }
  }
  #pragma unroll
  for (int t = 0; t < 2; ++t) {
    int n = 2*hh+t;
    l_ov[n*192+jj*3+0] = ov[t][0]*INV_SQRT128;
    l_ov[n*192+jj*3+1] = ov[t][1]*INV_SQRT128;
    l_ov[n*192+jj*3+2] = ov[t][2]*INV_SQRT128;
  }
  __syncthreads();

  #pragma unroll
  for (int t = 0; t < 2; ++t) {
    int n = 2*hh+t;
    float gv_s = siluf(l_outs[n*128+jj]);
    float gate = sigf (l_outs[n*128+64+jj]);
    l_gs[n*64+jj] = gv_s;
    gs_out[(n0+n)*64+jj] = gv_s;
    l_gv[n*192+jj*3+0] = gate*l_ov[n*192+jj*3+0];
    l_gv[n*192+jj*3+1] = gate*l_ov[n*192+jj*3+1];
    l_gv[n*192+jj*3+2] = gate*l_ov[n*192+jj*3+2];
  }
  __syncthreads();

  float ha[2] = {0.f,0.f};
  for (int k = 0; k < 64; ++k) {
    float w = W2s[k*64+jj];
    ha[0] += l_gs[(2*hh+0)*64+k]*w;
    ha[1] += l_gs[(2*hh+1)*64+k]*w;
  }
  hs_out[(n0+2*hh+0)*64+jj] = ha[0]*INV_SQRT64;
  hs_out[(n0+2*hh+1)*64+jj] = ha[1]*INV_SQRT64;

  float hv[2][3] = {{0.f,0.f,0.f},{0.f,0.f,0.f}};
  for (int u = 0; u < 64; ++u) {
    float w = W2v[u*64+jj];
    #pragma unroll
    for (int t = 0; t < 2; ++t) {
      int n = 2*hh+t;
      hv[t][0] += l_gv[n*192+u*3+0]*w;
      hv[t][1] += l_gv[n*192+u*3+1]*w;
      hv[t][2] += l_gv[n*192+u*3+2]*w;
    }
  }
  #pragma unroll
  for (int t = 0; t < 2; ++t) {
    int n = 2*hh+t;
    hv_out[(n0+n)*192+jj*3+0] = hv[t][0]*INV_SQRT64;
    hv_out[(n0+n)*192+jj*3+1] = hv[t][1]*INV_SQRT64;
    hv_out[(n0+n)*192+jj*3+2] = hv[t][2]*INV_SQRT64;
  }
}

// ---------------- FALLBACK conv2 node pass + pooling ----------------
__global__ __launch_bounds__(128) void k_node2(
    const float* __restrict__ n_mid, const float* __restrict__ gs,
    const float* __restrict__ na, const int* __restrict__ batch,
    const float* __restrict__ W, const float* __restrict__ Csc,
    float* __restrict__ pool) {
  __shared__ float l_nm[512], l_gs[256], l_na[64];
  const int j = threadIdx.x;
  const int n0 = blockIdx.x*4;
  for (int i = j; i < 512; i += 128) l_nm[i] = n_mid[n0*128+i];
  for (int i = j; i < 256; i += 128) l_gs[i] = gs[n0*64+i];
  if (j < 64) l_na[j] = na[n0*16+j];
  __syncthreads();
  float acc[4] = {0.f,0.f,0.f,0.f};
  for (int k = 0; k < 128; ++k) {
    float w = W[k*128+j];
    acc[0] += l_nm[k]*w; acc[1] += l_nm[128+k]*w;
    acc[2] += l_nm[256+k]*w; acc[3] += l_nm[384+k]*w;
  }
  float acc2[4] = {0.f,0.f,0.f,0.f};
  for (int vt = 0; vt < 16; vt += 4) {
    float a0[4],a1[4],a2[4],a3[4];
    #pragma unroll
    for (int n = 0; n < 4; ++n) {
      a0[n]=l_na[n*16+vt]; a1[n]=l_na[n*16+vt+1];
      a2[n]=l_na[n*16+vt+2]; a3[n]=l_na[n*16+vt+3];
    }
    for (int u = 0; u < 64; ++u) {
      const float* cp = Csc + (u*16+vt)*128 + j;
      float c0=cp[0], c1=cp[128], c2=cp[256], c3=cp[384];
      float s0=l_gs[u], s1=l_gs[64+u], s2=l_gs[128+u], s3=l_gs[192+u];
      acc2[0] += s0*(a0[0]*c0 + a1[0]*c1 + a2[0]*c2 + a3[0]*c3);
      acc2[1] += s1*(a0[1]*c0 + a1[1]*c1 + a2[1]*c2 + a3[1]*c3);
      acc2[2] += s2*(a0[2]*c0 + a1[2]*c1 + a2[2]*c2 + a3[2]*c3);
      acc2[3] += s3*(a0[3]*c0 + a1[3]*c1 + a2[3]*c2 + a3[3]*c3);
    }
  }
  float outv[4];
  #pragma unroll
  for (int n = 0; n < 4; ++n)
    outv[n] = acc[n]*INV_SQRT128 + acc2[n]*INV_SQRT1024;
  int b0 = batch[n0], b1 = batch[n0+1], b2 = batch[n0+2], b3 = batch[n0+3];
  float sum = outv[0]; int cur = b0;
  if (b1 == cur) sum += outv[1]; else { atomicAdd(&pool[cur*128+j], sum); cur = b1; sum = outv[1]; }
  if (b2 == cur) sum += outv[2]; else { atomicAdd(&pool[cur*128+j], sum); cur = b2; sum = outv[2]; }
  if (b3 == cur) sum += outv[3]; else { atomicAdd(&pool[cur*128+j], sum); cur = b3; sum = outv[3]; }
  atomicAdd(&pool[cur*128+j], sum);
}

// ---------------- readout head ----------------
__global__ __launch_bounds__(128) void k_head(
    const float* __restrict__ pool, const float* __restrict__ cnt,
    const float* __restrict__ Wr1, const float* __restrict__ Wr2,
    float* __restrict__ out) {
  __shared__ float lp[128];
  __shared__ float lt[128];
  const int j = threadIdx.x;
  for (int g = 0; g < N_GRAPHS; ++g) {
    float inv = 1.f / fmaxf(cnt[g], 1.f);
    lp[j] = pool[g*128+j]*inv;
    __syncthreads();
    float acc = 0.f;
    for (int k = 0; k < 128; ++k) acc += lp[k]*Wr1[k*128+j];
    lt[j] = siluf(acc*INV_SQRT128) * Wr2[j];
    __syncthreads();
    if (j == 0) {
      float ssum = 0.f;
      for (int k = 0; k < 128; ++k) ssum += lt[k];
      out[g] = ssum*INV_SQRT128;
    }
    __syncthreads();
  }
}

extern "C" void kernel_launch(void* const* d_in, const int* in_sizes, int n_in,
                              void* d_out, int out_size, void* d_ws, size_t ws_size,
                              hipStream_t stream) {
  const float* x         = (const float*)d_in[0];
  const float* node_attr = (const float*)d_in[1];
  const int*   esrc      = (const int*)d_in[2];
  const int*   edst      = (const int*)d_in[3];
  const float* evec      = (const float*)d_in[4];
  const int*   batch     = (const int*)d_in[5];
  const float* W_embed   = (const float*)d_in[6];
  const float* c1_lin1   = (const float*)d_in[7];
  const float* c1_fc_w0  = (const float*)d_in[8];
  const float* c1_fc_w1  = (const float*)d_in[9];
  const float* c1_fc_w2  = (const float*)d_in[10];
  const float* c1_lin2_s = (const float*)d_in[11];
  const float* c1_lin2_v = (const float*)d_in[12];
  const float* c1_sc     = (const float*)d_in[13];
  const float* c2_lin1_s = (const float*)d_in[14];
  const float* c2_lin1_v = (const float*)d_in[15];
  const float* c2_fc_w0  = (const float*)d_in[16];
  const float* c2_fc_w1  = (const float*)d_in[17];
  const float* c2_fc_w2  = (const float*)d_in[18];
  const float* c2_lin2   = (const float*)d_in[19];
  const float* c2_sc     = (const float*)d_in[20];
  const float* Wr1       = (const float*)d_in[21];
  const float* Wr2       = (const float*)d_in[22];

  float* ws    = (float*)d_ws;
  float* es8   = ws + OFF_ES8;
  float* shv   = ws + OFF_SHV;
  float* s_    = ws + OFF_S;
  float* h_    = ws + OFF_H;
  float* gs_   = ws + OFF_GS;
  float* hs_   = ws + OFF_HS;
  float* hv_   = ws + OFF_HV;
  float* ns_   = ws + OFF_NS;
  float* nv_   = ws + OFF_NV;
  float* nmid_ = ws + OFF_NMID;
  float* pool_ = ws + OFF_POOL;
  float* cnt_  = ws + OFF_CNT;
  int*   hist_ = (int*)(ws + OFF_HIST);
  int*   curs_ = (int*)(ws + OFF_CURS);
  int*   offs_ = (int*)(ws + OFF_OFFS);
  short* frag_ = (short*)(ws + OFF_FRAG);
  int*   slot_ = (int*)(ws + OFF_SLOT);
  float* wbuf_ = ws + OFF_WBUF;

  // regions carved out of the upper half of wbuf (dead after k_gather1;
  // k_mlp<8> writes only the lower N_EDGES*128 floats):
  float* out1_  = wbuf_ + (size_t)N_EDGES*128;               // 1.28M floats
  short* nfrag_ = (short*)(out1_ + (size_t)NM128);           // 851968 shorts
  float* part_  = out1_ + (size_t)NM128 + 425984;            // 9 x 1.28M floats
  float* out2_  = ns_;                                       // ns dead after conv1 densep

  const bool big = ws_size >= WS_NEED_BYTES;

  k_geom<<<N_EDGES/256, 256, 0, stream>>>(evec, es8, shv);
  k_linear128<<<(N_NODES*128)/256, 256, 0, stream>>>(x,  W_embed, s_, 32,  INV_SQRT32,  N_NODES*128);
  k_linear128<<<(N_NODES*128)/256, 256, 0, stream>>>(s_, c1_lin1, h_, 128, INV_SQRT128, N_NODES*128);

  if (big) {
    hipMemsetAsync(pool_, 0, (size_t)(OFF_OFFS - OFF_POOL)*sizeof(float), stream);
    k_cnt<<<(N_NODES+255)/256, 256, 0, stream>>>(batch, cnt_);
    k_hist<<<(N_EDGES+255)/256, 256, 0, stream>>>(edst, hist_);
    k_scan<<<1, 64, 0, stream>>>(hist_, offs_);
    k_slot<<<(N_EDGES+255)/256, 256, 0, stream>>>(edst, offs_, curs_, slot_);
    // MLP weight frags (persistent region)
    k_prepw<<<16, 256, 0, stream>>>(c1_fc_w0, 8, 64, 4, 1, INV_SQRT8,  frag_ + F_B1);
    k_prepw<<<32, 256, 0, stream>>>(c1_fc_w1, 64, 64, 4, 2, INV_SQRT64, frag_ + F_B2);
    k_prepw<<<128,256, 0, stream>>>(c1_fc_w2, 64, 256, 16, 2, INV_SQRT64, frag_ + F_B3);
    k_prepw<<<16, 256, 0, stream>>>(c2_fc_w0, 8, 64, 4, 1, INV_SQRT8,  frag_ + F_B1b);
    k_prepw<<<32, 256, 0, stream>>>(c2_fc_w1, 64, 64, 4, 2, INV_SQRT64, frag_ + F_B2b);
    k_prepw<<<64, 256, 0, stream>>>(c2_fc_w2, 64, 128, 8, 2, INV_SQRT64, frag_ + F_B3b);
    // conv1 edge MLP + gather
    k_mlp<16><<<625, 256, 0, stream>>>(es8, frag_ + F_B1, frag_ + F_B2, frag_ + F_B3, wbuf_);
    k_gather1<<<(N_NODES+3)/4, 256, 0, stream>>>(wbuf_, shv, esrc, offs_, slot_, h_, ns_, nv_);
    // sc/dense weight frags (upper-wbuf region, free after gather1)
    k_prepw<<<32, 256, 0, stream>>>(c1_lin2_s, 128, 128, 8, 4, INV_SQRT128, nfrag_ + NF_WLS);
    k_prepw<<<512,256, 0, stream>>>(c1_sc, 128, 2048, 128, 4, INV_SQRT2048, nfrag_ + NF_C1);
    k_prepw<<<32, 256, 0, stream>>>(c2_lin2, 128, 128, 8, 4, INV_SQRT128, nfrag_ + NF_W2);
    k_prepw<<<256,256, 0, stream>>>(c2_sc, 64, 2048, 128, 2, INV_SQRT1024, nfrag_ + NF_C2);
    // conv1 node: partials (dense slot 8 + 8 v-pair slots) -> reduce -> gate
    k_densep<<<79, 512, 0, stream>>>(ns_, nfrag_ + NF_WLS, part_ + (size_t)8*NM128);
    k_scp<4><<<dim3(79,8), 512, 0, stream>>>(s_, node_attr, nfrag_ + NF_C1, part_);
    k_reduce<<<(NM128+255)/256, 256, 0, stream>>>(part_, out1_);
    k_gate1<<<N_NODES/4, 128, 0, stream>>>(out1_, nv_, c1_lin2_v, c2_lin1_s, c2_lin1_v,
                                           gs_, hs_, hv_);
    // conv2 edge MLP + gather (lower wbuf only)
    k_mlp<8><<<625, 256, 0, stream>>>(es8, frag_ + F_B1b, frag_ + F_B2b, frag_ + F_B3b, wbuf_);
    k_gather2<<<(N_NODES+3)/4, 256, 0, stream>>>(wbuf_, shv, esrc, offs_, slot_, hs_, hv_, nmid_);
    // conv2 node: partials -> reduce -> pool
    k_densep<<<79, 512, 0, stream>>>(nmid_, nfrag_ + NF_W2, part_ + (size_t)8*NM128);
    k_scp<2><<<dim3(79,8), 512, 0, stream>>>(gs_, node_attr, nfrag_ + NF_C2, part_);
    k_reduce<<<(NM128+255)/256, 256, 0, stream>>>(part_, out2_);
    k_pool<<<N_NODES/4, 128, 0, stream>>>(out2_, batch, pool_);
  } else {
    hipMemsetAsync(ns_, 0, (size_t)(OFF_HIST - OFF_NS)*sizeof(float), stream);
    k_cnt<<<(N_NODES+255)/256, 256, 0, stream>>>(batch, cnt_);
    k_edge1_at<<<256, 512, 0, stream>>>(es8, shv, esrc, edst, h_,
                                        c1_fc_w0, c1_fc_w1, c1_fc_w2, ns_, nv_);
    k_node1<<<N_NODES/4, 128, 0, stream>>>(ns_, nv_, s_, node_attr,
                                           c1_lin2_s, c1_lin2_v, c1_sc,
                                           c2_lin1_s, c2_lin1_v, gs_, hs_, hv_);
    k_edge2_at<<<512, 512, 0, stream>>>(es8, shv, esrc, edst, hs_, hv_,
                                        c2_fc_w0, c2_fc_w1, c2_fc_w2, nmid_);
    k_node2<<<N_NODES/4, 128, 0, stream>>>(nmid_, gs_, node_attr, batch,
                                           c2_lin2, c2_sc, pool_);
  }

  k_head<<<1, 128, 0, stream>>>(pool_, cnt_, Wr1, Wr2, (float*)d_out);
}

// Round 6
// 476.707 us; speedup vs baseline: 2.6329x; 1.1941x over previous
//
#include <hip/hip_runtime.h>

#define N_NODES 10000
#define N_EDGES 160000
#define N_GRAPHS 16

typedef __attribute__((ext_vector_type(8))) short s16x8;
typedef __attribute__((ext_vector_type(4))) float f32x4;
typedef unsigned int uint32;

// ---- workspace layout (float offsets) ----
#define OFF_ES8  0
#define OFF_SHV  (OFF_ES8 + N_EDGES*8)
#define OFF_S    (OFF_SHV + N_EDGES*3)
#define OFF_H    (OFF_S   + N_NODES*128)
#define OFF_GS   (OFF_H   + N_NODES*128)
#define OFF_HS   (OFF_GS  + N_NODES*64)
#define OFF_HV   (OFF_HS  + N_NODES*64)
#define OFF_NS   (OFF_HV  + N_NODES*192)   /* fallback zero-region start */
#define OFF_NV   (OFF_NS  + N_NODES*128)
#define OFF_NMID (OFF_NV  + N_NODES*384)
#define OFF_POOL (OFF_NMID+ N_NODES*128)   /* new-path zero-region start */
#define OFF_CNT  (OFF_POOL+ N_GRAPHS*128)
#define OFF_HIST (OFF_CNT + N_GRAPHS)
#define OFF_CURS (OFF_HIST+ N_NODES)
#define OFF_OFFS (OFF_CURS+ N_NODES)       /* new-path zero-region end (excl) */
#define OFF_FRAG (OFF_OFFS+ N_NODES + 16)  /* MLP weight fragments: 73728 shorts */
#define OFF_SLOT (OFF_FRAG+ 36864)
#define OFF_WBUF (OFF_SLOT+ N_EDGES)
#define WBUF_FLOATS ((size_t)N_EDGES*256)
#define WS_NEED_BYTES ((size_t)(OFF_WBUF + WBUF_FLOATS) * 4)

// frag sub-offsets in shorts (each B: 2 planes * NF * KS * 512 shorts)
#define F_B1   0        /* conv1 L1: NF4 KS1 -> 4096  */
#define F_B2   4096     /* conv1 L2: NF4 KS2 -> 8192  */
#define F_B3   12288    /* conv1 L3: NF16 KS2 -> 32768 */
#define F_B1b  45056
#define F_B2b  49152
#define F_B3b  57344    /* conv2 L3: NF8 KS2 -> 16384 */

// node-frag sub-offsets in shorts, within the upper-wbuf nfrag region
#define NF_WLS 0        /* c1_lin2_s: NF8 KS4 -> 32768 */
#define NF_C1  32768    /* c1_sc:   NF128 KS4 -> 524288 */
#define NF_W2  557056   /* c2_lin2:  NF8 KS4 -> 32768 */
#define NF_C2  589824   /* c2_sc:   NF128 KS2 -> 262144 */
#define NF_LV  851968   /* c1_lin2_v: NF4 KS4 -> 16384 */
#define NF_2S  868352   /* c2_lin1_s: NF4 KS2 -> 8192 */
#define NF_2V  876544   /* c2_lin1_v: NF4 KS2 -> 8192 */
#define NFRAG_TOT 884736

#define NM128 (N_NODES*128)

#define INV_SQRT32   0.17677669529663687f
#define INV_SQRT128  0.08838834764831845f
#define INV_SQRT8    0.3535533905932738f
#define INV_SQRT64   0.125f
#define INV_SQRT2048 0.022097086912079608f
#define INV_SQRT1024 0.03125f
#define INV_SQRT10   0.31622776601683794f
#define INV_SQRT3    0.5773502691896258f
#define SQRT3_C      1.7320508075688772f

__device__ __forceinline__ float siluf(float x){ return x / (1.f + __expf(-x)); }
__device__ __forceinline__ float sigf (float x){ return 1.f / (1.f + __expf(-x)); }
__device__ __forceinline__ unsigned short bf16h(float x){
  uint32 u = __float_as_uint(x);
  u += 0x7FFFu + ((u >> 16) & 1u);
  return (unsigned short)(u >> 16);
}
__device__ __forceinline__ float bf2f(unsigned short h){
  return __uint_as_float(((uint32)h) << 16);
}
__device__ __forceinline__ void split8(const float* __restrict__ p, s16x8& hi, s16x8& lo) {
  f32x4 v0 = *(const f32x4*)p;
  f32x4 v1 = *(const f32x4*)(p + 4);
  float vals[8] = {v0[0],v0[1],v0[2],v0[3],v1[0],v1[1],v1[2],v1[3]};
  #pragma unroll
  for (int j = 0; j < 8; ++j) {
    unsigned short hh = bf16h(vals[j]);
    hi[j] = (short)hh;
    lo[j] = (short)bf16h(vals[j] - bf2f(hh));
  }
}

// ---------------- edge geometry ----------------
__global__ void k_geom(const float* __restrict__ evec,
                       float* __restrict__ es8, float* __restrict__ shv) {
  int e = blockIdx.x*256 + threadIdx.x;
  if (e >= N_EDGES) return;
  float vx = evec[e*3+0], vy = evec[e*3+1], vz = evec[e*3+2];
  float d  = sqrtf(vx*vx + vy*vy + vz*vz);
  float xs = d - 0.25f;
  bool  in = (xs > 0.f) && (xs < 4.0f);
  float safe = xs > 0.f ? xs : 1.f;
  float amp  = in ? 2.0f/safe : 0.f;
  const float PI4 = 0.7853981633974483f;
  #pragma unroll
  for (int k = 0; k < 8; ++k)
    es8[e*8+k] = amp * sinf((float)(k+1) * PI4 * safe);
  float invd = d > 0.f ? 1.f/d : 1.f;
  shv[e*3+0] = SQRT3_C*vx*invd;
  shv[e*3+1] = SQRT3_C*vy*invd;
  shv[e*3+2] = SQRT3_C*vz*invd;
}

// ---------------- generic rows x K -> rows x 128 linear (startup only) ----------------
__global__ void k_linear128(const float* __restrict__ A, const float* __restrict__ W,
                            float* __restrict__ O, int K, float scale, int total) {
  int t = blockIdx.x*256 + threadIdx.x;
  if (t >= total) return;
  int n = t >> 7, j = t & 127;
  const float* a = A + n*K;
  float a0=0.f,a1=0.f,a2=0.f,a3=0.f;
  for (int k = 0; k < K; k += 4) {
    a0 += a[k+0]*W[(k+0)*128+j];
    a1 += a[k+1]*W[(k+1)*128+j];
    a2 += a[k+2]*W[(k+2)*128+j];
    a3 += a[k+3]*W[(k+3)*128+j];
  }
  O[t] = (a0+a1+a2+a3)*scale;
}

// ---------------- graph node counts ----------------
__global__ void k_cnt(const int* __restrict__ batch, float* __restrict__ cnt) {
  __shared__ int lc[N_GRAPHS];
  int t = threadIdx.x;
  if (t < N_GRAPHS) lc[t] = 0;
  __syncthreads();
  int i = blockIdx.x*256 + t;
  if (i < N_NODES) atomicAdd(&lc[batch[i]], 1);
  __syncthreads();
  if (t < N_GRAPHS && lc[t] > 0) atomicAdd(&cnt[t], (float)lc[t]);
}

// ---------------- CSR build ----------------
__global__ void k_hist(const int* __restrict__ edst, int* __restrict__ hist) {
  int e = blockIdx.x*256 + threadIdx.x;
  if (e < N_EDGES) atomicAdd(&hist[edst[e]], 1);
}

// parallel exclusive scan over N_NODES ints, one 1024-thread block
__global__ __launch_bounds__(1024) void k_scanp(const int* __restrict__ hist,
                                                int* __restrict__ offs) {
  __shared__ int wsum[16];
  const int t = threadIdx.x;
  const int lane = t & 63, w = t >> 6;
  const int base = t*10;
  int v[10]; int s = 0;
  #pragma unroll
  for (int i = 0; i < 10; ++i) {
    int idx = base + i;
    int x = (idx < N_NODES) ? hist[idx] : 0;
    s += x; v[i] = s;                 // inclusive local prefix
  }
  int ws = s;
  #pragma unroll
  for (int d = 1; d < 64; d <<= 1) {
    int u = __shfl_up(ws, d);
    if (lane >= d) ws += u;
  }
  if (lane == 63) wsum[w] = ws;
  __syncthreads();
  if (w == 0) {
    int x = (lane < 16) ? wsum[lane] : 0;
    #pragma unroll
    for (int d = 1; d < 16; d <<= 1) {
      int u = __shfl_up(x, d);
      if (lane >= d) x += u;
    }
    if (lane < 16) wsum[lane] = x;    // inclusive wave sums
  }
  __syncthreads();
  int waveoff = (w > 0) ? wsum[w-1] : 0;
  int texcl = waveoff + ws - s;       // exclusive prefix for this thread
  if (t == 0) offs[0] = 0;
  #pragma unroll
  for (int i = 0; i < 10; ++i) {
    int idx = base + i;
    if (idx < N_NODES) offs[idx+1] = texcl + v[i];
  }
}

__global__ void k_slot(const int* __restrict__ edst, const int* __restrict__ offs,
                       int* __restrict__ curs, int* __restrict__ slot) {
  int e = blockIdx.x*256 + threadIdx.x;
  if (e < N_EDGES) {
    int d = edst[e];
    int p = offs[d] + atomicAdd(&curs[d], 1);
    slot[p] = e;
  }
}

// ---------------- merged weight fragment prep (split bf16, B-fragment order) ----------------
struct PD { const float* W; short* dst; int Keff, N, NF, KS, nElem; float scale; };
struct PD8 { PD d[8]; int nd; int tot; };

__global__ void k_prepmulti(PD8 ds) {
  int stride = gridDim.x*256;
  for (int t = blockIdx.x*256 + threadIdx.x; t < ds.tot; t += stride) {
    int rem = t, i = 0;
    while (i < ds.nd-1 && rem >= ds.d[i].nElem) { rem -= ds.d[i].nElem; ++i; }
    const PD p = ds.d[i];
    int j = rem & 7;
    int l = (rem >> 3) & 63;
    int rest = rem >> 9;
    int ks = rest % p.KS; rest /= p.KS;
    int nf = rest % p.NF;
    int pp = rest / p.NF;
    int k   = ks*32 + (l >> 4)*8 + j;
    int col = nf*16 + (l & 15);
    float v = (k < p.Keff) ? p.W[(size_t)k*p.N + col]*p.scale : 0.f;
    unsigned short hi = bf16h(v);
    unsigned short o = pp ? bf16h(v - bf2f(hi)) : hi;
    p.dst[rem] = (short)o;
  }
}

// ---------------- fused 3-layer edge MLP via MFMA (split bf16) ----------------
template<int NF3>
__global__ __launch_bounds__(256) void k_mlp(
    const float* __restrict__ es8,
    const short* __restrict__ fb1, const short* __restrict__ fb2,
    const short* __restrict__ fb3, float* __restrict__ wbuf) {
  __shared__ __align__(16) short route[4][4608];
  const int w = threadIdx.x >> 6, l = threadIdx.x & 63;
  const int lrow = l & 15, lhi = l >> 4;
  const int e0 = (blockIdx.x*4 + w)*64;
  short* rt = route[w];

  s16x8 ah1[4], al1[4];
  #pragma unroll
  for (int mt = 0; mt < 4; ++mt) {
    s16x8 h = {0,0,0,0,0,0,0,0}, lo = {0,0,0,0,0,0,0,0};
    if (lhi == 0) {
      const float* ep = es8 + (size_t)(e0 + mt*16 + lrow)*8;
      split8(ep, h, lo);
    }
    ah1[mt] = h; al1[mt] = lo;
  }

  f32x4 acc1[4][4];
  #pragma unroll
  for (int mt = 0; mt < 4; ++mt)
    #pragma unroll
    for (int nf = 0; nf < 4; ++nf) acc1[mt][nf] = (f32x4){0.f,0.f,0.f,0.f};
  #pragma unroll
  for (int nf = 0; nf < 4; ++nf) {
    s16x8 bh = *(const s16x8*)(fb1 + ((0*4 + nf)*1 + 0)*512 + l*8);
    s16x8 bl = *(const s16x8*)(fb1 + ((1*4 + nf)*1 + 0)*512 + l*8);
    #pragma unroll
    for (int mt = 0; mt < 4; ++mt) {
      acc1[mt][nf] = __builtin_amdgcn_mfma_f32_16x16x32_bf16(ah1[mt], bh, acc1[mt][nf], 0,0,0);
      acc1[mt][nf] = __builtin_amdgcn_mfma_f32_16x16x32_bf16(ah1[mt], bl, acc1[mt][nf], 0,0,0);
      acc1[mt][nf] = __builtin_amdgcn_mfma_f32_16x16x32_bf16(al1[mt], bh, acc1[mt][nf], 0,0,0);
    }
  }
  #pragma unroll
  for (int mt = 0; mt < 4; ++mt)
    #pragma unroll
    for (int nf = 0; nf < 4; ++nf)
      #pragma unroll
      for (int r = 0; r < 4; ++r) acc1[mt][nf][r] = siluf(acc1[mt][nf][r]);

  s16x8 ah2[4][2], al2[4][2];
  #pragma unroll
  for (int mt = 0; mt < 4; ++mt)
    #pragma unroll
    for (int nf = 0; nf < 4; ++nf)
      #pragma unroll
      for (int r = 0; r < 4; ++r)
        rt[(mt*16 + lhi*4 + r)*72 + nf*16 + lrow] = (short)bf16h(acc1[mt][nf][r]);
  #pragma unroll
  for (int mt = 0; mt < 4; ++mt)
    #pragma unroll
    for (int ks = 0; ks < 2; ++ks)
      ah2[mt][ks] = *(const s16x8*)&rt[(mt*16 + lrow)*72 + ks*32 + lhi*8];
  #pragma unroll
  for (int mt = 0; mt < 4; ++mt)
    #pragma unroll
    for (int nf = 0; nf < 4; ++nf)
      #pragma unroll
      for (int r = 0; r < 4; ++r) {
        float v = acc1[mt][nf][r];
        unsigned short hh = bf16h(v);
        rt[(mt*16 + lhi*4 + r)*72 + nf*16 + lrow] = (short)bf16h(v - bf2f(hh));
      }
  #pragma unroll
  for (int mt = 0; mt < 4; ++mt)
    #pragma unroll
    for (int ks = 0; ks < 2; ++ks)
      al2[mt][ks] = *(const s16x8*)&rt[(mt*16 + lrow)*72 + ks*32 + lhi*8];

  f32x4 acc2[4][4];
  #pragma unroll
  for (int mt = 0; mt < 4; ++mt)
    #pragma unroll
    for (int nf = 0; nf < 4; ++nf) acc2[mt][nf] = (f32x4){0.f,0.f,0.f,0.f};
  #pragma unroll
  for (int nf = 0; nf < 4; ++nf)
    #pragma unroll
    for (int ks = 0; ks < 2; ++ks) {
      s16x8 bh = *(const s16x8*)(fb2 + ((0*4 + nf)*2 + ks)*512 + l*8);
      s16x8 bl = *(const s16x8*)(fb2 + ((1*4 + nf)*2 + ks)*512 + l*8);
      #pragma unroll
      for (int mt = 0; mt < 4; ++mt) {
        acc2[mt][nf] = __builtin_amdgcn_mfma_f32_16x16x32_bf16(ah2[mt][ks], bh, acc2[mt][nf], 0,0,0);
        acc2[mt][nf] = __builtin_amdgcn_mfma_f32_16x16x32_bf16(ah2[mt][ks], bl, acc2[mt][nf], 0,0,0);
        acc2[mt][nf] = __builtin_amdgcn_mfma_f32_16x16x32_bf16(al2[mt][ks], bh, acc2[mt][nf], 0,0,0);
      }
    }
  #pragma unroll
  for (int mt = 0; mt < 4; ++mt)
    #pragma unroll
    for (int nf = 0; nf < 4; ++nf)
      #pragma unroll
      for (int r = 0; r < 4; ++r) acc2[mt][nf][r] = siluf(acc2[mt][nf][r]);

  s16x8 ah3[4][2], al3[4][2];
  #pragma unroll
  for (int mt = 0; mt < 4; ++mt)
    #pragma unroll
    for (int nf = 0; nf < 4; ++nf)
      #pragma unroll
      for (int r = 0; r < 4; ++r)
        rt[(mt*16 + lhi*4 + r)*72 + nf*16 + lrow] = (short)bf16h(acc2[mt][nf][r]);
  #pragma unroll
  for (int mt = 0; mt < 4; ++mt)
    #pragma unroll
    for (int ks = 0; ks < 2; ++ks)
      ah3[mt][ks] = *(const s16x8*)&rt[(mt*16 + lrow)*72 + ks*32 + lhi*8];
  #pragma unroll
  for (int mt = 0; mt < 4; ++mt)
    #pragma unroll
    for (int nf = 0; nf < 4; ++nf)
      #pragma unroll
      for (int r = 0; r < 4; ++r) {
        float v = acc2[mt][nf][r];
        unsigned short hh = bf16h(v);
        rt[(mt*16 + lhi*4 + r)*72 + nf*16 + lrow] = (short)bf16h(v - bf2f(hh));
      }
  #pragma unroll
  for (int mt = 0; mt < 4; ++mt)
    #pragma unroll
    for (int ks = 0; ks < 2; ++ks)
      al3[mt][ks] = *(const s16x8*)&rt[(mt*16 + lrow)*72 + ks*32 + lhi*8];

  for (int nf3 = 0; nf3 < NF3; ++nf3) {
    f32x4 acc3[4];
    #pragma unroll
    for (int mt = 0; mt < 4; ++mt) acc3[mt] = (f32x4){0.f,0.f,0.f,0.f};
    #pragma unroll
    for (int ks = 0; ks < 2; ++ks) {
      s16x8 bh = *(const s16x8*)(fb3 + ((size_t)(0*NF3 + nf3)*2 + ks)*512 + l*8);
      s16x8 bl = *(const s16x8*)(fb3 + ((size_t)(1*NF3 + nf3)*2 + ks)*512 + l*8);
      #pragma unroll
      for (int mt = 0; mt < 4; ++mt) {
        acc3[mt] = __builtin_amdgcn_mfma_f32_16x16x32_bf16(ah3[mt][ks], bh, acc3[mt], 0,0,0);
        acc3[mt] = __builtin_amdgcn_mfma_f32_16x16x32_bf16(ah3[mt][ks], bl, acc3[mt], 0,0,0);
        acc3[mt] = __builtin_amdgcn_mfma_f32_16x16x32_bf16(al3[mt][ks], bh, acc3[mt], 0,0,0);
      }
    }
    #pragma unroll
    for (int mt = 0; mt < 4; ++mt)
      #pragma unroll
      for (int r = 0; r < 4; ++r)
        wbuf[(size_t)(e0 + mt*16 + lhi*4 + r)*(NF3*16) + nf3*16 + lrow] = acc3[mt][r];
  }
}

// ---------------- generic MFMA GEMM: O[M x NF*16] = A[M x KS*32] @ fB (split bf16) ----------------
template<int KS, int NF>
__global__ __launch_bounds__(512, 4) void k_gemm(
    const float* __restrict__ A, int rstride, int M,
    const short* __restrict__ fB, float* __restrict__ O) {
  __shared__ __align__(16) short lB[2*NF*KS*512];
  const int tid = threadIdx.x;
  const int w = tid >> 6, l = tid & 63;
  const int lrow = l & 15, lhi = l >> 4;
  const int n0 = blockIdx.x*128 + w*16;
  for (int i = tid; i < 2*NF*KS*64; i += 512)
    *(s16x8*)&lB[(size_t)i*8] = *(const s16x8*)&fB[(size_t)i*8];
  s16x8 ah[KS], al[KS];
  {
    int row = n0 + lrow; if (row > M-1) row = M-1;
    #pragma unroll
    for (int ks = 0; ks < KS; ++ks)
      split8(A + (size_t)row*rstride + ks*32 + lhi*8, ah[ks], al[ks]);
  }
  __syncthreads();
  f32x4 acc[NF];
  #pragma unroll
  for (int nf = 0; nf < NF; ++nf) acc[nf] = (f32x4){0.f,0.f,0.f,0.f};
  #pragma unroll
  for (int nf = 0; nf < NF; ++nf)
    #pragma unroll
    for (int ks = 0; ks < KS; ++ks) {
      s16x8 bh = *(const s16x8*)&lB[((0*NF + nf)*KS + ks)*512 + l*8];
      s16x8 bl = *(const s16x8*)&lB[((1*NF + nf)*KS + ks)*512 + l*8];
      acc[nf] = __builtin_amdgcn_mfma_f32_16x16x32_bf16(ah[ks], bh, acc[nf], 0,0,0);
      acc[nf] = __builtin_amdgcn_mfma_f32_16x16x32_bf16(ah[ks], bl, acc[nf], 0,0,0);
      acc[nf] = __builtin_amdgcn_mfma_f32_16x16x32_bf16(al[ks], bh, acc[nf], 0,0,0);
    }
  #pragma unroll
  for (int nf = 0; nf < NF; ++nf)
    #pragma unroll
    for (int r = 0; r < 4; ++r) {
      int row = n0 + lhi*4 + r;
      if (row < M) O[(size_t)row*(NF*16) + nf*16 + lrow] = acc[nf][r];
    }
}

// ---------------- sc partial ----------------
template<int KSO>
__global__ __launch_bounds__(512, 4) void k_scp(
    const float* __restrict__ Ao, const float* __restrict__ na,
    const short* __restrict__ fBc, float* __restrict__ part) {
  __shared__ __align__(16) short lB[KSO*8192];
  const int tid = threadIdx.x;
  const int w = tid >> 6, l = tid & 63;
  const int lrow = l & 15, lhi = l >> 4;
  const int n0 = blockIdx.x*128 + w*16;
  const int vp = blockIdx.y;

  s16x8 aoh[KSO], aol[KSO];
  {
    int row = n0 + lrow; if (row > N_NODES-1) row = N_NODES-1;
    #pragma unroll
    for (int ks = 0; ks < KSO; ++ks)
      split8(Ao + (size_t)row*(KSO*32) + ks*32 + lhi*8, aoh[ks], aol[ks]);
  }

  f32x4 acc[8];
  #pragma unroll
  for (int nf = 0; nf < 8; ++nf) acc[nf] = (f32x4){0.f,0.f,0.f,0.f};

  #pragma unroll
  for (int c = 0; c < 2; ++c) {
    const int v = vp*2 + c;
    __syncthreads();
    for (int i = tid; i < KSO*1024; i += 512) {
      int gl = i & 63;
      int rest = i >> 6;
      int ks = rest % KSO;
      int rest2 = rest / KSO;
      int nf = rest2 & 7;
      int p  = rest2 >> 3;
      size_t src = ((((size_t)p*128 + (v*8 + nf))*KSO + ks)*64 + gl)*8;
      *(s16x8*)&lB[(size_t)i*8] = *(const s16x8*)&fBc[src];
    }
    __syncthreads();
    f32x4 dacc[8];
    #pragma unroll
    for (int nf = 0; nf < 8; ++nf) dacc[nf] = (f32x4){0.f,0.f,0.f,0.f};
    #pragma unroll
    for (int nf = 0; nf < 8; ++nf)
      #pragma unroll
      for (int ks = 0; ks < KSO; ++ks) {
        s16x8 bh = *(const s16x8*)&lB[((0*8 + nf)*KSO + ks)*512 + l*8];
        s16x8 bl = *(const s16x8*)&lB[((1*8 + nf)*KSO + ks)*512 + l*8];
        dacc[nf] = __builtin_amdgcn_mfma_f32_16x16x32_bf16(aoh[ks], bh, dacc[nf], 0,0,0);
        dacc[nf] = __builtin_amdgcn_mfma_f32_16x16x32_bf16(aoh[ks], bl, dacc[nf], 0,0,0);
        dacc[nf] = __builtin_amdgcn_mfma_f32_16x16x32_bf16(aol[ks], bh, dacc[nf], 0,0,0);
      }
    #pragma unroll
    for (int r = 0; r < 4; ++r) {
      int row = n0 + lhi*4 + r; if (row > N_NODES-1) row = N_NODES-1;
      float nav = na[(size_t)row*16 + v];
      #pragma unroll
      for (int nf = 0; nf < 8; ++nf) acc[nf][r] += nav * dacc[nf][r];
    }
  }

  float* pp = part + (size_t)vp*NM128;
  #pragma unroll
  for (int nf = 0; nf < 8; ++nf)
    #pragma unroll
    for (int r = 0; r < 4; ++r) {
      int row = n0 + lhi*4 + r;
      if (row < N_NODES) pp[(size_t)row*128 + nf*16 + lrow] = acc[nf][r];
    }
}

// ---------------- reduce 9 partials (float4) ----------------
__global__ void k_reduce(const float* __restrict__ part, float* __restrict__ outs) {
  int i = blockIdx.x*256 + threadIdx.x;
  if (i >= NM128/4) return;
  f32x4 s = {0.f,0.f,0.f,0.f};
  #pragma unroll
  for (int p = 0; p < 9; ++p)
    s += *(const f32x4*)(part + (size_t)p*NM128 + (size_t)i*4);
  *(f32x4*)(outs + (size_t)i*4) = s;
}

// ---------------- conv1 gather: CSR pull; n_v written as [n][3][128] ----------------
__global__ __launch_bounds__(256) void k_gather1(
    const float* __restrict__ wbuf, const float* __restrict__ shv,
    const int* __restrict__ esrc, const int* __restrict__ offs, const int* __restrict__ slot,
    const float* __restrict__ h,
    float* __restrict__ n_s, float* __restrict__ n_v) {
  const int wave = threadIdx.x >> 6, lane = threadIdx.x & 63;
  const int n = blockIdx.x*4 + wave;
  if (n >= N_NODES) return;
  const int s0 = offs[n], s1 = offs[n+1];
  float ns0=0.f, ns1=0.f;
  float nv00=0.f,nv01=0.f,nv02=0.f, nv10=0.f,nv11=0.f,nv12=0.f;
  for (int s = s0; s < s1; ++s) {
    int e = slot[s];
    int src = esrc[e];
    const float* wp = wbuf + (size_t)e*256;
    float c0 = wp[lane], c1 = wp[64+lane], c2 = wp[128+lane], c3 = wp[192+lane];
    float h0 = h[src*128+lane], h1 = h[src*128+64+lane];
    float sv0 = shv[e*3+0], sv1 = shv[e*3+1], sv2 = shv[e*3+2];
    ns0 += c0*h0; ns1 += c1*h1;
    float t0 = c2*h0, t1 = c3*h1;
    nv00 += t0*sv0; nv01 += t0*sv1; nv02 += t0*sv2;
    nv10 += t1*sv0; nv11 += t1*sv1; nv12 += t1*sv2;
  }
  n_s[n*128+lane]    = ns0*INV_SQRT10;
  n_s[n*128+64+lane] = ns1*INV_SQRT10;
  float* nvp = n_v + (size_t)n*384;      // [3][128]
  nvp[0*128+lane]    = nv00*INV_SQRT10;
  nvp[1*128+lane]    = nv01*INV_SQRT10;
  nvp[2*128+lane]    = nv02*INV_SQRT10;
  nvp[0*128+64+lane] = nv10*INV_SQRT10;
  nvp[1*128+64+lane] = nv11*INV_SQRT10;
  nvp[2*128+64+lane] = nv12*INV_SQRT10;
}

// ---------------- conv2 gather: h_v layout [n][3][64] ----------------
__global__ __launch_bounds__(256) void k_gather2(
    const float* __restrict__ wbuf, const float* __restrict__ shv,
    const int* __restrict__ esrc, const int* __restrict__ offs, const int* __restrict__ slot,
    const float* __restrict__ h_s, const float* __restrict__ h_v,
    float* __restrict__ n_mid) {
  const int wave = threadIdx.x >> 6, lane = threadIdx.x & 63;
  const int n = blockIdx.x*4 + wave;
  if (n >= N_NODES) return;
  const int s0 = offs[n], s1 = offs[n+1];
  float acc0 = 0.f, acc1 = 0.f;
  for (int s = s0; s < s1; ++s) {
    int e = slot[s];
    int src = esrc[e];
    const float* wp = wbuf + (size_t)e*128;
    float w0 = wp[lane], w1 = wp[64+lane];
    float hs = h_s[src*64+lane];
    const float* hvp = h_v + (size_t)src*192;
    float sv0 = shv[e*3+0], sv1 = shv[e*3+1], sv2 = shv[e*3+2];
    float dot = hvp[lane]*sv0 + hvp[64+lane]*sv1 + hvp[128+lane]*sv2;
    acc0 += w0*hs;
    acc1 += w1*dot;
  }
  n_mid[n*128+lane]    = acc0*INV_SQRT10;
  n_mid[n*128+64+lane] = acc1*INV_SQRT3*INV_SQRT10;
}

// ---------------- elementwise gating ----------------
__global__ void k_gatee(const float* __restrict__ outs, const float* __restrict__ ov,
                        float* __restrict__ gs_out, float* __restrict__ gv) {
  int t = blockIdx.x*256 + threadIdx.x;
  if (t >= N_NODES*64) return;
  int n = t >> 6, v = t & 63;
  float g = siluf(outs[(size_t)n*128 + v]);
  float gate = sigf(outs[(size_t)n*128 + 64 + v]);
  gs_out[(size_t)n*64 + v] = g;
  gv[(size_t)n*192 + 0*64 + v] = gate*ov[(size_t)n*192 + 0*64 + v];
  gv[(size_t)n*192 + 1*64 + v] = gate*ov[(size_t)n*192 + 1*64 + v];
  gv[(size_t)n*192 + 2*64 + v] = gate*ov[(size_t)n*192 + 2*64 + v];
}

// ---------------- pooled accumulation (RLE on sorted batch) ----------------
__global__ __launch_bounds__(128) void k_pool(
    const float* __restrict__ outs, const int* __restrict__ batch,
    float* __restrict__ pool) {
  const int j = threadIdx.x;
  const int n0 = blockIdx.x*4;
  float outv[4];
  #pragma unroll
  for (int n = 0; n < 4; ++n) outv[n] = outs[(size_t)(n0+n)*128 + j];
  int b0 = batch[n0], b1 = batch[n0+1], b2 = batch[n0+2], b3 = batch[n0+3];
  float sum = outv[0]; int cur = b0;
  if (b1 == cur) sum += outv[1]; else { atomicAdd(&pool[cur*128+j], sum); cur = b1; sum = outv[1]; }
  if (b2 == cur) sum += outv[2]; else { atomicAdd(&pool[cur*128+j], sum); cur = b2; sum = outv[2]; }
  if (b3 == cur) sum += outv[3]; else { atomicAdd(&pool[cur*128+j], sum); cur = b3; sum = outv[3]; }
  atomicAdd(&pool[cur*128+j], sum);
}

// ======== FALLBACK (atomic) kernels — used only if ws too small ========
__global__ __launch_bounds__(512) void k_edge1_at(
    const float* __restrict__ es8, const float* __restrict__ shv,
    const int* __restrict__ esrc, const int* __restrict__ edst,
    const float* __restrict__ h,
    const float* __restrict__ W0, const float* __restrict__ W1, const float* __restrict__ W2,
    float* __restrict__ n_s, float* __restrict__ n_v) {
  __shared__ float lW0[512];
  __shared__ float lW1[4096];
  __shared__ float lW2[16384];
  __shared__ float lA[8][64];
  __shared__ float lB[8][64];
  for (int i = threadIdx.x; i < 512;   i += 512) lW0[i] = W0[i];
  for (int i = threadIdx.x; i < 4096;  i += 512) lW1[i] = W1[i];
  for (int i = threadIdx.x; i < 16384; i += 512) lW2[i] = W2[i];
  __syncthreads();
  const int wave = threadIdx.x >> 6, lane = threadIdx.x & 63;
  const int nw = gridDim.x * 8;
  const int e0 = blockIdx.x*8 + wave;
  const int iters = (N_EDGES + nw - 1) / nw;
  for (int it = 0; it < iters; ++it) {
    int e = e0 + it*nw;
    bool valid = e < N_EDGES;
    float a = 0.f, sv0=0.f, sv1=0.f, sv2=0.f;
    int src = 0, dst = 0;
    if (valid) {
      const float* ep = es8 + e*8;
      sv0 = shv[e*3+0]; sv1 = shv[e*3+1]; sv2 = shv[e*3+2];
      src = esrc[e]; dst = edst[e];
      a = ep[0]*lW0[lane]      + ep[1]*lW0[64+lane]  + ep[2]*lW0[128+lane] + ep[3]*lW0[192+lane]
        + ep[4]*lW0[256+lane]  + ep[5]*lW0[320+lane] + ep[6]*lW0[384+lane] + ep[7]*lW0[448+lane];
      a = siluf(a * INV_SQRT8);
    }
    lA[wave][lane] = a;
    __syncthreads();
    {
      float b0=0.f;
      #pragma unroll
      for (int k = 0; k < 64; ++k) b0 += lA[wave][k]*lW1[k*64+lane];
      lB[wave][lane] = siluf(b0 * INV_SQRT64);
    }
    __syncthreads();
    if (valid) {
      float c0=0.f,c1=0.f,c2=0.f,c3=0.f;
      #pragma unroll
      for (int k = 0; k < 64; ++k) {
        float bk = lB[wave][k];
        const float* r = lW2 + k*256;
        c0 += bk*r[lane]; c1 += bk*r[64+lane]; c2 += bk*r[128+lane]; c3 += bk*r[192+lane];
      }
      float hs0 = h[src*128 + lane];
      float hs1 = h[src*128 + 64 + lane];
      atomicAdd(&n_s[dst*128 + lane],      c0*INV_SQRT64*hs0*INV_SQRT10);
      atomicAdd(&n_s[dst*128 + 64 + lane], c1*INV_SQRT64*hs1*INV_SQRT10);
      float t0 = c2*INV_SQRT64*hs0*INV_SQRT10;
      float t1 = c3*INV_SQRT64*hs1*INV_SQRT10;
      float* nvp = n_v + dst*384;
      atomicAdd(nvp + lane*3+0, t0*sv0);
      atomicAdd(nvp + lane*3+1, t0*sv1);
      atomicAdd(nvp + lane*3+2, t0*sv2);
      atomicAdd(nvp + (64+lane)*3+0, t1*sv0);
      atomicAdd(nvp + (64+lane)*3+1, t1*sv1);
      atomicAdd(nvp + (64+lane)*3+2, t1*sv2);
    }
  }
}

__global__ __launch_bounds__(512) void k_edge2_at(
    const float* __restrict__ es8, const float* __restrict__ shv,
    const int* __restrict__ esrc, const int* __restrict__ edst,
    const float* __restrict__ h_s, const float* __restrict__ h_v,
    const float* __restrict__ W0, const float* __restrict__ W1, const float* __restrict__ W2,
    float* __restrict__ n_mid) {
  __shared__ float lW0[512];
  __shared__ float lW1[4096];
  __shared__ float lW2[8192];
  __shared__ float lA[8][64];
  __shared__ float lB[8][64];
  for (int i = threadIdx.x; i < 512;  i += 512) lW0[i] = W0[i];
  for (int i = threadIdx.x; i < 4096; i += 512) lW1[i] = W1[i];
  for (int i = threadIdx.x; i < 8192; i += 512) lW2[i] = W2[i];
  __syncthreads();
  const int wave = threadIdx.x >> 6, lane = threadIdx.x & 63;
  const int nw = gridDim.x * 8;
  const int e0 = blockIdx.x*8 + wave;
  const int iters = (N_EDGES + nw - 1) / nw;
  for (int it = 0; it < iters; ++it) {
    int e = e0 + it*nw;
    bool valid = e < N_EDGES;
    float a = 0.f, sv0=0.f, sv1=0.f, sv2=0.f;
    int src = 0, dst = 0;
    if (valid) {
      const float* ep = es8 + e*8;
      sv0 = shv[e*3+0]; sv1 = shv[e*3+1]; sv2 = shv[e*3+2];
      src = esrc[e]; dst = edst[e];
      a = ep[0]*lW0[lane]      + ep[1]*lW0[64+lane]  + ep[2]*lW0[128+lane] + ep[3]*lW0[192+lane]
        + ep[4]*lW0[256+lane]  + ep[5]*lW0[320+lane] + ep[6]*lW0[384+lane] + ep[7]*lW0[448+lane];
      a = siluf(a * INV_SQRT8);
    }
    lA[wave][lane] = a;
    __syncthreads();
    {
      float b0=0.f;
      #pragma unroll
      for (int k = 0; k < 64; ++k) b0 += lA[wave][k]*lW1[k*64+lane];
      lB[wave][lane] = siluf(b0 * INV_SQRT64);
    }
    __syncthreads();
    if (valid) {
      float c0=0.f, c1=0.f;
      #pragma unroll
      for (int k = 0; k < 64; ++k) {
        float bk = lB[wave][k];
        const float* r = lW2 + k*128;
        c0 += bk*r[lane]; c1 += bk*r[64+lane];
      }
      float hsv = h_s[src*64 + lane];
      const float* hvp = h_v + src*192 + lane*3;
      float dotv = hvp[0]*sv0 + hvp[1]*sv1 + hvp[2]*sv2;
      atomicAdd(&n_mid[dst*128 + lane],      c0*INV_SQRT64*hsv*INV_SQRT10);
      atomicAdd(&n_mid[dst*128 + 64 + lane], c1*INV_SQRT64*dotv*INV_SQRT3*INV_SQRT10);
    }
  }
}

// ---------------- FALLBACK conv1 node pass (full, old n_v layout) ----------------
__global__ __launch_bounds__(128) void k_node1(
    const float* __restrict__ n_s, const float* __restrict__ n_v,
    const float* __restrict__ s,   const float* __restrict__ na,
    const float* __restrict__ Wls, const float* __restrict__ Wlv,
    const float* __restrict__ Csc, const float* __restrict__ W2s, const float* __restrict__ W2v,
    float* __restrict__ gs_out, float* __restrict__ hs_out, float* __restrict__ hv_out) {
  __shared__ float l_ns[512], l_s[512], l_na[64], l_nv[1536];
  __shared__ float l_outs[512], l_ov[768], l_gs[256], l_gv[768];
  const int j = threadIdx.x;
  const int n0 = blockIdx.x*4;
  for (int i = j; i < 512;  i += 128) { l_ns[i] = n_s[n0*128+i]; l_s[i] = s[n0*128+i]; }
  for (int i = j; i < 1536; i += 128) l_nv[i] = n_v[n0*384+i];
  if (j < 64) l_na[j] = na[n0*16+j];
  __syncthreads();

  float accs[4] = {0.f,0.f,0.f,0.f};
  for (int k = 0; k < 128; ++k) {
    float w = Wls[k*128+j];
    accs[0] += l_ns[k]*w; accs[1] += l_ns[128+k]*w;
    accs[2] += l_ns[256+k]*w; accs[3] += l_ns[384+k]*w;
  }
  float accc[4] = {0.f,0.f,0.f,0.f};
  for (int vt = 0; vt < 16; vt += 4) {
    float a0[4],a1[4],a2[4],a3[4];
    #pragma unroll
    for (int n = 0; n < 4; ++n) {
      a0[n]=l_na[n*16+vt]; a1[n]=l_na[n*16+vt+1];
      a2[n]=l_na[n*16+vt+2]; a3[n]=l_na[n*16+vt+3];
    }
    for (int u = 0; u < 128; ++u) {
      const float* cp = Csc + (u*16+vt)*128 + j;
      float c0=cp[0], c1=cp[128], c2=cp[256], c3=cp[384];
      float s0=l_s[u], s1=l_s[128+u], s2=l_s[256+u], s3=l_s[384+u];
      accc[0] += s0*(a0[0]*c0 + a1[0]*c1 + a2[0]*c2 + a3[0]*c3);
      accc[1] += s1*(a0[1]*c0 + a1[1]*c1 + a2[1]*c2 + a3[1]*c3);
      accc[2] += s2*(a0[2]*c0 + a1[2]*c1 + a2[2]*c2 + a3[2]*c3);
      accc[3] += s3*(a0[3]*c0 + a1[3]*c1 + a2[3]*c2 + a3[3]*c3);
    }
  }
  #pragma unroll
  for (int n = 0; n < 4; ++n)
    l_outs[n*128+j] = accs[n]*INV_SQRT128 + accc[n]*INV_SQRT2048;

  const int jj = j & 63, hh = j >> 6;
  float ov[2][3] = {{0.f,0.f,0.f},{0.f,0.f,0.f}};
  for (int u = 0; u < 128; ++u) {
    float w = Wlv[u*64+jj];
    #pragma unroll
    for (int t = 0; t < 2; ++t) {
      int n = 2*hh+t;
      ov[t][0] += l_nv[n*384+u*3+0]*w;
      ov[t][1] += l_nv[n*384+u*3+1]*w;
      ov[t][2] += l_nv[n*384+u*3+2]*w;
    }
  }
  #pragma unroll
  for (int t = 0; t < 2; ++t) {
    int n = 2*hh+t;
    l_ov[n*192+jj*3+0] = ov[t][0]*INV_SQRT128;
    l_ov[n*192+jj*3+1] = ov[t][1]*INV_SQRT128;
    l_ov[n*192+jj*3+2] = ov[t][2]*INV_SQRT128;
  }
  __syncthreads();

  #pragma unroll
  for (int t = 0; t < 2; ++t) {
    int n = 2*hh+t;
    float gv_s = siluf(l_outs[n*128+jj]);
    float gate = sigf (l_outs[n*128+64+jj]);
    l_gs[n*64+jj] = gv_s;
    gs_out[(n0+n)*64+jj] = gv_s;
    l_gv[n*192+jj*3+0] = gate*l_ov[n*192+jj*3+0];
    l_gv[n*192+jj*3+1] = gate*l_ov[n*192+jj*3+1];
    l_gv[n*192+jj*3+2] = gate*l_ov[n*192+jj*3+2];
  }
  __syncthreads();

  float ha[2] = {0.f,0.f};
  for (int k = 0; k < 64; ++k) {
    float w = W2s[k*64+jj];
    ha[0] += l_gs[(2*hh+0)*64+k]*w;
    ha[1] += l_gs[(2*hh+1)*64+k]*w;
  }
  hs_out[(n0+2*hh+0)*64+jj] = ha[0]*INV_SQRT64;
  hs_out[(n0+2*hh+1)*64+jj] = ha[1]*INV_SQRT64;

  float hv[2][3] = {{0.f,0.f,0.f},{0.f,0.f,0.f}};
  for (int u = 0; u < 64; ++u) {
    float w = W2v[u*64+jj];
    #pragma unroll
    for (int t = 0; t < 2; ++t) {
      int n = 2*hh+t;
      hv[t][0] += l_gv[n*192+u*3+0]*w;
      hv[t][1] += l_gv[n*192+u*3+1]*w;
      hv[t][2] += l_gv[n*192+u*3+2]*w;
    }
  }
  #pragma unroll
  for (int t = 0; t < 2; ++t) {
    int n = 2*hh+t;
    hv_out[(n0+n)*192+jj*3+0] = hv[t][0]*INV_SQRT64;
    hv_out[(n0+n)*192+jj*3+1] = hv[t][1]*INV_SQRT64;
    hv_out[(n0+n)*192+jj*3+2] = hv[t][2]*INV_SQRT64;
  }
}

// ---------------- FALLBACK conv2 node pass + pooling ----------------
__global__ __launch_bounds__(128) void k_node2(
    const float* __restrict__ n_mid, const float* __restrict__ gs,
    const float* __restrict__ na, const int* __restrict__ batch,
    const float* __restrict__ W, const float* __restrict__ Csc,
    float* __restrict__ pool) {
  __shared__ float l_nm[512], l_gs[256], l_na[64];
  const int j = threadIdx.x;
  const int n0 = blockIdx.x*4;
  for (int i = j; i < 512; i += 128) l_nm[i] = n_mid[n0*128+i];
  for (int i = j; i < 256; i += 128) l_gs[i] = gs[n0*64+i];
  if (j < 64) l_na[j] = na[n0*16+j];
  __syncthreads();
  float acc[4] = {0.f,0.f,0.f,0.f};
  for (int k = 0; k < 128; ++k) {
    float w = W[k*128+j];
    acc[0] += l_nm[k]*w; acc[1] += l_nm[128+k]*w;
    acc[2] += l_nm[256+k]*w; acc[3] += l_nm[384+k]*w;
  }
  float acc2[4] = {0.f,0.f,0.f,0.f};
  for (int vt = 0; vt < 16; vt += 4) {
    float a0[4],a1[4],a2[4],a3[4];
    #pragma unroll
    for (int n = 0; n < 4; ++n) {
      a0[n]=l_na[n*16+vt]; a1[n]=l_na[n*16+vt+1];
      a2[n]=l_na[n*16+vt+2]; a3[n]=l_na[n*16+vt+3];
    }
    for (int u = 0; u < 64; ++u) {
      const float* cp = Csc + (u*16+vt)*128 + j;
      float c0=cp[0], c1=cp[128], c2=cp[256], c3=cp[384];
      float s0=l_gs[u], s1=l_gs[64+u], s2=l_gs[128+u], s3=l_gs[192+u];
      acc2[0] += s0*(a0[0]*c0 + a1[0]*c1 + a2[0]*c2 + a3[0]*c3);
      acc2[1] += s1*(a0[1]*c0 + a1[1]*c1 + a2[1]*c2 + a3[1]*c3);
      acc2[2] += s2*(a0[2]*c0 + a1[2]*c1 + a2[2]*c2 + a3[2]*c3);
      acc2[3] += s3*(a0[3]*c0 + a1[3]*c1 + a2[3]*c2 + a3[3]*c3);
    }
  }
  float outv[4];
  #pragma unroll
  for (int n = 0; n < 4; ++n)
    outv[n] = acc[n]*INV_SQRT128 + acc2[n]*INV_SQRT1024;
  int b0 = batch[n0], b1 = batch[n0+1], b2 = batch[n0+2], b3 = batch[n0+3];
  float sum = outv[0]; int cur = b0;
  if (b1 == cur) sum += outv[1]; else { atomicAdd(&pool[cur*128+j], sum); cur = b1; sum = outv[1]; }
  if (b2 == cur) sum += outv[2]; else { atomicAdd(&pool[cur*128+j], sum); cur = b2; sum = outv[2]; }
  if (b3 == cur) sum += outv[3]; else { atomicAdd(&pool[cur*128+j], sum); cur = b3; sum = outv[3]; }
  atomicAdd(&pool[cur*128+j], sum);
}

// ---------------- readout head ----------------
__global__ __launch_bounds__(128) void k_head(
    const float* __restrict__ pool, const float* __restrict__ cnt,
    const float* __restrict__ Wr1, const float* __restrict__ Wr2,
    float* __restrict__ out) {
  __shared__ float lp[128];
  __shared__ float lt[128];
  const int j = threadIdx.x;
  for (int g = 0; g < N_GRAPHS; ++g) {
    float inv = 1.f / fmaxf(cnt[g], 1.f);
    lp[j] = pool[g*128+j]*inv;
    __syncthreads();
    float acc = 0.f;
    for (int k = 0; k < 128; ++k) acc += lp[k]*Wr1[k*128+j];
    lt[j] = siluf(acc*INV_SQRT128) * Wr2[j];
    __syncthreads();
    if (j == 0) {
      float ssum = 0.f;
      for (int k = 0; k < 128; ++k) ssum += lt[k];
      out[g] = ssum*INV_SQRT128;
    }
    __syncthreads();
  }
}

extern "C" void kernel_launch(void* const* d_in, const int* in_sizes, int n_in,
                              void* d_out, int out_size, void* d_ws, size_t ws_size,
                              hipStream_t stream) {
  const float* x         = (const float*)d_in[0];
  const float* node_attr = (const float*)d_in[1];
  const int*   esrc      = (const int*)d_in[2];
  const int*   edst      = (const int*)d_in[3];
  const float* evec      = (const float*)d_in[4];
  const int*   batch     = (const int*)d_in[5];
  const float* W_embed   = (const float*)d_in[6];
  const float* c1_lin1   = (const float*)d_in[7];
  const float* c1_fc_w0  = (const float*)d_in[8];
  const float* c1_fc_w1  = (const float*)d_in[9];
  const float* c1_fc_w2  = (const float*)d_in[10];
  const float* c1_lin2_s = (const float*)d_in[11];
  const float* c1_lin2_v = (const float*)d_in[12];
  const float* c1_sc     = (const float*)d_in[13];
  const float* c2_lin1_s = (const float*)d_in[14];
  const float* c2_lin1_v = (const float*)d_in[15];
  const float* c2_fc_w0  = (const float*)d_in[16];
  const float* c2_fc_w1  = (const float*)d_in[17];
  const float* c2_fc_w2  = (const float*)d_in[18];
  const float* c2_lin2   = (const float*)d_in[19];
  const float* c2_sc     = (const float*)d_in[20];
  const float* Wr1       = (const float*)d_in[21];
  const float* Wr2       = (const float*)d_in[22];

  float* ws    = (float*)d_ws;
  float* es8   = ws + OFF_ES8;
  float* shv   = ws + OFF_SHV;
  float* s_    = ws + OFF_S;
  float* h_    = ws + OFF_H;
  float* gs_   = ws + OFF_GS;
  float* hs_   = ws + OFF_HS;
  float* hv_   = ws + OFF_HV;
  float* ns_   = ws + OFF_NS;
  float* nv_   = ws + OFF_NV;
  float* nmid_ = ws + OFF_NMID;
  float* pool_ = ws + OFF_POOL;
  float* cnt_  = ws + OFF_CNT;
  int*   hist_ = (int*)(ws + OFF_HIST);
  int*   curs_ = (int*)(ws + OFF_CURS);
  int*   offs_ = (int*)(ws + OFF_OFFS);
  short* frag_ = (short*)(ws + OFF_FRAG);
  int*   slot_ = (int*)(ws + OFF_SLOT);
  float* wbuf_ = ws + OFF_WBUF;

  // upper-wbuf carve-outs (dead vs. k_mlp<16> output by ordering; k_mlp<8>
  // writes only the lower N_EDGES*128 floats):
  float* out1_  = wbuf_ + (size_t)N_EDGES*128;                 // 1.28M floats
  short* nfrag_ = (short*)(out1_ + (size_t)NM128);             // 884736 shorts
  float* part_  = out1_ + (size_t)NM128 + NFRAG_TOT/2;         // 9 x 1.28M floats
  float* ov_    = part_ + (size_t)9*NM128;                     // 1.92M floats
  float* gv_    = nv_;                                         // aliases nv (dead after ov GEMM)
  float* out2_  = ns_;                                         // ns dead after conv1 dense GEMM

  const bool big = ws_size >= WS_NEED_BYTES;

  k_geom<<<N_EDGES/256, 256, 0, stream>>>(evec, es8, shv);
  k_linear128<<<(N_NODES*128)/256, 256, 0, stream>>>(x,  W_embed, s_, 32,  INV_SQRT32,  N_NODES*128);
  k_linear128<<<(N_NODES*128)/256, 256, 0, stream>>>(s_, c1_lin1, h_, 128, INV_SQRT128, N_NODES*128);

  if (big) {
    hipMemsetAsync(pool_, 0, (size_t)(OFF_OFFS - OFF_POOL)*sizeof(float), stream);
    k_cnt<<<(N_NODES+255)/256, 256, 0, stream>>>(batch, cnt_);
    k_hist<<<(N_EDGES+255)/256, 256, 0, stream>>>(edst, hist_);
    k_scanp<<<1, 1024, 0, stream>>>(hist_, offs_);
    k_slot<<<(N_EDGES+255)/256, 256, 0, stream>>>(edst, offs_, curs_, slot_);

    // merged MLP weight frag prep (persistent region)
    {
      PD8 m{};
      m.d[0] = {c1_fc_w0, frag_ + F_B1,  8,  64,  4, 1, 4096,  INV_SQRT8};
      m.d[1] = {c1_fc_w1, frag_ + F_B2,  64, 64,  4, 2, 8192,  INV_SQRT64};
      m.d[2] = {c1_fc_w2, frag_ + F_B3,  64, 256, 16,2, 32768, INV_SQRT64};
      m.d[3] = {c2_fc_w0, frag_ + F_B1b, 8,  64,  4, 1, 4096,  INV_SQRT8};
      m.d[4] = {c2_fc_w1, frag_ + F_B2b, 64, 64,  4, 2, 8192,  INV_SQRT64};
      m.d[5] = {c2_fc_w2, frag_ + F_B3b, 64, 128, 8, 2, 16384, INV_SQRT64};
      m.nd = 6; m.tot = 73728;
      k_prepmulti<<<288, 256, 0, stream>>>(m);
    }

    // conv1 edge MLP + gather (n_v -> [n][3][128])
    k_mlp<16><<<625, 256, 0, stream>>>(es8, frag_ + F_B1, frag_ + F_B2, frag_ + F_B3, wbuf_);
    k_gather1<<<(N_NODES+3)/4, 256, 0, stream>>>(wbuf_, shv, esrc, offs_, slot_, h_, ns_, nv_);

    // merged node weight frag prep (upper-wbuf region, free after gather1)
    {
      PD8 m{};
      m.d[0] = {c1_lin2_s, nfrag_ + NF_WLS, 128, 128,  8,   4, 32768,  INV_SQRT128};
      m.d[1] = {c1_sc,     nfrag_ + NF_C1,  128, 2048, 128, 4, 524288, INV_SQRT2048};
      m.d[2] = {c2_lin2,   nfrag_ + NF_W2,  128, 128,  8,   4, 32768,  INV_SQRT128};
      m.d[3] = {c2_sc,     nfrag_ + NF_C2,  64,  2048, 128, 2, 262144, INV_SQRT1024};
      m.d[4] = {c1_lin2_v, nfrag_ + NF_LV,  128, 64,   4,   4, 16384,  INV_SQRT128};
      m.d[5] = {c2_lin1_s, nfrag_ + NF_2S,  64,  64,   4,   2, 8192,   INV_SQRT64};
      m.d[6] = {c2_lin1_v, nfrag_ + NF_2V,  64,  64,   4,   2, 8192,   INV_SQRT64};
      m.nd = 7; m.tot = NFRAG_TOT;
      k_prepmulti<<<1024, 256, 0, stream>>>(m);
    }

    // conv1 node: dense + sc partials -> reduce -> out1
    k_gemm<4,8><<<79, 512, 0, stream>>>(ns_, 128, N_NODES, nfrag_ + NF_WLS, part_ + (size_t)8*NM128);
    k_scp<4><<<dim3(79,8), 512, 0, stream>>>(s_, node_attr, nfrag_ + NF_C1, part_);
    k_reduce<<<(NM128/4+255)/256, 256, 0, stream>>>(part_, out1_);

    // gate phase via MFMA: ov = n_v@lin2_v ; gate elementwise ; hs,hv GEMMs
    k_gemm<4,4><<<235, 512, 0, stream>>>(nv_, 128, N_NODES*3, nfrag_ + NF_LV, ov_);
    k_gatee<<<(N_NODES*64+255)/256, 256, 0, stream>>>(out1_, ov_, gs_, gv_);
    k_gemm<2,4><<<79, 512, 0, stream>>>(gs_, 64, N_NODES, nfrag_ + NF_2S, hs_);
    k_gemm<2,4><<<235, 512, 0, stream>>>(gv_, 64, N_NODES*3, nfrag_ + NF_2V, hv_);

    // conv2 edge MLP + gather (lower wbuf only)
    k_mlp<8><<<625, 256, 0, stream>>>(es8, frag_ + F_B1b, frag_ + F_B2b, frag_ + F_B3b, wbuf_);
    k_gather2<<<(N_NODES+3)/4, 256, 0, stream>>>(wbuf_, shv, esrc, offs_, slot_, hs_, hv_, nmid_);

    // conv2 node: partials -> reduce -> pool
    k_gemm<4,8><<<79, 512, 0, stream>>>(nmid_, 128, N_NODES, nfrag_ + NF_W2, part_ + (size_t)8*NM128);
    k_scp<2><<<dim3(79,8), 512, 0, stream>>>(gs_, node_attr, nfrag_ + NF_C2, part_);
    k_reduce<<<(NM128/4+255)/256, 256, 0, stream>>>(part_, out2_);
    k_pool<<<N_NODES/4, 128, 0, stream>>>(out2_, batch, pool_);
  } else {
    hipMemsetAsync(ns_, 0, (size_t)(OFF_HIST - OFF_NS)*sizeof(float), stream);
    k_cnt<<<(N_NODES+255)/256, 256, 0, stream>>>(batch, cnt_);
    k_edge1_at<<<256, 512, 0, stream>>>(es8, shv, esrc, edst, h_,
                                        c1_fc_w0, c1_fc_w1, c1_fc_w2, ns_, nv_);
    k_node1<<<N_NODES/4, 128, 0, stream>>>(ns_, nv_, s_, node_attr,
                                           c1_lin2_s, c1_lin2_v, c1_sc,
                                           c2_lin1_s, c2_lin1_v, gs_, hs_, hv_);
    k_edge2_at<<<512, 512, 0, stream>>>(es8, shv, esrc, edst, hs_, hv_,
                                        c2_fc_w0, c2_fc_w1, c2_fc_w2, nmid_);
    k_node2<<<N_NODES/4, 128, 0, stream>>>(nmid_, gs_, node_attr, batch,
                                           c2_lin2, c2_sc, pool_);
  }

  k_head<<<1, 128, 0, stream>>>(pool_, cnt_, Wr1, Wr2, (float*)d_out);
}

// Round 7
// 399.079 us; speedup vs baseline: 3.1450x; 1.1945x over previous
//
#include <hip/hip_runtime.h>
#include <hip/hip_fp16.h>

#define N_NODES 10000
#define N_EDGES 160000
#define N_GRAPHS 16

typedef __attribute__((ext_vector_type(8))) short s16x8;
typedef __attribute__((ext_vector_type(4))) float f32x4;
typedef unsigned int uint32;
typedef unsigned short u16;

// ---- workspace layout (float offsets) ----
#define OFF_ES8  0
#define OFF_SHV  (OFF_ES8 + N_EDGES*8)
#define OFF_S    (OFF_SHV + N_EDGES*3)
#define OFF_H    (OFF_S   + N_NODES*128)
#define OFF_GS   (OFF_H   + N_NODES*128)
#define OFF_HS   (OFF_GS  + N_NODES*64)
#define OFF_HV   (OFF_HS  + N_NODES*64)
#define OFF_NS   (OFF_HV  + N_NODES*192)   /* fallback zero-region start */
#define OFF_NV   (OFF_NS  + N_NODES*128)
#define OFF_NMID (OFF_NV  + N_NODES*384)
#define OFF_POOL (OFF_NMID+ N_NODES*128)   /* new-path zero-region start */
#define OFF_CNT  (OFF_POOL+ N_GRAPHS*128)
#define OFF_HIST (OFF_CNT + N_GRAPHS)
#define OFF_CURS (OFF_HIST+ N_NODES)
#define OFF_OFFS (OFF_CURS+ N_NODES)       /* new-path zero-region end (excl) */
#define OFF_FRAG (OFF_OFFS+ N_NODES + 16)  /* persistent frags: 114688 shorts = 57344 floats */
#define OFF_SLOT (OFF_FRAG+ 57344)
#define OFF_WBUF (OFF_SLOT+ N_EDGES)
#define WBUF_FLOATS ((size_t)N_EDGES*256)
#define WS_NEED_BYTES ((size_t)(OFF_WBUF + WBUF_FLOATS) * 4)

// persistent frag sub-offsets in shorts
#define F_B1   0        /* conv1 L1: NF4 KS1 -> 4096  */
#define F_B2   4096     /* conv1 L2: NF4 KS2 -> 8192  */
#define F_B3   12288    /* conv1 L3: NF16 KS2 -> 32768 */
#define F_B1b  45056
#define F_B2b  49152
#define F_B3b  57344    /* conv2 L3: NF8 KS2 -> 16384 */
#define F_WE   73728    /* W_embed: NF8 KS1 -> 8192 */
#define F_L1   81920    /* c1_lin1: NF8 KS4 -> 32768 */
#define FRAG_TOT 114688

// node-frag sub-offsets in shorts, within the upper-wbuf nfrag region
#define NF_WLS 0        /* c1_lin2_s: NF8 KS4 -> 32768 */
#define NF_C1  32768    /* c1_sc:   NF128 KS4 -> 524288 */
#define NF_W2  557056   /* c2_lin2:  NF8 KS4 -> 32768 */
#define NF_C2  589824   /* c2_sc:   NF128 KS2 -> 262144 */
#define NF_LV  851968   /* c1_lin2_v: NF4 KS4 -> 16384 */
#define NF_2S  868352   /* c2_lin1_s: NF4 KS2 -> 8192 */
#define NF_2V  876544   /* c2_lin1_v: NF4 KS2 -> 8192 */
#define NFRAG_TOT 884736

#define NM128 (N_NODES*128)

#define INV_SQRT32   0.17677669529663687f
#define INV_SQRT128  0.08838834764831845f
#define INV_SQRT8    0.3535533905932738f
#define INV_SQRT64   0.125f
#define INV_SQRT2048 0.022097086912079608f
#define INV_SQRT1024 0.03125f
#define INV_SQRT10   0.31622776601683794f
#define INV_SQRT3    0.5773502691896258f
#define SQRT3_C      1.7320508075688772f

__device__ __forceinline__ float siluf(float x){ return x / (1.f + __expf(-x)); }
__device__ __forceinline__ float sigf (float x){ return 1.f / (1.f + __expf(-x)); }
__device__ __forceinline__ unsigned short bf16h(float x){
  uint32 u = __float_as_uint(x);
  u += 0x7FFFu + ((u >> 16) & 1u);
  return (unsigned short)(u >> 16);
}
__device__ __forceinline__ float bf2f(unsigned short h){
  return __uint_as_float(((uint32)h) << 16);
}
__device__ __forceinline__ u16 f2h(float x){ return __half_as_ushort(__float2half_rn(x)); }
__device__ __forceinline__ float h2f(u16 b){ return __half2float(__ushort_as_half(b)); }
__device__ __forceinline__ void split8(const float* __restrict__ p, s16x8& hi, s16x8& lo) {
  f32x4 v0 = *(const f32x4*)p;
  f32x4 v1 = *(const f32x4*)(p + 4);
  float vals[8] = {v0[0],v0[1],v0[2],v0[3],v1[0],v1[1],v1[2],v1[3]};
  #pragma unroll
  for (int j = 0; j < 8; ++j) {
    unsigned short hh = bf16h(vals[j]);
    hi[j] = (short)hh;
    lo[j] = (short)bf16h(vals[j] - bf2f(hh));
  }
}

// ---------------- edge geometry ----------------
__global__ void k_geom(const float* __restrict__ evec,
                       float* __restrict__ es8, float* __restrict__ shv) {
  int e = blockIdx.x*256 + threadIdx.x;
  if (e >= N_EDGES) return;
  float vx = evec[e*3+0], vy = evec[e*3+1], vz = evec[e*3+2];
  float d  = sqrtf(vx*vx + vy*vy + vz*vz);
  float xs = d - 0.25f;
  bool  in = (xs > 0.f) && (xs < 4.0f);
  float safe = xs > 0.f ? xs : 1.f;
  float amp  = in ? 2.0f/safe : 0.f;
  const float PI4 = 0.7853981633974483f;
  #pragma unroll
  for (int k = 0; k < 8; ++k)
    es8[e*8+k] = amp * sinf((float)(k+1) * PI4 * safe);
  float invd = d > 0.f ? 1.f/d : 1.f;
  shv[e*3+0] = SQRT3_C*vx*invd;
  shv[e*3+1] = SQRT3_C*vy*invd;
  shv[e*3+2] = SQRT3_C*vz*invd;
}

// ---------------- fallback scalar linear ----------------
__global__ void k_linear128(const float* __restrict__ A, const float* __restrict__ W,
                            float* __restrict__ O, int K, float scale, int total) {
  int t = blockIdx.x*256 + threadIdx.x;
  if (t >= total) return;
  int n = t >> 7, j = t & 127;
  const float* a = A + n*K;
  float a0=0.f,a1=0.f,a2=0.f,a3=0.f;
  for (int k = 0; k < K; k += 4) {
    a0 += a[k+0]*W[(k+0)*128+j];
    a1 += a[k+1]*W[(k+1)*128+j];
    a2 += a[k+2]*W[(k+2)*128+j];
    a3 += a[k+3]*W[(k+3)*128+j];
  }
  O[t] = (a0+a1+a2+a3)*scale;
}

// ---------------- graph node counts ----------------
__global__ void k_cnt(const int* __restrict__ batch, float* __restrict__ cnt) {
  __shared__ int lc[N_GRAPHS];
  int t = threadIdx.x;
  if (t < N_GRAPHS) lc[t] = 0;
  __syncthreads();
  int i = blockIdx.x*256 + t;
  if (i < N_NODES) atomicAdd(&lc[batch[i]], 1);
  __syncthreads();
  if (t < N_GRAPHS && lc[t] > 0) atomicAdd(&cnt[t], (float)lc[t]);
}

// ---------------- CSR build ----------------
__global__ void k_hist(const int* __restrict__ edst, int* __restrict__ hist) {
  int e = blockIdx.x*256 + threadIdx.x;
  if (e < N_EDGES) atomicAdd(&hist[edst[e]], 1);
}

__global__ __launch_bounds__(1024) void k_scanp(const int* __restrict__ hist,
                                                int* __restrict__ offs) {
  __shared__ int wsum[16];
  const int t = threadIdx.x;
  const int lane = t & 63, w = t >> 6;
  const int base = t*10;
  int v[10]; int s = 0;
  #pragma unroll
  for (int i = 0; i < 10; ++i) {
    int idx = base + i;
    int x = (idx < N_NODES) ? hist[idx] : 0;
    s += x; v[i] = s;
  }
  int ws = s;
  #pragma unroll
  for (int d = 1; d < 64; d <<= 1) {
    int u = __shfl_up(ws, d);
    if (lane >= d) ws += u;
  }
  if (lane == 63) wsum[w] = ws;
  __syncthreads();
  if (w == 0) {
    int x = (lane < 16) ? wsum[lane] : 0;
    #pragma unroll
    for (int d = 1; d < 16; d <<= 1) {
      int u = __shfl_up(x, d);
      if (lane >= d) x += u;
    }
    if (lane < 16) wsum[lane] = x;
  }
  __syncthreads();
  int waveoff = (w > 0) ? wsum[w-1] : 0;
  int texcl = waveoff + ws - s;
  if (t == 0) offs[0] = 0;
  #pragma unroll
  for (int i = 0; i < 10; ++i) {
    int idx = base + i;
    if (idx < N_NODES) offs[idx+1] = texcl + v[i];
  }
}

__global__ void k_slot(const int* __restrict__ edst, const int* __restrict__ offs,
                       int* __restrict__ curs, int* __restrict__ slot) {
  int e = blockIdx.x*256 + threadIdx.x;
  if (e < N_EDGES) {
    int d = edst[e];
    int p = offs[d] + atomicAdd(&curs[d], 1);
    slot[p] = e;
  }
}

// ---------------- merged weight fragment prep ----------------
struct PD { const float* W; short* dst; int Keff, N, NF, KS, nElem; float scale; };
struct PD8 { PD d[8]; int nd; int tot; };

__global__ void k_prepmulti(PD8 ds) {
  int stride = gridDim.x*256;
  for (int t = blockIdx.x*256 + threadIdx.x; t < ds.tot; t += stride) {
    int rem = t, i = 0;
    while (i < ds.nd-1 && rem >= ds.d[i].nElem) { rem -= ds.d[i].nElem; ++i; }
    const PD p = ds.d[i];
    int j = rem & 7;
    int l = (rem >> 3) & 63;
    int rest = rem >> 9;
    int ks = rest % p.KS; rest /= p.KS;
    int nf = rest % p.NF;
    int pp = rest / p.NF;
    int k   = ks*32 + (l >> 4)*8 + j;
    int col = nf*16 + (l & 15);
    float v = (k < p.Keff) ? p.W[(size_t)k*p.N + col]*p.scale : 0.f;
    unsigned short hi = bf16h(v);
    unsigned short o = pp ? bf16h(v - bf2f(hi)) : hi;
    p.dst[rem] = (short)o;
  }
}

// ---------------- fused 3-layer edge MLP via MFMA; outputs fp16 ----------------
template<int NF3>
__global__ __launch_bounds__(256) void k_mlp(
    const float* __restrict__ es8,
    const short* __restrict__ fb1, const short* __restrict__ fb2,
    const short* __restrict__ fb3, u16* __restrict__ wbuf) {
  __shared__ __align__(16) short route[4][4608];
  const int w = threadIdx.x >> 6, l = threadIdx.x & 63;
  const int lrow = l & 15, lhi = l >> 4;
  const int e0 = (blockIdx.x*4 + w)*64;
  short* rt = route[w];

  s16x8 ah1[4], al1[4];
  #pragma unroll
  for (int mt = 0; mt < 4; ++mt) {
    s16x8 h = {0,0,0,0,0,0,0,0}, lo = {0,0,0,0,0,0,0,0};
    if (lhi == 0) {
      const float* ep = es8 + (size_t)(e0 + mt*16 + lrow)*8;
      split8(ep, h, lo);
    }
    ah1[mt] = h; al1[mt] = lo;
  }

  f32x4 acc1[4][4];
  #pragma unroll
  for (int mt = 0; mt < 4; ++mt)
    #pragma unroll
    for (int nf = 0; nf < 4; ++nf) acc1[mt][nf] = (f32x4){0.f,0.f,0.f,0.f};
  #pragma unroll
  for (int nf = 0; nf < 4; ++nf) {
    s16x8 bh = *(const s16x8*)(fb1 + ((0*4 + nf)*1 + 0)*512 + l*8);
    s16x8 bl = *(const s16x8*)(fb1 + ((1*4 + nf)*1 + 0)*512 + l*8);
    #pragma unroll
    for (int mt = 0; mt < 4; ++mt) {
      acc1[mt][nf] = __builtin_amdgcn_mfma_f32_16x16x32_bf16(ah1[mt], bh, acc1[mt][nf], 0,0,0);
      acc1[mt][nf] = __builtin_amdgcn_mfma_f32_16x16x32_bf16(ah1[mt], bl, acc1[mt][nf], 0,0,0);
      acc1[mt][nf] = __builtin_amdgcn_mfma_f32_16x16x32_bf16(al1[mt], bh, acc1[mt][nf], 0,0,0);
    }
  }
  #pragma unroll
  for (int mt = 0; mt < 4; ++mt)
    #pragma unroll
    for (int nf = 0; nf < 4; ++nf)
      #pragma unroll
      for (int r = 0; r < 4; ++r) acc1[mt][nf][r] = siluf(acc1[mt][nf][r]);

  s16x8 ah2[4][2], al2[4][2];
  #pragma unroll
  for (int mt = 0; mt < 4; ++mt)
    #pragma unroll
    for (int nf = 0; nf < 4; ++nf)
      #pragma unroll
      for (int r = 0; r < 4; ++r)
        rt[(mt*16 + lhi*4 + r)*72 + nf*16 + lrow] = (short)bf16h(acc1[mt][nf][r]);
  #pragma unroll
  for (int mt = 0; mt < 4; ++mt)
    #pragma unroll
    for (int ks = 0; ks < 2; ++ks)
      ah2[mt][ks] = *(const s16x8*)&rt[(mt*16 + lrow)*72 + ks*32 + lhi*8];
  #pragma unroll
  for (int mt = 0; mt < 4; ++mt)
    #pragma unroll
    for (int nf = 0; nf < 4; ++nf)
      #pragma unroll
      for (int r = 0; r < 4; ++r) {
        float v = acc1[mt][nf][r];
        unsigned short hh = bf16h(v);
        rt[(mt*16 + lhi*4 + r)*72 + nf*16 + lrow] = (short)bf16h(v - bf2f(hh));
      }
  #pragma unroll
  for (int mt = 0; mt < 4; ++mt)
    #pragma unroll
    for (int ks = 0; ks < 2; ++ks)
      al2[mt][ks] = *(const s16x8*)&rt[(mt*16 + lrow)*72 + ks*32 + lhi*8];

  f32x4 acc2[4][4];
  #pragma unroll
  for (int mt = 0; mt < 4; ++mt)
    #pragma unroll
    for (int nf = 0; nf < 4; ++nf) acc2[mt][nf] = (f32x4){0.f,0.f,0.f,0.f};
  #pragma unroll
  for (int nf = 0; nf < 4; ++nf)
    #pragma unroll
    for (int ks = 0; ks < 2; ++ks) {
      s16x8 bh = *(const s16x8*)(fb2 + ((0*4 + nf)*2 + ks)*512 + l*8);
      s16x8 bl = *(const s16x8*)(fb2 + ((1*4 + nf)*2 + ks)*512 + l*8);
      #pragma unroll
      for (int mt = 0; mt < 4; ++mt) {
        acc2[mt][nf] = __builtin_amdgcn_mfma_f32_16x16x32_bf16(ah2[mt][ks], bh, acc2[mt][nf], 0,0,0);
        acc2[mt][nf] = __builtin_amdgcn_mfma_f32_16x16x32_bf16(ah2[mt][ks], bl, acc2[mt][nf], 0,0,0);
        acc2[mt][nf] = __builtin_amdgcn_mfma_f32_16x16x32_bf16(al2[mt][ks], bh, acc2[mt][nf], 0,0,0);
      }
    }
  #pragma unroll
  for (int mt = 0; mt < 4; ++mt)
    #pragma unroll
    for (int nf = 0; nf < 4; ++nf)
      #pragma unroll
      for (int r = 0; r < 4; ++r) acc2[mt][nf][r] = siluf(acc2[mt][nf][r]);

  s16x8 ah3[4][2], al3[4][2];
  #pragma unroll
  for (int mt = 0; mt < 4; ++mt)
    #pragma unroll
    for (int nf = 0; nf < 4; ++nf)
      #pragma unroll
      for (int r = 0; r < 4; ++r)
        rt[(mt*16 + lhi*4 + r)*72 + nf*16 + lrow] = (short)bf16h(acc2[mt][nf][r]);
  #pragma unroll
  for (int mt = 0; mt < 4; ++mt)
    #pragma unroll
    for (int ks = 0; ks < 2; ++ks)
      ah3[mt][ks] = *(const s16x8*)&rt[(mt*16 + lrow)*72 + ks*32 + lhi*8];
  #pragma unroll
  for (int mt = 0; mt < 4; ++mt)
    #pragma unroll
    for (int nf = 0; nf < 4; ++nf)
      #pragma unroll
      for (int r = 0; r < 4; ++r) {
        float v = acc2[mt][nf][r];
        unsigned short hh = bf16h(v);
        rt[(mt*16 + lhi*4 + r)*72 + nf*16 + lrow] = (short)bf16h(v - bf2f(hh));
      }
  #pragma unroll
  for (int mt = 0; mt < 4; ++mt)
    #pragma unroll
    for (int ks = 0; ks < 2; ++ks)
      al3[mt][ks] = *(const s16x8*)&rt[(mt*16 + lrow)*72 + ks*32 + lhi*8];

  for (int nf3 = 0; nf3 < NF3; ++nf3) {
    f32x4 acc3[4];
    #pragma unroll
    for (int mt = 0; mt < 4; ++mt) acc3[mt] = (f32x4){0.f,0.f,0.f,0.f};
    #pragma unroll
    for (int ks = 0; ks < 2; ++ks) {
      s16x8 bh = *(const s16x8*)(fb3 + ((size_t)(0*NF3 + nf3)*2 + ks)*512 + l*8);
      s16x8 bl = *(const s16x8*)(fb3 + ((size_t)(1*NF3 + nf3)*2 + ks)*512 + l*8);
      #pragma unroll
      for (int mt = 0; mt < 4; ++mt) {
        acc3[mt] = __builtin_amdgcn_mfma_f32_16x16x32_bf16(ah3[mt][ks], bh, acc3[mt], 0,0,0);
        acc3[mt] = __builtin_amdgcn_mfma_f32_16x16x32_bf16(ah3[mt][ks], bl, acc3[mt], 0,0,0);
        acc3[mt] = __builtin_amdgcn_mfma_f32_16x16x32_bf16(al3[mt][ks], bh, acc3[mt], 0,0,0);
      }
    }
    #pragma unroll
    for (int mt = 0; mt < 4; ++mt)
      #pragma unroll
      for (int r = 0; r < 4; ++r)
        wbuf[(size_t)(e0 + mt*16 + lhi*4 + r)*(NF3*16) + nf3*16 + lrow] = f2h(acc3[mt][r]);
  }
}

// ---------------- generic MFMA GEMM ----------------
template<int KS, int NF>
__global__ __launch_bounds__(512, 4) void k_gemm(
    const float* __restrict__ A, int rstride, int M,
    const short* __restrict__ fB, float* __restrict__ O) {
  __shared__ __align__(16) short lB[2*NF*KS*512];
  const int tid = threadIdx.x;
  const int w = tid >> 6, l = tid & 63;
  const int lrow = l & 15, lhi = l >> 4;
  const int n0 = blockIdx.x*128 + w*16;
  for (int i = tid; i < 2*NF*KS*64; i += 512)
    *(s16x8*)&lB[(size_t)i*8] = *(const s16x8*)&fB[(size_t)i*8];
  s16x8 ah[KS], al[KS];
  {
    int row = n0 + lrow; if (row > M-1) row = M-1;
    #pragma unroll
    for (int ks = 0; ks < KS; ++ks)
      split8(A + (size_t)row*rstride + ks*32 + lhi*8, ah[ks], al[ks]);
  }
  __syncthreads();
  f32x4 acc[NF];
  #pragma unroll
  for (int nf = 0; nf < NF; ++nf) acc[nf] = (f32x4){0.f,0.f,0.f,0.f};
  #pragma unroll
  for (int nf = 0; nf < NF; ++nf)
    #pragma unroll
    for (int ks = 0; ks < KS; ++ks) {
      s16x8 bh = *(const s16x8*)&lB[((0*NF + nf)*KS + ks)*512 + l*8];
      s16x8 bl = *(const s16x8*)&lB[((1*NF + nf)*KS + ks)*512 + l*8];
      acc[nf] = __builtin_amdgcn_mfma_f32_16x16x32_bf16(ah[ks], bh, acc[nf], 0,0,0);
      acc[nf] = __builtin_amdgcn_mfma_f32_16x16x32_bf16(ah[ks], bl, acc[nf], 0,0,0);
      acc[nf] = __builtin_amdgcn_mfma_f32_16x16x32_bf16(al[ks], bh, acc[nf], 0,0,0);
    }
  #pragma unroll
  for (int nf = 0; nf < NF; ++nf)
    #pragma unroll
    for (int r = 0; r < 4; ++r) {
      int row = n0 + lhi*4 + r;
      if (row < M) O[(size_t)row*(NF*16) + nf*16 + lrow] = acc[nf][r];
    }
}

// ---------------- sc partial ----------------
template<int KSO>
__global__ __launch_bounds__(512, 4) void k_scp(
    const float* __restrict__ Ao, const float* __restrict__ na,
    const short* __restrict__ fBc, float* __restrict__ part) {
  __shared__ __align__(16) short lB[KSO*8192];
  const int tid = threadIdx.x;
  const int w = tid >> 6, l = tid & 63;
  const int lrow = l & 15, lhi = l >> 4;
  const int n0 = blockIdx.x*128 + w*16;
  const int vp = blockIdx.y;

  s16x8 aoh[KSO], aol[KSO];
  {
    int row = n0 + lrow; if (row > N_NODES-1) row = N_NODES-1;
    #pragma unroll
    for (int ks = 0; ks < KSO; ++ks)
      split8(Ao + (size_t)row*(KSO*32) + ks*32 + lhi*8, aoh[ks], aol[ks]);
  }

  f32x4 acc[8];
  #pragma unroll
  for (int nf = 0; nf < 8; ++nf) acc[nf] = (f32x4){0.f,0.f,0.f,0.f};

  #pragma unroll
  for (int c = 0; c < 2; ++c) {
    const int v = vp*2 + c;
    __syncthreads();
    for (int i = tid; i < KSO*1024; i += 512) {
      int gl = i & 63;
      int rest = i >> 6;
      int ks = rest % KSO;
      int rest2 = rest / KSO;
      int nf = rest2 & 7;
      int p  = rest2 >> 3;
      size_t src = ((((size_t)p*128 + (v*8 + nf))*KSO + ks)*64 + gl)*8;
      *(s16x8*)&lB[(size_t)i*8] = *(const s16x8*)&fBc[src];
    }
    __syncthreads();
    f32x4 dacc[8];
    #pragma unroll
    for (int nf = 0; nf < 8; ++nf) dacc[nf] = (f32x4){0.f,0.f,0.f,0.f};
    #pragma unroll
    for (int nf = 0; nf < 8; ++nf)
      #pragma unroll
      for (int ks = 0; ks < KSO; ++ks) {
        s16x8 bh = *(const s16x8*)&lB[((0*8 + nf)*KSO + ks)*512 + l*8];
        s16x8 bl = *(const s16x8*)&lB[((1*8 + nf)*KSO + ks)*512 + l*8];
        dacc[nf] = __builtin_amdgcn_mfma_f32_16x16x32_bf16(aoh[ks], bh, dacc[nf], 0,0,0);
        dacc[nf] = __builtin_amdgcn_mfma_f32_16x16x32_bf16(aoh[ks], bl, dacc[nf], 0,0,0);
        dacc[nf] = __builtin_amdgcn_mfma_f32_16x16x32_bf16(aol[ks], bh, dacc[nf], 0,0,0);
      }
    #pragma unroll
    for (int r = 0; r < 4; ++r) {
      int row = n0 + lhi*4 + r; if (row > N_NODES-1) row = N_NODES-1;
      float nav = na[(size_t)row*16 + v];
      #pragma unroll
      for (int nf = 0; nf < 8; ++nf) acc[nf][r] += nav * dacc[nf][r];
    }
  }

  float* pp = part + (size_t)vp*NM128;
  #pragma unroll
  for (int nf = 0; nf < 8; ++nf)
    #pragma unroll
    for (int r = 0; r < 4; ++r) {
      int row = n0 + lhi*4 + r;
      if (row < N_NODES) pp[(size_t)row*128 + nf*16 + lrow] = acc[nf][r];
    }
}

// ---------------- reduce 9 partials (float4) ----------------
__global__ void k_reduce(const float* __restrict__ part, float* __restrict__ outs) {
  int i = blockIdx.x*256 + threadIdx.x;
  if (i >= NM128/4) return;
  f32x4 s = {0.f,0.f,0.f,0.f};
  #pragma unroll
  for (int p = 0; p < 9; ++p)
    s += *(const f32x4*)(part + (size_t)p*NM128 + (size_t)i*4);
  *(f32x4*)(outs + (size_t)i*4) = s;
}

// ---------------- conv1 gather: CSR pull (fp16 wbuf); n_v as [n][3][128] ----------------
__global__ __launch_bounds__(256) void k_gather1(
    const u16* __restrict__ wbuf, const float* __restrict__ shv,
    const int* __restrict__ esrc, const int* __restrict__ offs, const int* __restrict__ slot,
    const float* __restrict__ h,
    float* __restrict__ n_s, float* __restrict__ n_v) {
  const int wave = threadIdx.x >> 6, lane = threadIdx.x & 63;
  const int n = blockIdx.x*4 + wave;
  if (n >= N_NODES) return;
  const int s0 = offs[n], s1 = offs[n+1];
  float ns0=0.f, ns1=0.f;
  float nv00=0.f,nv01=0.f,nv02=0.f, nv10=0.f,nv11=0.f,nv12=0.f;
  for (int s = s0; s < s1; ++s) {
    int e = slot[s];
    int src = esrc[e];
    const u16* wp = wbuf + (size_t)e*256;
    float c0 = h2f(wp[lane]),     c1 = h2f(wp[64+lane]);
    float c2 = h2f(wp[128+lane]), c3 = h2f(wp[192+lane]);
    float h0 = h[src*128+lane], h1 = h[src*128+64+lane];
    float sv0 = shv[e*3+0], sv1 = shv[e*3+1], sv2 = shv[e*3+2];
    ns0 += c0*h0; ns1 += c1*h1;
    float t0 = c2*h0, t1 = c3*h1;
    nv00 += t0*sv0; nv01 += t0*sv1; nv02 += t0*sv2;
    nv10 += t1*sv0; nv11 += t1*sv1; nv12 += t1*sv2;
  }
  n_s[n*128+lane]    = ns0*INV_SQRT10;
  n_s[n*128+64+lane] = ns1*INV_SQRT10;
  float* nvp = n_v + (size_t)n*384;      // [3][128]
  nvp[0*128+lane]    = nv00*INV_SQRT10;
  nvp[1*128+lane]    = nv01*INV_SQRT10;
  nvp[2*128+lane]    = nv02*INV_SQRT10;
  nvp[0*128+64+lane] = nv10*INV_SQRT10;
  nvp[1*128+64+lane] = nv11*INV_SQRT10;
  nvp[2*128+64+lane] = nv12*INV_SQRT10;
}

// ---------------- conv2 gather (fp16 wbuf): h_v layout [n][3][64] ----------------
__global__ __launch_bounds__(256) void k_gather2(
    const u16* __restrict__ wbuf, const float* __restrict__ shv,
    const int* __restrict__ esrc, const int* __restrict__ offs, const int* __restrict__ slot,
    const float* __restrict__ h_s, const float* __restrict__ h_v,
    float* __restrict__ n_mid) {
  const int wave = threadIdx.x >> 6, lane = threadIdx.x & 63;
  const int n = blockIdx.x*4 + wave;
  if (n >= N_NODES) return;
  const int s0 = offs[n], s1 = offs[n+1];
  float acc0 = 0.f, acc1 = 0.f;
  for (int s = s0; s < s1; ++s) {
    int e = slot[s];
    int src = esrc[e];
    const u16* wp = wbuf + (size_t)e*128;
    float w0 = h2f(wp[lane]), w1 = h2f(wp[64+lane]);
    float hs = h_s[src*64+lane];
    const float* hvp = h_v + (size_t)src*192;
    float sv0 = shv[e*3+0], sv1 = shv[e*3+1], sv2 = shv[e*3+2];
    float dot = hvp[lane]*sv0 + hvp[64+lane]*sv1 + hvp[128+lane]*sv2;
    acc0 += w0*hs;
    acc1 += w1*dot;
  }
  n_mid[n*128+lane]    = acc0*INV_SQRT10;
  n_mid[n*128+64+lane] = acc1*INV_SQRT3*INV_SQRT10;
}

// ---------------- elementwise gating ----------------
__global__ void k_gatee(const float* __restrict__ outs, const float* __restrict__ ov,
                        float* __restrict__ gs_out, float* __restrict__ gv) {
  int t = blockIdx.x*256 + threadIdx.x;
  if (t >= N_NODES*64) return;
  int n = t >> 6, v = t & 63;
  float g = siluf(outs[(size_t)n*128 + v]);
  float gate = sigf(outs[(size_t)n*128 + 64 + v]);
  gs_out[(size_t)n*64 + v] = g;
  gv[(size_t)n*192 + 0*64 + v] = gate*ov[(size_t)n*192 + 0*64 + v];
  gv[(size_t)n*192 + 1*64 + v] = gate*ov[(size_t)n*192 + 1*64 + v];
  gv[(size_t)n*192 + 2*64 + v] = gate*ov[(size_t)n*192 + 2*64 + v];
}

// ---------------- pooled accumulation (RLE on sorted batch) ----------------
__global__ __launch_bounds__(128) void k_pool(
    const float* __restrict__ outs, const int* __restrict__ batch,
    float* __restrict__ pool) {
  const int j = threadIdx.x;
  const int n0 = blockIdx.x*4;
  float outv[4];
  #pragma unroll
  for (int n = 0; n < 4; ++n) outv[n] = outs[(size_t)(n0+n)*128 + j];
  int b0 = batch[n0], b1 = batch[n0+1], b2 = batch[n0+2], b3 = batch[n0+3];
  float sum = outv[0]; int cur = b0;
  if (b1 == cur) sum += outv[1]; else { atomicAdd(&pool[cur*128+j], sum); cur = b1; sum = outv[1]; }
  if (b2 == cur) sum += outv[2]; else { atomicAdd(&pool[cur*128+j], sum); cur = b2; sum = outv[2]; }
  if (b3 == cur) sum += outv[3]; else { atomicAdd(&pool[cur*128+j], sum); cur = b3; sum = outv[3]; }
  atomicAdd(&pool[cur*128+j], sum);
}

// ======== FALLBACK (atomic) kernels — used only if ws too small ========
__global__ __launch_bounds__(512) void k_edge1_at(
    const float* __restrict__ es8, const float* __restrict__ shv,
    const int* __restrict__ esrc, const int* __restrict__ edst,
    const float* __restrict__ h,
    const float* __restrict__ W0, const float* __restrict__ W1, const float* __restrict__ W2,
    float* __restrict__ n_s, float* __restrict__ n_v) {
  __shared__ float lW0[512];
  __shared__ float lW1[4096];
  __shared__ float lW2[16384];
  __shared__ float lA[8][64];
  __shared__ float lB[8][64];
  for (int i = threadIdx.x; i < 512;   i += 512) lW0[i] = W0[i];
  for (int i = threadIdx.x; i < 4096;  i += 512) lW1[i] = W1[i];
  for (int i = threadIdx.x; i < 16384; i += 512) lW2[i] = W2[i];
  __syncthreads();
  const int wave = threadIdx.x >> 6, lane = threadIdx.x & 63;
  const int nw = gridDim.x * 8;
  const int e0 = blockIdx.x*8 + wave;
  const int iters = (N_EDGES + nw - 1) / nw;
  for (int it = 0; it < iters; ++it) {
    int e = e0 + it*nw;
    bool valid = e < N_EDGES;
    float a = 0.f, sv0=0.f, sv1=0.f, sv2=0.f;
    int src = 0, dst = 0;
    if (valid) {
      const float* ep = es8 + e*8;
      sv0 = shv[e*3+0]; sv1 = shv[e*3+1]; sv2 = shv[e*3+2];
      src = esrc[e]; dst = edst[e];
      a = ep[0]*lW0[lane]      + ep[1]*lW0[64+lane]  + ep[2]*lW0[128+lane] + ep[3]*lW0[192+lane]
        + ep[4]*lW0[256+lane]  + ep[5]*lW0[320+lane] + ep[6]*lW0[384+lane] + ep[7]*lW0[448+lane];
      a = siluf(a * INV_SQRT8);
    }
    lA[wave][lane] = a;
    __syncthreads();
    {
      float b0=0.f;
      #pragma unroll
      for (int k = 0; k < 64; ++k) b0 += lA[wave][k]*lW1[k*64+lane];
      lB[wave][lane] = siluf(b0 * INV_SQRT64);
    }
    __syncthreads();
    if (valid) {
      float c0=0.f,c1=0.f,c2=0.f,c3=0.f;
      #pragma unroll
      for (int k = 0; k < 64; ++k) {
        float bk = lB[wave][k];
        const float* r = lW2 + k*256;
        c0 += bk*r[lane]; c1 += bk*r[64+lane]; c2 += bk*r[128+lane]; c3 += bk*r[192+lane];
      }
      float hs0 = h[src*128 + lane];
      float hs1 = h[src*128 + 64 + lane];
      atomicAdd(&n_s[dst*128 + lane],      c0*INV_SQRT64*hs0*INV_SQRT10);
      atomicAdd(&n_s[dst*128 + 64 + lane], c1*INV_SQRT64*hs1*INV_SQRT10);
      float t0 = c2*INV_SQRT64*hs0*INV_SQRT10;
      float t1 = c3*INV_SQRT64*hs1*INV_SQRT10;
      float* nvp = n_v + dst*384;
      atomicAdd(nvp + lane*3+0, t0*sv0);
      atomicAdd(nvp + lane*3+1, t0*sv1);
      atomicAdd(nvp + lane*3+2, t0*sv2);
      atomicAdd(nvp + (64+lane)*3+0, t1*sv0);
      atomicAdd(nvp + (64+lane)*3+1, t1*sv1);
      atomicAdd(nvp + (64+lane)*3+2, t1*sv2);
    }
  }
}

__global__ __launch_bounds__(512) void k_edge2_at(
    const float* __restrict__ es8, const float* __restrict__ shv,
    const int* __restrict__ esrc, const int* __restrict__ edst,
    const float* __restrict__ h_s, const float* __restrict__ h_v,
    const float* __restrict__ W0, const float* __restrict__ W1, const float* __restrict__ W2,
    float* __restrict__ n_mid) {
  __shared__ float lW0[512];
  __shared__ float lW1[4096];
  __shared__ float lW2[8192];
  __shared__ float lA[8][64];
  __shared__ float lB[8][64];
  for (int i = threadIdx.x; i < 512;  i += 512) lW0[i] = W0[i];
  for (int i = threadIdx.x; i < 4096; i += 512) lW1[i] = W1[i];
  for (int i = threadIdx.x; i < 8192; i += 512) lW2[i] = W2[i];
  __syncthreads();
  const int wave = threadIdx.x >> 6, lane = threadIdx.x & 63;
  const int nw = gridDim.x * 8;
  const int e0 = blockIdx.x*8 + wave;
  const int iters = (N_EDGES + nw - 1) / nw;
  for (int it = 0; it < iters; ++it) {
    int e = e0 + it*nw;
    bool valid = e < N_EDGES;
    float a = 0.f, sv0=0.f, sv1=0.f, sv2=0.f;
    int src = 0, dst = 0;
    if (valid) {
      const float* ep = es8 + e*8;
      sv0 = shv[e*3+0]; sv1 = shv[e*3+1]; sv2 = shv[e*3+2];
      src = esrc[e]; dst = edst[e];
      a = ep[0]*lW0[lane]      + ep[1]*lW0[64+lane]  + ep[2]*lW0[128+lane] + ep[3]*lW0[192+lane]
        + ep[4]*lW0[256+lane]  + ep[5]*lW0[320+lane] + ep[6]*lW0[384+lane] + ep[7]*lW0[448+lane];
      a = siluf(a * INV_SQRT8);
    }
    lA[wave][lane] = a;
    __syncthreads();
    {
      float b0=0.f;
      #pragma unroll
      for (int k = 0; k < 64; ++k) b0 += lA[wave][k]*lW1[k*64+lane];
      lB[wave][lane] = siluf(b0 * INV_SQRT64);
    }
    __syncthreads();
    if (valid) {
      float c0=0.f, c1=0.f;
      #pragma unroll
      for (int k = 0; k < 64; ++k) {
        float bk = lB[wave][k];
        const float* r = lW2 + k*128;
        c0 += bk*r[lane]; c1 += bk*r[64+lane];
      }
      float hsv = h_s[src*64 + lane];
      const float* hvp = h_v + src*192 + lane*3;
      float dotv = hvp[0]*sv0 + hvp[1]*sv1 + hvp[2]*sv2;
      atomicAdd(&n_mid[dst*128 + lane],      c0*INV_SQRT64*hsv*INV_SQRT10);
      atomicAdd(&n_mid[dst*128 + 64 + lane], c1*INV_SQRT64*dotv*INV_SQRT3*INV_SQRT10);
    }
  }
}

// ---------------- FALLBACK conv1 node pass (full, old n_v layout) ----------------
__global__ __launch_bounds__(128) void k_node1(
    const float* __restrict__ n_s, const float* __restrict__ n_v,
    const float* __restrict__ s,   const float* __restrict__ na,
    const float* __restrict__ Wls, const float* __restrict__ Wlv,
    const float* __restrict__ Csc, const float* __restrict__ W2s, const float* __restrict__ W2v,
    float* __restrict__ gs_out, float* __restrict__ hs_out, float* __restrict__ hv_out) {
  __shared__ float l_ns[512], l_s[512], l_na[64], l_nv[1536];
  __shared__ float l_outs[512], l_ov[768], l_gs[256], l_gv[768];
  const int j = threadIdx.x;
  const int n0 = blockIdx.x*4;
  for (int i = j; i < 512;  i += 128) { l_ns[i] = n_s[n0*128+i]; l_s[i] = s[n0*128+i]; }
  for (int i = j; i < 1536; i += 128) l_nv[i] = n_v[n0*384+i];
  if (j < 64) l_na[j] = na[n0*16+j];
  __syncthreads();

  float accs[4] = {0.f,0.f,0.f,0.f};
  for (int k = 0; k < 128; ++k) {
    float w = Wls[k*128+j];
    accs[0] += l_ns[k]*w; accs[1] += l_ns[128+k]*w;
    accs[2] += l_ns[256+k]*w; accs[3] += l_ns[384+k]*w;
  }
  float accc[4] = {0.f,0.f,0.f,0.f};
  for (int vt = 0; vt < 16; vt += 4) {
    float a0[4],a1[4],a2[4],a3[4];
    #pragma unroll
    for (int n = 0; n < 4; ++n) {
      a0[n]=l_na[n*16+vt]; a1[n]=l_na[n*16+vt+1];
      a2[n]=l_na[n*16+vt+2]; a3[n]=l_na[n*16+vt+3];
    }
    for (int u = 0; u < 128; ++u) {
      const float* cp = Csc + (u*16+vt)*128 + j;
      float c0=cp[0], c1=cp[128], c2=cp[256], c3=cp[384];
      float s0=l_s[u], s1=l_s[128+u], s2=l_s[256+u], s3=l_s[384+u];
      accc[0] += s0*(a0[0]*c0 + a1[0]*c1 + a2[0]*c2 + a3[0]*c3);
      accc[1] += s1*(a0[1]*c0 + a1[1]*c1 + a2[1]*c2 + a3[1]*c3);
      accc[2] += s2*(a0[2]*c0 + a1[2]*c1 + a2[2]*c2 + a3[2]*c3);
      accc[3] += s3*(a0[3]*c0 + a1[3]*c1 + a2[3]*c2 + a3[3]*c3);
    }
  }
  #pragma unroll
  for (int n = 0; n < 4; ++n)
    l_outs[n*128+j] = accs[n]*INV_SQRT128 + accc[n]*INV_SQRT2048;

  const int jj = j & 63, hh = j >> 6;
  float ov[2][3] = {{0.f,0.f,0.f},{0.f,0.f,0.f}};
  for (int u = 0; u < 128; ++u) {
    float w = Wlv[u*64+jj];
    #pragma unroll
    for (int t = 0; t < 2; ++t) {
      int n = 2*hh+t;
      ov[t][0] += l_nv[n*384+u*3+0]*w;
      ov[t][1] += l_nv[n*384+u*3+1]*w;
      ov[t][2] += l_nv[n*384+u*3+2]*w;
    }
  }
  #pragma unroll
  for (int t = 0; t < 2; ++t) {
    int n = 2*hh+t;
    l_ov[n*192+jj*3+0] = ov[t][0]*INV_SQRT128;
    l_ov[n*192+jj*3+1] = ov[t][1]*INV_SQRT128;
    l_ov[n*192+jj*3+2] = ov[t][2]*INV_SQRT128;
  }
  __syncthreads();

  #pragma unroll
  for (int t = 0; t < 2; ++t) {
    int n = 2*hh+t;
    float gv_s = siluf(l_outs[n*128+jj]);
    float gate = sigf (l_outs[n*128+64+jj]);
    l_gs[n*64+jj] = gv_s;
    gs_out[(n0+n)*64+jj] = gv_s;
    l_gv[n*192+jj*3+0] = gate*l_ov[n*192+jj*3+0];
    l_gv[n*192+jj*3+1] = gate*l_ov[n*192+jj*3+1];
    l_gv[n*192+jj*3+2] = gate*l_ov[n*192+jj*3+2];
  }
  __syncthreads();

  float ha[2] = {0.f,0.f};
  for (int k = 0; k < 64; ++k) {
    float w = W2s[k*64+jj];
    ha[0] += l_gs[(2*hh+0)*64+k]*w;
    ha[1] += l_gs[(2*hh+1)*64+k]*w;
  }
  hs_out[(n0+2*hh+0)*64+jj] = ha[0]*INV_SQRT64;
  hs_out[(n0+2*hh+1)*64+jj] = ha[1]*INV_SQRT64;

  float hv[2][3] = {{0.f,0.f,0.f},{0.f,0.f,0.f}};
  for (int u = 0; u < 64; ++u) {
    float w = W2v[u*64+jj];
    #pragma unroll
    for (int t = 0; t < 2; ++t) {
      int n = 2*hh+t;
      hv[t][0] += l_gv[n*192+u*3+0]*w;
      hv[t][1] += l_gv[n*192+u*3+1]*w;
      hv[t][2] += l_gv[n*192+u*3+2]*w;
    }
  }
  #pragma unroll
  for (int t = 0; t < 2; ++t) {
    int n = 2*hh+t;
    hv_out[(n0+n)*192+jj*3+0] = hv[t][0]*INV_SQRT64;
    hv_out[(n0+n)*192+jj*3+1] = hv[t][1]*INV_SQRT64;
    hv_out[(n0+n)*192+jj*3+2] = hv[t][2]*INV_SQRT64;
  }
}

// ---------------- FALLBACK conv2 node pass + pooling ----------------
__global__ __launch_bounds__(128) void k_node2(
    const float* __restrict__ n_mid, const float* __restrict__ gs,
    const float* __restrict__ na, const int* __restrict__ batch,
    const float* __restrict__ W, const float* __restrict__ Csc,
    float* __restrict__ pool) {
  __shared__ float l_nm[512], l_gs[256], l_na[64];
  const int j = threadIdx.x;
  const int n0 = blockIdx.x*4;
  for (int i = j; i < 512; i += 128) l_nm[i] = n_mid[n0*128+i];
  for (int i = j; i < 256; i += 128) l_gs[i] = gs[n0*64+i];
  if (j < 64) l_na[j] = na[n0*16+j];
  __syncthreads();
  float acc[4] = {0.f,0.f,0.f,0.f};
  for (int k = 0; k < 128; ++k) {
    float w = W[k*128+j];
    acc[0] += l_nm[k]*w; acc[1] += l_nm[128+k]*w;
    acc[2] += l_nm[256+k]*w; acc[3] += l_nm[384+k]*w;
  }
  float acc2[4] = {0.f,0.f,0.f,0.f};
  for (int vt = 0; vt < 16; vt += 4) {
    float a0[4],a1[4],a2[4],a3[4];
    #pragma unroll
    for (int n = 0; n < 4; ++n) {
      a0[n]=l_na[n*16+vt]; a1[n]=l_na[n*16+vt+1];
      a2[n]=l_na[n*16+vt+2]; a3[n]=l_na[n*16+vt+3];
    }
    for (int u = 0; u < 64; ++u) {
      const float* cp = Csc + (u*16+vt)*128 + j;
      float c0=cp[0], c1=cp[128], c2=cp[256], c3=cp[384];
      float s0=l_gs[u], s1=l_gs[64+u], s2=l_gs[128+u], s3=l_gs[192+u];
      acc2[0] += s0*(a0[0]*c0 + a1[0]*c1 + a2[0]*c2 + a3[0]*c3);
      acc2[1] += s1*(a0[1]*c0 + a1[1]*c1 + a2[1]*c2 + a3[1]*c3);
      acc2[2] += s2*(a0[2]*c0 + a1[2]*c1 + a2[2]*c2 + a3[2]*c3);
      acc2[3] += s3*(a0[3]*c0 + a1[3]*c1 + a2[3]*c2 + a3[3]*c3);
    }
  }
  float outv[4];
  #pragma unroll
  for (int n = 0; n < 4; ++n)
    outv[n] = acc[n]*INV_SQRT128 + acc2[n]*INV_SQRT1024;
  int b0 = batch[n0], b1 = batch[n0+1], b2 = batch[n0+2], b3 = batch[n0+3];
  float sum = outv[0]; int cur = b0;
  if (b1 == cur) sum += outv[1]; else { atomicAdd(&pool[cur*128+j], sum); cur = b1; sum = outv[1]; }
  if (b2 == cur) sum += outv[2]; else { atomicAdd(&pool[cur*128+j], sum); cur = b2; sum = outv[2]; }
  if (b3 == cur) sum += outv[3]; else { atomicAdd(&pool[cur*128+j], sum); cur = b3; sum = outv[3]; }
  atomicAdd(&pool[cur*128+j], sum);
}

// ---------------- readout head ----------------
__global__ __launch_bounds__(128) void k_head(
    const float* __restrict__ pool, const float* __restrict__ cnt,
    const float* __restrict__ Wr1, const float* __restrict__ Wr2,
    float* __restrict__ out) {
  __shared__ float lp[128];
  __shared__ float lt[128];
  const int j = threadIdx.x;
  for (int g = 0; g < N_GRAPHS; ++g) {
    float inv = 1.f / fmaxf(cnt[g], 1.f);
    lp[j] = pool[g*128+j]*inv;
    __syncthreads();
    float acc = 0.f;
    for (int k = 0; k < 128; ++k) acc += lp[k]*Wr1[k*128+j];
    lt[j] = siluf(acc*INV_SQRT128) * Wr2[j];
    __syncthreads();
    if (j == 0) {
      float ssum = 0.f;
      for (int k = 0; k < 128; ++k) ssum += lt[k];
      out[g] = ssum*INV_SQRT128;
    }
    __syncthreads();
  }
}

extern "C" void kernel_launch(void* const* d_in, const int* in_sizes, int n_in,
                              void* d_out, int out_size, void* d_ws, size_t ws_size,
                              hipStream_t stream) {
  const float* x         = (const float*)d_in[0];
  const float* node_attr = (const float*)d_in[1];
  const int*   esrc      = (const int*)d_in[2];
  const int*   edst      = (const int*)d_in[3];
  const float* evec      = (const float*)d_in[4];
  const int*   batch     = (const int*)d_in[5];
  const float* W_embed   = (const float*)d_in[6];
  const float* c1_lin1   = (const float*)d_in[7];
  const float* c1_fc_w0  = (const float*)d_in[8];
  const float* c1_fc_w1  = (const float*)d_in[9];
  const float* c1_fc_w2  = (const float*)d_in[10];
  const float* c1_lin2_s = (const float*)d_in[11];
  const float* c1_lin2_v = (const float*)d_in[12];
  const float* c1_sc     = (const float*)d_in[13];
  const float* c2_lin1_s = (const float*)d_in[14];
  const float* c2_lin1_v = (const float*)d_in[15];
  const float* c2_fc_w0  = (const float*)d_in[16];
  const float* c2_fc_w1  = (const float*)d_in[17];
  const float* c2_fc_w2  = (const float*)d_in[18];
  const float* c2_lin2   = (const float*)d_in[19];
  const float* c2_sc     = (const float*)d_in[20];
  const float* Wr1       = (const float*)d_in[21];
  const float* Wr2       = (const float*)d_in[22];

  float* ws    = (float*)d_ws;
  float* es8   = ws + OFF_ES8;
  float* shv   = ws + OFF_SHV;
  float* s_    = ws + OFF_S;
  float* h_    = ws + OFF_H;
  float* gs_   = ws + OFF_GS;
  float* hs_   = ws + OFF_HS;
  float* hv_   = ws + OFF_HV;
  float* ns_   = ws + OFF_NS;
  float* nv_   = ws + OFF_NV;
  float* nmid_ = ws + OFF_NMID;
  float* pool_ = ws + OFF_POOL;
  float* cnt_  = ws + OFF_CNT;
  int*   hist_ = (int*)(ws + OFF_HIST);
  int*   curs_ = (int*)(ws + OFF_CURS);
  int*   offs_ = (int*)(ws + OFF_OFFS);
  short* frag_ = (short*)(ws + OFF_FRAG);
  int*   slot_ = (int*)(ws + OFF_SLOT);
  float* wbuf_ = ws + OFF_WBUF;
  u16*   wb16_ = (u16*)wbuf_;   // fp16 wbuf occupies only lower half of WBUF region

  // upper-wbuf carve-outs (k_mlp<16> now writes only N_EDGES*128 floats worth of u16)
  float* out1_  = wbuf_ + (size_t)N_EDGES*128;                 // 1.28M floats
  short* nfrag_ = (short*)(out1_ + (size_t)NM128);             // 884736 shorts
  float* part_  = out1_ + (size_t)NM128 + NFRAG_TOT/2;         // 9 x 1.28M floats
  float* ov_    = part_ + (size_t)9*NM128;                     // 1.92M floats
  float* gv_    = nv_;                                         // aliases nv (dead after ov GEMM)
  float* out2_  = ns_;                                         // ns dead after conv1 dense GEMM

  const bool big = ws_size >= WS_NEED_BYTES;

  k_geom<<<N_EDGES/256, 256, 0, stream>>>(evec, es8, shv);

  if (big) {
    hipMemsetAsync(pool_, 0, (size_t)(OFF_OFFS - OFF_POOL)*sizeof(float), stream);
    k_cnt<<<(N_NODES+255)/256, 256, 0, stream>>>(batch, cnt_);
    k_hist<<<(N_EDGES+255)/256, 256, 0, stream>>>(edst, hist_);
    k_scanp<<<1, 1024, 0, stream>>>(hist_, offs_);
    k_slot<<<(N_EDGES+255)/256, 256, 0, stream>>>(edst, offs_, curs_, slot_);

    // merged startup frag prep: 6 MLP weights + W_embed + c1_lin1
    {
      PD8 m{};
      m.d[0] = {c1_fc_w0, frag_ + F_B1,  8,  64,  4, 1, 4096,  INV_SQRT8};
      m.d[1] = {c1_fc_w1, frag_ + F_B2,  64, 64,  4, 2, 8192,  INV_SQRT64};
      m.d[2] = {c1_fc_w2, frag_ + F_B3,  64, 256, 16,2, 32768, INV_SQRT64};
      m.d[3] = {c2_fc_w0, frag_ + F_B1b, 8,  64,  4, 1, 4096,  INV_SQRT8};
      m.d[4] = {c2_fc_w1, frag_ + F_B2b, 64, 64,  4, 2, 8192,  INV_SQRT64};
      m.d[5] = {c2_fc_w2, frag_ + F_B3b, 64, 128, 8, 2, 16384, INV_SQRT64};
      m.d[6] = {W_embed,  frag_ + F_WE,  32, 128, 8, 1, 8192,  INV_SQRT32};
      m.d[7] = {c1_lin1,  frag_ + F_L1,  128,128, 8, 4, 32768, INV_SQRT128};
      m.nd = 8; m.tot = FRAG_TOT;
      k_prepmulti<<<448, 256, 0, stream>>>(m);
    }

    // s = x@W_embed ; h = s@c1_lin1 (MFMA)
    k_gemm<1,8><<<79, 512, 0, stream>>>(x,  32,  N_NODES, frag_ + F_WE, s_);
    k_gemm<4,8><<<79, 512, 0, stream>>>(s_, 128, N_NODES, frag_ + F_L1, h_);

    // conv1 edge MLP (fp16 out) + gather
    k_mlp<16><<<625, 256, 0, stream>>>(es8, frag_ + F_B1, frag_ + F_B2, frag_ + F_B3, wb16_);
    k_gather1<<<(N_NODES+3)/4, 256, 0, stream>>>(wb16_, shv, esrc, offs_, slot_, h_, ns_, nv_);

    // merged node weight frag prep (upper-wbuf region)
    {
      PD8 m{};
      m.d[0] = {c1_lin2_s, nfrag_ + NF_WLS, 128, 128,  8,   4, 32768,  INV_SQRT128};
      m.d[1] = {c1_sc,     nfrag_ + NF_C1,  128, 2048, 128, 4, 524288, INV_SQRT2048};
      m.d[2] = {c2_lin2,   nfrag_ + NF_W2,  128, 128,  8,   4, 32768,  INV_SQRT128};
      m.d[3] = {c2_sc,     nfrag_ + NF_C2,  64,  2048, 128, 2, 262144, INV_SQRT1024};
      m.d[4] = {c1_lin2_v, nfrag_ + NF_LV,  128, 64,   4,   4, 16384,  INV_SQRT128};
      m.d[5] = {c2_lin1_s, nfrag_ + NF_2S,  64,  64,   4,   2, 8192,   INV_SQRT64};
      m.d[6] = {c2_lin1_v, nfrag_ + NF_2V,  64,  64,   4,   2, 8192,   INV_SQRT64};
      m.nd = 7; m.tot = NFRAG_TOT;
      k_prepmulti<<<1024, 256, 0, stream>>>(m);
    }

    // conv1 node: dense + sc partials -> reduce -> out1
    k_gemm<4,8><<<79, 512, 0, stream>>>(ns_, 128, N_NODES, nfrag_ + NF_WLS, part_ + (size_t)8*NM128);
    k_scp<4><<<dim3(79,8), 512, 0, stream>>>(s_, node_attr, nfrag_ + NF_C1, part_);
    k_reduce<<<(NM128/4+255)/256, 256, 0, stream>>>(part_, out1_);

    // gate phase via MFMA
    k_gemm<4,4><<<235, 512, 0, stream>>>(nv_, 128, N_NODES*3, nfrag_ + NF_LV, ov_);
    k_gatee<<<(N_NODES*64+255)/256, 256, 0, stream>>>(out1_, ov_, gs_, gv_);
    k_gemm<2,4><<<79, 512, 0, stream>>>(gs_, 64, N_NODES, nfrag_ + NF_2S, hs_);
    k_gemm<2,4><<<235, 512, 0, stream>>>(gv_, 64, N_NODES*3, nfrag_ + NF_2V, hv_);

    // conv2 edge MLP (fp16 out) + gather
    k_mlp<8><<<625, 256, 0, stream>>>(es8, frag_ + F_B1b, frag_ + F_B2b, frag_ + F_B3b, wb16_);
    k_gather2<<<(N_NODES+3)/4, 256, 0, stream>>>(wb16_, shv, esrc, offs_, slot_, hs_, hv_, nmid_);

    // conv2 node: partials -> reduce -> pool
    k_gemm<4,8><<<79, 512, 0, stream>>>(nmid_, 128, N_NODES, nfrag_ + NF_W2, part_ + (size_t)8*NM128);
    k_scp<2><<<dim3(79,8), 512, 0, stream>>>(gs_, node_attr, nfrag_ + NF_C2, part_);
    k_reduce<<<(NM128/4+255)/256, 256, 0, stream>>>(part_, out2_);
    k_pool<<<N_NODES/4, 128, 0, stream>>>(out2_, batch, pool_);
  } else {
    hipMemsetAsync(ns_, 0, (size_t)(OFF_HIST - OFF_NS)*sizeof(float), stream);
    k_linear128<<<(N_NODES*128)/256, 256, 0, stream>>>(x,  W_embed, s_, 32,  INV_SQRT32,  N_NODES*128);
    k_linear128<<<(N_NODES*128)/256, 256, 0, stream>>>(s_, c1_lin1, h_, 128, INV_SQRT128, N_NODES*128);
    k_cnt<<<(N_NODES+255)/256, 256, 0, stream>>>(batch, cnt_);
    k_edge1_at<<<256, 512, 0, stream>>>(es8, shv, esrc, edst, h_,
                                        c1_fc_w0, c1_fc_w1, c1_fc_w2, ns_, nv_);
    k_node1<<<N_NODES/4, 128, 0, stream>>>(ns_, nv_, s_, node_attr,
                                           c1_lin2_s, c1_lin2_v, c1_sc,
                                           c2_lin1_s, c2_lin1_v, gs_, hs_, hv_);
    k_edge2_at<<<512, 512, 0, stream>>>(es8, shv, esrc, edst, hs_, hv_,
                                        c2_fc_w0, c2_fc_w1, c2_fc_w2, nmid_);
    k_node2<<<N_NODES/4, 128, 0, stream>>>(nmid_, gs_, node_attr, batch,
                                           c2_lin2, c2_sc, pool_);
  }

  k_head<<<1, 128, 0, stream>>>(pool_, cnt_, Wr1, Wr2, (float*)d_out);
}

// Round 8
// 385.703 us; speedup vs baseline: 3.2541x; 1.0347x over previous
//
#include <hip/hip_runtime.h>
#include <hip/hip_fp16.h>

#define N_NODES 10000
#define N_EDGES 160000
#define N_GRAPHS 16

typedef __attribute__((ext_vector_type(8))) short s16x8;
typedef __attribute__((ext_vector_type(4))) float f32x4;
typedef __attribute__((ext_vector_type(4))) unsigned short u16x4;
typedef __attribute__((ext_vector_type(2))) unsigned short u16x2;
typedef unsigned int uint32;
typedef unsigned short u16;

// ---- workspace layout (float offsets) ----
#define OFF_ES8  0
#define OFF_SHV  (OFF_ES8 + N_EDGES*8)
#define OFF_S    (OFF_SHV + N_EDGES*3)
#define OFF_H    (OFF_S   + N_NODES*128)
#define OFF_GS   (OFF_H   + N_NODES*128)
#define OFF_HS   (OFF_GS  + N_NODES*64)
#define OFF_HV   (OFF_HS  + N_NODES*64)
#define OFF_NS   (OFF_HV  + N_NODES*192)   /* fallback zero-region start */
#define OFF_NV   (OFF_NS  + N_NODES*128)
#define OFF_NMID (OFF_NV  + N_NODES*384)
#define OFF_POOL (OFF_NMID+ N_NODES*128)   /* new-path zero-region start */
#define OFF_CNT  (OFF_POOL+ N_GRAPHS*128)
#define OFF_HIST (OFF_CNT + N_GRAPHS)
#define OFF_CURS (OFF_HIST+ N_NODES)
#define OFF_OFFS (OFF_CURS+ N_NODES)       /* new-path zero-region end (excl) */
#define OFF_FRAG (OFF_OFFS+ N_NODES + 16)  /* persistent frags: 114688 shorts = 57344 floats */
#define OFF_SLOT (OFF_FRAG+ 57344)
#define OFF_WBUF (OFF_SLOT+ N_EDGES)
#define WBUF_FLOATS ((size_t)N_EDGES*256)
#define WS_NEED_BYTES ((size_t)(OFF_WBUF + WBUF_FLOATS) * 4)

// persistent frag sub-offsets in shorts
#define F_B1   0        /* conv1 L1: NF4 KS1 -> 4096  */
#define F_B2   4096     /* conv1 L2: NF4 KS2 -> 8192  */
#define F_B3   12288    /* conv1 L3: NF16 KS2 -> 32768 */
#define F_B1b  45056
#define F_B2b  49152
#define F_B3b  57344    /* conv2 L3: NF8 KS2 -> 16384 */
#define F_WE   73728    /* W_embed: NF8 KS1 -> 8192 */
#define F_L1   81920    /* c1_lin1: NF8 KS4 -> 32768 */
#define FRAG_TOT 114688

// node-frag sub-offsets in shorts, within the upper-wbuf nfrag region
#define NF_WLS 0        /* c1_lin2_s: NF8 KS4 -> 32768 */
#define NF_C1  32768    /* c1_sc:   NF128 KS4 -> 524288 */
#define NF_W2  557056   /* c2_lin2:  NF8 KS4 -> 32768 */
#define NF_C2  589824   /* c2_sc:   NF128 KS2 -> 262144 */
#define NF_LV  851968   /* c1_lin2_v: NF4 KS4 -> 16384 */
#define NF_2S  868352   /* c2_lin1_s: NF4 KS2 -> 8192 */
#define NF_2V  876544   /* c2_lin1_v: NF4 KS2 -> 8192 */
#define NFRAG_TOT 884736

#define NM128 (N_NODES*128)

#define INV_SQRT32   0.17677669529663687f
#define INV_SQRT128  0.08838834764831845f
#define INV_SQRT8    0.3535533905932738f
#define INV_SQRT64   0.125f
#define INV_SQRT2048 0.022097086912079608f
#define INV_SQRT1024 0.03125f
#define INV_SQRT10   0.31622776601683794f
#define INV_SQRT3    0.5773502691896258f
#define SQRT3_C      1.7320508075688772f

__device__ __forceinline__ float siluf(float x){ return x / (1.f + __expf(-x)); }
__device__ __forceinline__ float sigf (float x){ return 1.f / (1.f + __expf(-x)); }
__device__ __forceinline__ unsigned short bf16h(float x){
  uint32 u = __float_as_uint(x);
  u += 0x7FFFu + ((u >> 16) & 1u);
  return (unsigned short)(u >> 16);
}
__device__ __forceinline__ float bf2f(unsigned short h){
  return __uint_as_float(((uint32)h) << 16);
}
__device__ __forceinline__ u16 f2h(float x){ return __half_as_ushort(__float2half_rn(x)); }
__device__ __forceinline__ float h2f(u16 b){ return __half2float(__ushort_as_half(b)); }
__device__ __forceinline__ void split8(const float* __restrict__ p, s16x8& hi, s16x8& lo) {
  f32x4 v0 = *(const f32x4*)p;
  f32x4 v1 = *(const f32x4*)(p + 4);
  float vals[8] = {v0[0],v0[1],v0[2],v0[3],v1[0],v1[1],v1[2],v1[3]};
  #pragma unroll
  for (int j = 0; j < 8; ++j) {
    unsigned short hh = bf16h(vals[j]);
    hi[j] = (short)hh;
    lo[j] = (short)bf16h(vals[j] - bf2f(hh));
  }
}

// ---------------- edge geometry ----------------
__global__ void k_geom(const float* __restrict__ evec,
                       float* __restrict__ es8, float* __restrict__ shv) {
  int e = blockIdx.x*256 + threadIdx.x;
  if (e >= N_EDGES) return;
  float vx = evec[e*3+0], vy = evec[e*3+1], vz = evec[e*3+2];
  float d  = sqrtf(vx*vx + vy*vy + vz*vz);
  float xs = d - 0.25f;
  bool  in = (xs > 0.f) && (xs < 4.0f);
  float safe = xs > 0.f ? xs : 1.f;
  float amp  = in ? 2.0f/safe : 0.f;
  const float PI4 = 0.7853981633974483f;
  #pragma unroll
  for (int k = 0; k < 8; ++k)
    es8[e*8+k] = amp * sinf((float)(k+1) * PI4 * safe);
  float invd = d > 0.f ? 1.f/d : 1.f;
  shv[e*3+0] = SQRT3_C*vx*invd;
  shv[e*3+1] = SQRT3_C*vy*invd;
  shv[e*3+2] = SQRT3_C*vz*invd;
}

// ---------------- fallback scalar linear ----------------
__global__ void k_linear128(const float* __restrict__ A, const float* __restrict__ W,
                            float* __restrict__ O, int K, float scale, int total) {
  int t = blockIdx.x*256 + threadIdx.x;
  if (t >= total) return;
  int n = t >> 7, j = t & 127;
  const float* a = A + n*K;
  float a0=0.f,a1=0.f,a2=0.f,a3=0.f;
  for (int k = 0; k < K; k += 4) {
    a0 += a[k+0]*W[(k+0)*128+j];
    a1 += a[k+1]*W[(k+1)*128+j];
    a2 += a[k+2]*W[(k+2)*128+j];
    a3 += a[k+3]*W[(k+3)*128+j];
  }
  O[t] = (a0+a1+a2+a3)*scale;
}

// ---------------- graph node counts + edge histogram (merged) ----------------
__global__ void k_cnthist(const int* __restrict__ batch, const int* __restrict__ edst,
                          float* __restrict__ cnt, int* __restrict__ hist) {
  __shared__ int lc[N_GRAPHS];
  int t = threadIdx.x;
  if (t < N_GRAPHS) lc[t] = 0;
  __syncthreads();
  int i = blockIdx.x*256 + t;
  if (i < N_NODES) atomicAdd(&lc[batch[i]], 1);
  if (i < N_EDGES) atomicAdd(&hist[edst[i]], 1);
  __syncthreads();
  if (t < N_GRAPHS && lc[t] > 0) atomicAdd(&cnt[t], (float)lc[t]);
}

__global__ __launch_bounds__(1024) void k_scanp(const int* __restrict__ hist,
                                                int* __restrict__ offs) {
  __shared__ int wsum[16];
  const int t = threadIdx.x;
  const int lane = t & 63, w = t >> 6;
  const int base = t*10;
  int v[10]; int s = 0;
  #pragma unroll
  for (int i = 0; i < 10; ++i) {
    int idx = base + i;
    int x = (idx < N_NODES) ? hist[idx] : 0;
    s += x; v[i] = s;
  }
  int ws = s;
  #pragma unroll
  for (int d = 1; d < 64; d <<= 1) {
    int u = __shfl_up(ws, d);
    if (lane >= d) ws += u;
  }
  if (lane == 63) wsum[w] = ws;
  __syncthreads();
  if (w == 0) {
    int x = (lane < 16) ? wsum[lane] : 0;
    #pragma unroll
    for (int d = 1; d < 16; d <<= 1) {
      int u = __shfl_up(x, d);
      if (lane >= d) x += u;
    }
    if (lane < 16) wsum[lane] = x;
  }
  __syncthreads();
  int waveoff = (w > 0) ? wsum[w-1] : 0;
  int texcl = waveoff + ws - s;
  if (t == 0) offs[0] = 0;
  #pragma unroll
  for (int i = 0; i < 10; ++i) {
    int idx = base + i;
    if (idx < N_NODES) offs[idx+1] = texcl + v[i];
  }
}

__global__ void k_slot(const int* __restrict__ edst, const int* __restrict__ offs,
                       int* __restrict__ curs, int* __restrict__ slot) {
  int e = blockIdx.x*256 + threadIdx.x;
  if (e < N_EDGES) {
    int d = edst[e];
    int p = offs[d] + atomicAdd(&curs[d], 1);
    slot[p] = e;
  }
}

// ---------------- merged weight fragment prep ----------------
struct PD { const float* W; short* dst; int Keff, N, NF, KS, nElem; float scale; };
struct PD8 { PD d[8]; int nd; int tot; };

__global__ void k_prepmulti(PD8 ds) {
  int stride = gridDim.x*256;
  for (int t = blockIdx.x*256 + threadIdx.x; t < ds.tot; t += stride) {
    int rem = t, i = 0;
    while (i < ds.nd-1 && rem >= ds.d[i].nElem) { rem -= ds.d[i].nElem; ++i; }
    const PD p = ds.d[i];
    int j = rem & 7;
    int l = (rem >> 3) & 63;
    int rest = rem >> 9;
    int ks = rest % p.KS; rest /= p.KS;
    int nf = rest % p.NF;
    int pp = rest / p.NF;
    int k   = ks*32 + (l >> 4)*8 + j;
    int col = nf*16 + (l & 15);
    float v = (k < p.Keff) ? p.W[(size_t)k*p.N + col]*p.scale : 0.f;
    unsigned short hi = bf16h(v);
    unsigned short o = pp ? bf16h(v - bf2f(hi)) : hi;
    p.dst[rem] = (short)o;
  }
}

// ---------------- fused 3-layer edge MLP via MFMA; 32 edges/wave; fp16 interleaved out ----------------
// wbuf layout: [e][64 cols][NQ quadrants] u16, NQ = NF3/4
template<int NF3>
__global__ __launch_bounds__(256) void k_mlp(
    const float* __restrict__ es8,
    const short* __restrict__ fb1, const short* __restrict__ fb2,
    const short* __restrict__ fb3, u16* __restrict__ wbuf) {
  __shared__ __align__(16) short route[4][2304];   // 4 waves x (32 rows x 72 shorts)
  const int w = threadIdx.x >> 6, l = threadIdx.x & 63;
  const int lrow = l & 15, lhi = l >> 4;
  const int e0 = (blockIdx.x*4 + w)*32;
  short* rt = route[w];
  constexpr int NQ = NF3/4;

  s16x8 ah1[2], al1[2];
  #pragma unroll
  for (int mt = 0; mt < 2; ++mt) {
    s16x8 h = {0,0,0,0,0,0,0,0}, lo = {0,0,0,0,0,0,0,0};
    if (lhi == 0) {
      const float* ep = es8 + (size_t)(e0 + mt*16 + lrow)*8;
      split8(ep, h, lo);
    }
    ah1[mt] = h; al1[mt] = lo;
  }

  f32x4 acc1[2][4];
  #pragma unroll
  for (int mt = 0; mt < 2; ++mt)
    #pragma unroll
    for (int nf = 0; nf < 4; ++nf) acc1[mt][nf] = (f32x4){0.f,0.f,0.f,0.f};
  #pragma unroll
  for (int nf = 0; nf < 4; ++nf) {
    s16x8 bh = *(const s16x8*)(fb1 + ((0*4 + nf)*1 + 0)*512 + l*8);
    s16x8 bl = *(const s16x8*)(fb1 + ((1*4 + nf)*1 + 0)*512 + l*8);
    #pragma unroll
    for (int mt = 0; mt < 2; ++mt) {
      acc1[mt][nf] = __builtin_amdgcn_mfma_f32_16x16x32_bf16(ah1[mt], bh, acc1[mt][nf], 0,0,0);
      acc1[mt][nf] = __builtin_amdgcn_mfma_f32_16x16x32_bf16(ah1[mt], bl, acc1[mt][nf], 0,0,0);
      acc1[mt][nf] = __builtin_amdgcn_mfma_f32_16x16x32_bf16(al1[mt], bh, acc1[mt][nf], 0,0,0);
    }
  }
  #pragma unroll
  for (int mt = 0; mt < 2; ++mt)
    #pragma unroll
    for (int nf = 0; nf < 4; ++nf)
      #pragma unroll
      for (int r = 0; r < 4; ++r) acc1[mt][nf][r] = siluf(acc1[mt][nf][r]);

  s16x8 ah2[2][2], al2[2][2];
  #pragma unroll
  for (int mt = 0; mt < 2; ++mt)
    #pragma unroll
    for (int nf = 0; nf < 4; ++nf)
      #pragma unroll
      for (int r = 0; r < 4; ++r)
        rt[(mt*16 + lhi*4 + r)*72 + nf*16 + lrow] = (short)bf16h(acc1[mt][nf][r]);
  #pragma unroll
  for (int mt = 0; mt < 2; ++mt)
    #pragma unroll
    for (int ks = 0; ks < 2; ++ks)
      ah2[mt][ks] = *(const s16x8*)&rt[(mt*16 + lrow)*72 + ks*32 + lhi*8];
  #pragma unroll
  for (int mt = 0; mt < 2; ++mt)
    #pragma unroll
    for (int nf = 0; nf < 4; ++nf)
      #pragma unroll
      for (int r = 0; r < 4; ++r) {
        float v = acc1[mt][nf][r];
        unsigned short hh = bf16h(v);
        rt[(mt*16 + lhi*4 + r)*72 + nf*16 + lrow] = (short)bf16h(v - bf2f(hh));
      }
  #pragma unroll
  for (int mt = 0; mt < 2; ++mt)
    #pragma unroll
    for (int ks = 0; ks < 2; ++ks)
      al2[mt][ks] = *(const s16x8*)&rt[(mt*16 + lrow)*72 + ks*32 + lhi*8];

  f32x4 acc2[2][4];
  #pragma unroll
  for (int mt = 0; mt < 2; ++mt)
    #pragma unroll
    for (int nf = 0; nf < 4; ++nf) acc2[mt][nf] = (f32x4){0.f,0.f,0.f,0.f};
  #pragma unroll
  for (int nf = 0; nf < 4; ++nf)
    #pragma unroll
    for (int ks = 0; ks < 2; ++ks) {
      s16x8 bh = *(const s16x8*)(fb2 + ((0*4 + nf)*2 + ks)*512 + l*8);
      s16x8 bl = *(const s16x8*)(fb2 + ((1*4 + nf)*2 + ks)*512 + l*8);
      #pragma unroll
      for (int mt = 0; mt < 2; ++mt) {
        acc2[mt][nf] = __builtin_amdgcn_mfma_f32_16x16x32_bf16(ah2[mt][ks], bh, acc2[mt][nf], 0,0,0);
        acc2[mt][nf] = __builtin_amdgcn_mfma_f32_16x16x32_bf16(ah2[mt][ks], bl, acc2[mt][nf], 0,0,0);
        acc2[mt][nf] = __builtin_amdgcn_mfma_f32_16x16x32_bf16(al2[mt][ks], bh, acc2[mt][nf], 0,0,0);
      }
    }
  #pragma unroll
  for (int mt = 0; mt < 2; ++mt)
    #pragma unroll
    for (int nf = 0; nf < 4; ++nf)
      #pragma unroll
      for (int r = 0; r < 4; ++r) acc2[mt][nf][r] = siluf(acc2[mt][nf][r]);

  s16x8 ah3[2][2], al3[2][2];
  #pragma unroll
  for (int mt = 0; mt < 2; ++mt)
    #pragma unroll
    for (int nf = 0; nf < 4; ++nf)
      #pragma unroll
      for (int r = 0; r < 4; ++r)
        rt[(mt*16 + lhi*4 + r)*72 + nf*16 + lrow] = (short)bf16h(acc2[mt][nf][r]);
  #pragma unroll
  for (int mt = 0; mt < 2; ++mt)
    #pragma unroll
    for (int ks = 0; ks < 2; ++ks)
      ah3[mt][ks] = *(const s16x8*)&rt[(mt*16 + lrow)*72 + ks*32 + lhi*8];
  #pragma unroll
  for (int mt = 0; mt < 2; ++mt)
    #pragma unroll
    for (int nf = 0; nf < 4; ++nf)
      #pragma unroll
      for (int r = 0; r < 4; ++r) {
        float v = acc2[mt][nf][r];
        unsigned short hh = bf16h(v);
        rt[(mt*16 + lhi*4 + r)*72 + nf*16 + lrow] = (short)bf16h(v - bf2f(hh));
      }
  #pragma unroll
  for (int mt = 0; mt < 2; ++mt)
    #pragma unroll
    for (int ks = 0; ks < 2; ++ks)
      al3[mt][ks] = *(const s16x8*)&rt[(mt*16 + lrow)*72 + ks*32 + lhi*8];

  for (int nf3 = 0; nf3 < NF3; ++nf3) {
    f32x4 acc3[2];
    #pragma unroll
    for (int mt = 0; mt < 2; ++mt) acc3[mt] = (f32x4){0.f,0.f,0.f,0.f};
    #pragma unroll
    for (int ks = 0; ks < 2; ++ks) {
      s16x8 bh = *(const s16x8*)(fb3 + ((size_t)(0*NF3 + nf3)*2 + ks)*512 + l*8);
      s16x8 bl = *(const s16x8*)(fb3 + ((size_t)(1*NF3 + nf3)*2 + ks)*512 + l*8);
      #pragma unroll
      for (int mt = 0; mt < 2; ++mt) {
        acc3[mt] = __builtin_amdgcn_mfma_f32_16x16x32_bf16(ah3[mt][ks], bh, acc3[mt], 0,0,0);
        acc3[mt] = __builtin_amdgcn_mfma_f32_16x16x32_bf16(ah3[mt][ks], bl, acc3[mt], 0,0,0);
        acc3[mt] = __builtin_amdgcn_mfma_f32_16x16x32_bf16(al3[mt][ks], bh, acc3[mt], 0,0,0);
      }
    }
    const int c = (nf3 & 3)*16 + lrow;     // col within 64-quadrant
    const int q = nf3 >> 2;                // quadrant
    #pragma unroll
    for (int mt = 0; mt < 2; ++mt)
      #pragma unroll
      for (int r = 0; r < 4; ++r)
        wbuf[(size_t)(e0 + mt*16 + lhi*4 + r)*(NF3*16) + c*NQ + q] = f2h(acc3[mt][r]);
  }
}

// ---------------- generic MFMA GEMM ----------------
template<int KS, int NF>
__global__ __launch_bounds__(512, 4) void k_gemm(
    const float* __restrict__ A, int rstride, int M,
    const short* __restrict__ fB, float* __restrict__ O) {
  __shared__ __align__(16) short lB[2*NF*KS*512];
  const int tid = threadIdx.x;
  const int w = tid >> 6, l = tid & 63;
  const int lrow = l & 15, lhi = l >> 4;
  const int n0 = blockIdx.x*128 + w*16;
  for (int i = tid; i < 2*NF*KS*64; i += 512)
    *(s16x8*)&lB[(size_t)i*8] = *(const s16x8*)&fB[(size_t)i*8];
  s16x8 ah[KS], al[KS];
  {
    int row = n0 + lrow; if (row > M-1) row = M-1;
    #pragma unroll
    for (int ks = 0; ks < KS; ++ks)
      split8(A + (size_t)row*rstride + ks*32 + lhi*8, ah[ks], al[ks]);
  }
  __syncthreads();
  f32x4 acc[NF];
  #pragma unroll
  for (int nf = 0; nf < NF; ++nf) acc[nf] = (f32x4){0.f,0.f,0.f,0.f};
  #pragma unroll
  for (int nf = 0; nf < NF; ++nf)
    #pragma unroll
    for (int ks = 0; ks < KS; ++ks) {
      s16x8 bh = *(const s16x8*)&lB[((0*NF + nf)*KS + ks)*512 + l*8];
      s16x8 bl = *(const s16x8*)&lB[((1*NF + nf)*KS + ks)*512 + l*8];
      acc[nf] = __builtin_amdgcn_mfma_f32_16x16x32_bf16(ah[ks], bh, acc[nf], 0,0,0);
      acc[nf] = __builtin_amdgcn_mfma_f32_16x16x32_bf16(ah[ks], bl, acc[nf], 0,0,0);
      acc[nf] = __builtin_amdgcn_mfma_f32_16x16x32_bf16(al[ks], bh, acc[nf], 0,0,0);
    }
  #pragma unroll
  for (int nf = 0; nf < NF; ++nf)
    #pragma unroll
    for (int r = 0; r < 4; ++r) {
      int row = n0 + lhi*4 + r;
      if (row < M) O[(size_t)row*(NF*16) + nf*16 + lrow] = acc[nf][r];
    }
}

// ---------------- sc partial ----------------
template<int KSO>
__global__ __launch_bounds__(512, 4) void k_scp(
    const float* __restrict__ Ao, const float* __restrict__ na,
    const short* __restrict__ fBc, float* __restrict__ part) {
  __shared__ __align__(16) short lB[KSO*8192];
  const int tid = threadIdx.x;
  const int w = tid >> 6, l = tid & 63;
  const int lrow = l & 15, lhi = l >> 4;
  const int n0 = blockIdx.x*128 + w*16;
  const int vp = blockIdx.y;

  s16x8 aoh[KSO], aol[KSO];
  {
    int row = n0 + lrow; if (row > N_NODES-1) row = N_NODES-1;
    #pragma unroll
    for (int ks = 0; ks < KSO; ++ks)
      split8(Ao + (size_t)row*(KSO*32) + ks*32 + lhi*8, aoh[ks], aol[ks]);
  }

  f32x4 acc[8];
  #pragma unroll
  for (int nf = 0; nf < 8; ++nf) acc[nf] = (f32x4){0.f,0.f,0.f,0.f};

  #pragma unroll
  for (int c = 0; c < 2; ++c) {
    const int v = vp*2 + c;
    __syncthreads();
    for (int i = tid; i < KSO*1024; i += 512) {
      int gl = i & 63;
      int rest = i >> 6;
      int ks = rest % KSO;
      int rest2 = rest / KSO;
      int nf = rest2 & 7;
      int p  = rest2 >> 3;
      size_t src = ((((size_t)p*128 + (v*8 + nf))*KSO + ks)*64 + gl)*8;
      *(s16x8*)&lB[(size_t)i*8] = *(const s16x8*)&fBc[src];
    }
    __syncthreads();
    f32x4 dacc[8];
    #pragma unroll
    for (int nf = 0; nf < 8; ++nf) dacc[nf] = (f32x4){0.f,0.f,0.f,0.f};
    #pragma unroll
    for (int nf = 0; nf < 8; ++nf)
      #pragma unroll
      for (int ks = 0; ks < KSO; ++ks) {
        s16x8 bh = *(const s16x8*)&lB[((0*8 + nf)*KSO + ks)*512 + l*8];
        s16x8 bl = *(const s16x8*)&lB[((1*8 + nf)*KSO + ks)*512 + l*8];
        dacc[nf] = __builtin_amdgcn_mfma_f32_16x16x32_bf16(aoh[ks], bh, dacc[nf], 0,0,0);
        dacc[nf] = __builtin_amdgcn_mfma_f32_16x16x32_bf16(aoh[ks], bl, dacc[nf], 0,0,0);
        dacc[nf] = __builtin_amdgcn_mfma_f32_16x16x32_bf16(aol[ks], bh, dacc[nf], 0,0,0);
      }
    #pragma unroll
    for (int r = 0; r < 4; ++r) {
      int row = n0 + lhi*4 + r; if (row > N_NODES-1) row = N_NODES-1;
      float nav = na[(size_t)row*16 + v];
      #pragma unroll
      for (int nf = 0; nf < 8; ++nf) acc[nf][r] += nav * dacc[nf][r];
    }
  }

  float* pp = part + (size_t)vp*NM128;
  #pragma unroll
  for (int nf = 0; nf < 8; ++nf)
    #pragma unroll
    for (int r = 0; r < 4; ++r) {
      int row = n0 + lhi*4 + r;
      if (row < N_NODES) pp[(size_t)row*128 + nf*16 + lrow] = acc[nf][r];
    }
}

// ---------------- reduce 9 partials (float4) ----------------
__global__ void k_reduce(const float* __restrict__ part, float* __restrict__ outs) {
  int i = blockIdx.x*256 + threadIdx.x;
  if (i >= NM128/4) return;
  f32x4 s = {0.f,0.f,0.f,0.f};
  #pragma unroll
  for (int p = 0; p < 9; ++p)
    s += *(const f32x4*)(part + (size_t)p*NM128 + (size_t)i*4);
  *(f32x4*)(outs + (size_t)i*4) = s;
}

// ---------------- conv1 gather: CSR pull (fp16 interleaved wbuf); n_v as [n][3][128] ----------------
__global__ __launch_bounds__(256) void k_gather1(
    const u16* __restrict__ wbuf, const float* __restrict__ shv,
    const int* __restrict__ esrc, const int* __restrict__ offs, const int* __restrict__ slot,
    const float* __restrict__ h,
    float* __restrict__ n_s, float* __restrict__ n_v) {
  const int wave = threadIdx.x >> 6, lane = threadIdx.x & 63;
  const int n = blockIdx.x*4 + wave;
  if (n >= N_NODES) return;
  const int s0 = offs[n], s1 = offs[n+1];
  float ns0=0.f, ns1=0.f;
  float nv00=0.f,nv01=0.f,nv02=0.f, nv10=0.f,nv11=0.f,nv12=0.f;
  for (int s = s0; s < s1; ++s) {
    int e = slot[s];
    int src = esrc[e];
    u16x4 wv = *(const u16x4*)(wbuf + (size_t)e*256 + lane*4);
    float c0 = h2f(wv[0]), c1 = h2f(wv[1]), c2 = h2f(wv[2]), c3 = h2f(wv[3]);
    float h0 = h[src*128+lane], h1 = h[src*128+64+lane];
    float sv0 = shv[e*3+0], sv1 = shv[e*3+1], sv2 = shv[e*3+2];
    ns0 += c0*h0; ns1 += c1*h1;
    float t0 = c2*h0, t1 = c3*h1;
    nv00 += t0*sv0; nv01 += t0*sv1; nv02 += t0*sv2;
    nv10 += t1*sv0; nv11 += t1*sv1; nv12 += t1*sv2;
  }
  n_s[n*128+lane]    = ns0*INV_SQRT10;
  n_s[n*128+64+lane] = ns1*INV_SQRT10;
  float* nvp = n_v + (size_t)n*384;      // [3][128]
  nvp[0*128+lane]    = nv00*INV_SQRT10;
  nvp[1*128+lane]    = nv01*INV_SQRT10;
  nvp[2*128+lane]    = nv02*INV_SQRT10;
  nvp[0*128+64+lane] = nv10*INV_SQRT10;
  nvp[1*128+64+lane] = nv11*INV_SQRT10;
  nvp[2*128+64+lane] = nv12*INV_SQRT10;
}

// ---------------- conv2 gather (fp16 interleaved wbuf): h_v layout [n][3][64] ----------------
__global__ __launch_bounds__(256) void k_gather2(
    const u16* __restrict__ wbuf, const float* __restrict__ shv,
    const int* __restrict__ esrc, const int* __restrict__ offs, const int* __restrict__ slot,
    const float* __restrict__ h_s, const float* __restrict__ h_v,
    float* __restrict__ n_mid) {
  const int wave = threadIdx.x >> 6, lane = threadIdx.x & 63;
  const int n = blockIdx.x*4 + wave;
  if (n >= N_NODES) return;
  const int s0 = offs[n], s1 = offs[n+1];
  float acc0 = 0.f, acc1 = 0.f;
  for (int s = s0; s < s1; ++s) {
    int e = slot[s];
    int src = esrc[e];
    u16x2 wv = *(const u16x2*)(wbuf + (size_t)e*128 + lane*2);
    float w0 = h2f(wv[0]), w1 = h2f(wv[1]);
    float hs = h_s[src*64+lane];
    const float* hvp = h_v + (size_t)src*192;
    float sv0 = shv[e*3+0], sv1 = shv[e*3+1], sv2 = shv[e*3+2];
    float dot = hvp[lane]*sv0 + hvp[64+lane]*sv1 + hvp[128+lane]*sv2;
    acc0 += w0*hs;
    acc1 += w1*dot;
  }
  n_mid[n*128+lane]    = acc0*INV_SQRT10;
  n_mid[n*128+64+lane] = acc1*INV_SQRT3*INV_SQRT10;
}

// ---------------- elementwise gating ----------------
__global__ void k_gatee(const float* __restrict__ outs, const float* __restrict__ ov,
                        float* __restrict__ gs_out, float* __restrict__ gv) {
  int t = blockIdx.x*256 + threadIdx.x;
  if (t >= N_NODES*64) return;
  int n = t >> 6, v = t & 63;
  float g = siluf(outs[(size_t)n*128 + v]);
  float gate = sigf(outs[(size_t)n*128 + 64 + v]);
  gs_out[(size_t)n*64 + v] = g;
  gv[(size_t)n*192 + 0*64 + v] = gate*ov[(size_t)n*192 + 0*64 + v];
  gv[(size_t)n*192 + 1*64 + v] = gate*ov[(size_t)n*192 + 1*64 + v];
  gv[(size_t)n*192 + 2*64 + v] = gate*ov[(size_t)n*192 + 2*64 + v];
}

// ---------------- pooled accumulation (RLE on sorted batch) ----------------
__global__ __launch_bounds__(128) void k_pool(
    const float* __restrict__ outs, const int* __restrict__ batch,
    float* __restrict__ pool) {
  const int j = threadIdx.x;
  const int n0 = blockIdx.x*4;
  float outv[4];
  #pragma unroll
  for (int n = 0; n < 4; ++n) outv[n] = outs[(size_t)(n0+n)*128 + j];
  int b0 = batch[n0], b1 = batch[n0+1], b2 = batch[n0+2], b3 = batch[n0+3];
  float sum = outv[0]; int cur = b0;
  if (b1 == cur) sum += outv[1]; else { atomicAdd(&pool[cur*128+j], sum); cur = b1; sum = outv[1]; }
  if (b2 == cur) sum += outv[2]; else { atomicAdd(&pool[cur*128+j], sum); cur = b2; sum = outv[2]; }
  if (b3 == cur) sum += outv[3]; else { atomicAdd(&pool[cur*128+j], sum); cur = b3; sum = outv[3]; }
  atomicAdd(&pool[cur*128+j], sum);
}

// ======== FALLBACK (atomic) kernels — used only if ws too small ========
__global__ __launch_bounds__(512) void k_edge1_at(
    const float* __restrict__ es8, const float* __restrict__ shv,
    const int* __restrict__ esrc, const int* __restrict__ edst,
    const float* __restrict__ h,
    const float* __restrict__ W0, const float* __restrict__ W1, const float* __restrict__ W2,
    float* __restrict__ n_s, float* __restrict__ n_v) {
  __shared__ float lW0[512];
  __shared__ float lW1[4096];
  __shared__ float lW2[16384];
  __shared__ float lA[8][64];
  __shared__ float lB[8][64];
  for (int i = threadIdx.x; i < 512;   i += 512) lW0[i] = W0[i];
  for (int i = threadIdx.x; i < 4096;  i += 512) lW1[i] = W1[i];
  for (int i = threadIdx.x; i < 16384; i += 512) lW2[i] = W2[i];
  __syncthreads();
  const int wave = threadIdx.x >> 6, lane = threadIdx.x & 63;
  const int nw = gridDim.x * 8;
  const int e0 = blockIdx.x*8 + wave;
  const int iters = (N_EDGES + nw - 1) / nw;
  for (int it = 0; it < iters; ++it) {
    int e = e0 + it*nw;
    bool valid = e < N_EDGES;
    float a = 0.f, sv0=0.f, sv1=0.f, sv2=0.f;
    int src = 0, dst = 0;
    if (valid) {
      const float* ep = es8 + e*8;
      sv0 = shv[e*3+0]; sv1 = shv[e*3+1]; sv2 = shv[e*3+2];
      src = esrc[e]; dst = edst[e];
      a = ep[0]*lW0[lane]      + ep[1]*lW0[64+lane]  + ep[2]*lW0[128+lane] + ep[3]*lW0[192+lane]
        + ep[4]*lW0[256+lane]  + ep[5]*lW0[320+lane] + ep[6]*lW0[384+lane] + ep[7]*lW0[448+lane];
      a = siluf(a * INV_SQRT8);
    }
    lA[wave][lane] = a;
    __syncthreads();
    {
      float b0=0.f;
      #pragma unroll
      for (int k = 0; k < 64; ++k) b0 += lA[wave][k]*lW1[k*64+lane];
      lB[wave][lane] = siluf(b0 * INV_SQRT64);
    }
    __syncthreads();
    if (valid) {
      float c0=0.f,c1=0.f,c2=0.f,c3=0.f;
      #pragma unroll
      for (int k = 0; k < 64; ++k) {
        float bk = lB[wave][k];
        const float* r = lW2 + k*256;
        c0 += bk*r[lane]; c1 += bk*r[64+lane]; c2 += bk*r[128+lane]; c3 += bk*r[192+lane];
      }
      float hs0 = h[src*128 + lane];
      float hs1 = h[src*128 + 64 + lane];
      atomicAdd(&n_s[dst*128 + lane],      c0*INV_SQRT64*hs0*INV_SQRT10);
      atomicAdd(&n_s[dst*128 + 64 + lane], c1*INV_SQRT64*hs1*INV_SQRT10);
      float t0 = c2*INV_SQRT64*hs0*INV_SQRT10;
      float t1 = c3*INV_SQRT64*hs1*INV_SQRT10;
      float* nvp = n_v + dst*384;
      atomicAdd(nvp + lane*3+0, t0*sv0);
      atomicAdd(nvp + lane*3+1, t0*sv1);
      atomicAdd(nvp + lane*3+2, t0*sv2);
      atomicAdd(nvp + (64+lane)*3+0, t1*sv0);
      atomicAdd(nvp + (64+lane)*3+1, t1*sv1);
      atomicAdd(nvp + (64+lane)*3+2, t1*sv2);
    }
  }
}

__global__ __launch_bounds__(512) void k_edge2_at(
    const float* __restrict__ es8, const float* __restrict__ shv,
    const int* __restrict__ esrc, const int* __restrict__ edst,
    const float* __restrict__ h_s, const float* __restrict__ h_v,
    const float* __restrict__ W0, const float* __restrict__ W1, const float* __restrict__ W2,
    float* __restrict__ n_mid) {
  __shared__ float lW0[512];
  __shared__ float lW1[4096];
  __shared__ float lW2[8192];
  __shared__ float lA[8][64];
  __shared__ float lB[8][64];
  for (int i = threadIdx.x; i < 512;  i += 512) lW0[i] = W0[i];
  for (int i = threadIdx.x; i < 4096; i += 512) lW1[i] = W1[i];
  for (int i = threadIdx.x; i < 8192; i += 512) lW2[i] = W2[i];
  __syncthreads();
  const int wave = threadIdx.x >> 6, lane = threadIdx.x & 63;
  const int nw = gridDim.x * 8;
  const int e0 = blockIdx.x*8 + wave;
  const int iters = (N_EDGES + nw - 1) / nw;
  for (int it = 0; it < iters; ++it) {
    int e = e0 + it*nw;
    bool valid = e < N_EDGES;
    float a = 0.f, sv0=0.f, sv1=0.f, sv2=0.f;
    int src = 0, dst = 0;
    if (valid) {
      const float* ep = es8 + e*8;
      sv0 = shv[e*3+0]; sv1 = shv[e*3+1]; sv2 = shv[e*3+2];
      src = esrc[e]; dst = edst[e];
      a = ep[0]*lW0[lane]      + ep[1]*lW0[64+lane]  + ep[2]*lW0[128+lane] + ep[3]*lW0[192+lane]
        + ep[4]*lW0[256+lane]  + ep[5]*lW0[320+lane] + ep[6]*lW0[384+lane] + ep[7]*lW0[448+lane];
      a = siluf(a * INV_SQRT8);
    }
    lA[wave][lane] = a;
    __syncthreads();
    {
      float b0=0.f;
      #pragma unroll
      for (int k = 0; k < 64; ++k) b0 += lA[wave][k]*lW1[k*64+lane];
      lB[wave][lane] = siluf(b0 * INV_SQRT64);
    }
    __syncthreads();
    if (valid) {
      float c0=0.f, c1=0.f;
      #pragma unroll
      for (int k = 0; k < 64; ++k) {
        float bk = lB[wave][k];
        const float* r = lW2 + k*128;
        c0 += bk*r[lane]; c1 += bk*r[64+lane];
      }
      float hsv = h_s[src*64 + lane];
      const float* hvp = h_v + src*192 + lane*3;
      float dotv = hvp[0]*sv0 + hvp[1]*sv1 + hvp[2]*sv2;
      atomicAdd(&n_mid[dst*128 + lane],      c0*INV_SQRT64*hsv*INV_SQRT10);
      atomicAdd(&n_mid[dst*128 + 64 + lane], c1*INV_SQRT64*dotv*INV_SQRT3*INV_SQRT10);
    }
  }
}

// ---------------- FALLBACK conv1 node pass (full, old n_v layout) ----------------
__global__ __launch_bounds__(128) void k_node1(
    const float* __restrict__ n_s, const float* __restrict__ n_v,
    const float* __restrict__ s,   const float* __restrict__ na,
    const float* __restrict__ Wls, const float* __restrict__ Wlv,
    const float* __restrict__ Csc, const float* __restrict__ W2s, const float* __restrict__ W2v,
    float* __restrict__ gs_out, float* __restrict__ hs_out, float* __restrict__ hv_out) {
  __shared__ float l_ns[512], l_s[512], l_na[64], l_nv[1536];
  __shared__ float l_outs[512], l_ov[768], l_gs[256], l_gv[768];
  const int j = threadIdx.x;
  const int n0 = blockIdx.x*4;
  for (int i = j; i < 512;  i += 128) { l_ns[i] = n_s[n0*128+i]; l_s[i] = s[n0*128+i]; }
  for (int i = j; i < 1536; i += 128) l_nv[i] = n_v[n0*384+i];
  if (j < 64) l_na[j] = na[n0*16+j];
  __syncthreads();

  float accs[4] = {0.f,0.f,0.f,0.f};
  for (int k = 0; k < 128; ++k) {
    float w = Wls[k*128+j];
    accs[0] += l_ns[k]*w; accs[1] += l_ns[128+k]*w;
    accs[2] += l_ns[256+k]*w; accs[3] += l_ns[384+k]*w;
  }
  float accc[4] = {0.f,0.f,0.f,0.f};
  for (int vt = 0; vt < 16; vt += 4) {
    float a0[4],a1[4],a2[4],a3[4];
    #pragma unroll
    for (int n = 0; n < 4; ++n) {
      a0[n]=l_na[n*16+vt]; a1[n]=l_na[n*16+vt+1];
      a2[n]=l_na[n*16+vt+2]; a3[n]=l_na[n*16+vt+3];
    }
    for (int u = 0; u < 128; ++u) {
      const float* cp = Csc + (u*16+vt)*128 + j;
      float c0=cp[0], c1=cp[128], c2=cp[256], c3=cp[384];
      float s0=l_s[u], s1=l_s[128+u], s2=l_s[256+u], s3=l_s[384+u];
      accc[0] += s0*(a0[0]*c0 + a1[0]*c1 + a2[0]*c2 + a3[0]*c3);
      accc[1] += s1*(a0[1]*c0 + a1[1]*c1 + a2[1]*c2 + a3[1]*c3);
      accc[2] += s2*(a0[2]*c0 + a1[2]*c1 + a2[2]*c2 + a3[2]*c3);
      accc[3] += s3*(a0[3]*c0 + a1[3]*c1 + a2[3]*c2 + a3[3]*c3);
    }
  }
  #pragma unroll
  for (int n = 0; n < 4; ++n)
    l_outs[n*128+j] = accs[n]*INV_SQRT128 + accc[n]*INV_SQRT2048;

  const int jj = j & 63, hh = j >> 6;
  float ov[2][3] = {{0.f,0.f,0.f},{0.f,0.f,0.f}};
  for (int u = 0; u < 128; ++u) {
    float w = Wlv[u*64+jj];
    #pragma unroll
    for (int t = 0; t < 2; ++t) {
      int n = 2*hh+t;
      ov[t][0] += l_nv[n*384+u*3+0]*w;
      ov[t][1] += l_nv[n*384+u*3+1]*w;
      ov[t][2] += l_nv[n*384+u*3+2]*w;
    }
  }
  #pragma unroll
  for (int t = 0; t < 2; ++t) {
    int n = 2*hh+t;
    l_ov[n*192+jj*3+0] = ov[t][0]*INV_SQRT128;
    l_ov[n*192+jj*3+1] = ov[t][1]*INV_SQRT128;
    l_ov[n*192+jj*3+2] = ov[t][2]*INV_SQRT128;
  }
  __syncthreads();

  #pragma unroll
  for (int t = 0; t < 2; ++t) {
    int n = 2*hh+t;
    float gv_s = siluf(l_outs[n*128+jj]);
    float gate = sigf (l_outs[n*128+64+jj]);
    l_gs[n*64+jj] = gv_s;
    gs_out[(n0+n)*64+jj] = gv_s;
    l_gv[n*192+jj*3+0] = gate*l_ov[n*192+jj*3+0];
    l_gv[n*192+jj*3+1] = gate*l_ov[n*192+jj*3+1];
    l_gv[n*192+jj*3+2] = gate*l_ov[n*192+jj*3+2];
  }
  __syncthreads();

  float ha[2] = {0.f,0.f};
  for (int k = 0; k < 64; ++k) {
    float w = W2s[k*64+jj];
    ha[0] += l_gs[(2*hh+0)*64+k]*w;
    ha[1] += l_gs[(2*hh+1)*64+k]*w;
  }
  hs_out[(n0+2*hh+0)*64+jj] = ha[0]*INV_SQRT64;
  hs_out[(n0+2*hh+1)*64+jj] = ha[1]*INV_SQRT64;

  float hv[2][3] = {{0.f,0.f,0.f},{0.f,0.f,0.f}};
  for (int u = 0; u < 64; ++u) {
    float w = W2v[u*64+jj];
    #pragma unroll
    for (int t = 0; t < 2; ++t) {
      int n = 2*hh+t;
      hv[t][0] += l_gv[n*192+u*3+0]*w;
      hv[t][1] += l_gv[n*192+u*3+1]*w;
      hv[t][2] += l_gv[n*192+u*3+2]*w;
    }
  }
  #pragma unroll
  for (int t = 0; t < 2; ++t) {
    int n = 2*hh+t;
    hv_out[(n0+n)*192+jj*3+0] = hv[t][0]*INV_SQRT64;
    hv_out[(n0+n)*192+jj*3+1] = hv[t][1]*INV_SQRT64;
    hv_out[(n0+n)*192+jj*3+2] = hv[t][2]*INV_SQRT64;
  }
}

// ---------------- FALLBACK conv2 node pass + pooling ----------------
__global__ __launch_bounds__(128) void k_node2(
    const float* __restrict__ n_mid, const float* __restrict__ gs,
    const float* __restrict__ na, const int* __restrict__ batch,
    const float* __restrict__ W, const float* __restrict__ Csc,
    float* __restrict__ pool) {
  __shared__ float l_nm[512], l_gs[256], l_na[64];
  const int j = threadIdx.x;
  const int n0 = blockIdx.x*4;
  for (int i = j; i < 512; i += 128) l_nm[i] = n_mid[n0*128+i];
  for (int i = j; i < 256; i += 128) l_gs[i] = gs[n0*64+i];
  if (j < 64) l_na[j] = na[n0*16+j];
  __syncthreads();
  float acc[4] = {0.f,0.f,0.f,0.f};
  for (int k = 0; k < 128; ++k) {
    float w = W[k*128+j];
    acc[0] += l_nm[k]*w; acc[1] += l_nm[128+k]*w;
    acc[2] += l_nm[256+k]*w; acc[3] += l_nm[384+k]*w;
  }
  float acc2[4] = {0.f,0.f,0.f,0.f};
  for (int vt = 0; vt < 16; vt += 4) {
    float a0[4],a1[4],a2[4],a3[4];
    #pragma unroll
    for (int n = 0; n < 4; ++n) {
      a0[n]=l_na[n*16+vt]; a1[n]=l_na[n*16+vt+1];
      a2[n]=l_na[n*16+vt+2]; a3[n]=l_na[n*16+vt+3];
    }
    for (int u = 0; u < 64; ++u) {
      const float* cp = Csc + (u*16+vt)*128 + j;
      float c0=cp[0], c1=cp[128], c2=cp[256], c3=cp[384];
      float s0=l_gs[u], s1=l_gs[64+u], s2=l_gs[128+u], s3=l_gs[192+u];
      acc2[0] += s0*(a0[0]*c0 + a1[0]*c1 + a2[0]*c2 + a3[0]*c3);
      acc2[1] += s1*(a0[1]*c0 + a1[1]*c1 + a2[1]*c2 + a3[1]*c3);
      acc2[2] += s2*(a0[2]*c0 + a1[2]*c1 + a2[2]*c2 + a3[2]*c3);
      acc2[3] += s3*(a0[3]*c0 + a1[3]*c1 + a2[3]*c2 + a3[3]*c3);
    }
  }
  float outv[4];
  #pragma unroll
  for (int n = 0; n < 4; ++n)
    outv[n] = acc[n]*INV_SQRT128 + acc2[n]*INV_SQRT1024;
  int b0 = batch[n0], b1 = batch[n0+1], b2 = batch[n0+2], b3 = batch[n0+3];
  float sum = outv[0]; int cur = b0;
  if (b1 == cur) sum += outv[1]; else { atomicAdd(&pool[cur*128+j], sum); cur = b1; sum = outv[1]; }
  if (b2 == cur) sum += outv[2]; else { atomicAdd(&pool[cur*128+j], sum); cur = b2; sum = outv[2]; }
  if (b3 == cur) sum += outv[3]; else { atomicAdd(&pool[cur*128+j], sum); cur = b3; sum = outv[3]; }
  atomicAdd(&pool[cur*128+j], sum);
}

// ---------------- readout head ----------------
__global__ __launch_bounds__(128) void k_head(
    const float* __restrict__ pool, const float* __restrict__ cnt,
    const float* __restrict__ Wr1, const float* __restrict__ Wr2,
    float* __restrict__ out) {
  __shared__ float lp[128];
  __shared__ float lt[128];
  const int j = threadIdx.x;
  for (int g = 0; g < N_GRAPHS; ++g) {
    float inv = 1.f / fmaxf(cnt[g], 1.f);
    lp[j] = pool[g*128+j]*inv;
    __syncthreads();
    float acc = 0.f;
    for (int k = 0; k < 128; ++k) acc += lp[k]*Wr1[k*128+j];
    lt[j] = siluf(acc*INV_SQRT128) * Wr2[j];
    __syncthreads();
    if (j == 0) {
      float ssum = 0.f;
      for (int k = 0; k < 128; ++k) ssum += lt[k];
      out[g] = ssum*INV_SQRT128;
    }
    __syncthreads();
  }
}

extern "C" void kernel_launch(void* const* d_in, const int* in_sizes, int n_in,
                              void* d_out, int out_size, void* d_ws, size_t ws_size,
                              hipStream_t stream) {
  const float* x         = (const float*)d_in[0];
  const float* node_attr = (const float*)d_in[1];
  const int*   esrc      = (const int*)d_in[2];
  const int*   edst      = (const int*)d_in[3];
  const float* evec      = (const float*)d_in[4];
  const int*   batch     = (const int*)d_in[5];
  const float* W_embed   = (const float*)d_in[6];
  const float* c1_lin1   = (const float*)d_in[7];
  const float* c1_fc_w0  = (const float*)d_in[8];
  const float* c1_fc_w1  = (const float*)d_in[9];
  const float* c1_fc_w2  = (const float*)d_in[10];
  const float* c1_lin2_s = (const float*)d_in[11];
  const float* c1_lin2_v = (const float*)d_in[12];
  const float* c1_sc     = (const float*)d_in[13];
  const float* c2_lin1_s = (const float*)d_in[14];
  const float* c2_lin1_v = (const float*)d_in[15];
  const float* c2_fc_w0  = (const float*)d_in[16];
  const float* c2_fc_w1  = (const float*)d_in[17];
  const float* c2_fc_w2  = (const float*)d_in[18];
  const float* c2_lin2   = (const float*)d_in[19];
  const float* c2_sc     = (const float*)d_in[20];
  const float* Wr1       = (const float*)d_in[21];
  const float* Wr2       = (const float*)d_in[22];

  float* ws    = (float*)d_ws;
  float* es8   = ws + OFF_ES8;
  float* shv   = ws + OFF_SHV;
  float* s_    = ws + OFF_S;
  float* h_    = ws + OFF_H;
  float* gs_   = ws + OFF_GS;
  float* hs_   = ws + OFF_HS;
  float* hv_   = ws + OFF_HV;
  float* ns_   = ws + OFF_NS;
  float* nv_   = ws + OFF_NV;
  float* nmid_ = ws + OFF_NMID;
  float* pool_ = ws + OFF_POOL;
  float* cnt_  = ws + OFF_CNT;
  int*   hist_ = (int*)(ws + OFF_HIST);
  int*   curs_ = (int*)(ws + OFF_CURS);
  int*   offs_ = (int*)(ws + OFF_OFFS);
  short* frag_ = (short*)(ws + OFF_FRAG);
  int*   slot_ = (int*)(ws + OFF_SLOT);
  float* wbuf_ = ws + OFF_WBUF;
  u16*   wb16_ = (u16*)wbuf_;   // fp16 wbuf occupies only lower half of WBUF region

  // upper-wbuf carve-outs (k_mlp<16> writes only N_EDGES*128 floats worth of u16)
  float* out1_  = wbuf_ + (size_t)N_EDGES*128;                 // 1.28M floats
  short* nfrag_ = (short*)(out1_ + (size_t)NM128);             // 884736 shorts
  float* part_  = out1_ + (size_t)NM128 + NFRAG_TOT/2;         // 9 x 1.28M floats
  float* ov_    = part_ + (size_t)9*NM128;                     // 1.92M floats
  float* gv_    = nv_;                                         // aliases nv (dead after ov GEMM)
  float* out2_  = ns_;                                         // ns dead after conv1 dense GEMM

  const bool big = ws_size >= WS_NEED_BYTES;

  k_geom<<<N_EDGES/256, 256, 0, stream>>>(evec, es8, shv);

  if (big) {
    hipMemsetAsync(pool_, 0, (size_t)(OFF_OFFS - OFF_POOL)*sizeof(float), stream);
    k_cnthist<<<(N_EDGES+255)/256, 256, 0, stream>>>(batch, edst, cnt_, hist_);
    k_scanp<<<1, 1024, 0, stream>>>(hist_, offs_);
    k_slot<<<(N_EDGES+255)/256, 256, 0, stream>>>(edst, offs_, curs_, slot_);

    // merged startup frag prep: 6 MLP weights + W_embed + c1_lin1
    {
      PD8 m{};
      m.d[0] = {c1_fc_w0, frag_ + F_B1,  8,  64,  4, 1, 4096,  INV_SQRT8};
      m.d[1] = {c1_fc_w1, frag_ + F_B2,  64, 64,  4, 2, 8192,  INV_SQRT64};
      m.d[2] = {c1_fc_w2, frag_ + F_B3,  64, 256, 16,2, 32768, INV_SQRT64};
      m.d[3] = {c2_fc_w0, frag_ + F_B1b, 8,  64,  4, 1, 4096,  INV_SQRT8};
      m.d[4] = {c2_fc_w1, frag_ + F_B2b, 64, 64,  4, 2, 8192,  INV_SQRT64};
      m.d[5] = {c2_fc_w2, frag_ + F_B3b, 64, 128, 8, 2, 16384, INV_SQRT64};
      m.d[6] = {W_embed,  frag_ + F_WE,  32, 128, 8, 1, 8192,  INV_SQRT32};
      m.d[7] = {c1_lin1,  frag_ + F_L1,  128,128, 8, 4, 32768, INV_SQRT128};
      m.nd = 8; m.tot = FRAG_TOT;
      k_prepmulti<<<448, 256, 0, stream>>>(m);
    }

    // s = x@W_embed ; h = s@c1_lin1 (MFMA)
    k_gemm<1,8><<<79, 512, 0, stream>>>(x,  32,  N_NODES, frag_ + F_WE, s_);
    k_gemm<4,8><<<79, 512, 0, stream>>>(s_, 128, N_NODES, frag_ + F_L1, h_);

    // conv1 edge MLP (fp16 interleaved out, 32 edges/wave) + gather
    k_mlp<16><<<1250, 256, 0, stream>>>(es8, frag_ + F_B1, frag_ + F_B2, frag_ + F_B3, wb16_);
    k_gather1<<<(N_NODES+3)/4, 256, 0, stream>>>(wb16_, shv, esrc, offs_, slot_, h_, ns_, nv_);

    // merged node weight frag prep (upper-wbuf region)
    {
      PD8 m{};
      m.d[0] = {c1_lin2_s, nfrag_ + NF_WLS, 128, 128,  8,   4, 32768,  INV_SQRT128};
      m.d[1] = {c1_sc,     nfrag_ + NF_C1,  128, 2048, 128, 4, 524288, INV_SQRT2048};
      m.d[2] = {c2_lin2,   nfrag_ + NF_W2,  128, 128,  8,   4, 32768,  INV_SQRT128};
      m.d[3] = {c2_sc,     nfrag_ + NF_C2,  64,  2048, 128, 2, 262144, INV_SQRT1024};
      m.d[4] = {c1_lin2_v, nfrag_ + NF_LV,  128, 64,   4,   4, 16384,  INV_SQRT128};
      m.d[5] = {c2_lin1_s, nfrag_ + NF_2S,  64,  64,   4,   2, 8192,   INV_SQRT64};
      m.d[6] = {c2_lin1_v, nfrag_ + NF_2V,  64,  64,   4,   2, 8192,   INV_SQRT64};
      m.nd = 7; m.tot = NFRAG_TOT;
      k_prepmulti<<<1024, 256, 0, stream>>>(m);
    }

    // conv1 node: dense + sc partials -> reduce -> out1
    k_gemm<4,8><<<79, 512, 0, stream>>>(ns_, 128, N_NODES, nfrag_ + NF_WLS, part_ + (size_t)8*NM128);
    k_scp<4><<<dim3(79,8), 512, 0, stream>>>(s_, node_attr, nfrag_ + NF_C1, part_);
    k_reduce<<<(NM128/4+255)/256, 256, 0, stream>>>(part_, out1_);

    // gate phase via MFMA
    k_gemm<4,4><<<235, 512, 0, stream>>>(nv_, 128, N_NODES*3, nfrag_ + NF_LV, ov_);
    k_gatee<<<(N_NODES*64+255)/256, 256, 0, stream>>>(out1_, ov_, gs_, gv_);
    k_gemm<2,4><<<79, 512, 0, stream>>>(gs_, 64, N_NODES, nfrag_ + NF_2S, hs_);
    k_gemm<2,4><<<235, 512, 0, stream>>>(gv_, 64, N_NODES*3, nfrag_ + NF_2V, hv_);

    // conv2 edge MLP (fp16 interleaved out) + gather
    k_mlp<8><<<1250, 256, 0, stream>>>(es8, frag_ + F_B1b, frag_ + F_B2b, frag_ + F_B3b, wb16_);
    k_gather2<<<(N_NODES+3)/4, 256, 0, stream>>>(wb16_, shv, esrc, offs_, slot_, hs_, hv_, nmid_);

    // conv2 node: partials -> reduce -> pool
    k_gemm<4,8><<<79, 512, 0, stream>>>(nmid_, 128, N_NODES, nfrag_ + NF_W2, part_ + (size_t)8*NM128);
    k_scp<2><<<dim3(79,8), 512, 0, stream>>>(gs_, node_attr, nfrag_ + NF_C2, part_);
    k_reduce<<<(NM128/4+255)/256, 256, 0, stream>>>(part_, out2_);
    k_pool<<<N_NODES/4, 128, 0, stream>>>(out2_, batch, pool_);
  } else {
    hipMemsetAsync(ns_, 0, (size_t)(OFF_HIST - OFF_NS)*sizeof(float), stream);
    k_linear128<<<(N_NODES*128)/256, 256, 0, stream>>>(x,  W_embed, s_, 32,  INV_SQRT32,  N_NODES*128);
    k_linear128<<<(N_NODES*128)/256, 256, 0, stream>>>(s_, c1_lin1, h_, 128, INV_SQRT128, N_NODES*128);
    k_cnthist<<<(N_EDGES+255)/256, 256, 0, stream>>>(batch, edst, cnt_, hist_);
    k_edge1_at<<<256, 512, 0, stream>>>(es8, shv, esrc, edst, h_,
                                        c1_fc_w0, c1_fc_w1, c1_fc_w2, ns_, nv_);
    k_node1<<<N_NODES/4, 128, 0, stream>>>(ns_, nv_, s_, node_attr,
                                           c1_lin2_s, c1_lin2_v, c1_sc,
                                           c2_lin1_s, c2_lin1_v, gs_, hs_, hv_);
    k_edge2_at<<<512, 512, 0, stream>>>(es8, shv, esrc, edst, hs_, hv_,
                                        c2_fc_w0, c2_fc_w1, c2_fc_w2, nmid_);
    k_node2<<<N_NODES/4, 128, 0, stream>>>(nmid_, gs_, node_attr, batch,
                                           c2_lin2, c2_sc, pool_);
  }

  k_head<<<1, 128, 0, stream>>>(pool_, cnt_, Wr1, Wr2, (float*)d_out);
}

// Round 9
// 378.249 us; speedup vs baseline: 3.3182x; 1.0197x over previous
//
#include <hip/hip_runtime.h>
#include <hip/hip_fp16.h>

#define N_NODES 10000
#define N_EDGES 160000
#define N_GRAPHS 16

typedef __attribute__((ext_vector_type(8))) short s16x8;
typedef __attribute__((ext_vector_type(4))) float f32x4;
typedef __attribute__((ext_vector_type(4))) unsigned short u16x4;
typedef __attribute__((ext_vector_type(2))) unsigned short u16x2;
typedef unsigned int uint32;
typedef unsigned short u16;

// ---- workspace layout (float offsets) ----
#define OFF_ES8  0
#define OFF_SHV  (OFF_ES8 + N_EDGES*8)
#define OFF_S    (OFF_SHV + N_EDGES*3)
#define OFF_H    (OFF_S   + N_NODES*128)
#define OFF_GS   (OFF_H   + N_NODES*128)
#define OFF_HS   (OFF_GS  + N_NODES*64)
#define OFF_HV   (OFF_HS  + N_NODES*64)
#define OFF_NS   (OFF_HV  + N_NODES*192)   /* fallback zero-region start */
#define OFF_NV   (OFF_NS  + N_NODES*128)
#define OFF_NMID (OFF_NV  + N_NODES*384)
#define OFF_POOL (OFF_NMID+ N_NODES*128)   /* new-path zero-region start */
#define OFF_CNT  (OFF_POOL+ N_GRAPHS*128)
#define OFF_HIST (OFF_CNT + N_GRAPHS)
#define OFF_CURS (OFF_HIST+ N_NODES)
#define OFF_OFFS (OFF_CURS+ N_NODES)       /* new-path zero-region end (excl) */
#define OFF_FRAG (OFF_OFFS+ N_NODES + 16)  /* persistent frags: 114688 shorts = 57344 floats */
#define OFF_SLOT (OFF_FRAG+ 57344)
#define OFF_WBUF (OFF_SLOT+ N_EDGES)
#define WBUF_FLOATS ((size_t)N_EDGES*256)
#define WS_NEED_BYTES ((size_t)(OFF_WBUF + WBUF_FLOATS) * 4)

// persistent frag sub-offsets in shorts
#define F_B1   0        /* conv1 L1: NF4 KS1 -> 4096  */
#define F_B2   4096     /* conv1 L2: NF4 KS2 -> 8192  */
#define F_B3   12288    /* conv1 L3: NF16 KS2 -> 32768 */
#define F_B1b  45056
#define F_B2b  49152
#define F_B3b  57344    /* conv2 L3: NF8 KS2 -> 16384 */
#define F_WE   73728    /* W_embed: NF8 KS1 -> 8192 */
#define F_L1   81920    /* c1_lin1: NF8 KS4 -> 32768 */
#define FRAG_TOT 114688

// node-frag sub-offsets in shorts, within the upper-wbuf nfrag region
#define NF_WLS 0        /* c1_lin2_s: NF8 KS4 -> 32768 */
#define NF_C1  32768    /* c1_sc:   NF128 KS4 -> 524288 */
#define NF_W2  557056   /* c2_lin2:  NF8 KS4 -> 32768 */
#define NF_C2  589824   /* c2_sc:   NF128 KS2 -> 262144 */
#define NF_LV  851968   /* c1_lin2_v: NF4 KS4 -> 16384 */
#define NF_2S  868352   /* c2_lin1_s: NF4 KS2 -> 8192 */
#define NF_2V  876544   /* c2_lin1_v: NF4 KS2 -> 8192 */
#define NFRAG_TOT 884736

#define NM128 (N_NODES*128)

#define INV_SQRT32   0.17677669529663687f
#define INV_SQRT128  0.08838834764831845f
#define INV_SQRT8    0.3535533905932738f
#define INV_SQRT64   0.125f
#define INV_SQRT2048 0.022097086912079608f
#define INV_SQRT1024 0.03125f
#define INV_SQRT10   0.31622776601683794f
#define INV_SQRT3    0.5773502691896258f
#define SQRT3_C      1.7320508075688772f

__device__ __forceinline__ float siluf(float x){ return x / (1.f + __expf(-x)); }
__device__ __forceinline__ float sigf (float x){ return 1.f / (1.f + __expf(-x)); }
__device__ __forceinline__ unsigned short bf16h(float x){
  uint32 u = __float_as_uint(x);
  u += 0x7FFFu + ((u >> 16) & 1u);
  return (unsigned short)(u >> 16);
}
__device__ __forceinline__ float bf2f(unsigned short h){
  return __uint_as_float(((uint32)h) << 16);
}
__device__ __forceinline__ u16 f2h(float x){ return __half_as_ushort(__float2half_rn(x)); }
__device__ __forceinline__ float h2f(u16 b){ return __half2float(__ushort_as_half(b)); }
__device__ __forceinline__ void split8(const float* __restrict__ p, s16x8& hi, s16x8& lo) {
  f32x4 v0 = *(const f32x4*)p;
  f32x4 v1 = *(const f32x4*)(p + 4);
  float vals[8] = {v0[0],v0[1],v0[2],v0[3],v1[0],v1[1],v1[2],v1[3]};
  #pragma unroll
  for (int j = 0; j < 8; ++j) {
    unsigned short hh = bf16h(vals[j]);
    hi[j] = (short)hh;
    lo[j] = (short)bf16h(vals[j] - bf2f(hh));
  }
}

// ---------------- edge geometry ----------------
__global__ void k_geom(const float* __restrict__ evec,
                       float* __restrict__ es8, float* __restrict__ shv) {
  int e = blockIdx.x*256 + threadIdx.x;
  if (e >= N_EDGES) return;
  float vx = evec[e*3+0], vy = evec[e*3+1], vz = evec[e*3+2];
  float d  = sqrtf(vx*vx + vy*vy + vz*vz);
  float xs = d - 0.25f;
  bool  in = (xs > 0.f) && (xs < 4.0f);
  float safe = xs > 0.f ? xs : 1.f;
  float amp  = in ? 2.0f/safe : 0.f;
  const float PI4 = 0.7853981633974483f;
  #pragma unroll
  for (int k = 0; k < 8; ++k)
    es8[e*8+k] = amp * sinf((float)(k+1) * PI4 * safe);
  float invd = d > 0.f ? 1.f/d : 1.f;
  shv[e*3+0] = SQRT3_C*vx*invd;
  shv[e*3+1] = SQRT3_C*vy*invd;
  shv[e*3+2] = SQRT3_C*vz*invd;
}

// ---------------- fallback scalar linear ----------------
__global__ void k_linear128(const float* __restrict__ A, const float* __restrict__ W,
                            float* __restrict__ O, int K, float scale, int total) {
  int t = blockIdx.x*256 + threadIdx.x;
  if (t >= total) return;
  int n = t >> 7, j = t & 127;
  const float* a = A + n*K;
  float a0=0.f,a1=0.f,a2=0.f,a3=0.f;
  for (int k = 0; k < K; k += 4) {
    a0 += a[k+0]*W[(k+0)*128+j];
    a1 += a[k+1]*W[(k+1)*128+j];
    a2 += a[k+2]*W[(k+2)*128+j];
    a3 += a[k+3]*W[(k+3)*128+j];
  }
  O[t] = (a0+a1+a2+a3)*scale;
}

// ---------------- graph node counts + edge histogram (merged) ----------------
__global__ void k_cnthist(const int* __restrict__ batch, const int* __restrict__ edst,
                          float* __restrict__ cnt, int* __restrict__ hist) {
  __shared__ int lc[N_GRAPHS];
  int t = threadIdx.x;
  if (t < N_GRAPHS) lc[t] = 0;
  __syncthreads();
  int i = blockIdx.x*256 + t;
  if (i < N_NODES) atomicAdd(&lc[batch[i]], 1);
  if (i < N_EDGES) atomicAdd(&hist[edst[i]], 1);
  __syncthreads();
  if (t < N_GRAPHS && lc[t] > 0) atomicAdd(&cnt[t], (float)lc[t]);
}

__global__ __launch_bounds__(1024) void k_scanp(const int* __restrict__ hist,
                                                int* __restrict__ offs) {
  __shared__ int wsum[16];
  const int t = threadIdx.x;
  const int lane = t & 63, w = t >> 6;
  const int base = t*10;
  int v[10]; int s = 0;
  #pragma unroll
  for (int i = 0; i < 10; ++i) {
    int idx = base + i;
    int x = (idx < N_NODES) ? hist[idx] : 0;
    s += x; v[i] = s;
  }
  int ws = s;
  #pragma unroll
  for (int d = 1; d < 64; d <<= 1) {
    int u = __shfl_up(ws, d);
    if (lane >= d) ws += u;
  }
  if (lane == 63) wsum[w] = ws;
  __syncthreads();
  if (w == 0) {
    int x = (lane < 16) ? wsum[lane] : 0;
    #pragma unroll
    for (int d = 1; d < 16; d <<= 1) {
      int u = __shfl_up(x, d);
      if (lane >= d) x += u;
    }
    if (lane < 16) wsum[lane] = x;
  }
  __syncthreads();
  int waveoff = (w > 0) ? wsum[w-1] : 0;
  int texcl = waveoff + ws - s;
  if (t == 0) offs[0] = 0;
  #pragma unroll
  for (int i = 0; i < 10; ++i) {
    int idx = base + i;
    if (idx < N_NODES) offs[idx+1] = texcl + v[i];
  }
}

__global__ void k_slot(const int* __restrict__ edst, const int* __restrict__ offs,
                       int* __restrict__ curs, int* __restrict__ slot) {
  int e = blockIdx.x*256 + threadIdx.x;
  if (e < N_EDGES) {
    int d = edst[e];
    int p = offs[d] + atomicAdd(&curs[d], 1);
    slot[p] = e;
  }
}

// ---------------- merged weight fragment prep ----------------
struct PD { const float* W; short* dst; int Keff, N, NF, KS, nElem; float scale; };
struct PD8 { PD d[8]; int nd; int tot; };

__global__ void k_prepmulti(PD8 ds) {
  int stride = gridDim.x*256;
  for (int t = blockIdx.x*256 + threadIdx.x; t < ds.tot; t += stride) {
    int rem = t, i = 0;
    while (i < ds.nd-1 && rem >= ds.d[i].nElem) { rem -= ds.d[i].nElem; ++i; }
    const PD p = ds.d[i];
    int j = rem & 7;
    int l = (rem >> 3) & 63;
    int rest = rem >> 9;
    int ks = rest % p.KS; rest /= p.KS;
    int nf = rest % p.NF;
    int pp = rest / p.NF;
    int k   = ks*32 + (l >> 4)*8 + j;
    int col = nf*16 + (l & 15);
    float v = (k < p.Keff) ? p.W[(size_t)k*p.N + col]*p.scale : 0.f;
    unsigned short hi = bf16h(v);
    unsigned short o = pp ? bf16h(v - bf2f(hi)) : hi;
    p.dst[rem] = (short)o;
  }
}

// ---------------- fused 3-layer edge MLP via MFMA; 32 edges/wave; packed fp16 interleaved out ----------------
// wbuf layout: [e][64 cols][NQ quadrants] u16, NQ = NF3/4
template<int NF3>
__global__ __launch_bounds__(256) void k_mlp(
    const float* __restrict__ es8,
    const short* __restrict__ fb1, const short* __restrict__ fb2,
    const short* __restrict__ fb3, u16* __restrict__ wbuf) {
  __shared__ __align__(16) short route[4][2304];   // 4 waves x (32 rows x 72 shorts)
  const int w = threadIdx.x >> 6, l = threadIdx.x & 63;
  const int lrow = l & 15, lhi = l >> 4;
  const int e0 = (blockIdx.x*4 + w)*32;
  short* rt = route[w];
  constexpr int NQ = NF3/4;

  s16x8 ah1[2], al1[2];
  #pragma unroll
  for (int mt = 0; mt < 2; ++mt) {
    s16x8 h = {0,0,0,0,0,0,0,0}, lo = {0,0,0,0,0,0,0,0};
    if (lhi == 0) {
      const float* ep = es8 + (size_t)(e0 + mt*16 + lrow)*8;
      split8(ep, h, lo);
    }
    ah1[mt] = h; al1[mt] = lo;
  }

  f32x4 acc1[2][4];
  #pragma unroll
  for (int mt = 0; mt < 2; ++mt)
    #pragma unroll
    for (int nf = 0; nf < 4; ++nf) acc1[mt][nf] = (f32x4){0.f,0.f,0.f,0.f};
  #pragma unroll
  for (int nf = 0; nf < 4; ++nf) {
    s16x8 bh = *(const s16x8*)(fb1 + ((0*4 + nf)*1 + 0)*512 + l*8);
    s16x8 bl = *(const s16x8*)(fb1 + ((1*4 + nf)*1 + 0)*512 + l*8);
    #pragma unroll
    for (int mt = 0; mt < 2; ++mt) {
      acc1[mt][nf] = __builtin_amdgcn_mfma_f32_16x16x32_bf16(ah1[mt], bh, acc1[mt][nf], 0,0,0);
      acc1[mt][nf] = __builtin_amdgcn_mfma_f32_16x16x32_bf16(ah1[mt], bl, acc1[mt][nf], 0,0,0);
      acc1[mt][nf] = __builtin_amdgcn_mfma_f32_16x16x32_bf16(al1[mt], bh, acc1[mt][nf], 0,0,0);
    }
  }
  #pragma unroll
  for (int mt = 0; mt < 2; ++mt)
    #pragma unroll
    for (int nf = 0; nf < 4; ++nf)
      #pragma unroll
      for (int r = 0; r < 4; ++r) acc1[mt][nf][r] = siluf(acc1[mt][nf][r]);

  s16x8 ah2[2][2], al2[2][2];
  #pragma unroll
  for (int mt = 0; mt < 2; ++mt)
    #pragma unroll
    for (int nf = 0; nf < 4; ++nf)
      #pragma unroll
      for (int r = 0; r < 4; ++r)
        rt[(mt*16 + lhi*4 + r)*72 + nf*16 + lrow] = (short)bf16h(acc1[mt][nf][r]);
  #pragma unroll
  for (int mt = 0; mt < 2; ++mt)
    #pragma unroll
    for (int ks = 0; ks < 2; ++ks)
      ah2[mt][ks] = *(const s16x8*)&rt[(mt*16 + lrow)*72 + ks*32 + lhi*8];
  #pragma unroll
  for (int mt = 0; mt < 2; ++mt)
    #pragma unroll
    for (int nf = 0; nf < 4; ++nf)
      #pragma unroll
      for (int r = 0; r < 4; ++r) {
        float v = acc1[mt][nf][r];
        unsigned short hh = bf16h(v);
        rt[(mt*16 + lhi*4 + r)*72 + nf*16 + lrow] = (short)bf16h(v - bf2f(hh));
      }
  #pragma unroll
  for (int mt = 0; mt < 2; ++mt)
    #pragma unroll
    for (int ks = 0; ks < 2; ++ks)
      al2[mt][ks] = *(const s16x8*)&rt[(mt*16 + lrow)*72 + ks*32 + lhi*8];

  f32x4 acc2[2][4];
  #pragma unroll
  for (int mt = 0; mt < 2; ++mt)
    #pragma unroll
    for (int nf = 0; nf < 4; ++nf) acc2[mt][nf] = (f32x4){0.f,0.f,0.f,0.f};
  #pragma unroll
  for (int nf = 0; nf < 4; ++nf)
    #pragma unroll
    for (int ks = 0; ks < 2; ++ks) {
      s16x8 bh = *(const s16x8*)(fb2 + ((0*4 + nf)*2 + ks)*512 + l*8);
      s16x8 bl = *(const s16x8*)(fb2 + ((1*4 + nf)*2 + ks)*512 + l*8);
      #pragma unroll
      for (int mt = 0; mt < 2; ++mt) {
        acc2[mt][nf] = __builtin_amdgcn_mfma_f32_16x16x32_bf16(ah2[mt][ks], bh, acc2[mt][nf], 0,0,0);
        acc2[mt][nf] = __builtin_amdgcn_mfma_f32_16x16x32_bf16(ah2[mt][ks], bl, acc2[mt][nf], 0,0,0);
        acc2[mt][nf] = __builtin_amdgcn_mfma_f32_16x16x32_bf16(al2[mt][ks], bh, acc2[mt][nf], 0,0,0);
      }
    }
  #pragma unroll
  for (int mt = 0; mt < 2; ++mt)
    #pragma unroll
    for (int nf = 0; nf < 4; ++nf)
      #pragma unroll
      for (int r = 0; r < 4; ++r) acc2[mt][nf][r] = siluf(acc2[mt][nf][r]);

  s16x8 ah3[2][2], al3[2][2];
  #pragma unroll
  for (int mt = 0; mt < 2; ++mt)
    #pragma unroll
    for (int nf = 0; nf < 4; ++nf)
      #pragma unroll
      for (int r = 0; r < 4; ++r)
        rt[(mt*16 + lhi*4 + r)*72 + nf*16 + lrow] = (short)bf16h(acc2[mt][nf][r]);
  #pragma unroll
  for (int mt = 0; mt < 2; ++mt)
    #pragma unroll
    for (int ks = 0; ks < 2; ++ks)
      ah3[mt][ks] = *(const s16x8*)&rt[(mt*16 + lrow)*72 + ks*32 + lhi*8];
  #pragma unroll
  for (int mt = 0; mt < 2; ++mt)
    #pragma unroll
    for (int nf = 0; nf < 4; ++nf)
      #pragma unroll
      for (int r = 0; r < 4; ++r) {
        float v = acc2[mt][nf][r];
        unsigned short hh = bf16h(v);
        rt[(mt*16 + lhi*4 + r)*72 + nf*16 + lrow] = (short)bf16h(v - bf2f(hh));
      }
  #pragma unroll
  for (int mt = 0; mt < 2; ++mt)
    #pragma unroll
    for (int ks = 0; ks < 2; ++ks)
      al3[mt][ks] = *(const s16x8*)&rt[(mt*16 + lrow)*72 + ks*32 + lhi*8];

  // L3: group by cc = nf3&3, accumulate NQ quadrants, emit one packed store per (mt,r)
  #pragma unroll
  for (int cc = 0; cc < 4; ++cc) {
    f32x4 acc3[NQ][2];
    #pragma unroll
    for (int q = 0; q < NQ; ++q)
      #pragma unroll
      for (int mt = 0; mt < 2; ++mt) acc3[q][mt] = (f32x4){0.f,0.f,0.f,0.f};
    #pragma unroll
    for (int q = 0; q < NQ; ++q) {
      const int nf3 = q*4 + cc;
      #pragma unroll
      for (int ks = 0; ks < 2; ++ks) {
        s16x8 bh = *(const s16x8*)(fb3 + ((size_t)(0*NF3 + nf3)*2 + ks)*512 + l*8);
        s16x8 bl = *(const s16x8*)(fb3 + ((size_t)(1*NF3 + nf3)*2 + ks)*512 + l*8);
        #pragma unroll
        for (int mt = 0; mt < 2; ++mt) {
          acc3[q][mt] = __builtin_amdgcn_mfma_f32_16x16x32_bf16(ah3[mt][ks], bh, acc3[q][mt], 0,0,0);
          acc3[q][mt] = __builtin_amdgcn_mfma_f32_16x16x32_bf16(ah3[mt][ks], bl, acc3[q][mt], 0,0,0);
          acc3[q][mt] = __builtin_amdgcn_mfma_f32_16x16x32_bf16(al3[mt][ks], bh, acc3[q][mt], 0,0,0);
        }
      }
    }
    const int cbase = (cc*16 + lrow)*NQ;
    #pragma unroll
    for (int mt = 0; mt < 2; ++mt)
      #pragma unroll
      for (int r = 0; r < 4; ++r) {
        const size_t rowoff = (size_t)(e0 + mt*16 + lhi*4 + r)*(NF3*16) + cbase;
        if constexpr (NQ == 4) {
          u16x4 pk;
          #pragma unroll
          for (int q = 0; q < 4; ++q) pk[q] = f2h(acc3[q][mt][r]);
          *(u16x4*)(wbuf + rowoff) = pk;
        } else {
          u16x2 pk;
          #pragma unroll
          for (int q = 0; q < 2; ++q) pk[q] = f2h(acc3[q][mt][r]);
          *(u16x2*)(wbuf + rowoff) = pk;
        }
      }
  }
}

// ---------------- generic MFMA GEMM ----------------
template<int KS, int NF>
__global__ __launch_bounds__(512, 4) void k_gemm(
    const float* __restrict__ A, int rstride, int M,
    const short* __restrict__ fB, float* __restrict__ O) {
  __shared__ __align__(16) short lB[2*NF*KS*512];
  const int tid = threadIdx.x;
  const int w = tid >> 6, l = tid & 63;
  const int lrow = l & 15, lhi = l >> 4;
  const int n0 = blockIdx.x*128 + w*16;
  for (int i = tid; i < 2*NF*KS*64; i += 512)
    *(s16x8*)&lB[(size_t)i*8] = *(const s16x8*)&fB[(size_t)i*8];
  s16x8 ah[KS], al[KS];
  {
    int row = n0 + lrow; if (row > M-1) row = M-1;
    #pragma unroll
    for (int ks = 0; ks < KS; ++ks)
      split8(A + (size_t)row*rstride + ks*32 + lhi*8, ah[ks], al[ks]);
  }
  __syncthreads();
  f32x4 acc[NF];
  #pragma unroll
  for (int nf = 0; nf < NF; ++nf) acc[nf] = (f32x4){0.f,0.f,0.f,0.f};
  #pragma unroll
  for (int nf = 0; nf < NF; ++nf)
    #pragma unroll
    for (int ks = 0; ks < KS; ++ks) {
      s16x8 bh = *(const s16x8*)&lB[((0*NF + nf)*KS + ks)*512 + l*8];
      s16x8 bl = *(const s16x8*)&lB[((1*NF + nf)*KS + ks)*512 + l*8];
      acc[nf] = __builtin_amdgcn_mfma_f32_16x16x32_bf16(ah[ks], bh, acc[nf], 0,0,0);
      acc[nf] = __builtin_amdgcn_mfma_f32_16x16x32_bf16(ah[ks], bl, acc[nf], 0,0,0);
      acc[nf] = __builtin_amdgcn_mfma_f32_16x16x32_bf16(al[ks], bh, acc[nf], 0,0,0);
    }
  #pragma unroll
  for (int nf = 0; nf < NF; ++nf)
    #pragma unroll
    for (int r = 0; r < 4; ++r) {
      int row = n0 + lhi*4 + r;
      if (row < M) O[(size_t)row*(NF*16) + nf*16 + lrow] = acc[nf][r];
    }
}

// ---------------- sc partial ----------------
template<int KSO>
__global__ __launch_bounds__(512, 4) void k_scp(
    const float* __restrict__ Ao, const float* __restrict__ na,
    const short* __restrict__ fBc, float* __restrict__ part) {
  __shared__ __align__(16) short lB[KSO*8192];
  const int tid = threadIdx.x;
  const int w = tid >> 6, l = tid & 63;
  const int lrow = l & 15, lhi = l >> 4;
  const int n0 = blockIdx.x*128 + w*16;
  const int vp = blockIdx.y;

  s16x8 aoh[KSO], aol[KSO];
  {
    int row = n0 + lrow; if (row > N_NODES-1) row = N_NODES-1;
    #pragma unroll
    for (int ks = 0; ks < KSO; ++ks)
      split8(Ao + (size_t)row*(KSO*32) + ks*32 + lhi*8, aoh[ks], aol[ks]);
  }

  f32x4 acc[8];
  #pragma unroll
  for (int nf = 0; nf < 8; ++nf) acc[nf] = (f32x4){0.f,0.f,0.f,0.f};

  #pragma unroll
  for (int c = 0; c < 2; ++c) {
    const int v = vp*2 + c;
    __syncthreads();
    for (int i = tid; i < KSO*1024; i += 512) {
      int gl = i & 63;
      int rest = i >> 6;
      int ks = rest % KSO;
      int rest2 = rest / KSO;
      int nf = rest2 & 7;
      int p  = rest2 >> 3;
      size_t src = ((((size_t)p*128 + (v*8 + nf))*KSO + ks)*64 + gl)*8;
      *(s16x8*)&lB[(size_t)i*8] = *(const s16x8*)&fBc[src];
    }
    __syncthreads();
    f32x4 dacc[8];
    #pragma unroll
    for (int nf = 0; nf < 8; ++nf) dacc[nf] = (f32x4){0.f,0.f,0.f,0.f};
    #pragma unroll
    for (int nf = 0; nf < 8; ++nf)
      #pragma unroll
      for (int ks = 0; ks < KSO; ++ks) {
        s16x8 bh = *(const s16x8*)&lB[((0*8 + nf)*KSO + ks)*512 + l*8];
        s16x8 bl = *(const s16x8*)&lB[((1*8 + nf)*KSO + ks)*512 + l*8];
        dacc[nf] = __builtin_amdgcn_mfma_f32_16x16x32_bf16(aoh[ks], bh, dacc[nf], 0,0,0);
        dacc[nf] = __builtin_amdgcn_mfma_f32_16x16x32_bf16(aoh[ks], bl, dacc[nf], 0,0,0);
        dacc[nf] = __builtin_amdgcn_mfma_f32_16x16x32_bf16(aol[ks], bh, dacc[nf], 0,0,0);
      }
    #pragma unroll
    for (int r = 0; r < 4; ++r) {
      int row = n0 + lhi*4 + r; if (row > N_NODES-1) row = N_NODES-1;
      float nav = na[(size_t)row*16 + v];
      #pragma unroll
      for (int nf = 0; nf < 8; ++nf) acc[nf][r] += nav * dacc[nf][r];
    }
  }

  float* pp = part + (size_t)vp*NM128;
  #pragma unroll
  for (int nf = 0; nf < 8; ++nf)
    #pragma unroll
    for (int r = 0; r < 4; ++r) {
      int row = n0 + lhi*4 + r;
      if (row < N_NODES) pp[(size_t)row*128 + nf*16 + lrow] = acc[nf][r];
    }
}

// ---------------- fused reduce(9) + gating ----------------
__global__ void k_redgate(const float* __restrict__ part, const float* __restrict__ ov,
                          float* __restrict__ gs_out, float* __restrict__ gv) {
  int t = blockIdx.x*256 + threadIdx.x;
  if (t >= N_NODES*64) return;
  int n = t >> 6, v = t & 63;
  float o1 = 0.f, o2 = 0.f;
  #pragma unroll
  for (int p = 0; p < 9; ++p) {
    const float* pp = part + (size_t)p*NM128 + (size_t)n*128;
    o1 += pp[v]; o2 += pp[64+v];
  }
  float g = siluf(o1), gate = sigf(o2);
  gs_out[(size_t)n*64+v] = g;
  gv[(size_t)n*192 + 0*64 + v] = gate*ov[(size_t)n*192 + 0*64 + v];
  gv[(size_t)n*192 + 1*64 + v] = gate*ov[(size_t)n*192 + 1*64 + v];
  gv[(size_t)n*192 + 2*64 + v] = gate*ov[(size_t)n*192 + 2*64 + v];
}

// ---------------- fused reduce(9) + pooled accumulation (RLE) ----------------
__global__ __launch_bounds__(128) void k_redpool(
    const float* __restrict__ part, const int* __restrict__ batch,
    float* __restrict__ pool) {
  const int j = threadIdx.x;
  const int n0 = blockIdx.x*4;
  float outv[4];
  #pragma unroll
  for (int nn = 0; nn < 4; ++nn) {
    float sv = 0.f;
    #pragma unroll
    for (int p = 0; p < 9; ++p)
      sv += part[(size_t)p*NM128 + (size_t)(n0+nn)*128 + j];
    outv[nn] = sv;
  }
  int b0 = batch[n0], b1 = batch[n0+1], b2 = batch[n0+2], b3 = batch[n0+3];
  float sum = outv[0]; int cur = b0;
  if (b1 == cur) sum += outv[1]; else { atomicAdd(&pool[cur*128+j], sum); cur = b1; sum = outv[1]; }
  if (b2 == cur) sum += outv[2]; else { atomicAdd(&pool[cur*128+j], sum); cur = b2; sum = outv[2]; }
  if (b3 == cur) sum += outv[3]; else { atomicAdd(&pool[cur*128+j], sum); cur = b3; sum = outv[3]; }
  atomicAdd(&pool[cur*128+j], sum);
}

// ---------------- conv1 gather: CSR pull (fp16 interleaved wbuf); n_v as [n][3][128] ----------------
__global__ __launch_bounds__(256) void k_gather1(
    const u16* __restrict__ wbuf, const float* __restrict__ shv,
    const int* __restrict__ esrc, const int* __restrict__ offs, const int* __restrict__ slot,
    const float* __restrict__ h,
    float* __restrict__ n_s, float* __restrict__ n_v) {
  const int wave = threadIdx.x >> 6, lane = threadIdx.x & 63;
  const int n = blockIdx.x*4 + wave;
  if (n >= N_NODES) return;
  const int s0 = offs[n], s1 = offs[n+1];
  float ns0=0.f, ns1=0.f;
  float nv00=0.f,nv01=0.f,nv02=0.f, nv10=0.f,nv11=0.f,nv12=0.f;
  for (int s = s0; s < s1; ++s) {
    int e = slot[s];
    int src = esrc[e];
    u16x4 wv = *(const u16x4*)(wbuf + (size_t)e*256 + lane*4);
    float c0 = h2f(wv[0]), c1 = h2f(wv[1]), c2 = h2f(wv[2]), c3 = h2f(wv[3]);
    float h0 = h[src*128+lane], h1 = h[src*128+64+lane];
    float sv0 = shv[e*3+0], sv1 = shv[e*3+1], sv2 = shv[e*3+2];
    ns0 += c0*h0; ns1 += c1*h1;
    float t0 = c2*h0, t1 = c3*h1;
    nv00 += t0*sv0; nv01 += t0*sv1; nv02 += t0*sv2;
    nv10 += t1*sv0; nv11 += t1*sv1; nv12 += t1*sv2;
  }
  n_s[n*128+lane]    = ns0*INV_SQRT10;
  n_s[n*128+64+lane] = ns1*INV_SQRT10;
  float* nvp = n_v + (size_t)n*384;      // [3][128]
  nvp[0*128+lane]    = nv00*INV_SQRT10;
  nvp[1*128+lane]    = nv01*INV_SQRT10;
  nvp[2*128+lane]    = nv02*INV_SQRT10;
  nvp[0*128+64+lane] = nv10*INV_SQRT10;
  nvp[1*128+64+lane] = nv11*INV_SQRT10;
  nvp[2*128+64+lane] = nv12*INV_SQRT10;
}

// ---------------- conv2 gather (fp16 interleaved wbuf): h_v layout [n][3][64] ----------------
__global__ __launch_bounds__(256) void k_gather2(
    const u16* __restrict__ wbuf, const float* __restrict__ shv,
    const int* __restrict__ esrc, const int* __restrict__ offs, const int* __restrict__ slot,
    const float* __restrict__ h_s, const float* __restrict__ h_v,
    float* __restrict__ n_mid) {
  const int wave = threadIdx.x >> 6, lane = threadIdx.x & 63;
  const int n = blockIdx.x*4 + wave;
  if (n >= N_NODES) return;
  const int s0 = offs[n], s1 = offs[n+1];
  float acc0 = 0.f, acc1 = 0.f;
  for (int s = s0; s < s1; ++s) {
    int e = slot[s];
    int src = esrc[e];
    u16x2 wv = *(const u16x2*)(wbuf + (size_t)e*128 + lane*2);
    float w0 = h2f(wv[0]), w1 = h2f(wv[1]);
    float hs = h_s[src*64+lane];
    const float* hvp = h_v + (size_t)src*192;
    float sv0 = shv[e*3+0], sv1 = shv[e*3+1], sv2 = shv[e*3+2];
    float dot = hvp[lane]*sv0 + hvp[64+lane]*sv1 + hvp[128+lane]*sv2;
    acc0 += w0*hs;
    acc1 += w1*dot;
  }
  n_mid[n*128+lane]    = acc0*INV_SQRT10;
  n_mid[n*128+64+lane] = acc1*INV_SQRT3*INV_SQRT10;
}

// ======== FALLBACK (atomic) kernels — used only if ws too small ========
__global__ __launch_bounds__(512) void k_edge1_at(
    const float* __restrict__ es8, const float* __restrict__ shv,
    const int* __restrict__ esrc, const int* __restrict__ edst,
    const float* __restrict__ h,
    const float* __restrict__ W0, const float* __restrict__ W1, const float* __restrict__ W2,
    float* __restrict__ n_s, float* __restrict__ n_v) {
  __shared__ float lW0[512];
  __shared__ float lW1[4096];
  __shared__ float lW2[16384];
  __shared__ float lA[8][64];
  __shared__ float lB[8][64];
  for (int i = threadIdx.x; i < 512;   i += 512) lW0[i] = W0[i];
  for (int i = threadIdx.x; i < 4096;  i += 512) lW1[i] = W1[i];
  for (int i = threadIdx.x; i < 16384; i += 512) lW2[i] = W2[i];
  __syncthreads();
  const int wave = threadIdx.x >> 6, lane = threadIdx.x & 63;
  const int nw = gridDim.x * 8;
  const int e0 = blockIdx.x*8 + wave;
  const int iters = (N_EDGES + nw - 1) / nw;
  for (int it = 0; it < iters; ++it) {
    int e = e0 + it*nw;
    bool valid = e < N_EDGES;
    float a = 0.f, sv0=0.f, sv1=0.f, sv2=0.f;
    int src = 0, dst = 0;
    if (valid) {
      const float* ep = es8 + e*8;
      sv0 = shv[e*3+0]; sv1 = shv[e*3+1]; sv2 = shv[e*3+2];
      src = esrc[e]; dst = edst[e];
      a = ep[0]*lW0[lane]      + ep[1]*lW0[64+lane]  + ep[2]*lW0[128+lane] + ep[3]*lW0[192+lane]
        + ep[4]*lW0[256+lane]  + ep[5]*lW0[320+lane] + ep[6]*lW0[384+lane] + ep[7]*lW0[448+lane];
      a = siluf(a * INV_SQRT8);
    }
    lA[wave][lane] = a;
    __syncthreads();
    {
      float b0=0.f;
      #pragma unroll
      for (int k = 0; k < 64; ++k) b0 += lA[wave][k]*lW1[k*64+lane];
      lB[wave][lane] = siluf(b0 * INV_SQRT64);
    }
    __syncthreads();
    if (valid) {
      float c0=0.f,c1=0.f,c2=0.f,c3=0.f;
      #pragma unroll
      for (int k = 0; k < 64; ++k) {
        float bk = lB[wave][k];
        const float* r = lW2 + k*256;
        c0 += bk*r[lane]; c1 += bk*r[64+lane]; c2 += bk*r[128+lane]; c3 += bk*r[192+lane];
      }
      float hs0 = h[src*128 + lane];
      float hs1 = h[src*128 + 64 + lane];
      atomicAdd(&n_s[dst*128 + lane],      c0*INV_SQRT64*hs0*INV_SQRT10);
      atomicAdd(&n_s[dst*128 + 64 + lane], c1*INV_SQRT64*hs1*INV_SQRT10);
      float t0 = c2*INV_SQRT64*hs0*INV_SQRT10;
      float t1 = c3*INV_SQRT64*hs1*INV_SQRT10;
      float* nvp = n_v + dst*384;
      atomicAdd(nvp + lane*3+0, t0*sv0);
      atomicAdd(nvp + lane*3+1, t0*sv1);
      atomicAdd(nvp + lane*3+2, t0*sv2);
      atomicAdd(nvp + (64+lane)*3+0, t1*sv0);
      atomicAdd(nvp + (64+lane)*3+1, t1*sv1);
      atomicAdd(nvp + (64+lane)*3+2, t1*sv2);
    }
  }
}

__global__ __launch_bounds__(512) void k_edge2_at(
    const float* __restrict__ es8, const float* __restrict__ shv,
    const int* __restrict__ esrc, const int* __restrict__ edst,
    const float* __restrict__ h_s, const float* __restrict__ h_v,
    const float* __restrict__ W0, const float* __restrict__ W1, const float* __restrict__ W2,
    float* __restrict__ n_mid) {
  __shared__ float lW0[512];
  __shared__ float lW1[4096];
  __shared__ float lW2[8192];
  __shared__ float lA[8][64];
  __shared__ float lB[8][64];
  for (int i = threadIdx.x; i < 512;  i += 512) lW0[i] = W0[i];
  for (int i = threadIdx.x; i < 4096; i += 512) lW1[i] = W1[i];
  for (int i = threadIdx.x; i < 8192; i += 512) lW2[i] = W2[i];
  __syncthreads();
  const int wave = threadIdx.x >> 6, lane = threadIdx.x & 63;
  const int nw = gridDim.x * 8;
  const int e0 = blockIdx.x*8 + wave;
  const int iters = (N_EDGES + nw - 1) / nw;
  for (int it = 0; it < iters; ++it) {
    int e = e0 + it*nw;
    bool valid = e < N_EDGES;
    float a = 0.f, sv0=0.f, sv1=0.f, sv2=0.f;
    int src = 0, dst = 0;
    if (valid) {
      const float* ep = es8 + e*8;
      sv0 = shv[e*3+0]; sv1 = shv[e*3+1]; sv2 = shv[e*3+2];
      src = esrc[e]; dst = edst[e];
      a = ep[0]*lW0[lane]      + ep[1]*lW0[64+lane]  + ep[2]*lW0[128+lane] + ep[3]*lW0[192+lane]
        + ep[4]*lW0[256+lane]  + ep[5]*lW0[320+lane] + ep[6]*lW0[384+lane] + ep[7]*lW0[448+lane];
      a = siluf(a * INV_SQRT8);
    }
    lA[wave][lane] = a;
    __syncthreads();
    {
      float b0=0.f;
      #pragma unroll
      for (int k = 0; k < 64; ++k) b0 += lA[wave][k]*lW1[k*64+lane];
      lB[wave][lane] = siluf(b0 * INV_SQRT64);
    }
    __syncthreads();
    if (valid) {
      float c0=0.f, c1=0.f;
      #pragma unroll
      for (int k = 0; k < 64; ++k) {
        float bk = lB[wave][k];
        const float* r = lW2 + k*128;
        c0 += bk*r[lane]; c1 += bk*r[64+lane];
      }
      float hsv = h_s[src*64 + lane];
      const float* hvp = h_v + src*192 + lane*3;
      float dotv = hvp[0]*sv0 + hvp[1]*sv1 + hvp[2]*sv2;
      atomicAdd(&n_mid[dst*128 + lane],      c0*INV_SQRT64*hsv*INV_SQRT10);
      atomicAdd(&n_mid[dst*128 + 64 + lane], c1*INV_SQRT64*dotv*INV_SQRT3*INV_SQRT10);
    }
  }
}

// ---------------- FALLBACK conv1 node pass (full, old n_v layout) ----------------
__global__ __launch_bounds__(128) void k_node1(
    const float* __restrict__ n_s, const float* __restrict__ n_v,
    const float* __restrict__ s,   const float* __restrict__ na,
    const float* __restrict__ Wls, const float* __restrict__ Wlv,
    const float* __restrict__ Csc, const float* __restrict__ W2s, const float* __restrict__ W2v,
    float* __restrict__ gs_out, float* __restrict__ hs_out, float* __restrict__ hv_out) {
  __shared__ float l_ns[512], l_s[512], l_na[64], l_nv[1536];
  __shared__ float l_outs[512], l_ov[768], l_gs[256], l_gv[768];
  const int j = threadIdx.x;
  const int n0 = blockIdx.x*4;
  for (int i = j; i < 512;  i += 128) { l_ns[i] = n_s[n0*128+i]; l_s[i] = s[n0*128+i]; }
  for (int i = j; i < 1536; i += 128) l_nv[i] = n_v[n0*384+i];
  if (j < 64) l_na[j] = na[n0*16+j];
  __syncthreads();

  float accs[4] = {0.f,0.f,0.f,0.f};
  for (int k = 0; k < 128; ++k) {
    float w = Wls[k*128+j];
    accs[0] += l_ns[k]*w; accs[1] += l_ns[128+k]*w;
    accs[2] += l_ns[256+k]*w; accs[3] += l_ns[384+k]*w;
  }
  float accc[4] = {0.f,0.f,0.f,0.f};
  for (int vt = 0; vt < 16; vt += 4) {
    float a0[4],a1[4],a2[4],a3[4];
    #pragma unroll
    for (int n = 0; n < 4; ++n) {
      a0[n]=l_na[n*16+vt]; a1[n]=l_na[n*16+vt+1];
      a2[n]=l_na[n*16+vt+2]; a3[n]=l_na[n*16+vt+3];
    }
    for (int u = 0; u < 128; ++u) {
      const float* cp = Csc + (u*16+vt)*128 + j;
      float c0=cp[0], c1=cp[128], c2=cp[256], c3=cp[384];
      float s0=l_s[u], s1=l_s[128+u], s2=l_s[256+u], s3=l_s[384+u];
      accc[0] += s0*(a0[0]*c0 + a1[0]*c1 + a2[0]*c2 + a3[0]*c3);
      accc[1] += s1*(a0[1]*c0 + a1[1]*c1 + a2[1]*c2 + a3[1]*c3);
      accc[2] += s2*(a0[2]*c0 + a1[2]*c1 + a2[2]*c2 + a3[2]*c3);
      accc[3] += s3*(a0[3]*c0 + a1[3]*c1 + a2[3]*c2 + a3[3]*c3);
    }
  }
  #pragma unroll
  for (int n = 0; n < 4; ++n)
    l_outs[n*128+j] = accs[n]*INV_SQRT128 + accc[n]*INV_SQRT2048;

  const int jj = j & 63, hh = j >> 6;
  float ov[2][3] = {{0.f,0.f,0.f},{0.f,0.f,0.f}};
  for (int u = 0; u < 128; ++u) {
    float w = Wlv[u*64+jj];
    #pragma unroll
    for (int t = 0; t < 2; ++t) {
      int n = 2*hh+t;
      ov[t][0] += l_nv[n*384+u*3+0]*w;
      ov[t][1] += l_nv[n*384+u*3+1]*w;
      ov[t][2] += l_nv[n*384+u*3+2]*w;
    }
  }
  #pragma unroll
  for (int t = 0; t < 2; ++t) {
    int n = 2*hh+t;
    l_ov[n*192+jj*3+0] = ov[t][0]*INV_SQRT128;
    l_ov[n*192+jj*3+1] = ov[t][1]*INV_SQRT128;
    l_ov[n*192+jj*3+2] = ov[t][2]*INV_SQRT128;
  }
  __syncthreads();

  #pragma unroll
  for (int t = 0; t < 2; ++t) {
    int n = 2*hh+t;
    float gv_s = siluf(l_outs[n*128+jj]);
    float gate = sigf (l_outs[n*128+64+jj]);
    l_gs[n*64+jj] = gv_s;
    gs_out[(n0+n)*64+jj] = gv_s;
    l_gv[n*192+jj*3+0] = gate*l_ov[n*192+jj*3+0];
    l_gv[n*192+jj*3+1] = gate*l_ov[n*192+jj*3+1];
    l_gv[n*192+jj*3+2] = gate*l_ov[n*192+jj*3+2];
  }
  __syncthreads();

  float ha[2] = {0.f,0.f};
  for (int k = 0; k < 64; ++k) {
    float w = W2s[k*64+jj];
    ha[0] += l_gs[(2*hh+0)*64+k]*w;
    ha[1] += l_gs[(2*hh+1)*64+k]*w;
  }
  hs_out[(n0+2*hh+0)*64+jj] = ha[0]*INV_SQRT64;
  hs_out[(n0+2*hh+1)*64+jj] = ha[1]*INV_SQRT64;

  float hv[2][3] = {{0.f,0.f,0.f},{0.f,0.f,0.f}};
  for (int u = 0; u < 64; ++u) {
    float w = W2v[u*64+jj];
    #pragma unroll
    for (int t = 0; t < 2; ++t) {
      int n = 2*hh+t;
      hv[t][0] += l_gv[n*192+u*3+0]*w;
      hv[t][1] += l_gv[n*192+u*3+1]*w;
      hv[t][2] += l_gv[n*192+u*3+2]*w;
    }
  }
  #pragma unroll
  for (int t = 0; t < 2; ++t) {
    int n = 2*hh+t;
    hv_out[(n0+n)*192+jj*3+0] = hv[t][0]*INV_SQRT64;
    hv_out[(n0+n)*192+jj*3+1] = hv[t][1]*INV_SQRT64;
    hv_out[(n0+n)*192+jj*3+2] = hv[t][2]*INV_SQRT64;
  }
}

// ---------------- FALLBACK conv2 node pass + pooling ----------------
__global__ __launch_bounds__(128) void k_node2(
    const float* __restrict__ n_mid, const float* __restrict__ gs,
    const float* __restrict__ na, const int* __restrict__ batch,
    const float* __restrict__ W, const float* __restrict__ Csc,
    float* __restrict__ pool) {
  __shared__ float l_nm[512], l_gs[256], l_na[64];
  const int j = threadIdx.x;
  const int n0 = blockIdx.x*4;
  for (int i = j; i < 512; i += 128) l_nm[i] = n_mid[n0*128+i];
  for (int i = j; i < 256; i += 128) l_gs[i] = gs[n0*64+i];
  if (j < 64) l_na[j] = na[n0*16+j];
  __syncthreads();
  float acc[4] = {0.f,0.f,0.f,0.f};
  for (int k = 0; k < 128; ++k) {
    float w = W[k*128+j];
    acc[0] += l_nm[k]*w; acc[1] += l_nm[128+k]*w;
    acc[2] += l_nm[256+k]*w; acc[3] += l_nm[384+k]*w;
  }
  float acc2[4] = {0.f,0.f,0.f,0.f};
  for (int vt = 0; vt < 16; vt += 4) {
    float a0[4],a1[4],a2[4],a3[4];
    #pragma unroll
    for (int n = 0; n < 4; ++n) {
      a0[n]=l_na[n*16+vt]; a1[n]=l_na[n*16+vt+1];
      a2[n]=l_na[n*16+vt+2]; a3[n]=l_na[n*16+vt+3];
    }
    for (int u = 0; u < 64; ++u) {
      const float* cp = Csc + (u*16+vt)*128 + j;
      float c0=cp[0], c1=cp[128], c2=cp[256], c3=cp[384];
      float s0=l_gs[u], s1=l_gs[64+u], s2=l_gs[128+u], s3=l_gs[192+u];
      acc2[0] += s0*(a0[0]*c0 + a1[0]*c1 + a2[0]*c2 + a3[0]*c3);
      acc2[1] += s1*(a0[1]*c0 + a1[1]*c1 + a2[1]*c2 + a3[1]*c3);
      acc2[2] += s2*(a0[2]*c0 + a1[2]*c1 + a2[2]*c2 + a3[2]*c3);
      acc2[3] += s3*(a0[3]*c0 + a1[3]*c1 + a2[3]*c2 + a3[3]*c3);
    }
  }
  float outv[4];
  #pragma unroll
  for (int n = 0; n < 4; ++n)
    outv[n] = acc[n]*INV_SQRT128 + acc2[n]*INV_SQRT1024;
  int b0 = batch[n0], b1 = batch[n0+1], b2 = batch[n0+2], b3 = batch[n0+3];
  float sum = outv[0]; int cur = b0;
  if (b1 == cur) sum += outv[1]; else { atomicAdd(&pool[cur*128+j], sum); cur = b1; sum = outv[1]; }
  if (b2 == cur) sum += outv[2]; else { atomicAdd(&pool[cur*128+j], sum); cur = b2; sum = outv[2]; }
  if (b3 == cur) sum += outv[3]; else { atomicAdd(&pool[cur*128+j], sum); cur = b3; sum = outv[3]; }
  atomicAdd(&pool[cur*128+j], sum);
}

// ---------------- readout head ----------------
__global__ __launch_bounds__(128) void k_head(
    const float* __restrict__ pool, const float* __restrict__ cnt,
    const float* __restrict__ Wr1, const float* __restrict__ Wr2,
    float* __restrict__ out) {
  __shared__ float lp[128];
  __shared__ float lt[128];
  const int j = threadIdx.x;
  for (int g = 0; g < N_GRAPHS; ++g) {
    float inv = 1.f / fmaxf(cnt[g], 1.f);
    lp[j] = pool[g*128+j]*inv;
    __syncthreads();
    float acc = 0.f;
    for (int k = 0; k < 128; ++k) acc += lp[k]*Wr1[k*128+j];
    lt[j] = siluf(acc*INV_SQRT128) * Wr2[j];
    __syncthreads();
    if (j == 0) {
      float ssum = 0.f;
      for (int k = 0; k < 128; ++k) ssum += lt[k];
      out[g] = ssum*INV_SQRT128;
    }
    __syncthreads();
  }
}

extern "C" void kernel_launch(void* const* d_in, const int* in_sizes, int n_in,
                              void* d_out, int out_size, void* d_ws, size_t ws_size,
                              hipStream_t stream) {
  const float* x         = (const float*)d_in[0];
  const float* node_attr = (const float*)d_in[1];
  const int*   esrc      = (const int*)d_in[2];
  const int*   edst      = (const int*)d_in[3];
  const float* evec      = (const float*)d_in[4];
  const int*   batch     = (const int*)d_in[5];
  const float* W_embed   = (const float*)d_in[6];
  const float* c1_lin1   = (const float*)d_in[7];
  const float* c1_fc_w0  = (const float*)d_in[8];
  const float* c1_fc_w1  = (const float*)d_in[9];
  const float* c1_fc_w2  = (const float*)d_in[10];
  const float* c1_lin2_s = (const float*)d_in[11];
  const float* c1_lin2_v = (const float*)d_in[12];
  const float* c1_sc     = (const float*)d_in[13];
  const float* c2_lin1_s = (const float*)d_in[14];
  const float* c2_lin1_v = (const float*)d_in[15];
  const float* c2_fc_w0  = (const float*)d_in[16];
  const float* c2_fc_w1  = (const float*)d_in[17];
  const float* c2_fc_w2  = (const float*)d_in[18];
  const float* c2_lin2   = (const float*)d_in[19];
  const float* c2_sc     = (const float*)d_in[20];
  const float* Wr1       = (const float*)d_in[21];
  const float* Wr2       = (const float*)d_in[22];

  float* ws    = (float*)d_ws;
  float* es8   = ws + OFF_ES8;
  float* shv   = ws + OFF_SHV;
  float* s_    = ws + OFF_S;
  float* h_    = ws + OFF_H;
  float* gs_   = ws + OFF_GS;
  float* hs_   = ws + OFF_HS;
  float* hv_   = ws + OFF_HV;
  float* ns_   = ws + OFF_NS;
  float* nv_   = ws + OFF_NV;
  float* nmid_ = ws + OFF_NMID;
  float* pool_ = ws + OFF_POOL;
  float* cnt_  = ws + OFF_CNT;
  int*   hist_ = (int*)(ws + OFF_HIST);
  int*   curs_ = (int*)(ws + OFF_CURS);
  int*   offs_ = (int*)(ws + OFF_OFFS);
  short* frag_ = (short*)(ws + OFF_FRAG);
  int*   slot_ = (int*)(ws + OFF_SLOT);
  float* wbuf_ = ws + OFF_WBUF;
  u16*   wb16_ = (u16*)wbuf_;   // fp16 wbuf occupies only lower half of WBUF region

  // upper-wbuf carve-outs (k_mlp<16> writes only N_EDGES*128 floats worth of u16)
  float* out1_  = wbuf_ + (size_t)N_EDGES*128;                 // reserved (layout stability)
  short* nfrag_ = (short*)(out1_ + (size_t)NM128);             // 884736 shorts
  float* part_  = out1_ + (size_t)NM128 + NFRAG_TOT/2;         // 9 x 1.28M floats
  float* ov_    = part_ + (size_t)9*NM128;                     // 1.92M floats
  float* gv_    = nv_;                                         // aliases nv (dead after ov GEMM)

  const bool big = ws_size >= WS_NEED_BYTES;

  k_geom<<<N_EDGES/256, 256, 0, stream>>>(evec, es8, shv);

  if (big) {
    hipMemsetAsync(pool_, 0, (size_t)(OFF_OFFS - OFF_POOL)*sizeof(float), stream);
    k_cnthist<<<(N_EDGES+255)/256, 256, 0, stream>>>(batch, edst, cnt_, hist_);
    k_scanp<<<1, 1024, 0, stream>>>(hist_, offs_);
    k_slot<<<(N_EDGES+255)/256, 256, 0, stream>>>(edst, offs_, curs_, slot_);

    // merged startup frag prep: 6 MLP weights + W_embed + c1_lin1
    {
      PD8 m{};
      m.d[0] = {c1_fc_w0, frag_ + F_B1,  8,  64,  4, 1, 4096,  INV_SQRT8};
      m.d[1] = {c1_fc_w1, frag_ + F_B2,  64, 64,  4, 2, 8192,  INV_SQRT64};
      m.d[2] = {c1_fc_w2, frag_ + F_B3,  64, 256, 16,2, 32768, INV_SQRT64};
      m.d[3] = {c2_fc_w0, frag_ + F_B1b, 8,  64,  4, 1, 4096,  INV_SQRT8};
      m.d[4] = {c2_fc_w1, frag_ + F_B2b, 64, 64,  4, 2, 8192,  INV_SQRT64};
      m.d[5] = {c2_fc_w2, frag_ + F_B3b, 64, 128, 8, 2, 16384, INV_SQRT64};
      m.d[6] = {W_embed,  frag_ + F_WE,  32, 128, 8, 1, 8192,  INV_SQRT32};
      m.d[7] = {c1_lin1,  frag_ + F_L1,  128,128, 8, 4, 32768, INV_SQRT128};
      m.nd = 8; m.tot = FRAG_TOT;
      k_prepmulti<<<448, 256, 0, stream>>>(m);
    }

    // s = x@W_embed ; h = s@c1_lin1 (MFMA)
    k_gemm<1,8><<<79, 512, 0, stream>>>(x,  32,  N_NODES, frag_ + F_WE, s_);
    k_gemm<4,8><<<79, 512, 0, stream>>>(s_, 128, N_NODES, frag_ + F_L1, h_);

    // conv1 edge MLP (packed fp16 interleaved out, 32 edges/wave) + gather
    k_mlp<16><<<1250, 256, 0, stream>>>(es8, frag_ + F_B1, frag_ + F_B2, frag_ + F_B3, wb16_);
    k_gather1<<<(N_NODES+3)/4, 256, 0, stream>>>(wb16_, shv, esrc, offs_, slot_, h_, ns_, nv_);

    // merged node weight frag prep (upper-wbuf region)
    {
      PD8 m{};
      m.d[0] = {c1_lin2_s, nfrag_ + NF_WLS, 128, 128,  8,   4, 32768,  INV_SQRT128};
      m.d[1] = {c1_sc,     nfrag_ + NF_C1,  128, 2048, 128, 4, 524288, INV_SQRT2048};
      m.d[2] = {c2_lin2,   nfrag_ + NF_W2,  128, 128,  8,   4, 32768,  INV_SQRT128};
      m.d[3] = {c2_sc,     nfrag_ + NF_C2,  64,  2048, 128, 2, 262144, INV_SQRT1024};
      m.d[4] = {c1_lin2_v, nfrag_ + NF_LV,  128, 64,   4,   4, 16384,  INV_SQRT128};
      m.d[5] = {c2_lin1_s, nfrag_ + NF_2S,  64,  64,   4,   2, 8192,   INV_SQRT64};
      m.d[6] = {c2_lin1_v, nfrag_ + NF_2V,  64,  64,   4,   2, 8192,   INV_SQRT64};
      m.nd = 7; m.tot = NFRAG_TOT;
      k_prepmulti<<<1024, 256, 0, stream>>>(m);
    }

    // conv1 node: dense + sc partials -> fused reduce+gate
    k_gemm<4,8><<<79, 512, 0, stream>>>(ns_, 128, N_NODES, nfrag_ + NF_WLS, part_ + (size_t)8*NM128);
    k_scp<4><<<dim3(79,8), 512, 0, stream>>>(s_, node_attr, nfrag_ + NF_C1, part_);
    k_gemm<4,4><<<235, 512, 0, stream>>>(nv_, 128, N_NODES*3, nfrag_ + NF_LV, ov_);
    k_redgate<<<(N_NODES*64+255)/256, 256, 0, stream>>>(part_, ov_, gs_, gv_);
    k_gemm<2,4><<<79, 512, 0, stream>>>(gs_, 64, N_NODES, nfrag_ + NF_2S, hs_);
    k_gemm<2,4><<<235, 512, 0, stream>>>(gv_, 64, N_NODES*3, nfrag_ + NF_2V, hv_);

    // conv2 edge MLP (packed fp16 interleaved out) + gather
    k_mlp<8><<<1250, 256, 0, stream>>>(es8, frag_ + F_B1b, frag_ + F_B2b, frag_ + F_B3b, wb16_);
    k_gather2<<<(N_NODES+3)/4, 256, 0, stream>>>(wb16_, shv, esrc, offs_, slot_, hs_, hv_, nmid_);

    // conv2 node: partials -> fused reduce+pool
    k_gemm<4,8><<<79, 512, 0, stream>>>(nmid_, 128, N_NODES, nfrag_ + NF_W2, part_ + (size_t)8*NM128);
    k_scp<2><<<dim3(79,8), 512, 0, stream>>>(gs_, node_attr, nfrag_ + NF_C2, part_);
    k_redpool<<<N_NODES/4, 128, 0, stream>>>(part_, batch, pool_);
  } else {
    hipMemsetAsync(ns_, 0, (size_t)(OFF_HIST - OFF_NS)*sizeof(float), stream);
    k_linear128<<<(N_NODES*128)/256, 256, 0, stream>>>(x,  W_embed, s_, 32,  INV_SQRT32,  N_NODES*128);
    k_linear128<<<(N_NODES*128)/256, 256, 0, stream>>>(s_, c1_lin1, h_, 128, INV_SQRT128, N_NODES*128);
    k_cnthist<<<(N_EDGES+255)/256, 256, 0, stream>>>(batch, edst, cnt_, hist_);
    k_edge1_at<<<256, 512, 0, stream>>>(es8, shv, esrc, edst, h_,
                                        c1_fc_w0, c1_fc_w1, c1_fc_w2, ns_, nv_);
    k_node1<<<N_NODES/4, 128, 0, stream>>>(ns_, nv_, s_, node_attr,
                                           c1_lin2_s, c1_lin2_v, c1_sc,
                                           c2_lin1_s, c2_lin1_v, gs_, hs_, hv_);
    k_edge2_at<<<512, 512, 0, stream>>>(es8, shv, esrc, edst, hs_, hv_,
                                        c2_fc_w0, c2_fc_w1, c2_fc_w2, nmid_);
    k_node2<<<N_NODES/4, 128, 0, stream>>>(nmid_, gs_, node_attr, batch,
                                           c2_lin2, c2_sc, pool_);
  }

  k_head<<<1, 128, 0, stream>>>(pool_, cnt_, Wr1, Wr2, (float*)d_out);
}

// Round 10
// 328.770 us; speedup vs baseline: 3.8176x; 1.1505x over previous
//
#include <hip/hip_runtime.h>
#include <hip/hip_fp16.h>

#define N_NODES 10000
#define N_EDGES 160000
#define N_GRAPHS 16

typedef __attribute__((ext_vector_type(8))) _Float16 f16x8;
typedef __attribute__((ext_vector_type(4))) float f32x4;
typedef __attribute__((ext_vector_type(4))) unsigned short u16x4;
typedef __attribute__((ext_vector_type(2))) unsigned short u16x2;
typedef unsigned int uint32;
typedef unsigned short u16;

// ---- workspace layout (float offsets) ----
#define OFF_ES8  0
#define OFF_SHV  (OFF_ES8 + N_EDGES*8)
#define OFF_S    (OFF_SHV + N_EDGES*3)
#define OFF_H    (OFF_S   + N_NODES*128)
#define OFF_GS   (OFF_H   + N_NODES*128)
#define OFF_HS   (OFF_GS  + N_NODES*64)
#define OFF_HV   (OFF_HS  + N_NODES*64)
#define OFF_NS   (OFF_HV  + N_NODES*192)   /* fallback zero-region start */
#define OFF_NV   (OFF_NS  + N_NODES*128)
#define OFF_NMID (OFF_NV  + N_NODES*384)
#define OFF_POOL (OFF_NMID+ N_NODES*128)   /* new-path zero-region start */
#define OFF_CNT  (OFF_POOL+ N_GRAPHS*128)
#define OFF_HIST (OFF_CNT + N_GRAPHS)
#define OFF_CURS (OFF_HIST+ N_NODES)
#define OFF_OFFS (OFF_CURS+ N_NODES)       /* new-path zero-region end (excl) */
#define OFF_FRAG (OFF_OFFS+ N_NODES + 16)  /* persistent frags: 57344 u16 (f16 single-plane) */
#define OFF_SLOT (OFF_FRAG+ 57344)
#define OFF_WBUF (OFF_SLOT+ N_EDGES)
#define WBUF_FLOATS ((size_t)N_EDGES*256)
#define WS_NEED_BYTES ((size_t)(OFF_WBUF + WBUF_FLOATS) * 4)

// persistent frag sub-offsets in u16 (single-plane f16: NF*KS*512 each)
#define F_B1   0        /* conv1 L1: NF4 KS1 -> 2048  */
#define F_B2   2048     /* conv1 L2: NF4 KS2 -> 4096  */
#define F_B3   6144     /* conv1 L3: NF16 KS2 -> 16384 */
#define F_B1b  22528
#define F_B2b  24576
#define F_B3b  28672    /* conv2 L3: NF8 KS2 -> 8192 */
#define F_WE   36864    /* W_embed: NF8 KS1 -> 4096 */
#define F_L1   40960    /* c1_lin1: NF8 KS4 -> 16384 */
#define FRAG_TOT 57344

// node-frag sub-offsets in u16
#define NF_WLS 0        /* c1_lin2_s: NF8 KS4 -> 16384 */
#define NF_C1  16384    /* c1_sc:   NF128 KS4 -> 262144 */
#define NF_W2  278528   /* c2_lin2:  NF8 KS4 -> 16384 */
#define NF_C2  294912   /* c2_sc:   NF128 KS2 -> 131072 */
#define NF_LV  425984   /* c1_lin2_v: NF4 KS4 -> 8192 */
#define NF_2S  434176   /* c2_lin1_s: NF4 KS2 -> 4096 */
#define NF_2V  438272   /* c2_lin1_v: NF4 KS2 -> 4096 */
#define NFRAG_TOT 442368

#define NM128 (N_NODES*128)

#define INV_SQRT32   0.17677669529663687f
#define INV_SQRT128  0.08838834764831845f
#define INV_SQRT8    0.3535533905932738f
#define INV_SQRT64   0.125f
#define INV_SQRT2048 0.022097086912079608f
#define INV_SQRT1024 0.03125f
#define INV_SQRT10   0.31622776601683794f
#define INV_SQRT3    0.5773502691896258f
#define SQRT3_C      1.7320508075688772f

__device__ __forceinline__ float siluf(float x){ return x / (1.f + __expf(-x)); }
__device__ __forceinline__ float sigf (float x){ return 1.f / (1.f + __expf(-x)); }
__device__ __forceinline__ u16 f2h(float x){ return __half_as_ushort(__float2half_rn(x)); }
__device__ __forceinline__ float h2f(u16 b){ return __half2float(__ushort_as_half(b)); }
__device__ __forceinline__ f16x8 cvt8(const float* __restrict__ p) {
  f32x4 v0 = *(const f32x4*)p;
  f32x4 v1 = *(const f32x4*)(p + 4);
  f16x8 r;
  r[0]=(_Float16)v0[0]; r[1]=(_Float16)v0[1]; r[2]=(_Float16)v0[2]; r[3]=(_Float16)v0[3];
  r[4]=(_Float16)v1[0]; r[5]=(_Float16)v1[1]; r[6]=(_Float16)v1[2]; r[7]=(_Float16)v1[3];
  return r;
}

// ---------------- edge geometry ----------------
__global__ void k_geom(const float* __restrict__ evec,
                       float* __restrict__ es8, float* __restrict__ shv) {
  int e = blockIdx.x*256 + threadIdx.x;
  if (e >= N_EDGES) return;
  float vx = evec[e*3+0], vy = evec[e*3+1], vz = evec[e*3+2];
  float d  = sqrtf(vx*vx + vy*vy + vz*vz);
  float xs = d - 0.25f;
  bool  in = (xs > 0.f) && (xs < 4.0f);
  float safe = xs > 0.f ? xs : 1.f;
  float amp  = in ? 2.0f/safe : 0.f;
  const float PI4 = 0.7853981633974483f;
  #pragma unroll
  for (int k = 0; k < 8; ++k)
    es8[e*8+k] = amp * sinf((float)(k+1) * PI4 * safe);
  float invd = d > 0.f ? 1.f/d : 1.f;
  shv[e*3+0] = SQRT3_C*vx*invd;
  shv[e*3+1] = SQRT3_C*vy*invd;
  shv[e*3+2] = SQRT3_C*vz*invd;
}

// ---------------- fallback scalar linear ----------------
__global__ void k_linear128(const float* __restrict__ A, const float* __restrict__ W,
                            float* __restrict__ O, int K, float scale, int total) {
  int t = blockIdx.x*256 + threadIdx.x;
  if (t >= total) return;
  int n = t >> 7, j = t & 127;
  const float* a = A + n*K;
  float a0=0.f,a1=0.f,a2=0.f,a3=0.f;
  for (int k = 0; k < K; k += 4) {
    a0 += a[k+0]*W[(k+0)*128+j];
    a1 += a[k+1]*W[(k+1)*128+j];
    a2 += a[k+2]*W[(k+2)*128+j];
    a3 += a[k+3]*W[(k+3)*128+j];
  }
  O[t] = (a0+a1+a2+a3)*scale;
}

// ---------------- graph node counts + edge histogram (merged) ----------------
__global__ void k_cnthist(const int* __restrict__ batch, const int* __restrict__ edst,
                          float* __restrict__ cnt, int* __restrict__ hist) {
  __shared__ int lc[N_GRAPHS];
  int t = threadIdx.x;
  if (t < N_GRAPHS) lc[t] = 0;
  __syncthreads();
  int i = blockIdx.x*256 + t;
  if (i < N_NODES) atomicAdd(&lc[batch[i]], 1);
  if (i < N_EDGES) atomicAdd(&hist[edst[i]], 1);
  __syncthreads();
  if (t < N_GRAPHS && lc[t] > 0) atomicAdd(&cnt[t], (float)lc[t]);
}

__global__ __launch_bounds__(1024) void k_scanp(const int* __restrict__ hist,
                                                int* __restrict__ offs) {
  __shared__ int wsum[16];
  const int t = threadIdx.x;
  const int lane = t & 63, w = t >> 6;
  const int base = t*10;
  int v[10]; int s = 0;
  #pragma unroll
  for (int i = 0; i < 10; ++i) {
    int idx = base + i;
    int x = (idx < N_NODES) ? hist[idx] : 0;
    s += x; v[i] = s;
  }
  int ws = s;
  #pragma unroll
  for (int d = 1; d < 64; d <<= 1) {
    int u = __shfl_up(ws, d);
    if (lane >= d) ws += u;
  }
  if (lane == 63) wsum[w] = ws;
  __syncthreads();
  if (w == 0) {
    int x = (lane < 16) ? wsum[lane] : 0;
    #pragma unroll
    for (int d = 1; d < 16; d <<= 1) {
      int u = __shfl_up(x, d);
      if (lane >= d) x += u;
    }
    if (lane < 16) wsum[lane] = x;
  }
  __syncthreads();
  int waveoff = (w > 0) ? wsum[w-1] : 0;
  int texcl = waveoff + ws - s;
  if (t == 0) offs[0] = 0;
  #pragma unroll
  for (int i = 0; i < 10; ++i) {
    int idx = base + i;
    if (idx < N_NODES) offs[idx+1] = texcl + v[i];
  }
}

__global__ void k_slot(const int* __restrict__ edst, const int* __restrict__ offs,
                       int* __restrict__ curs, int* __restrict__ slot) {
  int e = blockIdx.x*256 + threadIdx.x;
  if (e < N_EDGES) {
    int d = edst[e];
    int p = offs[d] + atomicAdd(&curs[d], 1);
    slot[p] = e;
  }
}

// ---------------- merged weight fragment prep (f16 single-plane, B-frag order) ----------------
// flat idx: ((nf*KS + ks)*64 + lane)*8 + j ; k = ks*32+(lane>>4)*8+j ; col = nf*16+(lane&15)
struct PD { const float* W; u16* dst; int Keff, N, KS, nElem; float scale; };
struct PD8 { PD d[8]; int nd; int tot; };

__global__ void k_prepmulti(PD8 ds) {
  int stride = gridDim.x*256;
  for (int t = blockIdx.x*256 + threadIdx.x; t < ds.tot; t += stride) {
    int rem = t, i = 0;
    while (i < ds.nd-1 && rem >= ds.d[i].nElem) { rem -= ds.d[i].nElem; ++i; }
    const PD p = ds.d[i];
    int j = rem & 7;
    int l = (rem >> 3) & 63;
    int rest = rem >> 9;
    int ks = rest % p.KS;
    int nf = rest / p.KS;
    int k   = ks*32 + (l >> 4)*8 + j;
    int col = nf*16 + (l & 15);
    float v = (k < p.Keff) ? p.W[(size_t)k*p.N + col]*p.scale : 0.f;
    p.dst[rem] = f2h(v);
  }
}

// ---------------- fused 3-layer edge MLP via f16 MFMA; 32 edges/wave; packed interleaved out ----------------
// wbuf layout: [e][64 cols][NQ quadrants] u16, NQ = NF3/4
template<int NF3>
__global__ __launch_bounds__(256) void k_mlp(
    const float* __restrict__ es8,
    const u16* __restrict__ fb1, const u16* __restrict__ fb2,
    const u16* __restrict__ fb3, u16* __restrict__ wbuf) {
  __shared__ __align__(16) _Float16 route[4][2304];   // 4 waves x (32 rows x 72 halves)
  const int w = threadIdx.x >> 6, l = threadIdx.x & 63;
  const int lrow = l & 15, lhi = l >> 4;
  const int e0 = (blockIdx.x*4 + w)*32;
  _Float16* rt = route[w];
  constexpr int NQ = NF3/4;

  // L1 A-fragments (valid k<8 -> lanes lhi==0)
  f16x8 a1[2];
  #pragma unroll
  for (int mt = 0; mt < 2; ++mt) {
    f16x8 z = {0,0,0,0,0,0,0,0};
    if (lhi == 0) z = cvt8(es8 + (size_t)(e0 + mt*16 + lrow)*8);
    a1[mt] = z;
  }

  // L1: 8 MFMAs
  f32x4 acc1[2][4];
  #pragma unroll
  for (int mt = 0; mt < 2; ++mt)
    #pragma unroll
    for (int nf = 0; nf < 4; ++nf) acc1[mt][nf] = (f32x4){0.f,0.f,0.f,0.f};
  #pragma unroll
  for (int nf = 0; nf < 4; ++nf) {
    f16x8 b = *(const f16x8*)(fb1 + nf*512 + l*8);
    #pragma unroll
    for (int mt = 0; mt < 2; ++mt)
      acc1[mt][nf] = __builtin_amdgcn_mfma_f32_16x16x32_f16(a1[mt], b, acc1[mt][nf], 0,0,0);
  }
  #pragma unroll
  for (int mt = 0; mt < 2; ++mt)
    #pragma unroll
    for (int nf = 0; nf < 4; ++nf)
      #pragma unroll
      for (int r = 0; r < 4; ++r) acc1[mt][nf][r] = siluf(acc1[mt][nf][r]);

  // route L1 -> L2 A-frags (single f16 plane)
  f16x8 a2[2][2];
  #pragma unroll
  for (int mt = 0; mt < 2; ++mt)
    #pragma unroll
    for (int nf = 0; nf < 4; ++nf)
      #pragma unroll
      for (int r = 0; r < 4; ++r)
        rt[(mt*16 + lhi*4 + r)*72 + nf*16 + lrow] = (_Float16)acc1[mt][nf][r];
  #pragma unroll
  for (int mt = 0; mt < 2; ++mt)
    #pragma unroll
    for (int ks = 0; ks < 2; ++ks)
      a2[mt][ks] = *(const f16x8*)&rt[(mt*16 + lrow)*72 + ks*32 + lhi*8];

  // L2: 16 MFMAs
  f32x4 acc2[2][4];
  #pragma unroll
  for (int mt = 0; mt < 2; ++mt)
    #pragma unroll
    for (int nf = 0; nf < 4; ++nf) acc2[mt][nf] = (f32x4){0.f,0.f,0.f,0.f};
  #pragma unroll
  for (int nf = 0; nf < 4; ++nf)
    #pragma unroll
    for (int ks = 0; ks < 2; ++ks) {
      f16x8 b = *(const f16x8*)(fb2 + (nf*2 + ks)*512 + l*8);
      #pragma unroll
      for (int mt = 0; mt < 2; ++mt)
        acc2[mt][nf] = __builtin_amdgcn_mfma_f32_16x16x32_f16(a2[mt][ks], b, acc2[mt][nf], 0,0,0);
    }
  #pragma unroll
  for (int mt = 0; mt < 2; ++mt)
    #pragma unroll
    for (int nf = 0; nf < 4; ++nf)
      #pragma unroll
      for (int r = 0; r < 4; ++r) acc2[mt][nf][r] = siluf(acc2[mt][nf][r]);

  // route L2 -> L3 A-frags
  f16x8 a3[2][2];
  #pragma unroll
  for (int mt = 0; mt < 2; ++mt)
    #pragma unroll
    for (int nf = 0; nf < 4; ++nf)
      #pragma unroll
      for (int r = 0; r < 4; ++r)
        rt[(mt*16 + lhi*4 + r)*72 + nf*16 + lrow] = (_Float16)acc2[mt][nf][r];
  #pragma unroll
  for (int mt = 0; mt < 2; ++mt)
    #pragma unroll
    for (int ks = 0; ks < 2; ++ks)
      a3[mt][ks] = *(const f16x8*)&rt[(mt*16 + lrow)*72 + ks*32 + lhi*8];

  // L3: grouped by cc, packed stores
  #pragma unroll
  for (int cc = 0; cc < 4; ++cc) {
    f32x4 acc3[NQ][2];
    #pragma unroll
    for (int q = 0; q < NQ; ++q)
      #pragma unroll
      for (int mt = 0; mt < 2; ++mt) acc3[q][mt] = (f32x4){0.f,0.f,0.f,0.f};
    #pragma unroll
    for (int q = 0; q < NQ; ++q) {
      const int nf3 = q*4 + cc;
      #pragma unroll
      for (int ks = 0; ks < 2; ++ks) {
        f16x8 b = *(const f16x8*)(fb3 + ((size_t)nf3*2 + ks)*512 + l*8);
        #pragma unroll
        for (int mt = 0; mt < 2; ++mt)
          acc3[q][mt] = __builtin_amdgcn_mfma_f32_16x16x32_f16(a3[mt][ks], b, acc3[q][mt], 0,0,0);
      }
    }
    const int cbase = (cc*16 + lrow)*NQ;
    #pragma unroll
    for (int mt = 0; mt < 2; ++mt)
      #pragma unroll
      for (int r = 0; r < 4; ++r) {
        const size_t rowoff = (size_t)(e0 + mt*16 + lhi*4 + r)*(NF3*16) + cbase;
        if constexpr (NQ == 4) {
          u16x4 pk;
          #pragma unroll
          for (int q = 0; q < 4; ++q) pk[q] = f2h(acc3[q][mt][r]);
          *(u16x4*)(wbuf + rowoff) = pk;
        } else {
          u16x2 pk;
          #pragma unroll
          for (int q = 0; q < 2; ++q) pk[q] = f2h(acc3[q][mt][r]);
          *(u16x2*)(wbuf + rowoff) = pk;
        }
      }
  }
}

// ---------------- generic f16 MFMA GEMM ----------------
template<int KS, int NF>
__global__ __launch_bounds__(512, 4) void k_gemm(
    const float* __restrict__ A, int rstride, int M,
    const u16* __restrict__ fB, float* __restrict__ O) {
  __shared__ __align__(16) _Float16 lB[NF*KS*512];
  const int tid = threadIdx.x;
  const int w = tid >> 6, l = tid & 63;
  const int lrow = l & 15, lhi = l >> 4;
  const int n0 = blockIdx.x*128 + w*16;
  for (int i = tid; i < NF*KS*64; i += 512)
    *(f16x8*)&lB[(size_t)i*8] = *(const f16x8*)&fB[(size_t)i*8];
  f16x8 a[KS];
  {
    int row = n0 + lrow; if (row > M-1) row = M-1;
    #pragma unroll
    for (int ks = 0; ks < KS; ++ks)
      a[ks] = cvt8(A + (size_t)row*rstride + ks*32 + lhi*8);
  }
  __syncthreads();
  f32x4 acc[NF];
  #pragma unroll
  for (int nf = 0; nf < NF; ++nf) acc[nf] = (f32x4){0.f,0.f,0.f,0.f};
  #pragma unroll
  for (int nf = 0; nf < NF; ++nf)
    #pragma unroll
    for (int ks = 0; ks < KS; ++ks) {
      f16x8 b = *(const f16x8*)&lB[((size_t)(nf*KS + ks))*512 + l*8];
      acc[nf] = __builtin_amdgcn_mfma_f32_16x16x32_f16(a[ks], b, acc[nf], 0,0,0);
    }
  #pragma unroll
  for (int nf = 0; nf < NF; ++nf)
    #pragma unroll
    for (int r = 0; r < 4; ++r) {
      int row = n0 + lhi*4 + r;
      if (row < M) O[(size_t)row*(NF*16) + nf*16 + lrow] = acc[nf][r];
    }
}

// ---------------- sc partial (f16) ----------------
template<int KSO>
__global__ __launch_bounds__(512, 4) void k_scp(
    const float* __restrict__ Ao, const float* __restrict__ na,
    const u16* __restrict__ fBc, float* __restrict__ part) {
  __shared__ __align__(16) _Float16 lB[KSO*4096];
  const int tid = threadIdx.x;
  const int w = tid >> 6, l = tid & 63;
  const int lrow = l & 15, lhi = l >> 4;
  const int n0 = blockIdx.x*128 + w*16;
  const int vp = blockIdx.y;

  f16x8 ao[KSO];
  {
    int row = n0 + lrow; if (row > N_NODES-1) row = N_NODES-1;
    #pragma unroll
    for (int ks = 0; ks < KSO; ++ks)
      ao[ks] = cvt8(Ao + (size_t)row*(KSO*32) + ks*32 + lhi*8);
  }

  f32x4 acc[8];
  #pragma unroll
  for (int nf = 0; nf < 8; ++nf) acc[nf] = (f32x4){0.f,0.f,0.f,0.f};

  #pragma unroll
  for (int c = 0; c < 2; ++c) {
    const int v = vp*2 + c;
    __syncthreads();
    for (int i = tid; i < KSO*512; i += 512) {   // 16B groups
      int gl = i & 63;
      int rest = i >> 6;
      int ks = rest % KSO;
      int nf = rest / KSO;
      size_t src = (((size_t)(v*8 + nf)*KSO + ks)*64 + gl)*8;
      *(f16x8*)&lB[(size_t)i*8] = *(const f16x8*)&fBc[src];
    }
    __syncthreads();
    f32x4 dacc[8];
    #pragma unroll
    for (int nf = 0; nf < 8; ++nf) dacc[nf] = (f32x4){0.f,0.f,0.f,0.f};
    #pragma unroll
    for (int nf = 0; nf < 8; ++nf)
      #pragma unroll
      for (int ks = 0; ks < KSO; ++ks) {
        f16x8 b = *(const f16x8*)&lB[((size_t)(nf*KSO + ks))*512 + l*8];
        dacc[nf] = __builtin_amdgcn_mfma_f32_16x16x32_f16(ao[ks], b, dacc[nf], 0,0,0);
      }
    #pragma unroll
    for (int r = 0; r < 4; ++r) {
      int row = n0 + lhi*4 + r; if (row > N_NODES-1) row = N_NODES-1;
      float nav = na[(size_t)row*16 + v];
      #pragma unroll
      for (int nf = 0; nf < 8; ++nf) acc[nf][r] += nav * dacc[nf][r];
    }
  }

  float* pp = part + (size_t)vp*NM128;
  #pragma unroll
  for (int nf = 0; nf < 8; ++nf)
    #pragma unroll
    for (int r = 0; r < 4; ++r) {
      int row = n0 + lhi*4 + r;
      if (row < N_NODES) pp[(size_t)row*128 + nf*16 + lrow] = acc[nf][r];
    }
}

// ---------------- fused reduce(9) + gating ----------------
__global__ void k_redgate(const float* __restrict__ part, const float* __restrict__ ov,
                          float* __restrict__ gs_out, float* __restrict__ gv) {
  int t = blockIdx.x*256 + threadIdx.x;
  if (t >= N_NODES*64) return;
  int n = t >> 6, v = t & 63;
  float o1 = 0.f, o2 = 0.f;
  #pragma unroll
  for (int p = 0; p < 9; ++p) {
    const float* pp = part + (size_t)p*NM128 + (size_t)n*128;
    o1 += pp[v]; o2 += pp[64+v];
  }
  float g = siluf(o1), gate = sigf(o2);
  gs_out[(size_t)n*64+v] = g;
  gv[(size_t)n*192 + 0*64 + v] = gate*ov[(size_t)n*192 + 0*64 + v];
  gv[(size_t)n*192 + 1*64 + v] = gate*ov[(size_t)n*192 + 1*64 + v];
  gv[(size_t)n*192 + 2*64 + v] = gate*ov[(size_t)n*192 + 2*64 + v];
}

// ---------------- fused reduce(9) + pooled accumulation (RLE) ----------------
__global__ __launch_bounds__(128) void k_redpool(
    const float* __restrict__ part, const int* __restrict__ batch,
    float* __restrict__ pool) {
  const int j = threadIdx.x;
  const int n0 = blockIdx.x*4;
  float outv[4];
  #pragma unroll
  for (int nn = 0; nn < 4; ++nn) {
    float sv = 0.f;
    #pragma unroll
    for (int p = 0; p < 9; ++p)
      sv += part[(size_t)p*NM128 + (size_t)(n0+nn)*128 + j];
    outv[nn] = sv;
  }
  int b0 = batch[n0], b1 = batch[n0+1], b2 = batch[n0+2], b3 = batch[n0+3];
  float sum = outv[0]; int cur = b0;
  if (b1 == cur) sum += outv[1]; else { atomicAdd(&pool[cur*128+j], sum); cur = b1; sum = outv[1]; }
  if (b2 == cur) sum += outv[2]; else { atomicAdd(&pool[cur*128+j], sum); cur = b2; sum = outv[2]; }
  if (b3 == cur) sum += outv[3]; else { atomicAdd(&pool[cur*128+j], sum); cur = b3; sum = outv[3]; }
  atomicAdd(&pool[cur*128+j], sum);
}

// ---------------- conv1 gather: CSR pull (fp16 interleaved wbuf); n_v as [n][3][128] ----------------
__global__ __launch_bounds__(256) void k_gather1(
    const u16* __restrict__ wbuf, const float* __restrict__ shv,
    const int* __restrict__ esrc, const int* __restrict__ offs, const int* __restrict__ slot,
    const float* __restrict__ h,
    float* __restrict__ n_s, float* __restrict__ n_v) {
  const int wave = threadIdx.x >> 6, lane = threadIdx.x & 63;
  const int n = blockIdx.x*4 + wave;
  if (n >= N_NODES) return;
  const int s0 = offs[n], s1 = offs[n+1];
  float ns0=0.f, ns1=0.f;
  float nv00=0.f,nv01=0.f,nv02=0.f, nv10=0.f,nv11=0.f,nv12=0.f;
  for (int s = s0; s < s1; ++s) {
    int e = slot[s];
    int src = esrc[e];
    u16x4 wv = *(const u16x4*)(wbuf + (size_t)e*256 + lane*4);
    float c0 = h2f(wv[0]), c1 = h2f(wv[1]), c2 = h2f(wv[2]), c3 = h2f(wv[3]);
    float h0 = h[src*128+lane], h1 = h[src*128+64+lane];
    float sv0 = shv[e*3+0], sv1 = shv[e*3+1], sv2 = shv[e*3+2];
    ns0 += c0*h0; ns1 += c1*h1;
    float t0 = c2*h0, t1 = c3*h1;
    nv00 += t0*sv0; nv01 += t0*sv1; nv02 += t0*sv2;
    nv10 += t1*sv0; nv11 += t1*sv1; nv12 += t1*sv2;
  }
  n_s[n*128+lane]    = ns0*INV_SQRT10;
  n_s[n*128+64+lane] = ns1*INV_SQRT10;
  float* nvp = n_v + (size_t)n*384;      // [3][128]
  nvp[0*128+lane]    = nv00*INV_SQRT10;
  nvp[1*128+lane]    = nv01*INV_SQRT10;
  nvp[2*128+lane]    = nv02*INV_SQRT10;
  nvp[0*128+64+lane] = nv10*INV_SQRT10;
  nvp[1*128+64+lane] = nv11*INV_SQRT10;
  nvp[2*128+64+lane] = nv12*INV_SQRT10;
}

// ---------------- conv2 gather (fp16 interleaved wbuf): h_v layout [n][3][64] ----------------
__global__ __launch_bounds__(256) void k_gather2(
    const u16* __restrict__ wbuf, const float* __restrict__ shv,
    const int* __restrict__ esrc, const int* __restrict__ offs, const int* __restrict__ slot,
    const float* __restrict__ h_s, const float* __restrict__ h_v,
    float* __restrict__ n_mid) {
  const int wave = threadIdx.x >> 6, lane = threadIdx.x & 63;
  const int n = blockIdx.x*4 + wave;
  if (n >= N_NODES) return;
  const int s0 = offs[n], s1 = offs[n+1];
  float acc0 = 0.f, acc1 = 0.f;
  for (int s = s0; s < s1; ++s) {
    int e = slot[s];
    int src = esrc[e];
    u16x2 wv = *(const u16x2*)(wbuf + (size_t)e*128 + lane*2);
    float w0 = h2f(wv[0]), w1 = h2f(wv[1]);
    float hs = h_s[src*64+lane];
    const float* hvp = h_v + (size_t)src*192;
    float sv0 = shv[e*3+0], sv1 = shv[e*3+1], sv2 = shv[e*3+2];
    float dot = hvp[lane]*sv0 + hvp[64+lane]*sv1 + hvp[128+lane]*sv2;
    acc0 += w0*hs;
    acc1 += w1*dot;
  }
  n_mid[n*128+lane]    = acc0*INV_SQRT10;
  n_mid[n*128+64+lane] = acc1*INV_SQRT3*INV_SQRT10;
}

// ======== FALLBACK (atomic) kernels — used only if ws too small ========
__global__ __launch_bounds__(512) void k_edge1_at(
    const float* __restrict__ es8, const float* __restrict__ shv,
    const int* __restrict__ esrc, const int* __restrict__ edst,
    const float* __restrict__ h,
    const float* __restrict__ W0, const float* __restrict__ W1, const float* __restrict__ W2,
    float* __restrict__ n_s, float* __restrict__ n_v) {
  __shared__ float lW0[512];
  __shared__ float lW1[4096];
  __shared__ float lW2[16384];
  __shared__ float lA[8][64];
  __shared__ float lB[8][64];
  for (int i = threadIdx.x; i < 512;   i += 512) lW0[i] = W0[i];
  for (int i = threadIdx.x; i < 4096;  i += 512) lW1[i] = W1[i];
  for (int i = threadIdx.x; i < 16384; i += 512) lW2[i] = W2[i];
  __syncthreads();
  const int wave = threadIdx.x >> 6, lane = threadIdx.x & 63;
  const int nw = gridDim.x * 8;
  const int e0 = blockIdx.x*8 + wave;
  const int iters = (N_EDGES + nw - 1) / nw;
  for (int it = 0; it < iters; ++it) {
    int e = e0 + it*nw;
    bool valid = e < N_EDGES;
    float a = 0.f, sv0=0.f, sv1=0.f, sv2=0.f;
    int src = 0, dst = 0;
    if (valid) {
      const float* ep = es8 + e*8;
      sv0 = shv[e*3+0]; sv1 = shv[e*3+1]; sv2 = shv[e*3+2];
      src = esrc[e]; dst = edst[e];
      a = ep[0]*lW0[lane]      + ep[1]*lW0[64+lane]  + ep[2]*lW0[128+lane] + ep[3]*lW0[192+lane]
        + ep[4]*lW0[256+lane]  + ep[5]*lW0[320+lane] + ep[6]*lW0[384+lane] + ep[7]*lW0[448+lane];
      a = siluf(a * INV_SQRT8);
    }
    lA[wave][lane] = a;
    __syncthreads();
    {
      float b0=0.f;
      #pragma unroll
      for (int k = 0; k < 64; ++k) b0 += lA[wave][k]*lW1[k*64+lane];
      lB[wave][lane] = siluf(b0 * INV_SQRT64);
    }
    __syncthreads();
    if (valid) {
      float c0=0.f,c1=0.f,c2=0.f,c3=0.f;
      #pragma unroll
      for (int k = 0; k < 64; ++k) {
        float bk = lB[wave][k];
        const float* r = lW2 + k*256;
        c0 += bk*r[lane]; c1 += bk*r[64+lane]; c2 += bk*r[128+lane]; c3 += bk*r[192+lane];
      }
      float hs0 = h[src*128 + lane];
      float hs1 = h[src*128 + 64 + lane];
      atomicAdd(&n_s[dst*128 + lane],      c0*INV_SQRT64*hs0*INV_SQRT10);
      atomicAdd(&n_s[dst*128 + 64 + lane], c1*INV_SQRT64*hs1*INV_SQRT10);
      float t0 = c2*INV_SQRT64*hs0*INV_SQRT10;
      float t1 = c3*INV_SQRT64*hs1*INV_SQRT10;
      float* nvp = n_v + dst*384;
      atomicAdd(nvp + lane*3+0, t0*sv0);
      atomicAdd(nvp + lane*3+1, t0*sv1);
      atomicAdd(nvp + lane*3+2, t0*sv2);
      atomicAdd(nvp + (64+lane)*3+0, t1*sv0);
      atomicAdd(nvp + (64+lane)*3+1, t1*sv1);
      atomicAdd(nvp + (64+lane)*3+2, t1*sv2);
    }
  }
}

__global__ __launch_bounds__(512) void k_edge2_at(
    const float* __restrict__ es8, const float* __restrict__ shv,
    const int* __restrict__ esrc, const int* __restrict__ edst,
    const float* __restrict__ h_s, const float* __restrict__ h_v,
    const float* __restrict__ W0, const float* __restrict__ W1, const float* __restrict__ W2,
    float* __restrict__ n_mid) {
  __shared__ float lW0[512];
  __shared__ float lW1[4096];
  __shared__ float lW2[8192];
  __shared__ float lA[8][64];
  __shared__ float lB[8][64];
  for (int i = threadIdx.x; i < 512;  i += 512) lW0[i] = W0[i];
  for (int i = threadIdx.x; i < 4096; i += 512) lW1[i] = W1[i];
  for (int i = threadIdx.x; i < 8192; i += 512) lW2[i] = W2[i];
  __syncthreads();
  const int wave = threadIdx.x >> 6, lane = threadIdx.x & 63;
  const int nw = gridDim.x * 8;
  const int e0 = blockIdx.x*8 + wave;
  const int iters = (N_EDGES + nw - 1) / nw;
  for (int it = 0; it < iters; ++it) {
    int e = e0 + it*nw;
    bool valid = e < N_EDGES;
    float a = 0.f, sv0=0.f, sv1=0.f, sv2=0.f;
    int src = 0, dst = 0;
    if (valid) {
      const float* ep = es8 + e*8;
      sv0 = shv[e*3+0]; sv1 = shv[e*3+1]; sv2 = shv[e*3+2];
      src = esrc[e]; dst = edst[e];
      a = ep[0]*lW0[lane]      + ep[1]*lW0[64+lane]  + ep[2]*lW0[128+lane] + ep[3]*lW0[192+lane]
        + ep[4]*lW0[256+lane]  + ep[5]*lW0[320+lane] + ep[6]*lW0[384+lane] + ep[7]*lW0[448+lane];
      a = siluf(a * INV_SQRT8);
    }
    lA[wave][lane] = a;
    __syncthreads();
    {
      float b0=0.f;
      #pragma unroll
      for (int k = 0; k < 64; ++k) b0 += lA[wave][k]*lW1[k*64+lane];
      lB[wave][lane] = siluf(b0 * INV_SQRT64);
    }
    __syncthreads();
    if (valid) {
      float c0=0.f, c1=0.f;
      #pragma unroll
      for (int k = 0; k < 64; ++k) {
        float bk = lB[wave][k];
        const float* r = lW2 + k*128;
        c0 += bk*r[lane]; c1 += bk*r[64+lane];
      }
      float hsv = h_s[src*64 + lane];
      const float* hvp = h_v + src*192 + lane*3;
      float dotv = hvp[0]*sv0 + hvp[1]*sv1 + hvp[2]*sv2;
      atomicAdd(&n_mid[dst*128 + lane],      c0*INV_SQRT64*hsv*INV_SQRT10);
      atomicAdd(&n_mid[dst*128 + 64 + lane], c1*INV_SQRT64*dotv*INV_SQRT3*INV_SQRT10);
    }
  }
}

// ---------------- FALLBACK conv1 node pass (full, old n_v layout) ----------------
__global__ __launch_bounds__(128) void k_node1(
    const float* __restrict__ n_s, const float* __restrict__ n_v,
    const float* __restrict__ s,   const float* __restrict__ na,
    const float* __restrict__ Wls, const float* __restrict__ Wlv,
    const float* __restrict__ Csc, const float* __restrict__ W2s, const float* __restrict__ W2v,
    float* __restrict__ gs_out, float* __restrict__ hs_out, float* __restrict__ hv_out) {
  __shared__ float l_ns[512], l_s[512], l_na[64], l_nv[1536];
  __shared__ float l_outs[512], l_ov[768], l_gs[256], l_gv[768];
  const int j = threadIdx.x;
  const int n0 = blockIdx.x*4;
  for (int i = j; i < 512;  i += 128) { l_ns[i] = n_s[n0*128+i]; l_s[i] = s[n0*128+i]; }
  for (int i = j; i < 1536; i += 128) l_nv[i] = n_v[n0*384+i];
  if (j < 64) l_na[j] = na[n0*16+j];
  __syncthreads();

  float accs[4] = {0.f,0.f,0.f,0.f};
  for (int k = 0; k < 128; ++k) {
    float w = Wls[k*128+j];
    accs[0] += l_ns[k]*w; accs[1] += l_ns[128+k]*w;
    accs[2] += l_ns[256+k]*w; accs[3] += l_ns[384+k]*w;
  }
  float accc[4] = {0.f,0.f,0.f,0.f};
  for (int vt = 0; vt < 16; vt += 4) {
    float a0[4],a1[4],a2[4],a3[4];
    #pragma unroll
    for (int n = 0; n < 4; ++n) {
      a0[n]=l_na[n*16+vt]; a1[n]=l_na[n*16+vt+1];
      a2[n]=l_na[n*16+vt+2]; a3[n]=l_na[n*16+vt+3];
    }
    for (int u = 0; u < 128; ++u) {
      const float* cp = Csc + (u*16+vt)*128 + j;
      float c0=cp[0], c1=cp[128], c2=cp[256], c3=cp[384];
      float s0=l_s[u], s1=l_s[128+u], s2=l_s[256+u], s3=l_s[384+u];
      accc[0] += s0*(a0[0]*c0 + a1[0]*c1 + a2[0]*c2 + a3[0]*c3);
      accc[1] += s1*(a0[1]*c0 + a1[1]*c1 + a2[1]*c2 + a3[1]*c3);
      accc[2] += s2*(a0[2]*c0 + a1[2]*c1 + a2[2]*c2 + a3[2]*c3);
      accc[3] += s3*(a0[3]*c0 + a1[3]*c1 + a2[3]*c2 + a3[3]*c3);
    }
  }
  #pragma unroll
  for (int n = 0; n < 4; ++n)
    l_outs[n*128+j] = accs[n]*INV_SQRT128 + accc[n]*INV_SQRT2048;

  const int jj = j & 63, hh = j >> 6;
  float ov[2][3] = {{0.f,0.f,0.f},{0.f,0.f,0.f}};
  for (int u = 0; u < 128; ++u) {
    float w = Wlv[u*64+jj];
    #pragma unroll
    for (int t = 0; t < 2; ++t) {
      int n = 2*hh+t;
      ov[t][0] += l_nv[n*384+u*3+0]*w;
      ov[t][1] += l_nv[n*384+u*3+1]*w;
      ov[t][2] += l_nv[n*384+u*3+2]*w;
    }
  }
  #pragma unroll
  for (int t = 0; t < 2; ++t) {
    int n = 2*hh+t;
    l_ov[n*192+jj*3+0] = ov[t][0]*INV_SQRT128;
    l_ov[n*192+jj*3+1] = ov[t][1]*INV_SQRT128;
    l_ov[n*192+jj*3+2] = ov[t][2]*INV_SQRT128;
  }
  __syncthreads();

  #pragma unroll
  for (int t = 0; t < 2; ++t) {
    int n = 2*hh+t;
    float gv_s = siluf(l_outs[n*128+jj]);
    float gate = sigf (l_outs[n*128+64+jj]);
    l_gs[n*64+jj] = gv_s;
    gs_out[(n0+n)*64+jj] = gv_s;
    l_gv[n*192+jj*3+0] = gate*l_ov[n*192+jj*3+0];
    l_gv[n*192+jj*3+1] = gate*l_ov[n*192+jj*3+1];
    l_gv[n*192+jj*3+2] = gate*l_ov[n*192+jj*3+2];
  }
  __syncthreads();

  float ha[2] = {0.f,0.f};
  for (int k = 0; k < 64; ++k) {
    float w = W2s[k*64+jj];
    ha[0] += l_gs[(2*hh+0)*64+k]*w;
    ha[1] += l_gs[(2*hh+1)*64+k]*w;
  }
  hs_out[(n0+2*hh+0)*64+jj] = ha[0]*INV_SQRT64;
  hs_out[(n0+2*hh+1)*64+jj] = ha[1]*INV_SQRT64;

  float hv[2][3] = {{0.f,0.f,0.f},{0.f,0.f,0.f}};
  for (int u = 0; u < 64; ++u) {
    float w = W2v[u*64+jj];
    #pragma unroll
    for (int t = 0; t < 2; ++t) {
      int n = 2*hh+t;
      hv[t][0] += l_gv[n*192+u*3+0]*w;
      hv[t][1] += l_gv[n*192+u*3+1]*w;
      hv[t][2] += l_gv[n*192+u*3+2]*w;
    }
  }
  #pragma unroll
  for (int t = 0; t < 2; ++t) {
    int n = 2*hh+t;
    hv_out[(n0+n)*192+jj*3+0] = hv[t][0]*INV_SQRT64;
    hv_out[(n0+n)*192+jj*3+1] = hv[t][1]*INV_SQRT64;
    hv_out[(n0+n)*192+jj*3+2] = hv[t][2]*INV_SQRT64;
  }
}

// ---------------- FALLBACK conv2 node pass + pooling ----------------
__global__ __launch_bounds__(128) void k_node2(
    const float* __restrict__ n_mid, const float* __restrict__ gs,
    const float* __restrict__ na, const int* __restrict__ batch,
    const float* __restrict__ W, const float* __restrict__ Csc,
    float* __restrict__ pool) {
  __shared__ float l_nm[512], l_gs[256], l_na[64];
  const int j = threadIdx.x;
  const int n0 = blockIdx.x*4;
  for (int i = j; i < 512; i += 128) l_nm[i] = n_mid[n0*128+i];
  for (int i = j; i < 256; i += 128) l_gs[i] = gs[n0*64+i];
  if (j < 64) l_na[j] = na[n0*16+j];
  __syncthreads();
  float acc[4] = {0.f,0.f,0.f,0.f};
  for (int k = 0; k < 128; ++k) {
    float w = W[k*128+j];
    acc[0] += l_nm[k]*w; acc[1] += l_nm[128+k]*w;
    acc[2] += l_nm[256+k]*w; acc[3] += l_nm[384+k]*w;
  }
  float acc2[4] = {0.f,0.f,0.f,0.f};
  for (int vt = 0; vt < 16; vt += 4) {
    float a0[4],a1[4],a2[4],a3[4];
    #pragma unroll
    for (int n = 0; n < 4; ++n) {
      a0[n]=l_na[n*16+vt]; a1[n]=l_na[n*16+vt+1];
      a2[n]=l_na[n*16+vt+2]; a3[n]=l_na[n*16+vt+3];
    }
    for (int u = 0; u < 64; ++u) {
      const float* cp = Csc + (u*16+vt)*128 + j;
      float c0=cp[0], c1=cp[128], c2=cp[256], c3=cp[384];
      float s0=l_gs[u], s1=l_gs[64+u], s2=l_gs[128+u], s3=l_gs[192+u];
      acc2[0] += s0*(a0[0]*c0 + a1[0]*c1 + a2[0]*c2 + a3[0]*c3);
      acc2[1] += s1*(a0[1]*c0 + a1[1]*c1 + a2[1]*c2 + a3[1]*c3);
      acc2[2] += s2*(a0[2]*c0 + a1[2]*c1 + a2[2]*c2 + a3[2]*c3);
      acc2[3] += s3*(a0[3]*c0 + a1[3]*c1 + a2[3]*c2 + a3[3]*c3);
    }
  }
  float outv[4];
  #pragma unroll
  for (int n = 0; n < 4; ++n)
    outv[n] = acc[n]*INV_SQRT128 + acc2[n]*INV_SQRT1024;
  int b0 = batch[n0], b1 = batch[n0+1], b2 = batch[n0+2], b3 = batch[n0+3];
  float sum = outv[0]; int cur = b0;
  if (b1 == cur) sum += outv[1]; else { atomicAdd(&pool[cur*128+j], sum); cur = b1; sum = outv[1]; }
  if (b2 == cur) sum += outv[2]; else { atomicAdd(&pool[cur*128+j], sum); cur = b2; sum = outv[2]; }
  if (b3 == cur) sum += outv[3]; else { atomicAdd(&pool[cur*128+j], sum); cur = b3; sum = outv[3]; }
  atomicAdd(&pool[cur*128+j], sum);
}

// ---------------- readout head ----------------
__global__ __launch_bounds__(128) void k_head(
    const float* __restrict__ pool, const float* __restrict__ cnt,
    const float* __restrict__ Wr1, const float* __restrict__ Wr2,
    float* __restrict__ out) {
  __shared__ float lp[128];
  __shared__ float lt[128];
  const int j = threadIdx.x;
  for (int g = 0; g < N_GRAPHS; ++g) {
    float inv = 1.f / fmaxf(cnt[g], 1.f);
    lp[j] = pool[g*128+j]*inv;
    __syncthreads();
    float acc = 0.f;
    for (int k = 0; k < 128; ++k) acc += lp[k]*Wr1[k*128+j];
    lt[j] = siluf(acc*INV_SQRT128) * Wr2[j];
    __syncthreads();
    if (j == 0) {
      float ssum = 0.f;
      for (int k = 0; k < 128; ++k) ssum += lt[k];
      out[g] = ssum*INV_SQRT128;
    }
    __syncthreads();
  }
}

extern "C" void kernel_launch(void* const* d_in, const int* in_sizes, int n_in,
                              void* d_out, int out_size, void* d_ws, size_t ws_size,
                              hipStream_t stream) {
  const float* x         = (const float*)d_in[0];
  const float* node_attr = (const float*)d_in[1];
  const int*   esrc      = (const int*)d_in[2];
  const int*   edst      = (const int*)d_in[3];
  const float* evec      = (const float*)d_in[4];
  const int*   batch     = (const int*)d_in[5];
  const float* W_embed   = (const float*)d_in[6];
  const float* c1_lin1   = (const float*)d_in[7];
  const float* c1_fc_w0  = (const float*)d_in[8];
  const float* c1_fc_w1  = (const float*)d_in[9];
  const float* c1_fc_w2  = (const float*)d_in[10];
  const float* c1_lin2_s = (const float*)d_in[11];
  const float* c1_lin2_v = (const float*)d_in[12];
  const float* c1_sc     = (const float*)d_in[13];
  const float* c2_lin1_s = (const float*)d_in[14];
  const float* c2_lin1_v = (const float*)d_in[15];
  const float* c2_fc_w0  = (const float*)d_in[16];
  const float* c2_fc_w1  = (const float*)d_in[17];
  const float* c2_fc_w2  = (const float*)d_in[18];
  const float* c2_lin2   = (const float*)d_in[19];
  const float* c2_sc     = (const float*)d_in[20];
  const float* Wr1       = (const float*)d_in[21];
  const float* Wr2       = (const float*)d_in[22];

  float* ws    = (float*)d_ws;
  float* es8   = ws + OFF_ES8;
  float* shv   = ws + OFF_SHV;
  float* s_    = ws + OFF_S;
  float* h_    = ws + OFF_H;
  float* gs_   = ws + OFF_GS;
  float* hs_   = ws + OFF_HS;
  float* hv_   = ws + OFF_HV;
  float* ns_   = ws + OFF_NS;
  float* nv_   = ws + OFF_NV;
  float* nmid_ = ws + OFF_NMID;
  float* pool_ = ws + OFF_POOL;
  float* cnt_  = ws + OFF_CNT;
  int*   hist_ = (int*)(ws + OFF_HIST);
  int*   curs_ = (int*)(ws + OFF_CURS);
  int*   offs_ = (int*)(ws + OFF_OFFS);
  u16*   frag_ = (u16*)(ws + OFF_FRAG);
  int*   slot_ = (int*)(ws + OFF_SLOT);
  float* wbuf_ = ws + OFF_WBUF;
  u16*   wb16_ = (u16*)wbuf_;   // fp16 wbuf occupies only lower half of WBUF region

  // upper-wbuf carve-outs
  float* out1_  = wbuf_ + (size_t)N_EDGES*128;                 // reserved (layout stability)
  u16*   nfrag_ = (u16*)(out1_ + (size_t)NM128);               // 442368 u16
  float* part_  = out1_ + (size_t)NM128 + NFRAG_TOT/2;         // 9 x 1.28M floats
  float* ov_    = part_ + (size_t)9*NM128;                     // 1.92M floats
  float* gv_    = nv_;                                         // aliases nv (dead after ov GEMM)

  const bool big = ws_size >= WS_NEED_BYTES;

  k_geom<<<N_EDGES/256, 256, 0, stream>>>(evec, es8, shv);

  if (big) {
    hipMemsetAsync(pool_, 0, (size_t)(OFF_OFFS - OFF_POOL)*sizeof(float), stream);
    k_cnthist<<<(N_EDGES+255)/256, 256, 0, stream>>>(batch, edst, cnt_, hist_);
    k_scanp<<<1, 1024, 0, stream>>>(hist_, offs_);
    k_slot<<<(N_EDGES+255)/256, 256, 0, stream>>>(edst, offs_, curs_, slot_);

    // merged startup frag prep: 6 MLP weights + W_embed + c1_lin1 (f16 single-plane)
    {
      PD8 m{};
      m.d[0] = {c1_fc_w0, frag_ + F_B1,  8,  64,  1, 2048,  INV_SQRT8};
      m.d[1] = {c1_fc_w1, frag_ + F_B2,  64, 64,  2, 4096,  INV_SQRT64};
      m.d[2] = {c1_fc_w2, frag_ + F_B3,  64, 256, 2, 16384, INV_SQRT64};
      m.d[3] = {c2_fc_w0, frag_ + F_B1b, 8,  64,  1, 2048,  INV_SQRT8};
      m.d[4] = {c2_fc_w1, frag_ + F_B2b, 64, 64,  2, 4096,  INV_SQRT64};
      m.d[5] = {c2_fc_w2, frag_ + F_B3b, 64, 128, 2, 8192,  INV_SQRT64};
      m.d[6] = {W_embed,  frag_ + F_WE,  32, 128, 1, 4096,  INV_SQRT32};
      m.d[7] = {c1_lin1,  frag_ + F_L1,  128,128, 4, 16384, INV_SQRT128};
      m.nd = 8; m.tot = FRAG_TOT;
      k_prepmulti<<<224, 256, 0, stream>>>(m);
    }

    // s = x@W_embed ; h = s@c1_lin1 (f16 MFMA)
    k_gemm<1,8><<<79, 512, 0, stream>>>(x,  32,  N_NODES, frag_ + F_WE, s_);
    k_gemm<4,8><<<79, 512, 0, stream>>>(s_, 128, N_NODES, frag_ + F_L1, h_);

    // conv1 edge MLP + gather
    k_mlp<16><<<1250, 256, 0, stream>>>(es8, frag_ + F_B1, frag_ + F_B2, frag_ + F_B3, wb16_);
    k_gather1<<<(N_NODES+3)/4, 256, 0, stream>>>(wb16_, shv, esrc, offs_, slot_, h_, ns_, nv_);

    // merged node weight frag prep (f16 single-plane)
    {
      PD8 m{};
      m.d[0] = {c1_lin2_s, nfrag_ + NF_WLS, 128, 128,  4, 16384,  INV_SQRT128};
      m.d[1] = {c1_sc,     nfrag_ + NF_C1,  128, 2048, 4, 262144, INV_SQRT2048};
      m.d[2] = {c2_lin2,   nfrag_ + NF_W2,  128, 128,  4, 16384,  INV_SQRT128};
      m.d[3] = {c2_sc,     nfrag_ + NF_C2,  64,  2048, 2, 131072, INV_SQRT1024};
      m.d[4] = {c1_lin2_v, nfrag_ + NF_LV,  128, 64,   4, 8192,   INV_SQRT128};
      m.d[5] = {c2_lin1_s, nfrag_ + NF_2S,  64,  64,   2, 4096,   INV_SQRT64};
      m.d[6] = {c2_lin1_v, nfrag_ + NF_2V,  64,  64,   2, 4096,   INV_SQRT64};
      m.nd = 7; m.tot = NFRAG_TOT;
      k_prepmulti<<<864, 256, 0, stream>>>(m);
    }

    // conv1 node: dense + sc partials -> fused reduce+gate
    k_gemm<4,8><<<79, 512, 0, stream>>>(ns_, 128, N_NODES, nfrag_ + NF_WLS, part_ + (size_t)8*NM128);
    k_scp<4><<<dim3(79,8), 512, 0, stream>>>(s_, node_attr, nfrag_ + NF_C1, part_);
    k_gemm<4,4><<<235, 512, 0, stream>>>(nv_, 128, N_NODES*3, nfrag_ + NF_LV, ov_);
    k_redgate<<<(N_NODES*64+255)/256, 256, 0, stream>>>(part_, ov_, gs_, gv_);
    k_gemm<2,4><<<79, 512, 0, stream>>>(gs_, 64, N_NODES, nfrag_ + NF_2S, hs_);
    k_gemm<2,4><<<235, 512, 0, stream>>>(gv_, 64, N_NODES*3, nfrag_ + NF_2V, hv_);

    // conv2 edge MLP + gather
    k_mlp<8><<<1250, 256, 0, stream>>>(es8, frag_ + F_B1b, frag_ + F_B2b, frag_ + F_B3b, wb16_);
    k_gather2<<<(N_NODES+3)/4, 256, 0, stream>>>(wb16_, shv, esrc, offs_, slot_, hs_, hv_, nmid_);

    // conv2 node: partials -> fused reduce+pool
    k_gemm<4,8><<<79, 512, 0, stream>>>(nmid_, 128, N_NODES, nfrag_ + NF_W2, part_ + (size_t)8*NM128);
    k_scp<2><<<dim3(79,8), 512, 0, stream>>>(gs_, node_attr, nfrag_ + NF_C2, part_);
    k_redpool<<<N_NODES/4, 128, 0, stream>>>(part_, batch, pool_);
  } else {
    hipMemsetAsync(ns_, 0, (size_t)(OFF_HIST - OFF_NS)*sizeof(float), stream);
    k_linear128<<<(N_NODES*128)/256, 256, 0, stream>>>(x,  W_embed, s_, 32,  INV_SQRT32,  N_NODES*128);
    k_linear128<<<(N_NODES*128)/256, 256, 0, stream>>>(s_, c1_lin1, h_, 128, INV_SQRT128, N_NODES*128);
    k_cnthist<<<(N_EDGES+255)/256, 256, 0, stream>>>(batch, edst, cnt_, hist_);
    k_edge1_at<<<256, 512, 0, stream>>>(es8, shv, esrc, edst, h_,
                                        c1_fc_w0, c1_fc_w1, c1_fc_w2, ns_, nv_);
    k_node1<<<N_NODES/4, 128, 0, stream>>>(ns_, nv_, s_, node_attr,
                                           c1_lin2_s, c1_lin2_v, c1_sc,
                                           c2_lin1_s, c2_lin1_v, gs_, hs_, hv_);
    k_edge2_at<<<512, 512, 0, stream>>>(es8, shv, esrc, edst, hs_, hv_,
                                        c2_fc_w0, c2_fc_w1, c2_fc_w2, nmid_);
    k_node2<<<N_NODES/4, 128, 0, stream>>>(nmid_, gs_, node_attr, batch,
                                           c2_lin2, c2_sc, pool_);
  }

  k_head<<<1, 128, 0, stream>>>(pool_, cnt_, Wr1, Wr2, (float*)d_out);
}